// Round 13
// baseline (2310.989 us; speedup 1.0000x reference)
//
#include <hip/hip_runtime.h>
#include <hip/hip_bf16.h>
#include <math.h>

#define SEQ 2048
#define HID 1024
#define NHEAD 16
#define HDIM 64
#define IDIM 2816
#define NEXP 8
#define VOCAB 32000

#define ASTRIDE 144  // padded rows (attention)

typedef float f32x4v __attribute__((ext_vector_type(4)));
typedef __bf16 bf16x8v __attribute__((ext_vector_type(8)));
typedef __bf16 bf16x4v __attribute__((ext_vector_type(4)));

__device__ __forceinline__ bf16x8v cvt8(const float4& a, const float4& b) {
  bf16x8v r;
  r[0] = (__bf16)a.x; r[1] = (__bf16)a.y; r[2] = (__bf16)a.z; r[3] = (__bf16)a.w;
  r[4] = (__bf16)b.x; r[5] = (__bf16)b.y; r[6] = (__bf16)b.z; r[7] = (__bf16)b.w;
  return r;
}

#define MFMA(a, b, c) __builtin_amdgcn_mfma_f32_16x16x32_bf16(a, b, c, 0, 0, 0)

// async global->LDS DMA, 16B per lane; lds base must be wave-uniform
__device__ __forceinline__ void gld_lds16(const void* g, void* l) {
  __builtin_amdgcn_global_load_lds(
      (const __attribute__((address_space(1))) unsigned int*)(unsigned long long)g,
      (__attribute__((address_space(3))) unsigned int*)(unsigned int)(unsigned long long)l,
      16, 0, 0);
}

// ---------------------------------------------------------------------------
// Weight preprocessing: W[K,N] f32 -> WH,WL [N,K] bf16 (transposed hi/lo).
// ---------------------------------------------------------------------------
__global__ __launch_bounds__(256) void wsplit_t_kernel(
    const float* __restrict__ W, __bf16* __restrict__ WH, __bf16* __restrict__ WL,
    int K, int N)
{
  __shared__ float tile[64][65];
  const int tid = threadIdx.x;
  const size_t zofs = (size_t)blockIdx.z * K * N;
  const int n0 = blockIdx.x * 64, k0 = blockIdx.y * 64;
#pragma unroll
  for (int r = 0; r < 4; ++r) {
    int kk = (tid >> 4) + r * 16;
    int nn = (tid & 15) * 4;
    float4 v = *(const float4*)(W + zofs + (size_t)(k0 + kk) * N + n0 + nn);
    tile[kk][nn] = v.x; tile[kk][nn + 1] = v.y;
    tile[kk][nn + 2] = v.z; tile[kk][nn + 3] = v.w;
  }
  __syncthreads();
  const int nn = tid >> 2;
  const int kk = (tid & 3) * 16;
  __bf16* dh = WH + zofs + (size_t)(n0 + nn) * K + k0 + kk;
  __bf16* dl = WL + zofs + (size_t)(n0 + nn) * K + k0 + kk;
  bf16x8v h0, l0, h1, l1;
#pragma unroll
  for (int j = 0; j < 8; ++j) {
    float f = tile[kk + j][nn];
    __bf16 hb = (__bf16)f; h0[j] = hb; l0[j] = (__bf16)(f - (float)hb);
    f = tile[kk + 8 + j][nn];
    hb = (__bf16)f; h1[j] = hb; l1[j] = (__bf16)(f - (float)hb);
  }
  *(bf16x8v*)dh = h0; *(bf16x8v*)(dh + 8) = h1;
  *(bf16x8v*)dl = l0; *(bf16x8v*)(dl + 8) = l1;
}

// hi-only variant (MoE weights; plain-bf16 path needs no lo)
__global__ __launch_bounds__(256) void wsplit_th_kernel(
    const float* __restrict__ W, __bf16* __restrict__ WH, int K, int N)
{
  __shared__ float tile[64][65];
  const int tid = threadIdx.x;
  const size_t zofs = (size_t)blockIdx.z * K * N;
  const int n0 = blockIdx.x * 64, k0 = blockIdx.y * 64;
#pragma unroll
  for (int r = 0; r < 4; ++r) {
    int kk = (tid >> 4) + r * 16;
    int nn = (tid & 15) * 4;
    float4 v = *(const float4*)(W + zofs + (size_t)(k0 + kk) * N + n0 + nn);
    tile[kk][nn] = v.x; tile[kk][nn + 1] = v.y;
    tile[kk][nn + 2] = v.z; tile[kk][nn + 3] = v.w;
  }
  __syncthreads();
  const int nn = tid >> 2;
  const int kk = (tid & 3) * 16;
  __bf16* dh = WH + zofs + (size_t)(n0 + nn) * K + k0 + kk;
  bf16x8v h0, h1;
#pragma unroll
  for (int j = 0; j < 8; ++j) {
    h0[j] = (__bf16)tile[kk + j][nn];
    h1[j] = (__bf16)tile[kk + 8 + j][nn];
  }
  *(bf16x8v*)dh = h0; *(bf16x8v*)(dh + 8) = h1;
}

__global__ __launch_bounds__(256) void esplit_kernel(
    const float* __restrict__ E, __bf16* __restrict__ EH)
{
  size_t i = ((size_t)blockIdx.x * 256 + threadIdx.x) * 8;
  float4 a = *(const float4*)(E + i);
  float4 b = *(const float4*)(E + i + 4);
  *(bf16x8v*)(EH + i) = cvt8(a, b);
}

// ---------------------------------------------------------------------------
// Unified BT GEMM. A,B pre-split bf16. Staging = global_load_lds DMA (16B),
// LINEAR LDS rows (64B/row).
// ---------------------------------------------------------------------------
template<bool COMP, bool ACCUM, bool SWAP, int BM>
__global__ __launch_bounds__(256) void gemm_bt_kernel(
    const __bf16* __restrict__ Ah, const __bf16* __restrict__ Al,
    const __bf16* __restrict__ B0h, const __bf16* __restrict__ B0l,
    const __bf16* __restrict__ B1h, const __bf16* __restrict__ B1l,
    const __bf16* __restrict__ B2h, const __bf16* __restrict__ B2l,
    float* __restrict__ C0, float* __restrict__ C1, float* __restrict__ C2,
    int M, int N, int Kd)
{
  const __bf16* __restrict__ Bh = (blockIdx.z == 0) ? B0h : (blockIdx.z == 1 ? B1h : B2h);
  const __bf16* __restrict__ Bl = (blockIdx.z == 0) ? B0l : (blockIdx.z == 1 ? B1l : B2l);
  float* __restrict__ C         = (blockIdx.z == 0) ? C0 : (blockIdx.z == 1 ? C1 : C2);
  constexpr int ATILE = BM * 64;
  constexpr int BTILE = 128 * 64;
  constexpr int MFR = BM / 32;
  __shared__ __align__(16) char smem[COMP ? 2 * (ATILE + BTILE) : (ATILE + BTILE)];
  char* AsH = smem;
  char* BsH = smem + ATILE;
  char* AsL = COMP ? smem + ATILE + BTILE : smem;
  char* BsL = COMP ? smem + 2 * ATILE + BTILE : smem + ATILE;
  const int tid = threadIdx.x;
  const int bm = SWAP ? blockIdx.x : blockIdx.y;
  const int bn = SWAP ? blockIdx.y : blockIdx.x;
  const int wid = tid >> 6, lane = tid & 63;
  const int wm = (wid >> 1) * (BM / 2), wn = (wid & 1) << 6;
  const int lr = lane & 15, kh = lane >> 4;
  const int lrow = lane >> 2;
  const int lcol = (lane & 3) << 3;

  f32x4v acc[MFR][4];
  const f32x4v z4 = {0.f, 0.f, 0.f, 0.f};
#pragma unroll
  for (int i = 0; i < MFR; ++i)
#pragma unroll
    for (int j = 0; j < 4; ++j) acc[i][j] = z4;

  for (int k0 = 0; k0 < Kd; k0 += 32) {
    __syncthreads();
#pragma unroll
    for (int c = wid; c < BM / 16; c += 4) {
      size_t gofs = (size_t)(bm * BM + c * 16 + lrow) * Kd + k0 + lcol;
      gld_lds16(Ah + gofs, AsH + c * 1024);
      if (COMP) gld_lds16(Al + gofs, AsL + c * 1024);
    }
#pragma unroll
    for (int c = wid; c < 8; c += 4) {
      size_t gofs = (size_t)(bn * 128 + c * 16 + lrow) * Kd + k0 + lcol;
      gld_lds16(Bh + gofs, BsH + c * 1024);
      if (COMP) gld_lds16(Bl + gofs, BsL + c * 1024);
    }
    __syncthreads();

    bf16x8v ah[MFR], al[MFR], bh4[4], bl4[4];
#pragma unroll
    for (int i = 0; i < MFR; ++i) {
      int r = wm + (i << 4) + lr;
      int off = r * 64 + (kh << 4);
      ah[i] = *(const bf16x8v*)(AsH + off);
      if (COMP) al[i] = *(const bf16x8v*)(AsL + off);
    }
#pragma unroll
    for (int i = 0; i < 4; ++i) {
      int r = wn + (i << 4) + lr;
      int off = r * 64 + (kh << 4);
      bh4[i] = *(const bf16x8v*)(BsH + off);
      if (COMP) bl4[i] = *(const bf16x8v*)(BsL + off);
    }
#pragma unroll
    for (int mi = 0; mi < MFR; ++mi)
#pragma unroll
      for (int ni = 0; ni < 4; ++ni) {
        if (COMP) {
          acc[mi][ni] = MFMA(al[mi], bh4[ni], acc[mi][ni]);
          acc[mi][ni] = MFMA(ah[mi], bl4[ni], acc[mi][ni]);
        }
        acc[mi][ni] = MFMA(ah[mi], bh4[ni], acc[mi][ni]);
      }
  }

  const int cr0 = kh << 2;
#pragma unroll
  for (int mi = 0; mi < MFR; ++mi)
#pragma unroll
    for (int ni = 0; ni < 4; ++ni)
#pragma unroll
      for (int r = 0; r < 4; ++r) {
        int row = bm * BM + wm + (mi << 4) + cr0 + r;
        int col = bn * 128 + wn + (ni << 4) + lr;
        size_t idx = (size_t)row * N + col;
        if (ACCUM) C[idx] += acc[mi][ni][r];
        else       C[idx] = acc[mi][ni][r];
      }
}

// ---------------------------------------------------------------------------
// rope + hi/lo split for Q (scale 1/8) and K
// ---------------------------------------------------------------------------
__global__ __launch_bounds__(256) void rope_split_kernel(
    const float* __restrict__ Q, const float* __restrict__ K,
    __bf16* __restrict__ QH, __bf16* __restrict__ QL,
    __bf16* __restrict__ KH, __bf16* __restrict__ KL,
    const float* __restrict__ CT, const float* __restrict__ ST)
{
  int idx = blockIdx.x * 256 + threadIdx.x;
  int s = idx >> 9;
  int rr = idx & 511;
  int hd = rr >> 5;
  int i = rr & 31;
  float c = CT[(s << 5) + i], sn = ST[(s << 5) + i];
  size_t base = (size_t)s * HID + hd * 64 + i;
  {
    float x1 = Q[base], x2 = Q[base + 32];
    float o1 = (x1 * c - x2 * sn) * 0.125f;
    float o2 = (x2 * c + x1 * sn) * 0.125f;
    __bf16 h1 = (__bf16)o1, h2 = (__bf16)o2;
    QH[base] = h1;      QL[base] = (__bf16)(o1 - (float)h1);
    QH[base + 32] = h2; QL[base + 32] = (__bf16)(o2 - (float)h2);
  }
  {
    float x1 = K[base], x2 = K[base + 32];
    float o1 = x1 * c - x2 * sn;
    float o2 = x2 * c + x1 * sn;
    __bf16 h1 = (__bf16)o1, h2 = (__bf16)o2;
    KH[base] = h1;      KL[base] = (__bf16)(o1 - (float)h1);
    KH[base + 32] = h2; KL[base + 32] = (__bf16)(o2 - (float)h2);
  }
}

// V f32 [S][HID] -> per-head transposed hi/lo bf16 [NHEAD][HDIM][SEQ]
__global__ __launch_bounds__(256) void vtsplit_kernel(
    const float* __restrict__ V, __bf16* __restrict__ VTH, __bf16* __restrict__ VTL)
{
  __shared__ float tile[64][65];
  const int tid = threadIdx.x;
  const int s0 = blockIdx.x * 64;
  const int head = blockIdx.y;
#pragma unroll
  for (int r = 0; r < 4; ++r) {
    int ss = (tid >> 4) + r * 16;
    int dd = (tid & 15) * 4;
    float4 v = *(const float4*)(V + (size_t)(s0 + ss) * HID + head * 64 + dd);
    tile[ss][dd] = v.x; tile[ss][dd + 1] = v.y;
    tile[ss][dd + 2] = v.z; tile[ss][dd + 3] = v.w;
  }
  __syncthreads();
#pragma unroll
  for (int half = 0; half < 2; ++half) {
    const int d = (tid >> 3) + (half << 5);
    const int c = tid & 7;
    bf16x8v hv, lv;
#pragma unroll
    for (int j = 0; j < 8; ++j) {
      float f = tile[c * 8 + j][d];
      __bf16 hb = (__bf16)f;
      hv[j] = hb; lv[j] = (__bf16)(f - (float)hb);
    }
    size_t dst = (size_t)(head * 64 + d) * SEQ + s0 + c * 8;
    *(bf16x8v*)(VTH + dst) = hv;
    *(bf16x8v*)(VTL + dst) = lv;
  }
}

// ---------------------------------------------------------------------------
// Compensated flash attention; padded LDS; O -> bf16 hi/lo
// ---------------------------------------------------------------------------
__global__ __launch_bounds__(256) void attn_flash_kernel(
    const __bf16* __restrict__ QH, const __bf16* __restrict__ QL,
    const __bf16* __restrict__ KH, const __bf16* __restrict__ KL,
    const __bf16* __restrict__ VTH, const __bf16* __restrict__ VTL,
    __bf16* __restrict__ OH, __bf16* __restrict__ OL)
{
  const int qt = blockIdx.x;
  const int head = blockIdx.y;
  const int tid = threadIdx.x, wid = tid >> 6, lane = tid & 63;
  const int lr = lane & 15, kh = lane >> 4;
  __shared__ __align__(16) char KsH[64 * ASTRIDE], KsL[64 * ASTRIDE];
  __shared__ __align__(16) char VtH[64 * ASTRIDE], VtL[64 * ASTRIDE];
  __shared__ __align__(16) char PsH[4][16 * ASTRIDE], PsL[4][16 * ASTRIDE];

  const size_t qofs = (size_t)(qt * 64 + wid * 16 + lr) * HID + head * HDIM;
  const bf16x8v qfh0 = *(const bf16x8v*)(QH + qofs + (kh << 3));
  const bf16x8v qfh1 = *(const bf16x8v*)(QH + qofs + 32 + (kh << 3));
  const bf16x8v qfl0 = *(const bf16x8v*)(QL + qofs + (kh << 3));
  const bf16x8v qfl1 = *(const bf16x8v*)(QL + qofs + 32 + (kh << 3));

  float m_run[4], l_run[4];
  f32x4v oacc[4];
  const f32x4v z4 = {0.f, 0.f, 0.f, 0.f};
#pragma unroll
  for (int i = 0; i < 4; ++i) { m_run[i] = -1e30f; l_run[i] = 0.f; oacc[i] = z4; }

  for (int kt = 0; kt <= qt; ++kt) {
    __syncthreads();
#pragma unroll
    for (int p = 0; p < 2; ++p) {
      int g = tid + (p << 8);
      int r = g >> 3;
      int c = g & 7;
      int off = r * ASTRIDE + (c << 4);
      const size_t kofs = (size_t)(kt * 64 + r) * HID + head * HDIM + (c << 3);
      *(bf16x8v*)(KsH + off) = *(const bf16x8v*)(KH + kofs);
      *(bf16x8v*)(KsL + off) = *(const bf16x8v*)(KL + kofs);
      const size_t vofs = (size_t)(head * 64 + r) * SEQ + kt * 64 + (c << 3);
      *(bf16x8v*)(VtH + off) = *(const bf16x8v*)(VTH + vofs);
      *(bf16x8v*)(VtL + off) = *(const bf16x8v*)(VTL + vofs);
    }
    __syncthreads();

    float sv[4][4];
#pragma unroll
    for (int stt = 0; stt < 4; ++stt) {
      int r = (stt << 4) + lr;
      int off0 = r * ASTRIDE + (kh << 4);
      int off1 = off0 + 64;
      bf16x8v kfh0 = *(const bf16x8v*)(KsH + off0);
      bf16x8v kfl0 = *(const bf16x8v*)(KsL + off0);
      bf16x8v kfh1 = *(const bf16x8v*)(KsH + off1);
      bf16x8v kfl1 = *(const bf16x8v*)(KsL + off1);
      f32x4v s = z4;
      s = MFMA(qfl0, kfh0, s);
      s = MFMA(qfh0, kfl0, s);
      s = MFMA(qfh0, kfh0, s);
      s = MFMA(qfl1, kfh1, s);
      s = MFMA(qfh1, kfl1, s);
      s = MFMA(qfh1, kfh1, s);
      int key = kt * 64 + (stt << 4) + lr;
#pragma unroll
      for (int rr = 0; rr < 4; ++rr) {
        int qr = qt * 64 + wid * 16 + (kh << 2) + rr;
        sv[stt][rr] = (key <= qr) ? s[rr] : -1e30f;
      }
    }

#pragma unroll
    for (int rr = 0; rr < 4; ++rr) {
      float mx = fmaxf(fmaxf(sv[0][rr], sv[1][rr]), fmaxf(sv[2][rr], sv[3][rr]));
#pragma unroll
      for (int d = 1; d < 16; d <<= 1) mx = fmaxf(mx, __shfl_xor(mx, d));
      float mnew = fmaxf(m_run[rr], mx);
      float scl = __expf(m_run[rr] - mnew);
      float pv[4];
#pragma unroll
      for (int stt = 0; stt < 4; ++stt) pv[stt] = __expf(sv[stt][rr] - mnew);
      float rs = pv[0] + pv[1] + pv[2] + pv[3];
#pragma unroll
      for (int d = 1; d < 16; d <<= 1) rs += __shfl_xor(rs, d);
      l_run[rr] = l_run[rr] * scl + rs;
      m_run[rr] = mnew;
#pragma unroll
      for (int n = 0; n < 4; ++n) oacc[n][rr] *= scl;
      int qlr = (kh << 2) + rr;
#pragma unroll
      for (int stt = 0; stt < 4; ++stt) {
        __bf16 hb = (__bf16)pv[stt];
        __bf16 lb = (__bf16)(pv[stt] - (float)hb);
        int off = qlr * ASTRIDE + (((stt << 4) + lr) << 1);
        *(__bf16*)(PsH[wid] + off) = hb;
        *(__bf16*)(PsL[wid] + off) = lb;
      }
    }

    int poff0 = lr * ASTRIDE + (kh << 4);
    int poff1 = poff0 + 64;
    bf16x8v pah0 = *(const bf16x8v*)(PsH[wid] + poff0);
    bf16x8v pal0 = *(const bf16x8v*)(PsL[wid] + poff0);
    bf16x8v pah1 = *(const bf16x8v*)(PsH[wid] + poff1);
    bf16x8v pal1 = *(const bf16x8v*)(PsL[wid] + poff1);
#pragma unroll
    for (int n = 0; n < 4; ++n) {
      int vr = (n << 4) + lr;
      int voff0 = vr * ASTRIDE + (kh << 4);
      int voff1 = voff0 + 64;
      bf16x8v vfh0 = *(const bf16x8v*)(VtH + voff0);
      bf16x8v vfl0 = *(const bf16x8v*)(VtL + voff0);
      bf16x8v vfh1 = *(const bf16x8v*)(VtH + voff1);
      bf16x8v vfl1 = *(const bf16x8v*)(VtL + voff1);
      oacc[n] = MFMA(pal0, vfh0, oacc[n]);
      oacc[n] = MFMA(pah0, vfl0, oacc[n]);
      oacc[n] = MFMA(pah0, vfh0, oacc[n]);
      oacc[n] = MFMA(pal1, vfh1, oacc[n]);
      oacc[n] = MFMA(pah1, vfl1, oacc[n]);
      oacc[n] = MFMA(pah1, vfh1, oacc[n]);
    }
  }

#pragma unroll
  for (int n = 0; n < 4; ++n)
#pragma unroll
    for (int rr = 0; rr < 4; ++rr) {
      int qr = qt * 64 + wid * 16 + (kh << 2) + rr;
      size_t ofs = (size_t)qr * HID + head * HDIM + (n << 4) + lr;
      float val = oacc[n][rr] / l_run[rr];
      __bf16 hb = (__bf16)val;
      OH[ofs] = hb;
      OL[ofs] = (__bf16)(val - (float)hb);
    }
}

// ---------------------------------------------------------------------------
// MoE: fused gate+up+silu. BM=64 tiles, bm-fast grid (B-panel L2 reuse).
// ---------------------------------------------------------------------------
__global__ __launch_bounds__(256) void gemm_moe_guf_kernel(
    const __bf16* __restrict__ Xh,
    const __bf16* __restrict__ MGH, const __bf16* __restrict__ MUH,
    __bf16* __restrict__ A2, const float* __restrict__ W,
    const int* __restrict__ list, const int* __restrict__ cnt8,
    const int* __restrict__ off8)
{
  const int e = blockIdx.z;
  const int cnt = cnt8[e];
  const int bm = blockIdx.x, bn = blockIdx.y;   // bm fast-varying
  if (bm * 64 >= cnt) return;
  const int base = off8[e];
  __shared__ __align__(16) char AsB[4096];
  __shared__ __align__(16) char BgB[8192];
  __shared__ __align__(16) char BuB[8192];
  const int tid = threadIdx.x;
  const int wid = tid >> 6, lane = tid & 63;
  const int wm = (wid >> 1) << 5, wn = (wid & 1) << 6;
  const int lr = lane & 15, kh = lane >> 4;
  const int lrow = lane >> 2;
  const int lcol = (lane & 3) << 3;

  f32x4v accg[2][4], accu[2][4];
  const f32x4v z4 = {0.f, 0.f, 0.f, 0.f};
#pragma unroll
  for (int i = 0; i < 2; ++i)
#pragma unroll
    for (int j = 0; j < 4; ++j) { accg[i][j] = z4; accu[i][j] = z4; }

  for (int k0 = 0; k0 < HID; k0 += 32) {
    __syncthreads();
    {   // A: 4 chunks, one per wave
      int rg = bm * 64 + wid * 16 + lrow;
      int tok = list[e * SEQ + (rg < cnt ? rg : cnt - 1)];
      gld_lds16(Xh + (size_t)tok * HID + k0 + lcol, AsB + wid * 1024);
    }
#pragma unroll
    for (int c = wid; c < 8; c += 4) {
      size_t wofs = (size_t)(e * IDIM + bn * 128 + c * 16 + lrow) * HID + k0 + lcol;
      gld_lds16(MGH + wofs, BgB + c * 1024);
      gld_lds16(MUH + wofs, BuB + c * 1024);
    }
    __syncthreads();

    bf16x8v af[2], bg4[4], bu4[4];
#pragma unroll
    for (int i = 0; i < 2; ++i) {
      int r = wm + (i << 4) + lr;
      af[i] = *(const bf16x8v*)(AsB + r * 64 + (kh << 4));
    }
#pragma unroll
    for (int i = 0; i < 4; ++i) {
      int r = wn + (i << 4) + lr;
      bg4[i] = *(const bf16x8v*)(BgB + r * 64 + (kh << 4));
      bu4[i] = *(const bf16x8v*)(BuB + r * 64 + (kh << 4));
    }
#pragma unroll
    for (int mi = 0; mi < 2; ++mi)
#pragma unroll
      for (int ni = 0; ni < 4; ++ni) {
        accg[mi][ni] = MFMA(af[mi], bg4[ni], accg[mi][ni]);
        accu[mi][ni] = MFMA(af[mi], bu4[ni], accu[mi][ni]);
      }
  }

  const int cr0 = kh << 2;
#pragma unroll
  for (int mi = 0; mi < 2; ++mi)
#pragma unroll
    for (int ni = 0; ni < 4; ++ni)
#pragma unroll
      for (int r = 0; r < 4; ++r) {
        int row = bm * 64 + wm + (mi << 4) + cr0 + r;
        if (row < cnt) {
          int col = bn * 128 + wn + (ni << 4) + lr;
          int tok = list[e * SEQ + row];
          float w = W[tok * 8 + e];
          float gval = accg[mi][ni][r];
          float uval = accu[mi][ni][r];
          float a = gval / (1.f + __expf(-gval)) * uval * w;
          A2[(size_t)(base + row) * IDIM + col] = (__bf16)a;
        }
      }
}

__global__ __launch_bounds__(256) void gemm_moe_down2_kernel(
    const __bf16* __restrict__ A2, const __bf16* __restrict__ MDH,
    float* __restrict__ Y2,
    const int* __restrict__ cnt8, const int* __restrict__ off8)
{
  const int e = blockIdx.z;
  const int cnt = cnt8[e];
  const int bm = blockIdx.x, bn = blockIdx.y;   // bm fast-varying
  if (bm * 64 >= cnt) return;
  const int base = off8[e];
  __shared__ __align__(16) char AsB[4096];
  __shared__ __align__(16) char BsB[8192];
  const int tid = threadIdx.x;
  const int wid = tid >> 6, lane = tid & 63;
  const int wm = (wid >> 1) << 5, wn = (wid & 1) << 6;
  const int lr = lane & 15, kh = lane >> 4;
  const int lrow = lane >> 2;
  const int lcol = (lane & 3) << 3;

  f32x4v acc[2][4];
  const f32x4v z4 = {0.f, 0.f, 0.f, 0.f};
#pragma unroll
  for (int i = 0; i < 2; ++i)
#pragma unroll
    for (int j = 0; j < 4; ++j) acc[i][j] = z4;

  for (int k0 = 0; k0 < IDIM; k0 += 32) {
    __syncthreads();
    {
      int rg = bm * 64 + wid * 16 + lrow;
      int row = (rg < cnt ? rg : cnt - 1);
      gld_lds16(A2 + (size_t)(base + row) * IDIM + k0 + lcol, AsB + wid * 1024);
    }
#pragma unroll
    for (int c = wid; c < 8; c += 4) {
      gld_lds16(MDH + (size_t)(e * HID + bn * 128 + c * 16 + lrow) * IDIM + k0 + lcol,
                BsB + c * 1024);
    }
    __syncthreads();

    bf16x8v af[2], bfv[4];
#pragma unroll
    for (int i = 0; i < 2; ++i) {
      int r = wm + (i << 4) + lr;
      af[i] = *(const bf16x8v*)(AsB + r * 64 + (kh << 4));
    }
#pragma unroll
    for (int i = 0; i < 4; ++i) {
      int r = wn + (i << 4) + lr;
      bfv[i] = *(const bf16x8v*)(BsB + r * 64 + (kh << 4));
    }
#pragma unroll
    for (int mi = 0; mi < 2; ++mi)
#pragma unroll
      for (int ni = 0; ni < 4; ++ni)
        acc[mi][ni] = MFMA(af[mi], bfv[ni], acc[mi][ni]);
  }

  const int cr0 = kh << 2;
#pragma unroll
  for (int mi = 0; mi < 2; ++mi)
#pragma unroll
    for (int ni = 0; ni < 4; ++ni)
#pragma unroll
      for (int r = 0; r < 4; ++r) {
        int row = bm * 64 + wm + (mi << 4) + cr0 + r;
        if (row < cnt) {
          int col = bn * 128 + wn + (ni << 4) + lr;
          Y2[(size_t)(base + row) * HID + col] = acc[mi][ni][r];
        }
      }
}

// h[t] += y(e_lo) + y(e_hi)  (ascending-e order == old serial order)
__global__ __launch_bounds__(256) void moe_scatter_kernel(
    const int* __restrict__ tokpair, const int* __restrict__ off8,
    const float* __restrict__ Y2, float* __restrict__ H)
{
  const int t = blockIdx.x;
  const int i = threadIdx.x;
  int p0 = tokpair[t * 2], p1 = tokpair[t * 2 + 1];
  size_t r0 = off8[p0 >> 16] + (p0 & 0xffff);
  size_t r1 = off8[p1 >> 16] + (p1 & 0xffff);
  float4 a = ((const float4*)(Y2 + r0 * HID))[i];
  float4 b = ((const float4*)(Y2 + r1 * HID))[i];
  float4 hv = ((float4*)(H + (size_t)t * HID))[i];
  hv.x = (hv.x + a.x) + b.x;
  hv.y = (hv.y + a.y) + b.y;
  hv.z = (hv.z + a.z) + b.z;
  hv.w = (hv.w + a.w) + b.w;
  ((float4*)(H + (size_t)t * HID))[i] = hv;
}

// ---------------------------------------------------------------------------
// Small kernels
// ---------------------------------------------------------------------------
__global__ void tables_kernel(float* __restrict__ CT, float* __restrict__ ST)
{
  int idx = blockIdx.x * 256 + threadIdx.x;
  int s = idx >> 5, i = idx & 31;
  double inv = exp(-log(10000.0) * (double)i / 32.0);
  double ang = (double)s * inv;
  CT[idx] = (float)cos(ang);
  ST[idx] = (float)sin(ang);
}

__global__ __launch_bounds__(256) void embed_kernel(
    const int* __restrict__ ids, const float* __restrict__ E, float* __restrict__ H)
{
  int t = blockIdx.x;
  int id = ids[t];
  ((float4*)(H + (size_t)t * HID))[threadIdx.x] =
      ((const float4*)(E + (size_t)id * HID))[threadIdx.x];
}

__global__ __launch_bounds__(256) void rmsnorm_kernel(
    const float* __restrict__ X, const float* __restrict__ W,
    float* __restrict__ O, __bf16* __restrict__ OHb, __bf16* __restrict__ OLb)
{
  int t = blockIdx.x;
  int tid = threadIdx.x;
  float4 v = ((const float4*)(X + (size_t)t * HID))[tid];
  float ss = v.x * v.x + v.y * v.y + v.z * v.z + v.w * v.w;
#pragma unroll
  for (int d = 1; d < 64; d <<= 1) ss += __shfl_xor(ss, d);
  __shared__ float red[4];
  if ((tid & 63) == 0) red[tid >> 6] = ss;
  __syncthreads();
  float tot = red[0] + red[1] + red[2] + red[3];
  float inv = 1.0f / sqrtf(tot * (1.0f / 1024.0f) + 1e-6f);
  float4 w = ((const float4*)W)[tid];
  float4 r;
  r.x = v.x * inv * w.x; r.y = v.y * inv * w.y;
  r.z = v.z * inv * w.z; r.w = v.w * inv * w.w;
  ((float4*)(O + (size_t)t * HID))[tid] = r;
  float f[4] = {r.x, r.y, r.z, r.w};
  bf16x4v hv, lv;
#pragma unroll
  for (int j = 0; j < 4; ++j) {
    __bf16 hb = (__bf16)f[j];
    hv[j] = hb; lv[j] = (__bf16)(f[j] - (float)hb);
  }
  *(bf16x4v*)(OHb + (size_t)t * HID + tid * 4) = hv;
  *(bf16x4v*)(OLb + (size_t)t * HID + tid * 4) = lv;
}

__global__ __launch_bounds__(256) void silu_kernel(
    const float* __restrict__ G, const float* __restrict__ U,
    __bf16* __restrict__ AH, __bf16* __restrict__ AL)
{
  int t = blockIdx.y;
  int i = blockIdx.x * 256 + threadIdx.x;
  size_t idx = (size_t)t * IDIM + i;
  float gv = G[idx], uv = U[idx];
  float a = gv / (1.f + __expf(-gv)) * uv;
  __bf16 hb = (__bf16)a;
  AH[idx] = hb;
  AL[idx] = (__bf16)(a - (float)hb);
}

__global__ __launch_bounds__(256) void router_kernel(
    const float* __restrict__ X, const float* __restrict__ RW, float* __restrict__ RL)
{
  int wid = threadIdx.x >> 6, lane = threadIdx.x & 63;
  int t = blockIdx.x * 4 + wid;
  const float* x = X + (size_t)t * HID;
  float a0 = 0, a1 = 0, a2 = 0, a3 = 0, a4 = 0, a5 = 0, a6 = 0, a7 = 0;
  for (int hh = lane; hh < HID; hh += 64) {
    float xv = x[hh];
    float4 f0 = *(const float4*)(RW + hh * 8);
    float4 f1 = *(const float4*)(RW + hh * 8 + 4);
    a0 += xv * f0.x; a1 += xv * f0.y; a2 += xv * f0.z; a3 += xv * f0.w;
    a4 += xv * f1.x; a5 += xv * f1.y; a6 += xv * f1.z; a7 += xv * f1.w;
  }
#pragma unroll
  for (int d = 1; d < 64; d <<= 1) {
    a0 += __shfl_xor(a0, d); a1 += __shfl_xor(a1, d);
    a2 += __shfl_xor(a2, d); a3 += __shfl_xor(a3, d);
    a4 += __shfl_xor(a4, d); a5 += __shfl_xor(a5, d);
    a6 += __shfl_xor(a6, d); a7 += __shfl_xor(a7, d);
  }
  if (lane == 0) {
    float* dst = RL + (size_t)t * 8;
    dst[0] = a0; dst[1] = a1; dst[2] = a2; dst[3] = a3;
    dst[4] = a4; dst[5] = a5; dst[6] = a6; dst[7] = a7;
  }
}

__global__ void zero_kernel(float* __restrict__ p, int n)
{
  int i = threadIdx.x;
  if (i < n) p[i] = 0.f;
}

__global__ void zeroi_kernel(int* __restrict__ p, int n)
{
  int i = threadIdx.x;
  if (i < n) p[i] = 0;
}

__global__ __launch_bounds__(256) void topk_kernel(
    const float* __restrict__ RL, float* __restrict__ W, float* __restrict__ AUX)
{
  int t = blockIdx.x * 256 + threadIdx.x;
  int lane = threadIdx.x & 63;
  float r[8];
#pragma unroll
  for (int e = 0; e < 8; ++e) r[e] = RL[t * 8 + e];
  float mx = r[0];
#pragma unroll
  for (int e = 1; e < 8; ++e) mx = fmaxf(mx, r[e]);
  float p[8];
  float se = 0.f;
#pragma unroll
  for (int e = 0; e < 8; ++e) { p[e] = __expf(r[e] - mx); se += p[e]; }
  float inv = 1.f / se;
#pragma unroll
  for (int e = 0; e < 8; ++e) p[e] *= inv;
  float lse = logf(se) + mx;
  int i1 = 0; float v1 = p[0];
#pragma unroll
  for (int e = 1; e < 8; ++e) if (p[e] > v1) { v1 = p[e]; i1 = e; }
  int i2 = -1; float v2 = -1.f;
#pragma unroll
  for (int e = 0; e < 8; ++e) if (e != i1 && p[e] > v2) { v2 = p[e]; i2 = e; }
  float s12 = v1 + v2;
#pragma unroll
  for (int e = 0; e < 8; ++e)
    W[t * 8 + e] = (e == i1) ? v1 / s12 : ((e == i2) ? v2 / s12 : 0.f);
#pragma unroll
  for (int e = 0; e < 8; ++e) {
    float fe = ((i1 == e) ? 1.f : 0.f) + ((i2 == e) ? 1.f : 0.f);
    float pe = p[e];
#pragma unroll
    for (int d = 1; d < 64; d <<= 1) { fe += __shfl_xor(fe, d); pe += __shfl_xor(pe, d); }
    if (lane == 0) { atomicAdd(&AUX[e], fe); atomicAdd(&AUX[8 + e], pe); }
  }
  float zz = lse * lse;
#pragma unroll
  for (int d = 1; d < 64; d <<= 1) zz += __shfl_xor(zz, d);
  if (lane == 0) atomicAdd(&AUX[16], zz);
}

__global__ void aux_kernel(const float* __restrict__ AUX, float* __restrict__ OUT)
{
  float s = 0.f;
#pragma unroll
  for (int e = 0; e < 8; ++e)
    s += (AUX[e] * (1.f / 2048.f)) * (AUX[8 + e] * (1.f / 2048.f));
  float auxv = 0.01f * 8.f * s;
  float z = 0.001f * (AUX[16] * (1.f / 2048.f));
  OUT[(size_t)SEQ * VOCAB] = auxv + z;
}

// records per-token (expert, pos) pairs in ascending-e order
__global__ __launch_bounds__(256) void build_list_kernel(
    const float* __restrict__ W, int* __restrict__ cnt, int* __restrict__ list,
    int* __restrict__ tokpair)
{
  int t = blockIdx.x * 256 + threadIdx.x;
  int j = 0;
#pragma unroll
  for (int e = 0; e < 8; ++e) {
    if (W[t * 8 + e] > 0.f) {
      int p = atomicAdd(&cnt[e], 1);
      list[e * SEQ + p] = t;
      tokpair[t * 2 + j] = (e << 16) | p;
      ++j;
    }
  }
}

__global__ void prefix_kernel(const int* __restrict__ cnt, int* __restrict__ off)
{
  if (threadIdx.x == 0) {
    int s = 0;
    for (int e = 0; e < 8; ++e) { off[e] = s; s += cnt[e]; }
  }
}

// ---------------------------------------------------------------------------
extern "C" void kernel_launch(void* const* d_in, const int* in_sizes, int n_in,
                              void* d_out, int out_size, void* d_ws, size_t ws_size,
                              hipStream_t stream)
{
  const int*   ids   = (const int*)d_in[0];
  const float* embed = (const float*)d_in[1];
  const float* ln1   = (const float*)d_in[2];
  const float* ln2   = (const float*)d_in[3];
  const float* wq    = (const float*)d_in[4];
  const float* wk    = (const float*)d_in[5];
  const float* wv    = (const float*)d_in[6];
  const float* wo    = (const float*)d_in[7];
  const float* dg    = (const float*)d_in[8];
  const float* du    = (const float*)d_in[9];
  const float* dd    = (const float*)d_in[10];
  const float* rw    = (const float*)d_in[11];
  const float* mg    = (const float*)d_in[12];
  const float* mu    = (const float*)d_in[13];
  const float* md    = (const float*)d_in[14];
  const float* fin   = (const float*)d_in[15];
  float* out = (float*)d_out;

  char* ws = (char*)d_ws;
  float* h    = (float*)(ws + 0);
  float* hn   = (float*)(ws + 8388608);
  float* q    = (float*)(ws + 16777216);
  float* k    = (float*)(ws + 25165824);
  float* v    = (float*)(ws + 33554432);
  __bf16* oh  = (__bf16*)(ws + 41943040);
  __bf16* ol  = (__bf16*)(ws + 46137344);
  float* g    = (float*)(ws + 50331648);
  float* u    = (float*)(ws + 73400320);
  float* ct   = (float*)(ws + 96468992);
  float* st   = (float*)(ws + 96731136);
  float* rl   = (float*)(ws + 96993280);
  float* wmoe = (float*)(ws + 97058816);
  float* aux  = (float*)(ws + 97124352);
  int*   cnt  = (int*)  (ws + 97124608);
  int*   list = (int*)  (ws + 97124864);
  int*   tokp = (int*)  (ws + 97190400);
  int*   off8 = (int*)  (ws + 97206784);
  __bf16* wqh = (__bf16*)(ws + 97320960);
  __bf16* wql = (__bf16*)(ws + 105709568);
  __bf16* wkh = (__bf16*)(ws + 114098176);
  __bf16* wkl = (__bf16*)(ws + 122486784);
  __bf16* wvh = (__bf16*)(ws + 130875392);
  __bf16* wvl = (__bf16*)(ws + 139264000);
  __bf16* woh = (__bf16*)(ws + 147652608);
  __bf16* wol = (__bf16*)(ws + 156041216);
  __bf16* dgh = (__bf16*)(ws + 164429824);
  __bf16* dgl = (__bf16*)(ws + 181731328);
  __bf16* duh = (__bf16*)(ws + 199032832);
  __bf16* dul = (__bf16*)(ws + 216334336);
  __bf16* ddh = (__bf16*)(ws + 233635840);
  __bf16* ddl = (__bf16*)(ws + 250937344);
  __bf16* eh  = (__bf16*)(ws + 268238848);
  __bf16* hnh = (__bf16*)(ws + 333774848);
  __bf16* hnl = (__bf16*)(ws + 337969152);
  __bf16* gh  = (__bf16*)(ws + 342163456);
  __bf16* gl  = (__bf16*)(ws + 353697792);
  __bf16* mgh = (__bf16*)(ws + 365232128);
  __bf16* muh = (__bf16*)(ws + 411369472);
  __bf16* mdh = (__bf16*)(ws + 457506816);
  // end: 503,644,160 bytes
  __bf16* qh  = (__bf16*)g;
  __bf16* ql  = (__bf16*)((char*)g + 4194304);
  __bf16* kbh = (__bf16*)((char*)g + 8388608);
  __bf16* kbl = (__bf16*)((char*)g + 12582912);
  __bf16* vth = (__bf16*)u;
  __bf16* vtl = (__bf16*)((char*)u + 4194304);
  __bf16* a2  = (__bf16*)g;
  float*  y2  = u;

  wsplit_t_kernel<<<dim3(16, 16, 4), 256, 0, stream>>>(wq, wqh, wql, HID, HID);
  wsplit_t_kernel<<<dim3(16, 16, 4), 256, 0, stream>>>(wk, wkh, wkl, HID, HID);
  wsplit_t_kernel<<<dim3(16, 16, 4), 256, 0, stream>>>(wv, wvh, wvl, HID, HID);
  wsplit_t_kernel<<<dim3(16, 16, 4), 256, 0, stream>>>(wo, woh, wol, HID, HID);
  wsplit_t_kernel<<<dim3(44, 16, 3), 256, 0, stream>>>(dg, dgh, dgl, HID, IDIM);
  wsplit_t_kernel<<<dim3(44, 16, 3), 256, 0, stream>>>(du, duh, dul, HID, IDIM);
  wsplit_t_kernel<<<dim3(16, 44, 3), 256, 0, stream>>>(dd, ddh, ddl, IDIM, HID);
  wsplit_th_kernel<<<dim3(44, 16, 8), 256, 0, stream>>>(mg, mgh, HID, IDIM);
  wsplit_th_kernel<<<dim3(44, 16, 8), 256, 0, stream>>>(mu, muh, HID, IDIM);
  wsplit_th_kernel<<<dim3(16, 44, 8), 256, 0, stream>>>(md, mdh, IDIM, HID);
  esplit_kernel<<<16000, 256, 0, stream>>>(embed, eh);

  tables_kernel<<<256, 256, 0, stream>>>(ct, st);
  embed_kernel<<<SEQ, 256, 0, stream>>>(ids, embed, h);

  for (int li = 0; li < 4; ++li) {
    const bool comp = (li <= 2);
    rmsnorm_kernel<<<SEQ, 256, 0, stream>>>(h, ln1 + li * HID, hn, hnh, hnl);
    size_t wofs = (size_t)li * HID * HID;
    if (comp)
      gemm_bt_kernel<true, false, false, 64><<<dim3(8, 32, 3), 256, 0, stream>>>(
          hnh, hnl, wqh + wofs, wql + wofs, wkh + wofs, wkl + wofs,
          wvh + wofs, wvl + wofs, q, k, v, SEQ, HID, HID);
    else
      gemm_bt_kernel<false, false, false, 64><<<dim3(8, 32, 3), 256, 0, stream>>>(
          hnh, hnh, wqh + wofs, wqh + wofs, wkh + wofs, wkh + wofs,
          wvh + wofs, wvh + wofs, q, k, v, SEQ, HID, HID);

    rope_split_kernel<<<4096, 256, 0, stream>>>(q, k, qh, ql, kbh, kbl, ct, st);
    vtsplit_kernel<<<dim3(32, 16), 256, 0, stream>>>(v, vth, vtl);

    attn_flash_kernel<<<dim3(32, 16), 256, 0, stream>>>(
        qh, ql, kbh, kbl, vth, vtl, oh, ol);

    if (comp)
      gemm_bt_kernel<true, true, false, 64><<<dim3(8, 32, 1), 256, 0, stream>>>(
          oh, ol, woh + wofs, wol + wofs, woh + wofs, wol + wofs,
          woh + wofs, wol + wofs, h, h, h, SEQ, HID, HID);
    else
      gemm_bt_kernel<false, true, false, 64><<<dim3(8, 32, 1), 256, 0, stream>>>(
          oh, oh, woh + wofs, woh + wofs, woh + wofs, woh + wofs,
          woh + wofs, woh + wofs, h, h, h, SEQ, HID, HID);

    rmsnorm_kernel<<<SEQ, 256, 0, stream>>>(h, ln2 + li * HID, hn, hnh, hnl);
    if (li == 2) {
      router_kernel<<<512, 256, 0, stream>>>(hn, rw, rl);
      zero_kernel<<<1, 32, 0, stream>>>(aux, 17);
      topk_kernel<<<8, 256, 0, stream>>>(rl, wmoe, aux);
      aux_kernel<<<1, 1, 0, stream>>>(aux, out);
      zeroi_kernel<<<1, 32, 0, stream>>>(cnt, 8);
      build_list_kernel<<<8, 256, 0, stream>>>(wmoe, cnt, list, tokp);
      prefix_kernel<<<1, 64, 0, stream>>>(cnt, off8);
      gemm_moe_guf_kernel<<<dim3(32, 22, 8), 256, 0, stream>>>(
          hnh, mgh, muh, a2, wmoe, list, cnt, off8);
      gemm_moe_down2_kernel<<<dim3(32, 8, 8), 256, 0, stream>>>(
          a2, mdh, y2, cnt, off8);
      moe_scatter_kernel<<<SEQ, 256, 0, stream>>>(tokp, off8, y2, h);
    } else {
      int d = (li < 2) ? li : li - 1;
      size_t go = (size_t)d * HID * IDIM;
      if (comp) {
        gemm_bt_kernel<true, false, false, 128><<<dim3(22, 16, 2), 256, 0, stream>>>(
            hnh, hnl, dgh + go, dgl + go, duh + go, dul + go,
            duh + go, dul + go, g, u, u, SEQ, IDIM, HID);
        silu_kernel<<<dim3(11, SEQ), 256, 0, stream>>>(g, u, gh, gl);
        gemm_bt_kernel<true, true, false, 64><<<dim3(8, 32, 1), 256, 0, stream>>>(
            gh, gl, ddh + go, ddl + go, ddh + go, ddl + go,
            ddh + go, ddl + go, h, h, h, SEQ, HID, IDIM);
      } else {
        gemm_bt_kernel<false, false, false, 128><<<dim3(22, 16, 2), 256, 0, stream>>>(
            hnh, hnh, dgh + go, dgh + go, duh + go, duh + go,
            duh + go, duh + go, g, u, u, SEQ, IDIM, HID);
        silu_kernel<<<dim3(11, SEQ), 256, 0, stream>>>(g, u, gh, gl);
        gemm_bt_kernel<false, true, false, 64><<<dim3(8, 32, 1), 256, 0, stream>>>(
            gh, gh, ddh + go, ddh + go, ddh + go, ddh + go,
            ddh + go, ddh + go, h, h, h, SEQ, HID, IDIM);
      }
    }
  }
  rmsnorm_kernel<<<SEQ, 256, 0, stream>>>(h, fin, hn, hnh, hnl);
  gemm_bt_kernel<false, false, true, 128><<<dim3(16, 250, 1), 256, 0, stream>>>(
      hnh, hnh, eh, eh, eh, eh, eh, eh, out, out, out, SEQ, VOCAB, HID);
}

// Round 14
// 2049.227 us; speedup vs baseline: 1.1277x; 1.1277x over previous
//
#include <hip/hip_runtime.h>
#include <hip/hip_bf16.h>
#include <math.h>

#define SEQ 2048
#define HID 1024
#define NHEAD 16
#define HDIM 64
#define IDIM 2816
#define NEXP 8
#define VOCAB 32000

#define ASTRIDE 144  // padded rows (attention)

typedef float f32x4v __attribute__((ext_vector_type(4)));
typedef __bf16 bf16x8v __attribute__((ext_vector_type(8)));
typedef __bf16 bf16x4v __attribute__((ext_vector_type(4)));

__device__ __forceinline__ bf16x8v cvt8(const float4& a, const float4& b) {
  bf16x8v r;
  r[0] = (__bf16)a.x; r[1] = (__bf16)a.y; r[2] = (__bf16)a.z; r[3] = (__bf16)a.w;
  r[4] = (__bf16)b.x; r[5] = (__bf16)b.y; r[6] = (__bf16)b.z; r[7] = (__bf16)b.w;
  return r;
}

#define MFMA(a, b, c) __builtin_amdgcn_mfma_f32_16x16x32_bf16(a, b, c, 0, 0, 0)

// async global->LDS DMA, 16B per lane; lds base must be wave-uniform
__device__ __forceinline__ void gld_lds16(const void* g, void* l) {
  __builtin_amdgcn_global_load_lds(
      (const __attribute__((address_space(1))) unsigned int*)(unsigned long long)g,
      (__attribute__((address_space(3))) unsigned int*)(unsigned int)(unsigned long long)l,
      16, 0, 0);
}

// ---------------------------------------------------------------------------
// Weight preprocessing: W[K,N] f32 -> WH,WL [N,K] bf16 (transposed hi/lo).
// ---------------------------------------------------------------------------
__global__ __launch_bounds__(256) void wsplit_t_kernel(
    const float* __restrict__ W, __bf16* __restrict__ WH, __bf16* __restrict__ WL,
    int K, int N)
{
  __shared__ float tile[64][65];
  const int tid = threadIdx.x;
  const size_t zofs = (size_t)blockIdx.z * K * N;
  const int n0 = blockIdx.x * 64, k0 = blockIdx.y * 64;
#pragma unroll
  for (int r = 0; r < 4; ++r) {
    int kk = (tid >> 4) + r * 16;
    int nn = (tid & 15) * 4;
    float4 v = *(const float4*)(W + zofs + (size_t)(k0 + kk) * N + n0 + nn);
    tile[kk][nn] = v.x; tile[kk][nn + 1] = v.y;
    tile[kk][nn + 2] = v.z; tile[kk][nn + 3] = v.w;
  }
  __syncthreads();
  const int nn = tid >> 2;
  const int kk = (tid & 3) * 16;
  __bf16* dh = WH + zofs + (size_t)(n0 + nn) * K + k0 + kk;
  __bf16* dl = WL + zofs + (size_t)(n0 + nn) * K + k0 + kk;
  bf16x8v h0, l0, h1, l1;
#pragma unroll
  for (int j = 0; j < 8; ++j) {
    float f = tile[kk + j][nn];
    __bf16 hb = (__bf16)f; h0[j] = hb; l0[j] = (__bf16)(f - (float)hb);
    f = tile[kk + 8 + j][nn];
    hb = (__bf16)f; h1[j] = hb; l1[j] = (__bf16)(f - (float)hb);
  }
  *(bf16x8v*)dh = h0; *(bf16x8v*)(dh + 8) = h1;
  *(bf16x8v*)dl = l0; *(bf16x8v*)(dl + 8) = l1;
}

// hi-only variant (MoE weights; plain-bf16 path needs no lo)
__global__ __launch_bounds__(256) void wsplit_th_kernel(
    const float* __restrict__ W, __bf16* __restrict__ WH, int K, int N)
{
  __shared__ float tile[64][65];
  const int tid = threadIdx.x;
  const size_t zofs = (size_t)blockIdx.z * K * N;
  const int n0 = blockIdx.x * 64, k0 = blockIdx.y * 64;
#pragma unroll
  for (int r = 0; r < 4; ++r) {
    int kk = (tid >> 4) + r * 16;
    int nn = (tid & 15) * 4;
    float4 v = *(const float4*)(W + zofs + (size_t)(k0 + kk) * N + n0 + nn);
    tile[kk][nn] = v.x; tile[kk][nn + 1] = v.y;
    tile[kk][nn + 2] = v.z; tile[kk][nn + 3] = v.w;
  }
  __syncthreads();
  const int nn = tid >> 2;
  const int kk = (tid & 3) * 16;
  __bf16* dh = WH + zofs + (size_t)(n0 + nn) * K + k0 + kk;
  bf16x8v h0, h1;
#pragma unroll
  for (int j = 0; j < 8; ++j) {
    h0[j] = (__bf16)tile[kk + j][nn];
    h1[j] = (__bf16)tile[kk + 8 + j][nn];
  }
  *(bf16x8v*)dh = h0; *(bf16x8v*)(dh + 8) = h1;
}

__global__ __launch_bounds__(256) void esplit_kernel(
    const float* __restrict__ E, __bf16* __restrict__ EH)
{
  size_t i = ((size_t)blockIdx.x * 256 + threadIdx.x) * 8;
  float4 a = *(const float4*)(E + i);
  float4 b = *(const float4*)(E + i + 4);
  *(bf16x8v*)(EH + i) = cvt8(a, b);
}

// ---------------------------------------------------------------------------
// Unified BT GEMM. A,B pre-split bf16. Staging = global_load_lds DMA (16B),
// LINEAR LDS rows (64B/row).
// ---------------------------------------------------------------------------
template<bool COMP, bool ACCUM, bool SWAP, int BM>
__global__ __launch_bounds__(256) void gemm_bt_kernel(
    const __bf16* __restrict__ Ah, const __bf16* __restrict__ Al,
    const __bf16* __restrict__ B0h, const __bf16* __restrict__ B0l,
    const __bf16* __restrict__ B1h, const __bf16* __restrict__ B1l,
    const __bf16* __restrict__ B2h, const __bf16* __restrict__ B2l,
    float* __restrict__ C0, float* __restrict__ C1, float* __restrict__ C2,
    int M, int N, int Kd)
{
  const __bf16* __restrict__ Bh = (blockIdx.z == 0) ? B0h : (blockIdx.z == 1 ? B1h : B2h);
  const __bf16* __restrict__ Bl = (blockIdx.z == 0) ? B0l : (blockIdx.z == 1 ? B1l : B2l);
  float* __restrict__ C         = (blockIdx.z == 0) ? C0 : (blockIdx.z == 1 ? C1 : C2);
  constexpr int ATILE = BM * 64;
  constexpr int BTILE = 128 * 64;
  constexpr int MFR = BM / 32;
  __shared__ __align__(16) char smem[COMP ? 2 * (ATILE + BTILE) : (ATILE + BTILE)];
  char* AsH = smem;
  char* BsH = smem + ATILE;
  char* AsL = COMP ? smem + ATILE + BTILE : smem;
  char* BsL = COMP ? smem + 2 * ATILE + BTILE : smem + ATILE;
  const int tid = threadIdx.x;
  const int bm = SWAP ? blockIdx.x : blockIdx.y;
  const int bn = SWAP ? blockIdx.y : blockIdx.x;
  const int wid = tid >> 6, lane = tid & 63;
  const int wm = (wid >> 1) * (BM / 2), wn = (wid & 1) << 6;
  const int lr = lane & 15, kh = lane >> 4;
  const int lrow = lane >> 2;
  const int lcol = (lane & 3) << 3;

  f32x4v acc[MFR][4];
  const f32x4v z4 = {0.f, 0.f, 0.f, 0.f};
#pragma unroll
  for (int i = 0; i < MFR; ++i)
#pragma unroll
    for (int j = 0; j < 4; ++j) acc[i][j] = z4;

  for (int k0 = 0; k0 < Kd; k0 += 32) {
    __syncthreads();
#pragma unroll
    for (int c = wid; c < BM / 16; c += 4) {
      size_t gofs = (size_t)(bm * BM + c * 16 + lrow) * Kd + k0 + lcol;
      gld_lds16(Ah + gofs, AsH + c * 1024);
      if (COMP) gld_lds16(Al + gofs, AsL + c * 1024);
    }
#pragma unroll
    for (int c = wid; c < 8; c += 4) {
      size_t gofs = (size_t)(bn * 128 + c * 16 + lrow) * Kd + k0 + lcol;
      gld_lds16(Bh + gofs, BsH + c * 1024);
      if (COMP) gld_lds16(Bl + gofs, BsL + c * 1024);
    }
    __syncthreads();

    bf16x8v ah[MFR], al[MFR], bh4[4], bl4[4];
#pragma unroll
    for (int i = 0; i < MFR; ++i) {
      int r = wm + (i << 4) + lr;
      int off = r * 64 + (kh << 4);
      ah[i] = *(const bf16x8v*)(AsH + off);
      if (COMP) al[i] = *(const bf16x8v*)(AsL + off);
    }
#pragma unroll
    for (int i = 0; i < 4; ++i) {
      int r = wn + (i << 4) + lr;
      int off = r * 64 + (kh << 4);
      bh4[i] = *(const bf16x8v*)(BsH + off);
      if (COMP) bl4[i] = *(const bf16x8v*)(BsL + off);
    }
#pragma unroll
    for (int mi = 0; mi < MFR; ++mi)
#pragma unroll
      for (int ni = 0; ni < 4; ++ni) {
        if (COMP) {
          acc[mi][ni] = MFMA(al[mi], bh4[ni], acc[mi][ni]);
          acc[mi][ni] = MFMA(ah[mi], bl4[ni], acc[mi][ni]);
        }
        acc[mi][ni] = MFMA(ah[mi], bh4[ni], acc[mi][ni]);
      }
  }

  const int cr0 = kh << 2;
#pragma unroll
  for (int mi = 0; mi < MFR; ++mi)
#pragma unroll
    for (int ni = 0; ni < 4; ++ni)
#pragma unroll
      for (int r = 0; r < 4; ++r) {
        int row = bm * BM + wm + (mi << 4) + cr0 + r;
        int col = bn * 128 + wn + (ni << 4) + lr;
        size_t idx = (size_t)row * N + col;
        if (ACCUM) C[idx] += acc[mi][ni][r];
        else       C[idx] = acc[mi][ni][r];
      }
}

// ---------------------------------------------------------------------------
// rope + hi/lo split for Q (scale 1/8) and K
// ---------------------------------------------------------------------------
__global__ __launch_bounds__(256) void rope_split_kernel(
    const float* __restrict__ Q, const float* __restrict__ K,
    __bf16* __restrict__ QH, __bf16* __restrict__ QL,
    __bf16* __restrict__ KH, __bf16* __restrict__ KL,
    const float* __restrict__ CT, const float* __restrict__ ST)
{
  int idx = blockIdx.x * 256 + threadIdx.x;
  int s = idx >> 9;
  int rr = idx & 511;
  int hd = rr >> 5;
  int i = rr & 31;
  float c = CT[(s << 5) + i], sn = ST[(s << 5) + i];
  size_t base = (size_t)s * HID + hd * 64 + i;
  {
    float x1 = Q[base], x2 = Q[base + 32];
    float o1 = (x1 * c - x2 * sn) * 0.125f;
    float o2 = (x2 * c + x1 * sn) * 0.125f;
    __bf16 h1 = (__bf16)o1, h2 = (__bf16)o2;
    QH[base] = h1;      QL[base] = (__bf16)(o1 - (float)h1);
    QH[base + 32] = h2; QL[base + 32] = (__bf16)(o2 - (float)h2);
  }
  {
    float x1 = K[base], x2 = K[base + 32];
    float o1 = x1 * c - x2 * sn;
    float o2 = x2 * c + x1 * sn;
    __bf16 h1 = (__bf16)o1, h2 = (__bf16)o2;
    KH[base] = h1;      KL[base] = (__bf16)(o1 - (float)h1);
    KH[base + 32] = h2; KL[base + 32] = (__bf16)(o2 - (float)h2);
  }
}

// V f32 [S][HID] -> per-head transposed hi/lo bf16 [NHEAD][HDIM][SEQ]
__global__ __launch_bounds__(256) void vtsplit_kernel(
    const float* __restrict__ V, __bf16* __restrict__ VTH, __bf16* __restrict__ VTL)
{
  __shared__ float tile[64][65];
  const int tid = threadIdx.x;
  const int s0 = blockIdx.x * 64;
  const int head = blockIdx.y;
#pragma unroll
  for (int r = 0; r < 4; ++r) {
    int ss = (tid >> 4) + r * 16;
    int dd = (tid & 15) * 4;
    float4 v = *(const float4*)(V + (size_t)(s0 + ss) * HID + head * 64 + dd);
    tile[ss][dd] = v.x; tile[ss][dd + 1] = v.y;
    tile[ss][dd + 2] = v.z; tile[ss][dd + 3] = v.w;
  }
  __syncthreads();
#pragma unroll
  for (int half = 0; half < 2; ++half) {
    const int d = (tid >> 3) + (half << 5);
    const int c = tid & 7;
    bf16x8v hv, lv;
#pragma unroll
    for (int j = 0; j < 8; ++j) {
      float f = tile[c * 8 + j][d];
      __bf16 hb = (__bf16)f;
      hv[j] = hb; lv[j] = (__bf16)(f - (float)hb);
    }
    size_t dst = (size_t)(head * 64 + d) * SEQ + s0 + c * 8;
    *(bf16x8v*)(VTH + dst) = hv;
    *(bf16x8v*)(VTL + dst) = lv;
  }
}

// ---------------------------------------------------------------------------
// Compensated flash attention; padded LDS; O -> bf16 hi/lo
// ---------------------------------------------------------------------------
__global__ __launch_bounds__(256) void attn_flash_kernel(
    const __bf16* __restrict__ QH, const __bf16* __restrict__ QL,
    const __bf16* __restrict__ KH, const __bf16* __restrict__ KL,
    const __bf16* __restrict__ VTH, const __bf16* __restrict__ VTL,
    __bf16* __restrict__ OH, __bf16* __restrict__ OL)
{
  const int qt = blockIdx.x;
  const int head = blockIdx.y;
  const int tid = threadIdx.x, wid = tid >> 6, lane = tid & 63;
  const int lr = lane & 15, kh = lane >> 4;
  __shared__ __align__(16) char KsH[64 * ASTRIDE], KsL[64 * ASTRIDE];
  __shared__ __align__(16) char VtH[64 * ASTRIDE], VtL[64 * ASTRIDE];
  __shared__ __align__(16) char PsH[4][16 * ASTRIDE], PsL[4][16 * ASTRIDE];

  const size_t qofs = (size_t)(qt * 64 + wid * 16 + lr) * HID + head * HDIM;
  const bf16x8v qfh0 = *(const bf16x8v*)(QH + qofs + (kh << 3));
  const bf16x8v qfh1 = *(const bf16x8v*)(QH + qofs + 32 + (kh << 3));
  const bf16x8v qfl0 = *(const bf16x8v*)(QL + qofs + (kh << 3));
  const bf16x8v qfl1 = *(const bf16x8v*)(QL + qofs + 32 + (kh << 3));

  float m_run[4], l_run[4];
  f32x4v oacc[4];
  const f32x4v z4 = {0.f, 0.f, 0.f, 0.f};
#pragma unroll
  for (int i = 0; i < 4; ++i) { m_run[i] = -1e30f; l_run[i] = 0.f; oacc[i] = z4; }

  for (int kt = 0; kt <= qt; ++kt) {
    __syncthreads();
#pragma unroll
    for (int p = 0; p < 2; ++p) {
      int g = tid + (p << 8);
      int r = g >> 3;
      int c = g & 7;
      int off = r * ASTRIDE + (c << 4);
      const size_t kofs = (size_t)(kt * 64 + r) * HID + head * HDIM + (c << 3);
      *(bf16x8v*)(KsH + off) = *(const bf16x8v*)(KH + kofs);
      *(bf16x8v*)(KsL + off) = *(const bf16x8v*)(KL + kofs);
      const size_t vofs = (size_t)(head * 64 + r) * SEQ + kt * 64 + (c << 3);
      *(bf16x8v*)(VtH + off) = *(const bf16x8v*)(VTH + vofs);
      *(bf16x8v*)(VtL + off) = *(const bf16x8v*)(VTL + vofs);
    }
    __syncthreads();

    float sv[4][4];
#pragma unroll
    for (int stt = 0; stt < 4; ++stt) {
      int r = (stt << 4) + lr;
      int off0 = r * ASTRIDE + (kh << 4);
      int off1 = off0 + 64;
      bf16x8v kfh0 = *(const bf16x8v*)(KsH + off0);
      bf16x8v kfl0 = *(const bf16x8v*)(KsL + off0);
      bf16x8v kfh1 = *(const bf16x8v*)(KsH + off1);
      bf16x8v kfl1 = *(const bf16x8v*)(KsL + off1);
      f32x4v s = z4;
      s = MFMA(qfl0, kfh0, s);
      s = MFMA(qfh0, kfl0, s);
      s = MFMA(qfh0, kfh0, s);
      s = MFMA(qfl1, kfh1, s);
      s = MFMA(qfh1, kfl1, s);
      s = MFMA(qfh1, kfh1, s);
      int key = kt * 64 + (stt << 4) + lr;
#pragma unroll
      for (int rr = 0; rr < 4; ++rr) {
        int qr = qt * 64 + wid * 16 + (kh << 2) + rr;
        sv[stt][rr] = (key <= qr) ? s[rr] : -1e30f;
      }
    }

#pragma unroll
    for (int rr = 0; rr < 4; ++rr) {
      float mx = fmaxf(fmaxf(sv[0][rr], sv[1][rr]), fmaxf(sv[2][rr], sv[3][rr]));
#pragma unroll
      for (int d = 1; d < 16; d <<= 1) mx = fmaxf(mx, __shfl_xor(mx, d));
      float mnew = fmaxf(m_run[rr], mx);
      float scl = __expf(m_run[rr] - mnew);
      float pv[4];
#pragma unroll
      for (int stt = 0; stt < 4; ++stt) pv[stt] = __expf(sv[stt][rr] - mnew);
      float rs = pv[0] + pv[1] + pv[2] + pv[3];
#pragma unroll
      for (int d = 1; d < 16; d <<= 1) rs += __shfl_xor(rs, d);
      l_run[rr] = l_run[rr] * scl + rs;
      m_run[rr] = mnew;
#pragma unroll
      for (int n = 0; n < 4; ++n) oacc[n][rr] *= scl;
      int qlr = (kh << 2) + rr;
#pragma unroll
      for (int stt = 0; stt < 4; ++stt) {
        __bf16 hb = (__bf16)pv[stt];
        __bf16 lb = (__bf16)(pv[stt] - (float)hb);
        int off = qlr * ASTRIDE + (((stt << 4) + lr) << 1);
        *(__bf16*)(PsH[wid] + off) = hb;
        *(__bf16*)(PsL[wid] + off) = lb;
      }
    }

    int poff0 = lr * ASTRIDE + (kh << 4);
    int poff1 = poff0 + 64;
    bf16x8v pah0 = *(const bf16x8v*)(PsH[wid] + poff0);
    bf16x8v pal0 = *(const bf16x8v*)(PsL[wid] + poff0);
    bf16x8v pah1 = *(const bf16x8v*)(PsH[wid] + poff1);
    bf16x8v pal1 = *(const bf16x8v*)(PsL[wid] + poff1);
#pragma unroll
    for (int n = 0; n < 4; ++n) {
      int vr = (n << 4) + lr;
      int voff0 = vr * ASTRIDE + (kh << 4);
      int voff1 = voff0 + 64;
      bf16x8v vfh0 = *(const bf16x8v*)(VtH + voff0);
      bf16x8v vfl0 = *(const bf16x8v*)(VtL + voff0);
      bf16x8v vfh1 = *(const bf16x8v*)(VtH + voff1);
      bf16x8v vfl1 = *(const bf16x8v*)(VtL + voff1);
      oacc[n] = MFMA(pal0, vfh0, oacc[n]);
      oacc[n] = MFMA(pah0, vfl0, oacc[n]);
      oacc[n] = MFMA(pah0, vfh0, oacc[n]);
      oacc[n] = MFMA(pal1, vfh1, oacc[n]);
      oacc[n] = MFMA(pah1, vfl1, oacc[n]);
      oacc[n] = MFMA(pah1, vfh1, oacc[n]);
    }
  }

#pragma unroll
  for (int n = 0; n < 4; ++n)
#pragma unroll
    for (int rr = 0; rr < 4; ++rr) {
      int qr = qt * 64 + wid * 16 + (kh << 2) + rr;
      size_t ofs = (size_t)qr * HID + head * HDIM + (n << 4) + lr;
      float val = oacc[n][rr] / l_run[rr];
      __bf16 hb = (__bf16)val;
      OH[ofs] = hb;
      OL[ofs] = (__bf16)(val - (float)hb);
    }
}

// ---------------------------------------------------------------------------
// MoE: fused gate+up+silu. BM=128, BN=64 (2x blocks, same B traffic).
// Wave layout 2m x 2n: each wave 64m x 32n, accg/accu[4][2].
// ---------------------------------------------------------------------------
__global__ __launch_bounds__(256) void gemm_moe_guf_kernel(
    const __bf16* __restrict__ Xh,
    const __bf16* __restrict__ MGH, const __bf16* __restrict__ MUH,
    __bf16* __restrict__ A2, const float* __restrict__ W,
    const int* __restrict__ list, const int* __restrict__ cnt8,
    const int* __restrict__ off8)
{
  const int e = blockIdx.z;
  const int cnt = cnt8[e];
  const int bn = blockIdx.x, bm = blockIdx.y;
  if (bm * 128 >= cnt) return;
  const int base = off8[e];
  __shared__ __align__(16) char AsB[8192];
  __shared__ __align__(16) char BgB[4096];
  __shared__ __align__(16) char BuB[4096];
  const int tid = threadIdx.x;
  const int wid = tid >> 6, lane = tid & 63;
  const int wm = (wid >> 1) << 6, wn = (wid & 1) << 5;
  const int lr = lane & 15, kh = lane >> 4;
  const int lrow = lane >> 2;
  const int lcol = (lane & 3) << 3;

  f32x4v accg[4][2], accu[4][2];
  const f32x4v z4 = {0.f, 0.f, 0.f, 0.f};
#pragma unroll
  for (int i = 0; i < 4; ++i)
#pragma unroll
    for (int j = 0; j < 2; ++j) { accg[i][j] = z4; accu[i][j] = z4; }

  for (int k0 = 0; k0 < HID; k0 += 32) {
    __syncthreads();
#pragma unroll
    for (int c = wid; c < 8; c += 4) {     // A: 128 rows
      int rg = bm * 128 + c * 16 + lrow;
      int tok = list[e * SEQ + (rg < cnt ? rg : cnt - 1)];
      gld_lds16(Xh + (size_t)tok * HID + k0 + lcol, AsB + c * 1024);
    }
    {                                       // B: 64 rows each (g,u), 4 chunks
      int c = wid;
      size_t wofs = (size_t)(e * IDIM + bn * 64 + c * 16 + lrow) * HID + k0 + lcol;
      gld_lds16(MGH + wofs, BgB + c * 1024);
      gld_lds16(MUH + wofs, BuB + c * 1024);
    }
    __syncthreads();

    bf16x8v af[4], bg4[2], bu4[2];
#pragma unroll
    for (int i = 0; i < 4; ++i) {
      int r = wm + (i << 4) + lr;
      af[i] = *(const bf16x8v*)(AsB + r * 64 + (kh << 4));
    }
#pragma unroll
    for (int i = 0; i < 2; ++i) {
      int r = wn + (i << 4) + lr;
      bg4[i] = *(const bf16x8v*)(BgB + r * 64 + (kh << 4));
      bu4[i] = *(const bf16x8v*)(BuB + r * 64 + (kh << 4));
    }
#pragma unroll
    for (int mi = 0; mi < 4; ++mi)
#pragma unroll
      for (int ni = 0; ni < 2; ++ni) {
        accg[mi][ni] = MFMA(af[mi], bg4[ni], accg[mi][ni]);
        accu[mi][ni] = MFMA(af[mi], bu4[ni], accu[mi][ni]);
      }
  }

  const int cr0 = kh << 2;
#pragma unroll
  for (int mi = 0; mi < 4; ++mi)
#pragma unroll
    for (int ni = 0; ni < 2; ++ni)
#pragma unroll
      for (int r = 0; r < 4; ++r) {
        int row = bm * 128 + wm + (mi << 4) + cr0 + r;
        if (row < cnt) {
          int col = bn * 64 + wn + (ni << 4) + lr;
          int tok = list[e * SEQ + row];
          float w = W[tok * 8 + e];
          float gval = accg[mi][ni][r];
          float uval = accu[mi][ni][r];
          float a = gval / (1.f + __expf(-gval)) * uval * w;
          A2[(size_t)(base + row) * IDIM + col] = (__bf16)a;
        }
      }
}

__global__ __launch_bounds__(256) void gemm_moe_down2_kernel(
    const __bf16* __restrict__ A2, const __bf16* __restrict__ MDH,
    float* __restrict__ Y2,
    const int* __restrict__ cnt8, const int* __restrict__ off8)
{
  const int e = blockIdx.z;
  const int cnt = cnt8[e];
  const int bn = blockIdx.x, bm = blockIdx.y;
  if (bm * 128 >= cnt) return;
  const int base = off8[e];
  __shared__ __align__(16) char AsB[8192];
  __shared__ __align__(16) char BsB[4096];
  const int tid = threadIdx.x;
  const int wid = tid >> 6, lane = tid & 63;
  const int wm = (wid >> 1) << 6, wn = (wid & 1) << 5;
  const int lr = lane & 15, kh = lane >> 4;
  const int lrow = lane >> 2;
  const int lcol = (lane & 3) << 3;

  f32x4v acc[4][2];
  const f32x4v z4 = {0.f, 0.f, 0.f, 0.f};
#pragma unroll
  for (int i = 0; i < 4; ++i)
#pragma unroll
    for (int j = 0; j < 2; ++j) acc[i][j] = z4;

  for (int k0 = 0; k0 < IDIM; k0 += 32) {
    __syncthreads();
#pragma unroll
    for (int c = wid; c < 8; c += 4) {
      int rg = bm * 128 + c * 16 + lrow;
      int row = (rg < cnt ? rg : cnt - 1);
      gld_lds16(A2 + (size_t)(base + row) * IDIM + k0 + lcol, AsB + c * 1024);
    }
    {
      int c = wid;
      gld_lds16(MDH + (size_t)(e * HID + bn * 64 + c * 16 + lrow) * IDIM + k0 + lcol,
                BsB + c * 1024);
    }
    __syncthreads();

    bf16x8v af[4], bfv[2];
#pragma unroll
    for (int i = 0; i < 4; ++i) {
      int r = wm + (i << 4) + lr;
      af[i] = *(const bf16x8v*)(AsB + r * 64 + (kh << 4));
    }
#pragma unroll
    for (int i = 0; i < 2; ++i) {
      int r = wn + (i << 4) + lr;
      bfv[i] = *(const bf16x8v*)(BsB + r * 64 + (kh << 4));
    }
#pragma unroll
    for (int mi = 0; mi < 4; ++mi)
#pragma unroll
      for (int ni = 0; ni < 2; ++ni)
        acc[mi][ni] = MFMA(af[mi], bfv[ni], acc[mi][ni]);
  }

  const int cr0 = kh << 2;
#pragma unroll
  for (int mi = 0; mi < 4; ++mi)
#pragma unroll
    for (int ni = 0; ni < 2; ++ni)
#pragma unroll
      for (int r = 0; r < 4; ++r) {
        int row = bm * 128 + wm + (mi << 4) + cr0 + r;
        if (row < cnt) {
          int col = bn * 64 + wn + (ni << 4) + lr;
          Y2[(size_t)(base + row) * HID + col] = acc[mi][ni][r];
        }
      }
}

// h[t] += y(e_lo) + y(e_hi)  (ascending-e order == old serial order)
__global__ __launch_bounds__(256) void moe_scatter_kernel(
    const int* __restrict__ tokpair, const int* __restrict__ off8,
    const float* __restrict__ Y2, float* __restrict__ H)
{
  const int t = blockIdx.x;
  const int i = threadIdx.x;
  int p0 = tokpair[t * 2], p1 = tokpair[t * 2 + 1];
  size_t r0 = off8[p0 >> 16] + (p0 & 0xffff);
  size_t r1 = off8[p1 >> 16] + (p1 & 0xffff);
  float4 a = ((const float4*)(Y2 + r0 * HID))[i];
  float4 b = ((const float4*)(Y2 + r1 * HID))[i];
  float4 hv = ((float4*)(H + (size_t)t * HID))[i];
  hv.x = (hv.x + a.x) + b.x;
  hv.y = (hv.y + a.y) + b.y;
  hv.z = (hv.z + a.z) + b.z;
  hv.w = (hv.w + a.w) + b.w;
  ((float4*)(H + (size_t)t * HID))[i] = hv;
}

// ---------------------------------------------------------------------------
// Small kernels
// ---------------------------------------------------------------------------
__global__ void tables_kernel(float* __restrict__ CT, float* __restrict__ ST)
{
  int idx = blockIdx.x * 256 + threadIdx.x;
  int s = idx >> 5, i = idx & 31;
  double inv = exp(-log(10000.0) * (double)i / 32.0);
  double ang = (double)s * inv;
  CT[idx] = (float)cos(ang);
  ST[idx] = (float)sin(ang);
}

__global__ __launch_bounds__(256) void embed_kernel(
    const int* __restrict__ ids, const float* __restrict__ E, float* __restrict__ H)
{
  int t = blockIdx.x;
  int id = ids[t];
  ((float4*)(H + (size_t)t * HID))[threadIdx.x] =
      ((const float4*)(E + (size_t)id * HID))[threadIdx.x];
}

__global__ __launch_bounds__(256) void rmsnorm_kernel(
    const float* __restrict__ X, const float* __restrict__ W,
    float* __restrict__ O, __bf16* __restrict__ OHb, __bf16* __restrict__ OLb)
{
  int t = blockIdx.x;
  int tid = threadIdx.x;
  float4 v = ((const float4*)(X + (size_t)t * HID))[tid];
  float ss = v.x * v.x + v.y * v.y + v.z * v.z + v.w * v.w;
#pragma unroll
  for (int d = 1; d < 64; d <<= 1) ss += __shfl_xor(ss, d);
  __shared__ float red[4];
  if ((tid & 63) == 0) red[tid >> 6] = ss;
  __syncthreads();
  float tot = red[0] + red[1] + red[2] + red[3];
  float inv = 1.0f / sqrtf(tot * (1.0f / 1024.0f) + 1e-6f);
  float4 w = ((const float4*)W)[tid];
  float4 r;
  r.x = v.x * inv * w.x; r.y = v.y * inv * w.y;
  r.z = v.z * inv * w.z; r.w = v.w * inv * w.w;
  ((float4*)(O + (size_t)t * HID))[tid] = r;
  float f[4] = {r.x, r.y, r.z, r.w};
  bf16x4v hv, lv;
#pragma unroll
  for (int j = 0; j < 4; ++j) {
    __bf16 hb = (__bf16)f[j];
    hv[j] = hb; lv[j] = (__bf16)(f[j] - (float)hb);
  }
  *(bf16x4v*)(OHb + (size_t)t * HID + tid * 4) = hv;
  *(bf16x4v*)(OLb + (size_t)t * HID + tid * 4) = lv;
}

__global__ __launch_bounds__(256) void silu_kernel(
    const float* __restrict__ G, const float* __restrict__ U,
    __bf16* __restrict__ AH, __bf16* __restrict__ AL)
{
  int t = blockIdx.y;
  int i = blockIdx.x * 256 + threadIdx.x;
  size_t idx = (size_t)t * IDIM + i;
  float gv = G[idx], uv = U[idx];
  float a = gv / (1.f + __expf(-gv)) * uv;
  __bf16 hb = (__bf16)a;
  AH[idx] = hb;
  AL[idx] = (__bf16)(a - (float)hb);
}

__global__ __launch_bounds__(256) void router_kernel(
    const float* __restrict__ X, const float* __restrict__ RW, float* __restrict__ RL)
{
  int wid = threadIdx.x >> 6, lane = threadIdx.x & 63;
  int t = blockIdx.x * 4 + wid;
  const float* x = X + (size_t)t * HID;
  float a0 = 0, a1 = 0, a2 = 0, a3 = 0, a4 = 0, a5 = 0, a6 = 0, a7 = 0;
  for (int hh = lane; hh < HID; hh += 64) {
    float xv = x[hh];
    float4 f0 = *(const float4*)(RW + hh * 8);
    float4 f1 = *(const float4*)(RW + hh * 8 + 4);
    a0 += xv * f0.x; a1 += xv * f0.y; a2 += xv * f0.z; a3 += xv * f0.w;
    a4 += xv * f1.x; a5 += xv * f1.y; a6 += xv * f1.z; a7 += xv * f1.w;
  }
#pragma unroll
  for (int d = 1; d < 64; d <<= 1) {
    a0 += __shfl_xor(a0, d); a1 += __shfl_xor(a1, d);
    a2 += __shfl_xor(a2, d); a3 += __shfl_xor(a3, d);
    a4 += __shfl_xor(a4, d); a5 += __shfl_xor(a5, d);
    a6 += __shfl_xor(a6, d); a7 += __shfl_xor(a7, d);
  }
  if (lane == 0) {
    float* dst = RL + (size_t)t * 8;
    dst[0] = a0; dst[1] = a1; dst[2] = a2; dst[3] = a3;
    dst[4] = a4; dst[5] = a5; dst[6] = a6; dst[7] = a7;
  }
}

__global__ void zero_kernel(float* __restrict__ p, int n)
{
  int i = threadIdx.x;
  if (i < n) p[i] = 0.f;
}

__global__ void zeroi_kernel(int* __restrict__ p, int n)
{
  int i = threadIdx.x;
  if (i < n) p[i] = 0;
}

__global__ __launch_bounds__(256) void topk_kernel(
    const float* __restrict__ RL, float* __restrict__ W, float* __restrict__ AUX)
{
  int t = blockIdx.x * 256 + threadIdx.x;
  int lane = threadIdx.x & 63;
  float r[8];
#pragma unroll
  for (int e = 0; e < 8; ++e) r[e] = RL[t * 8 + e];
  float mx = r[0];
#pragma unroll
  for (int e = 1; e < 8; ++e) mx = fmaxf(mx, r[e]);
  float p[8];
  float se = 0.f;
#pragma unroll
  for (int e = 0; e < 8; ++e) { p[e] = __expf(r[e] - mx); se += p[e]; }
  float inv = 1.f / se;
#pragma unroll
  for (int e = 0; e < 8; ++e) p[e] *= inv;
  float lse = logf(se) + mx;
  int i1 = 0; float v1 = p[0];
#pragma unroll
  for (int e = 1; e < 8; ++e) if (p[e] > v1) { v1 = p[e]; i1 = e; }
  int i2 = -1; float v2 = -1.f;
#pragma unroll
  for (int e = 0; e < 8; ++e) if (e != i1 && p[e] > v2) { v2 = p[e]; i2 = e; }
  float s12 = v1 + v2;
#pragma unroll
  for (int e = 0; e < 8; ++e)
    W[t * 8 + e] = (e == i1) ? v1 / s12 : ((e == i2) ? v2 / s12 : 0.f);
#pragma unroll
  for (int e = 0; e < 8; ++e) {
    float fe = ((i1 == e) ? 1.f : 0.f) + ((i2 == e) ? 1.f : 0.f);
    float pe = p[e];
#pragma unroll
    for (int d = 1; d < 64; d <<= 1) { fe += __shfl_xor(fe, d); pe += __shfl_xor(pe, d); }
    if (lane == 0) { atomicAdd(&AUX[e], fe); atomicAdd(&AUX[8 + e], pe); }
  }
  float zz = lse * lse;
#pragma unroll
  for (int d = 1; d < 64; d <<= 1) zz += __shfl_xor(zz, d);
  if (lane == 0) atomicAdd(&AUX[16], zz);
}

__global__ void aux_kernel(const float* __restrict__ AUX, float* __restrict__ OUT)
{
  float s = 0.f;
#pragma unroll
  for (int e = 0; e < 8; ++e)
    s += (AUX[e] * (1.f / 2048.f)) * (AUX[8 + e] * (1.f / 2048.f));
  float auxv = 0.01f * 8.f * s;
  float z = 0.001f * (AUX[16] * (1.f / 2048.f));
  OUT[(size_t)SEQ * VOCAB] = auxv + z;
}

// records per-token (expert, pos) pairs in ascending-e order
__global__ __launch_bounds__(256) void build_list_kernel(
    const float* __restrict__ W, int* __restrict__ cnt, int* __restrict__ list,
    int* __restrict__ tokpair)
{
  int t = blockIdx.x * 256 + threadIdx.x;
  int j = 0;
#pragma unroll
  for (int e = 0; e < 8; ++e) {
    if (W[t * 8 + e] > 0.f) {
      int p = atomicAdd(&cnt[e], 1);
      list[e * SEQ + p] = t;
      tokpair[t * 2 + j] = (e << 16) | p;
      ++j;
    }
  }
}

__global__ void prefix_kernel(const int* __restrict__ cnt, int* __restrict__ off)
{
  if (threadIdx.x == 0) {
    int s = 0;
    for (int e = 0; e < 8; ++e) { off[e] = s; s += cnt[e]; }
  }
}

// ---------------------------------------------------------------------------
extern "C" void kernel_launch(void* const* d_in, const int* in_sizes, int n_in,
                              void* d_out, int out_size, void* d_ws, size_t ws_size,
                              hipStream_t stream)
{
  const int*   ids   = (const int*)d_in[0];
  const float* embed = (const float*)d_in[1];
  const float* ln1   = (const float*)d_in[2];
  const float* ln2   = (const float*)d_in[3];
  const float* wq    = (const float*)d_in[4];
  const float* wk    = (const float*)d_in[5];
  const float* wv    = (const float*)d_in[6];
  const float* wo    = (const float*)d_in[7];
  const float* dg    = (const float*)d_in[8];
  const float* du    = (const float*)d_in[9];
  const float* dd    = (const float*)d_in[10];
  const float* rw    = (const float*)d_in[11];
  const float* mg    = (const float*)d_in[12];
  const float* mu    = (const float*)d_in[13];
  const float* md    = (const float*)d_in[14];
  const float* fin   = (const float*)d_in[15];
  float* out = (float*)d_out;

  char* ws = (char*)d_ws;
  float* h    = (float*)(ws + 0);
  float* hn   = (float*)(ws + 8388608);
  float* q    = (float*)(ws + 16777216);
  float* k    = (float*)(ws + 25165824);
  float* v    = (float*)(ws + 33554432);
  __bf16* oh  = (__bf16*)(ws + 41943040);
  __bf16* ol  = (__bf16*)(ws + 46137344);
  float* g    = (float*)(ws + 50331648);
  float* u    = (float*)(ws + 73400320);
  float* ct   = (float*)(ws + 96468992);
  float* st   = (float*)(ws + 96731136);
  float* rl   = (float*)(ws + 96993280);
  float* wmoe = (float*)(ws + 97058816);
  float* aux  = (float*)(ws + 97124352);
  int*   cnt  = (int*)  (ws + 97124608);
  int*   list = (int*)  (ws + 97124864);
  int*   tokp = (int*)  (ws + 97190400);
  int*   off8 = (int*)  (ws + 97206784);
  __bf16* wqh = (__bf16*)(ws + 97320960);
  __bf16* wql = (__bf16*)(ws + 105709568);
  __bf16* wkh = (__bf16*)(ws + 114098176);
  __bf16* wkl = (__bf16*)(ws + 122486784);
  __bf16* wvh = (__bf16*)(ws + 130875392);
  __bf16* wvl = (__bf16*)(ws + 139264000);
  __bf16* woh = (__bf16*)(ws + 147652608);
  __bf16* wol = (__bf16*)(ws + 156041216);
  __bf16* dgh = (__bf16*)(ws + 164429824);
  __bf16* dgl = (__bf16*)(ws + 181731328);
  __bf16* duh = (__bf16*)(ws + 199032832);
  __bf16* dul = (__bf16*)(ws + 216334336);
  __bf16* ddh = (__bf16*)(ws + 233635840);
  __bf16* ddl = (__bf16*)(ws + 250937344);
  __bf16* eh  = (__bf16*)(ws + 268238848);
  __bf16* hnh = (__bf16*)(ws + 333774848);
  __bf16* hnl = (__bf16*)(ws + 337969152);
  __bf16* gh  = (__bf16*)(ws + 342163456);
  __bf16* gl  = (__bf16*)(ws + 353697792);
  __bf16* mgh = (__bf16*)(ws + 365232128);
  __bf16* muh = (__bf16*)(ws + 411369472);
  __bf16* mdh = (__bf16*)(ws + 457506816);
  // end: 503,644,160 bytes
  __bf16* qh  = (__bf16*)g;
  __bf16* ql  = (__bf16*)((char*)g + 4194304);
  __bf16* kbh = (__bf16*)((char*)g + 8388608);
  __bf16* kbl = (__bf16*)((char*)g + 12582912);
  __bf16* vth = (__bf16*)u;
  __bf16* vtl = (__bf16*)((char*)u + 4194304);
  __bf16* a2  = (__bf16*)g;
  float*  y2  = u;

  wsplit_t_kernel<<<dim3(16, 16, 4), 256, 0, stream>>>(wq, wqh, wql, HID, HID);
  wsplit_t_kernel<<<dim3(16, 16, 4), 256, 0, stream>>>(wk, wkh, wkl, HID, HID);
  wsplit_t_kernel<<<dim3(16, 16, 4), 256, 0, stream>>>(wv, wvh, wvl, HID, HID);
  wsplit_t_kernel<<<dim3(16, 16, 4), 256, 0, stream>>>(wo, woh, wol, HID, HID);
  wsplit_t_kernel<<<dim3(44, 16, 3), 256, 0, stream>>>(dg, dgh, dgl, HID, IDIM);
  wsplit_t_kernel<<<dim3(44, 16, 3), 256, 0, stream>>>(du, duh, dul, HID, IDIM);
  wsplit_t_kernel<<<dim3(16, 44, 3), 256, 0, stream>>>(dd, ddh, ddl, IDIM, HID);
  wsplit_th_kernel<<<dim3(44, 16, 8), 256, 0, stream>>>(mg, mgh, HID, IDIM);
  wsplit_th_kernel<<<dim3(44, 16, 8), 256, 0, stream>>>(mu, muh, HID, IDIM);
  wsplit_th_kernel<<<dim3(16, 44, 8), 256, 0, stream>>>(md, mdh, IDIM, HID);
  esplit_kernel<<<16000, 256, 0, stream>>>(embed, eh);

  tables_kernel<<<256, 256, 0, stream>>>(ct, st);
  embed_kernel<<<SEQ, 256, 0, stream>>>(ids, embed, h);

  for (int li = 0; li < 4; ++li) {
    const bool comp = (li <= 2);
    rmsnorm_kernel<<<SEQ, 256, 0, stream>>>(h, ln1 + li * HID, hn, hnh, hnl);
    size_t wofs = (size_t)li * HID * HID;
    if (comp)
      gemm_bt_kernel<true, false, false, 64><<<dim3(8, 32, 3), 256, 0, stream>>>(
          hnh, hnl, wqh + wofs, wql + wofs, wkh + wofs, wkl + wofs,
          wvh + wofs, wvl + wofs, q, k, v, SEQ, HID, HID);
    else
      gemm_bt_kernel<false, false, false, 64><<<dim3(8, 32, 3), 256, 0, stream>>>(
          hnh, hnh, wqh + wofs, wqh + wofs, wkh + wofs, wkh + wofs,
          wvh + wofs, wvh + wofs, q, k, v, SEQ, HID, HID);

    rope_split_kernel<<<4096, 256, 0, stream>>>(q, k, qh, ql, kbh, kbl, ct, st);
    vtsplit_kernel<<<dim3(32, 16), 256, 0, stream>>>(v, vth, vtl);

    attn_flash_kernel<<<dim3(32, 16), 256, 0, stream>>>(
        qh, ql, kbh, kbl, vth, vtl, oh, ol);

    if (comp)
      gemm_bt_kernel<true, true, false, 64><<<dim3(8, 32, 1), 256, 0, stream>>>(
          oh, ol, woh + wofs, wol + wofs, woh + wofs, wol + wofs,
          woh + wofs, wol + wofs, h, h, h, SEQ, HID, HID);
    else
      gemm_bt_kernel<false, true, false, 64><<<dim3(8, 32, 1), 256, 0, stream>>>(
          oh, oh, woh + wofs, woh + wofs, woh + wofs, woh + wofs,
          woh + wofs, woh + wofs, h, h, h, SEQ, HID, HID);

    rmsnorm_kernel<<<SEQ, 256, 0, stream>>>(h, ln2 + li * HID, hn, hnh, hnl);
    if (li == 2) {
      router_kernel<<<512, 256, 0, stream>>>(hn, rw, rl);
      zero_kernel<<<1, 32, 0, stream>>>(aux, 17);
      topk_kernel<<<8, 256, 0, stream>>>(rl, wmoe, aux);
      aux_kernel<<<1, 1, 0, stream>>>(aux, out);
      zeroi_kernel<<<1, 32, 0, stream>>>(cnt, 8);
      build_list_kernel<<<8, 256, 0, stream>>>(wmoe, cnt, list, tokp);
      prefix_kernel<<<1, 64, 0, stream>>>(cnt, off8);
      gemm_moe_guf_kernel<<<dim3(44, 16, 8), 256, 0, stream>>>(
          hnh, mgh, muh, a2, wmoe, list, cnt, off8);
      gemm_moe_down2_kernel<<<dim3(16, 16, 8), 256, 0, stream>>>(
          a2, mdh, y2, cnt, off8);
      moe_scatter_kernel<<<SEQ, 256, 0, stream>>>(tokp, off8, y2, h);
    } else {
      int d = (li < 2) ? li : li - 1;
      size_t go = (size_t)d * HID * IDIM;
      if (comp) {
        gemm_bt_kernel<true, false, false, 128><<<dim3(22, 16, 2), 256, 0, stream>>>(
            hnh, hnl, dgh + go, dgl + go, duh + go, dul + go,
            duh + go, dul + go, g, u, u, SEQ, IDIM, HID);
        silu_kernel<<<dim3(11, SEQ), 256, 0, stream>>>(g, u, gh, gl);
        gemm_bt_kernel<true, true, false, 64><<<dim3(8, 32, 1), 256, 0, stream>>>(
            gh, gl, ddh + go, ddl + go, ddh + go, ddl + go,
            ddh + go, ddl + go, h, h, h, SEQ, HID, IDIM);
      } else {
        gemm_bt_kernel<false, false, false, 128><<<dim3(22, 16, 2), 256, 0, stream>>>(
            hnh, hnh, dgh + go, dgh + go, duh + go, duh + go,
            duh + go, duh + go, g, u, u, SEQ, IDIM, HID);
        silu_kernel<<<dim3(11, SEQ), 256, 0, stream>>>(g, u, gh, gl);
        gemm_bt_kernel<false, true, false, 64><<<dim3(8, 32, 1), 256, 0, stream>>>(
            gh, gh, ddh + go, ddh + go, ddh + go, ddh + go,
            ddh + go, ddh + go, h, h, h, SEQ, HID, IDIM);
      }
    }
  }
  rmsnorm_kernel<<<SEQ, 256, 0, stream>>>(h, fin, hn, hnh, hnl);
  gemm_bt_kernel<false, false, true, 128><<<dim3(16, 250, 1), 256, 0, stream>>>(
      hnh, hnh, eh, eh, eh, eh, eh, eh, out, out, out, SEQ, VOCAB, HID);
}

// Round 15
// 2048.583 us; speedup vs baseline: 1.1281x; 1.0003x over previous
//
#include <hip/hip_runtime.h>
#include <hip/hip_bf16.h>
#include <math.h>

#define SEQ 2048
#define HID 1024
#define NHEAD 16
#define HDIM 64
#define IDIM 2816
#define NEXP 8
#define VOCAB 32000

#define ASTRIDE 144  // padded rows (attention)

typedef float f32x4v __attribute__((ext_vector_type(4)));
typedef __bf16 bf16x8v __attribute__((ext_vector_type(8)));
typedef __bf16 bf16x4v __attribute__((ext_vector_type(4)));

__device__ __forceinline__ bf16x8v cvt8(const float4& a, const float4& b) {
  bf16x8v r;
  r[0] = (__bf16)a.x; r[1] = (__bf16)a.y; r[2] = (__bf16)a.z; r[3] = (__bf16)a.w;
  r[4] = (__bf16)b.x; r[5] = (__bf16)b.y; r[6] = (__bf16)b.z; r[7] = (__bf16)b.w;
  return r;
}

#define MFMA(a, b, c) __builtin_amdgcn_mfma_f32_16x16x32_bf16(a, b, c, 0, 0, 0)

// async global->LDS DMA, 16B per lane; lds base must be wave-uniform
__device__ __forceinline__ void gld_lds16(const void* g, void* l) {
  __builtin_amdgcn_global_load_lds(
      (const __attribute__((address_space(1))) unsigned int*)(unsigned long long)g,
      (__attribute__((address_space(3))) unsigned int*)(unsigned int)(unsigned long long)l,
      16, 0, 0);
}

// ---------------------------------------------------------------------------
// Weight preprocessing: W[K,N] f32 -> WH,WL [N,K] bf16 (transposed hi/lo).
// ---------------------------------------------------------------------------
__global__ __launch_bounds__(256) void wsplit_t_kernel(
    const float* __restrict__ W, __bf16* __restrict__ WH, __bf16* __restrict__ WL,
    int K, int N)
{
  __shared__ float tile[64][65];
  const int tid = threadIdx.x;
  const size_t zofs = (size_t)blockIdx.z * K * N;
  const int n0 = blockIdx.x * 64, k0 = blockIdx.y * 64;
#pragma unroll
  for (int r = 0; r < 4; ++r) {
    int kk = (tid >> 4) + r * 16;
    int nn = (tid & 15) * 4;
    float4 v = *(const float4*)(W + zofs + (size_t)(k0 + kk) * N + n0 + nn);
    tile[kk][nn] = v.x; tile[kk][nn + 1] = v.y;
    tile[kk][nn + 2] = v.z; tile[kk][nn + 3] = v.w;
  }
  __syncthreads();
  const int nn = tid >> 2;
  const int kk = (tid & 3) * 16;
  __bf16* dh = WH + zofs + (size_t)(n0 + nn) * K + k0 + kk;
  __bf16* dl = WL + zofs + (size_t)(n0 + nn) * K + k0 + kk;
  bf16x8v h0, l0, h1, l1;
#pragma unroll
  for (int j = 0; j < 8; ++j) {
    float f = tile[kk + j][nn];
    __bf16 hb = (__bf16)f; h0[j] = hb; l0[j] = (__bf16)(f - (float)hb);
    f = tile[kk + 8 + j][nn];
    hb = (__bf16)f; h1[j] = hb; l1[j] = (__bf16)(f - (float)hb);
  }
  *(bf16x8v*)dh = h0; *(bf16x8v*)(dh + 8) = h1;
  *(bf16x8v*)dl = l0; *(bf16x8v*)(dl + 8) = l1;
}

// hi-only variant (MoE weights; plain-bf16 path needs no lo)
__global__ __launch_bounds__(256) void wsplit_th_kernel(
    const float* __restrict__ W, __bf16* __restrict__ WH, int K, int N)
{
  __shared__ float tile[64][65];
  const int tid = threadIdx.x;
  const size_t zofs = (size_t)blockIdx.z * K * N;
  const int n0 = blockIdx.x * 64, k0 = blockIdx.y * 64;
#pragma unroll
  for (int r = 0; r < 4; ++r) {
    int kk = (tid >> 4) + r * 16;
    int nn = (tid & 15) * 4;
    float4 v = *(const float4*)(W + zofs + (size_t)(k0 + kk) * N + n0 + nn);
    tile[kk][nn] = v.x; tile[kk][nn + 1] = v.y;
    tile[kk][nn + 2] = v.z; tile[kk][nn + 3] = v.w;
  }
  __syncthreads();
  const int nn = tid >> 2;
  const int kk = (tid & 3) * 16;
  __bf16* dh = WH + zofs + (size_t)(n0 + nn) * K + k0 + kk;
  bf16x8v h0, h1;
#pragma unroll
  for (int j = 0; j < 8; ++j) {
    h0[j] = (__bf16)tile[kk + j][nn];
    h1[j] = (__bf16)tile[kk + 8 + j][nn];
  }
  *(bf16x8v*)dh = h0; *(bf16x8v*)(dh + 8) = h1;
}

__global__ __launch_bounds__(256) void esplit_kernel(
    const float* __restrict__ E, __bf16* __restrict__ EH)
{
  size_t i = ((size_t)blockIdx.x * 256 + threadIdx.x) * 8;
  float4 a = *(const float4*)(E + i);
  float4 b = *(const float4*)(E + i + 4);
  *(bf16x8v*)(EH + i) = cvt8(a, b);
}

// ---------------------------------------------------------------------------
// Unified BT GEMM. A,B pre-split bf16. Staging = global_load_lds DMA (16B),
// LINEAR LDS rows (64B/row). XSWZ: XCD-aware bijective 1D grid (logits).
// ---------------------------------------------------------------------------
template<bool COMP, bool ACCUM, bool SWAP, int BM, bool XSWZ>
__global__ __launch_bounds__(256) void gemm_bt_kernel(
    const __bf16* __restrict__ Ah, const __bf16* __restrict__ Al,
    const __bf16* __restrict__ B0h, const __bf16* __restrict__ B0l,
    const __bf16* __restrict__ B1h, const __bf16* __restrict__ B1l,
    const __bf16* __restrict__ B2h, const __bf16* __restrict__ B2l,
    float* __restrict__ C0, float* __restrict__ C1, float* __restrict__ C2,
    int M, int N, int Kd)
{
  const __bf16* __restrict__ Bh = (blockIdx.z == 0) ? B0h : (blockIdx.z == 1 ? B1h : B2h);
  const __bf16* __restrict__ Bl = (blockIdx.z == 0) ? B0l : (blockIdx.z == 1 ? B1l : B2l);
  float* __restrict__ C         = (blockIdx.z == 0) ? C0 : (blockIdx.z == 1 ? C1 : C2);
  constexpr int ATILE = BM * 64;
  constexpr int BTILE = 128 * 64;
  constexpr int MFR = BM / 32;
  __shared__ __align__(16) char smem[COMP ? 2 * (ATILE + BTILE) : (ATILE + BTILE)];
  char* AsH = smem;
  char* BsH = smem + ATILE;
  char* AsL = COMP ? smem + ATILE + BTILE : smem;
  char* BsL = COMP ? smem + 2 * ATILE + BTILE : smem + ATILE;
  const int tid = threadIdx.x;
  int bm, bn;
  if (XSWZ) {
    // XCD-aware: 16 bm-blocks of one B panel land on one XCD, consecutively.
    int id = blockIdx.x;            // padded grid (e.g. 4096)
    int xcd = id & 7;
    int j = id >> 3;
    bm = j & 15;
    bn = xcd * 32 + (j >> 4);
    if (bn >= N / 128) return;
  } else {
    bm = SWAP ? blockIdx.x : blockIdx.y;
    bn = SWAP ? blockIdx.y : blockIdx.x;
  }
  const int wid = tid >> 6, lane = tid & 63;
  const int wm = (wid >> 1) * (BM / 2), wn = (wid & 1) << 6;
  const int lr = lane & 15, kh = lane >> 4;
  const int lrow = lane >> 2;
  const int lcol = (lane & 3) << 3;

  f32x4v acc[MFR][4];
  const f32x4v z4 = {0.f, 0.f, 0.f, 0.f};
#pragma unroll
  for (int i = 0; i < MFR; ++i)
#pragma unroll
    for (int j2 = 0; j2 < 4; ++j2) acc[i][j2] = z4;

  for (int k0 = 0; k0 < Kd; k0 += 32) {
    __syncthreads();
#pragma unroll
    for (int c = wid; c < BM / 16; c += 4) {
      size_t gofs = (size_t)(bm * BM + c * 16 + lrow) * Kd + k0 + lcol;
      gld_lds16(Ah + gofs, AsH + c * 1024);
      if (COMP) gld_lds16(Al + gofs, AsL + c * 1024);
    }
#pragma unroll
    for (int c = wid; c < 8; c += 4) {
      size_t gofs = (size_t)(bn * 128 + c * 16 + lrow) * Kd + k0 + lcol;
      gld_lds16(Bh + gofs, BsH + c * 1024);
      if (COMP) gld_lds16(Bl + gofs, BsL + c * 1024);
    }
    __syncthreads();

    bf16x8v ah[MFR], al[MFR], bh4[4], bl4[4];
#pragma unroll
    for (int i = 0; i < MFR; ++i) {
      int r = wm + (i << 4) + lr;
      int off = r * 64 + (kh << 4);
      ah[i] = *(const bf16x8v*)(AsH + off);
      if (COMP) al[i] = *(const bf16x8v*)(AsL + off);
    }
#pragma unroll
    for (int i = 0; i < 4; ++i) {
      int r = wn + (i << 4) + lr;
      int off = r * 64 + (kh << 4);
      bh4[i] = *(const bf16x8v*)(BsH + off);
      if (COMP) bl4[i] = *(const bf16x8v*)(BsL + off);
    }
#pragma unroll
    for (int mi = 0; mi < MFR; ++mi)
#pragma unroll
      for (int ni = 0; ni < 4; ++ni) {
        if (COMP) {
          acc[mi][ni] = MFMA(al[mi], bh4[ni], acc[mi][ni]);
          acc[mi][ni] = MFMA(ah[mi], bl4[ni], acc[mi][ni]);
        }
        acc[mi][ni] = MFMA(ah[mi], bh4[ni], acc[mi][ni]);
      }
  }

  const int cr0 = kh << 2;
#pragma unroll
  for (int mi = 0; mi < MFR; ++mi)
#pragma unroll
    for (int ni = 0; ni < 4; ++ni)
#pragma unroll
      for (int r = 0; r < 4; ++r) {
        int row = bm * BM + wm + (mi << 4) + cr0 + r;
        int col = bn * 128 + wn + (ni << 4) + lr;
        size_t idx = (size_t)row * N + col;
        if (ACCUM) C[idx] += acc[mi][ni][r];
        else       C[idx] = acc[mi][ni][r];
      }
}

// ---------------------------------------------------------------------------
// rope + hi/lo split for Q (scale 1/8) and K
// ---------------------------------------------------------------------------
__global__ __launch_bounds__(256) void rope_split_kernel(
    const float* __restrict__ Q, const float* __restrict__ K,
    __bf16* __restrict__ QH, __bf16* __restrict__ QL,
    __bf16* __restrict__ KH, __bf16* __restrict__ KL,
    const float* __restrict__ CT, const float* __restrict__ ST)
{
  int idx = blockIdx.x * 256 + threadIdx.x;
  int s = idx >> 9;
  int rr = idx & 511;
  int hd = rr >> 5;
  int i = rr & 31;
  float c = CT[(s << 5) + i], sn = ST[(s << 5) + i];
  size_t base = (size_t)s * HID + hd * 64 + i;
  {
    float x1 = Q[base], x2 = Q[base + 32];
    float o1 = (x1 * c - x2 * sn) * 0.125f;
    float o2 = (x2 * c + x1 * sn) * 0.125f;
    __bf16 h1 = (__bf16)o1, h2 = (__bf16)o2;
    QH[base] = h1;      QL[base] = (__bf16)(o1 - (float)h1);
    QH[base + 32] = h2; QL[base + 32] = (__bf16)(o2 - (float)h2);
  }
  {
    float x1 = K[base], x2 = K[base + 32];
    float o1 = x1 * c - x2 * sn;
    float o2 = x2 * c + x1 * sn;
    __bf16 h1 = (__bf16)o1, h2 = (__bf16)o2;
    KH[base] = h1;      KL[base] = (__bf16)(o1 - (float)h1);
    KH[base + 32] = h2; KL[base + 32] = (__bf16)(o2 - (float)h2);
  }
}

// V f32 [S][HID] -> per-head transposed hi/lo bf16 [NHEAD][HDIM][SEQ]
__global__ __launch_bounds__(256) void vtsplit_kernel(
    const float* __restrict__ V, __bf16* __restrict__ VTH, __bf16* __restrict__ VTL)
{
  __shared__ float tile[64][65];
  const int tid = threadIdx.x;
  const int s0 = blockIdx.x * 64;
  const int head = blockIdx.y;
#pragma unroll
  for (int r = 0; r < 4; ++r) {
    int ss = (tid >> 4) + r * 16;
    int dd = (tid & 15) * 4;
    float4 v = *(const float4*)(V + (size_t)(s0 + ss) * HID + head * 64 + dd);
    tile[ss][dd] = v.x; tile[ss][dd + 1] = v.y;
    tile[ss][dd + 2] = v.z; tile[ss][dd + 3] = v.w;
  }
  __syncthreads();
#pragma unroll
  for (int half = 0; half < 2; ++half) {
    const int d = (tid >> 3) + (half << 5);
    const int c = tid & 7;
    bf16x8v hv, lv;
#pragma unroll
    for (int j = 0; j < 8; ++j) {
      float f = tile[c * 8 + j][d];
      __bf16 hb = (__bf16)f;
      hv[j] = hb; lv[j] = (__bf16)(f - (float)hb);
    }
    size_t dst = (size_t)(head * 64 + d) * SEQ + s0 + c * 8;
    *(bf16x8v*)(VTH + dst) = hv;
    *(bf16x8v*)(VTL + dst) = lv;
  }
}

// ---------------------------------------------------------------------------
// Compensated flash attention; padded LDS; O -> bf16 hi/lo
// ---------------------------------------------------------------------------
__global__ __launch_bounds__(256) void attn_flash_kernel(
    const __bf16* __restrict__ QH, const __bf16* __restrict__ QL,
    const __bf16* __restrict__ KH, const __bf16* __restrict__ KL,
    const __bf16* __restrict__ VTH, const __bf16* __restrict__ VTL,
    __bf16* __restrict__ OH, __bf16* __restrict__ OL)
{
  const int qt = blockIdx.x;
  const int head = blockIdx.y;
  const int tid = threadIdx.x, wid = tid >> 6, lane = tid & 63;
  const int lr = lane & 15, kh = lane >> 4;
  __shared__ __align__(16) char KsH[64 * ASTRIDE], KsL[64 * ASTRIDE];
  __shared__ __align__(16) char VtH[64 * ASTRIDE], VtL[64 * ASTRIDE];
  __shared__ __align__(16) char PsH[4][16 * ASTRIDE], PsL[4][16 * ASTRIDE];

  const size_t qofs = (size_t)(qt * 64 + wid * 16 + lr) * HID + head * HDIM;
  const bf16x8v qfh0 = *(const bf16x8v*)(QH + qofs + (kh << 3));
  const bf16x8v qfh1 = *(const bf16x8v*)(QH + qofs + 32 + (kh << 3));
  const bf16x8v qfl0 = *(const bf16x8v*)(QL + qofs + (kh << 3));
  const bf16x8v qfl1 = *(const bf16x8v*)(QL + qofs + 32 + (kh << 3));

  float m_run[4], l_run[4];
  f32x4v oacc[4];
  const f32x4v z4 = {0.f, 0.f, 0.f, 0.f};
#pragma unroll
  for (int i = 0; i < 4; ++i) { m_run[i] = -1e30f; l_run[i] = 0.f; oacc[i] = z4; }

  for (int kt = 0; kt <= qt; ++kt) {
    __syncthreads();
#pragma unroll
    for (int p = 0; p < 2; ++p) {
      int g = tid + (p << 8);
      int r = g >> 3;
      int c = g & 7;
      int off = r * ASTRIDE + (c << 4);
      const size_t kofs = (size_t)(kt * 64 + r) * HID + head * HDIM + (c << 3);
      *(bf16x8v*)(KsH + off) = *(const bf16x8v*)(KH + kofs);
      *(bf16x8v*)(KsL + off) = *(const bf16x8v*)(KL + kofs);
      const size_t vofs = (size_t)(head * 64 + r) * SEQ + kt * 64 + (c << 3);
      *(bf16x8v*)(VtH + off) = *(const bf16x8v*)(VTH + vofs);
      *(bf16x8v*)(VtL + off) = *(const bf16x8v*)(VTL + vofs);
    }
    __syncthreads();

    float sv[4][4];
#pragma unroll
    for (int stt = 0; stt < 4; ++stt) {
      int r = (stt << 4) + lr;
      int off0 = r * ASTRIDE + (kh << 4);
      int off1 = off0 + 64;
      bf16x8v kfh0 = *(const bf16x8v*)(KsH + off0);
      bf16x8v kfl0 = *(const bf16x8v*)(KsL + off0);
      bf16x8v kfh1 = *(const bf16x8v*)(KsH + off1);
      bf16x8v kfl1 = *(const bf16x8v*)(KsL + off1);
      f32x4v s = z4;
      s = MFMA(qfl0, kfh0, s);
      s = MFMA(qfh0, kfl0, s);
      s = MFMA(qfh0, kfh0, s);
      s = MFMA(qfl1, kfh1, s);
      s = MFMA(qfh1, kfl1, s);
      s = MFMA(qfh1, kfh1, s);
      int key = kt * 64 + (stt << 4) + lr;
#pragma unroll
      for (int rr = 0; rr < 4; ++rr) {
        int qr = qt * 64 + wid * 16 + (kh << 2) + rr;
        sv[stt][rr] = (key <= qr) ? s[rr] : -1e30f;
      }
    }

#pragma unroll
    for (int rr = 0; rr < 4; ++rr) {
      float mx = fmaxf(fmaxf(sv[0][rr], sv[1][rr]), fmaxf(sv[2][rr], sv[3][rr]));
#pragma unroll
      for (int d = 1; d < 16; d <<= 1) mx = fmaxf(mx, __shfl_xor(mx, d));
      float mnew = fmaxf(m_run[rr], mx);
      float scl = __expf(m_run[rr] - mnew);
      float pv[4];
#pragma unroll
      for (int stt = 0; stt < 4; ++stt) pv[stt] = __expf(sv[stt][rr] - mnew);
      float rs = pv[0] + pv[1] + pv[2] + pv[3];
#pragma unroll
      for (int d = 1; d < 16; d <<= 1) rs += __shfl_xor(rs, d);
      l_run[rr] = l_run[rr] * scl + rs;
      m_run[rr] = mnew;
#pragma unroll
      for (int n = 0; n < 4; ++n) oacc[n][rr] *= scl;
      int qlr = (kh << 2) + rr;
#pragma unroll
      for (int stt = 0; stt < 4; ++stt) {
        __bf16 hb = (__bf16)pv[stt];
        __bf16 lb = (__bf16)(pv[stt] - (float)hb);
        int off = qlr * ASTRIDE + (((stt << 4) + lr) << 1);
        *(__bf16*)(PsH[wid] + off) = hb;
        *(__bf16*)(PsL[wid] + off) = lb;
      }
    }

    int poff0 = lr * ASTRIDE + (kh << 4);
    int poff1 = poff0 + 64;
    bf16x8v pah0 = *(const bf16x8v*)(PsH[wid] + poff0);
    bf16x8v pal0 = *(const bf16x8v*)(PsL[wid] + poff0);
    bf16x8v pah1 = *(const bf16x8v*)(PsH[wid] + poff1);
    bf16x8v pal1 = *(const bf16x8v*)(PsL[wid] + poff1);
#pragma unroll
    for (int n = 0; n < 4; ++n) {
      int vr = (n << 4) + lr;
      int voff0 = vr * ASTRIDE + (kh << 4);
      int voff1 = voff0 + 64;
      bf16x8v vfh0 = *(const bf16x8v*)(VtH + voff0);
      bf16x8v vfl0 = *(const bf16x8v*)(VtL + voff0);
      bf16x8v vfh1 = *(const bf16x8v*)(VtH + voff1);
      bf16x8v vfl1 = *(const bf16x8v*)(VtL + voff1);
      oacc[n] = MFMA(pal0, vfh0, oacc[n]);
      oacc[n] = MFMA(pah0, vfl0, oacc[n]);
      oacc[n] = MFMA(pah0, vfh0, oacc[n]);
      oacc[n] = MFMA(pal1, vfh1, oacc[n]);
      oacc[n] = MFMA(pah1, vfl1, oacc[n]);
      oacc[n] = MFMA(pah1, vfh1, oacc[n]);
    }
  }

#pragma unroll
  for (int n = 0; n < 4; ++n)
#pragma unroll
    for (int rr = 0; rr < 4; ++rr) {
      int qr = qt * 64 + wid * 16 + (kh << 2) + rr;
      size_t ofs = (size_t)qr * HID + head * HDIM + (n << 4) + lr;
      float val = oacc[n][rr] / l_run[rr];
      __bf16 hb = (__bf16)val;
      OH[ofs] = hb;
      OL[ofs] = (__bf16)(val - (float)hb);
    }
}

// ---------------------------------------------------------------------------
// MoE: fused gate+up+silu. BM=128, BN=64. DMA staging, pre-split weights.
// ---------------------------------------------------------------------------
__global__ __launch_bounds__(256) void gemm_moe_guf_kernel(
    const __bf16* __restrict__ Xh,
    const __bf16* __restrict__ MGH, const __bf16* __restrict__ MUH,
    __bf16* __restrict__ A2, const float* __restrict__ W,
    const int* __restrict__ list, const int* __restrict__ cnt8,
    const int* __restrict__ off8)
{
  const int e = blockIdx.z;
  const int cnt = cnt8[e];
  const int bn = blockIdx.x, bm = blockIdx.y;
  if (bm * 128 >= cnt) return;
  const int base = off8[e];
  __shared__ __align__(16) char AsB[8192];
  __shared__ __align__(16) char BgB[4096];
  __shared__ __align__(16) char BuB[4096];
  const int tid = threadIdx.x;
  const int wid = tid >> 6, lane = tid & 63;
  const int wm = (wid >> 1) << 6, wn = (wid & 1) << 5;
  const int lr = lane & 15, kh = lane >> 4;
  const int lrow = lane >> 2;
  const int lcol = (lane & 3) << 3;

  f32x4v accg[4][2], accu[4][2];
  const f32x4v z4 = {0.f, 0.f, 0.f, 0.f};
#pragma unroll
  for (int i = 0; i < 4; ++i)
#pragma unroll
    for (int j = 0; j < 2; ++j) { accg[i][j] = z4; accu[i][j] = z4; }

  for (int k0 = 0; k0 < HID; k0 += 32) {
    __syncthreads();
#pragma unroll
    for (int c = wid; c < 8; c += 4) {     // A: 128 rows
      int rg = bm * 128 + c * 16 + lrow;
      int tok = list[e * SEQ + (rg < cnt ? rg : cnt - 1)];
      gld_lds16(Xh + (size_t)tok * HID + k0 + lcol, AsB + c * 1024);
    }
    {                                       // B: 64 rows each (g,u)
      int c = wid;
      size_t wofs = (size_t)(e * IDIM + bn * 64 + c * 16 + lrow) * HID + k0 + lcol;
      gld_lds16(MGH + wofs, BgB + c * 1024);
      gld_lds16(MUH + wofs, BuB + c * 1024);
    }
    __syncthreads();

    bf16x8v af[4], bg4[2], bu4[2];
#pragma unroll
    for (int i = 0; i < 4; ++i) {
      int r = wm + (i << 4) + lr;
      af[i] = *(const bf16x8v*)(AsB + r * 64 + (kh << 4));
    }
#pragma unroll
    for (int i = 0; i < 2; ++i) {
      int r = wn + (i << 4) + lr;
      bg4[i] = *(const bf16x8v*)(BgB + r * 64 + (kh << 4));
      bu4[i] = *(const bf16x8v*)(BuB + r * 64 + (kh << 4));
    }
#pragma unroll
    for (int mi = 0; mi < 4; ++mi)
#pragma unroll
      for (int ni = 0; ni < 2; ++ni) {
        accg[mi][ni] = MFMA(af[mi], bg4[ni], accg[mi][ni]);
        accu[mi][ni] = MFMA(af[mi], bu4[ni], accu[mi][ni]);
      }
  }

  const int cr0 = kh << 2;
#pragma unroll
  for (int mi = 0; mi < 4; ++mi)
#pragma unroll
    for (int ni = 0; ni < 2; ++ni)
#pragma unroll
      for (int r = 0; r < 4; ++r) {
        int row = bm * 128 + wm + (mi << 4) + cr0 + r;
        if (row < cnt) {
          int col = bn * 64 + wn + (ni << 4) + lr;
          int tok = list[e * SEQ + row];
          float w = W[tok * 8 + e];
          float gval = accg[mi][ni][r];
          float uval = accu[mi][ni][r];
          float a = gval / (1.f + __expf(-gval)) * uval * w;
          A2[(size_t)(base + row) * IDIM + col] = (__bf16)a;
        }
      }
}

__global__ __launch_bounds__(256) void gemm_moe_down2_kernel(
    const __bf16* __restrict__ A2, const __bf16* __restrict__ MDH,
    float* __restrict__ Y2,
    const int* __restrict__ cnt8, const int* __restrict__ off8)
{
  const int e = blockIdx.z;
  const int cnt = cnt8[e];
  const int bn = blockIdx.x, bm = blockIdx.y;
  if (bm * 128 >= cnt) return;
  const int base = off8[e];
  __shared__ __align__(16) char AsB[8192];
  __shared__ __align__(16) char BsB[4096];
  const int tid = threadIdx.x;
  const int wid = tid >> 6, lane = tid & 63;
  const int wm = (wid >> 1) << 6, wn = (wid & 1) << 5;
  const int lr = lane & 15, kh = lane >> 4;
  const int lrow = lane >> 2;
  const int lcol = (lane & 3) << 3;

  f32x4v acc[4][2];
  const f32x4v z4 = {0.f, 0.f, 0.f, 0.f};
#pragma unroll
  for (int i = 0; i < 4; ++i)
#pragma unroll
    for (int j = 0; j < 2; ++j) acc[i][j] = z4;

  for (int k0 = 0; k0 < IDIM; k0 += 32) {
    __syncthreads();
#pragma unroll
    for (int c = wid; c < 8; c += 4) {
      int rg = bm * 128 + c * 16 + lrow;
      int row = (rg < cnt ? rg : cnt - 1);
      gld_lds16(A2 + (size_t)(base + row) * IDIM + k0 + lcol, AsB + c * 1024);
    }
    {
      int c = wid;
      gld_lds16(MDH + (size_t)(e * HID + bn * 64 + c * 16 + lrow) * IDIM + k0 + lcol,
                BsB + c * 1024);
    }
    __syncthreads();

    bf16x8v af[4], bfv[2];
#pragma unroll
    for (int i = 0; i < 4; ++i) {
      int r = wm + (i << 4) + lr;
      af[i] = *(const bf16x8v*)(AsB + r * 64 + (kh << 4));
    }
#pragma unroll
    for (int i = 0; i < 2; ++i) {
      int r = wn + (i << 4) + lr;
      bfv[i] = *(const bf16x8v*)(BsB + r * 64 + (kh << 4));
    }
#pragma unroll
    for (int mi = 0; mi < 4; ++mi)
#pragma unroll
      for (int ni = 0; ni < 2; ++ni)
        acc[mi][ni] = MFMA(af[mi], bfv[ni], acc[mi][ni]);
  }

  const int cr0 = kh << 2;
#pragma unroll
  for (int mi = 0; mi < 4; ++mi)
#pragma unroll
    for (int ni = 0; ni < 2; ++ni)
#pragma unroll
      for (int r = 0; r < 4; ++r) {
        int row = bm * 128 + wm + (mi << 4) + cr0 + r;
        if (row < cnt) {
          int col = bn * 64 + wn + (ni << 4) + lr;
          Y2[(size_t)(base + row) * HID + col] = acc[mi][ni][r];
        }
      }
}

// h[t] += y(e_lo) + y(e_hi)  (ascending-e order == old serial order)
__global__ __launch_bounds__(256) void moe_scatter_kernel(
    const int* __restrict__ tokpair, const int* __restrict__ off8,
    const float* __restrict__ Y2, float* __restrict__ H)
{
  const int t = blockIdx.x;
  const int i = threadIdx.x;
  int p0 = tokpair[t * 2], p1 = tokpair[t * 2 + 1];
  size_t r0 = off8[p0 >> 16] + (p0 & 0xffff);
  size_t r1 = off8[p1 >> 16] + (p1 & 0xffff);
  float4 a = ((const float4*)(Y2 + r0 * HID))[i];
  float4 b = ((const float4*)(Y2 + r1 * HID))[i];
  float4 hv = ((float4*)(H + (size_t)t * HID))[i];
  hv.x = (hv.x + a.x) + b.x;
  hv.y = (hv.y + a.y) + b.y;
  hv.z = (hv.z + a.z) + b.z;
  hv.w = (hv.w + a.w) + b.w;
  ((float4*)(H + (size_t)t * HID))[i] = hv;
}

// ---------------------------------------------------------------------------
// Small kernels
// ---------------------------------------------------------------------------
__global__ void tables_kernel(float* __restrict__ CT, float* __restrict__ ST)
{
  int idx = blockIdx.x * 256 + threadIdx.x;
  int s = idx >> 5, i = idx & 31;
  double inv = exp(-log(10000.0) * (double)i / 32.0);
  double ang = (double)s * inv;
  CT[idx] = (float)cos(ang);
  ST[idx] = (float)sin(ang);
}

__global__ __launch_bounds__(256) void embed_kernel(
    const int* __restrict__ ids, const float* __restrict__ E, float* __restrict__ H)
{
  int t = blockIdx.x;
  int id = ids[t];
  ((float4*)(H + (size_t)t * HID))[threadIdx.x] =
      ((const float4*)(E + (size_t)id * HID))[threadIdx.x];
}

__global__ __launch_bounds__(256) void rmsnorm_kernel(
    const float* __restrict__ X, const float* __restrict__ W,
    float* __restrict__ O, __bf16* __restrict__ OHb, __bf16* __restrict__ OLb)
{
  int t = blockIdx.x;
  int tid = threadIdx.x;
  float4 v = ((const float4*)(X + (size_t)t * HID))[tid];
  float ss = v.x * v.x + v.y * v.y + v.z * v.z + v.w * v.w;
#pragma unroll
  for (int d = 1; d < 64; d <<= 1) ss += __shfl_xor(ss, d);
  __shared__ float red[4];
  if ((tid & 63) == 0) red[tid >> 6] = ss;
  __syncthreads();
  float tot = red[0] + red[1] + red[2] + red[3];
  float inv = 1.0f / sqrtf(tot * (1.0f / 1024.0f) + 1e-6f);
  float4 w = ((const float4*)W)[tid];
  float4 r;
  r.x = v.x * inv * w.x; r.y = v.y * inv * w.y;
  r.z = v.z * inv * w.z; r.w = v.w * inv * w.w;
  ((float4*)(O + (size_t)t * HID))[tid] = r;
  float f[4] = {r.x, r.y, r.z, r.w};
  bf16x4v hv, lv;
#pragma unroll
  for (int j = 0; j < 4; ++j) {
    __bf16 hb = (__bf16)f[j];
    hv[j] = hb; lv[j] = (__bf16)(f[j] - (float)hb);
  }
  *(bf16x4v*)(OHb + (size_t)t * HID + tid * 4) = hv;
  *(bf16x4v*)(OLb + (size_t)t * HID + tid * 4) = lv;
}

__global__ __launch_bounds__(256) void silu_kernel(
    const float* __restrict__ G, const float* __restrict__ U,
    __bf16* __restrict__ AH, __bf16* __restrict__ AL)
{
  int t = blockIdx.y;
  int i = blockIdx.x * 256 + threadIdx.x;
  size_t idx = (size_t)t * IDIM + i;
  float gv = G[idx], uv = U[idx];
  float a = gv / (1.f + __expf(-gv)) * uv;
  __bf16 hb = (__bf16)a;
  AH[idx] = hb;
  AL[idx] = (__bf16)(a - (float)hb);
}

__global__ __launch_bounds__(256) void router_kernel(
    const float* __restrict__ X, const float* __restrict__ RW, float* __restrict__ RL)
{
  int wid = threadIdx.x >> 6, lane = threadIdx.x & 63;
  int t = blockIdx.x * 4 + wid;
  const float* x = X + (size_t)t * HID;
  float a0 = 0, a1 = 0, a2 = 0, a3 = 0, a4 = 0, a5 = 0, a6 = 0, a7 = 0;
  for (int hh = lane; hh < HID; hh += 64) {
    float xv = x[hh];
    float4 f0 = *(const float4*)(RW + hh * 8);
    float4 f1 = *(const float4*)(RW + hh * 8 + 4);
    a0 += xv * f0.x; a1 += xv * f0.y; a2 += xv * f0.z; a3 += xv * f0.w;
    a4 += xv * f1.x; a5 += xv * f1.y; a6 += xv * f1.z; a7 += xv * f1.w;
  }
#pragma unroll
  for (int d = 1; d < 64; d <<= 1) {
    a0 += __shfl_xor(a0, d); a1 += __shfl_xor(a1, d);
    a2 += __shfl_xor(a2, d); a3 += __shfl_xor(a3, d);
    a4 += __shfl_xor(a4, d); a5 += __shfl_xor(a5, d);
    a6 += __shfl_xor(a6, d); a7 += __shfl_xor(a7, d);
  }
  if (lane == 0) {
    float* dst = RL + (size_t)t * 8;
    dst[0] = a0; dst[1] = a1; dst[2] = a2; dst[3] = a3;
    dst[4] = a4; dst[5] = a5; dst[6] = a6; dst[7] = a7;
  }
}

__global__ void zero_kernel(float* __restrict__ p, int n)
{
  int i = threadIdx.x;
  if (i < n) p[i] = 0.f;
}

__global__ void zeroi_kernel(int* __restrict__ p, int n)
{
  int i = threadIdx.x;
  if (i < n) p[i] = 0;
}

__global__ __launch_bounds__(256) void topk_kernel(
    const float* __restrict__ RL, float* __restrict__ W, float* __restrict__ AUX)
{
  int t = blockIdx.x * 256 + threadIdx.x;
  int lane = threadIdx.x & 63;
  float r[8];
#pragma unroll
  for (int e = 0; e < 8; ++e) r[e] = RL[t * 8 + e];
  float mx = r[0];
#pragma unroll
  for (int e = 1; e < 8; ++e) mx = fmaxf(mx, r[e]);
  float p[8];
  float se = 0.f;
#pragma unroll
  for (int e = 0; e < 8; ++e) { p[e] = __expf(r[e] - mx); se += p[e]; }
  float inv = 1.f / se;
#pragma unroll
  for (int e = 0; e < 8; ++e) p[e] *= inv;
  float lse = logf(se) + mx;
  int i1 = 0; float v1 = p[0];
#pragma unroll
  for (int e = 1; e < 8; ++e) if (p[e] > v1) { v1 = p[e]; i1 = e; }
  int i2 = -1; float v2 = -1.f;
#pragma unroll
  for (int e = 0; e < 8; ++e) if (e != i1 && p[e] > v2) { v2 = p[e]; i2 = e; }
  float s12 = v1 + v2;
#pragma unroll
  for (int e = 0; e < 8; ++e)
    W[t * 8 + e] = (e == i1) ? v1 / s12 : ((e == i2) ? v2 / s12 : 0.f);
#pragma unroll
  for (int e = 0; e < 8; ++e) {
    float fe = ((i1 == e) ? 1.f : 0.f) + ((i2 == e) ? 1.f : 0.f);
    float pe = p[e];
#pragma unroll
    for (int d = 1; d < 64; d <<= 1) { fe += __shfl_xor(fe, d); pe += __shfl_xor(pe, d); }
    if (lane == 0) { atomicAdd(&AUX[e], fe); atomicAdd(&AUX[8 + e], pe); }
  }
  float zz = lse * lse;
#pragma unroll
  for (int d = 1; d < 64; d <<= 1) zz += __shfl_xor(zz, d);
  if (lane == 0) atomicAdd(&AUX[16], zz);
}

__global__ void aux_kernel(const float* __restrict__ AUX, float* __restrict__ OUT)
{
  float s = 0.f;
#pragma unroll
  for (int e = 0; e < 8; ++e)
    s += (AUX[e] * (1.f / 2048.f)) * (AUX[8 + e] * (1.f / 2048.f));
  float auxv = 0.01f * 8.f * s;
  float z = 0.001f * (AUX[16] * (1.f / 2048.f));
  OUT[(size_t)SEQ * VOCAB] = auxv + z;
}

// records per-token (expert, pos) pairs in ascending-e order
__global__ __launch_bounds__(256) void build_list_kernel(
    const float* __restrict__ W, int* __restrict__ cnt, int* __restrict__ list,
    int* __restrict__ tokpair)
{
  int t = blockIdx.x * 256 + threadIdx.x;
  int j = 0;
#pragma unroll
  for (int e = 0; e < 8; ++e) {
    if (W[t * 8 + e] > 0.f) {
      int p = atomicAdd(&cnt[e], 1);
      list[e * SEQ + p] = t;
      tokpair[t * 2 + j] = (e << 16) | p;
      ++j;
    }
  }
}

__global__ void prefix_kernel(const int* __restrict__ cnt, int* __restrict__ off)
{
  if (threadIdx.x == 0) {
    int s = 0;
    for (int e = 0; e < 8; ++e) { off[e] = s; s += cnt[e]; }
  }
}

// ---------------------------------------------------------------------------
extern "C" void kernel_launch(void* const* d_in, const int* in_sizes, int n_in,
                              void* d_out, int out_size, void* d_ws, size_t ws_size,
                              hipStream_t stream)
{
  const int*   ids   = (const int*)d_in[0];
  const float* embed = (const float*)d_in[1];
  const float* ln1   = (const float*)d_in[2];
  const float* ln2   = (const float*)d_in[3];
  const float* wq    = (const float*)d_in[4];
  const float* wk    = (const float*)d_in[5];
  const float* wv    = (const float*)d_in[6];
  const float* wo    = (const float*)d_in[7];
  const float* dg    = (const float*)d_in[8];
  const float* du    = (const float*)d_in[9];
  const float* dd    = (const float*)d_in[10];
  const float* rw    = (const float*)d_in[11];
  const float* mg    = (const float*)d_in[12];
  const float* mu    = (const float*)d_in[13];
  const float* md    = (const float*)d_in[14];
  const float* fin   = (const float*)d_in[15];
  float* out = (float*)d_out;

  char* ws = (char*)d_ws;
  float* h    = (float*)(ws + 0);
  float* hn   = (float*)(ws + 8388608);
  float* q    = (float*)(ws + 16777216);
  float* k    = (float*)(ws + 25165824);
  float* v    = (float*)(ws + 33554432);
  __bf16* oh  = (__bf16*)(ws + 41943040);
  __bf16* ol  = (__bf16*)(ws + 46137344);
  float* g    = (float*)(ws + 50331648);
  float* u    = (float*)(ws + 73400320);
  float* ct   = (float*)(ws + 96468992);
  float* st   = (float*)(ws + 96731136);
  float* rl   = (float*)(ws + 96993280);
  float* wmoe = (float*)(ws + 97058816);
  float* aux  = (float*)(ws + 97124352);
  int*   cnt  = (int*)  (ws + 97124608);
  int*   list = (int*)  (ws + 97124864);
  int*   tokp = (int*)  (ws + 97190400);
  int*   off8 = (int*)  (ws + 97206784);
  __bf16* wqh = (__bf16*)(ws + 97320960);
  __bf16* wql = (__bf16*)(ws + 105709568);
  __bf16* wkh = (__bf16*)(ws + 114098176);
  __bf16* wkl = (__bf16*)(ws + 122486784);
  __bf16* wvh = (__bf16*)(ws + 130875392);
  __bf16* wvl = (__bf16*)(ws + 139264000);
  __bf16* woh = (__bf16*)(ws + 147652608);
  __bf16* wol = (__bf16*)(ws + 156041216);
  __bf16* dgh = (__bf16*)(ws + 164429824);
  __bf16* dgl = (__bf16*)(ws + 181731328);
  __bf16* duh = (__bf16*)(ws + 199032832);
  __bf16* dul = (__bf16*)(ws + 216334336);
  __bf16* ddh = (__bf16*)(ws + 233635840);
  __bf16* ddl = (__bf16*)(ws + 250937344);
  __bf16* eh  = (__bf16*)(ws + 268238848);
  __bf16* hnh = (__bf16*)(ws + 333774848);
  __bf16* hnl = (__bf16*)(ws + 337969152);
  __bf16* gh  = (__bf16*)(ws + 342163456);
  __bf16* gl  = (__bf16*)(ws + 353697792);
  __bf16* mgh = (__bf16*)(ws + 365232128);
  __bf16* muh = (__bf16*)(ws + 411369472);
  __bf16* mdh = (__bf16*)(ws + 457506816);
  // end: 503,644,160 bytes
  __bf16* qh  = (__bf16*)g;
  __bf16* ql  = (__bf16*)((char*)g + 4194304);
  __bf16* kbh = (__bf16*)((char*)g + 8388608);
  __bf16* kbl = (__bf16*)((char*)g + 12582912);
  __bf16* vth = (__bf16*)u;
  __bf16* vtl = (__bf16*)((char*)u + 4194304);
  __bf16* a2  = (__bf16*)g;
  float*  y2  = u;

  wsplit_t_kernel<<<dim3(16, 16, 4), 256, 0, stream>>>(wq, wqh, wql, HID, HID);
  wsplit_t_kernel<<<dim3(16, 16, 4), 256, 0, stream>>>(wk, wkh, wkl, HID, HID);
  wsplit_t_kernel<<<dim3(16, 16, 4), 256, 0, stream>>>(wv, wvh, wvl, HID, HID);
  wsplit_t_kernel<<<dim3(16, 16, 4), 256, 0, stream>>>(wo, woh, wol, HID, HID);
  wsplit_t_kernel<<<dim3(44, 16, 3), 256, 0, stream>>>(dg, dgh, dgl, HID, IDIM);
  wsplit_t_kernel<<<dim3(44, 16, 3), 256, 0, stream>>>(du, duh, dul, HID, IDIM);
  wsplit_t_kernel<<<dim3(16, 44, 3), 256, 0, stream>>>(dd, ddh, ddl, IDIM, HID);
  wsplit_th_kernel<<<dim3(44, 16, 8), 256, 0, stream>>>(mg, mgh, HID, IDIM);
  wsplit_th_kernel<<<dim3(44, 16, 8), 256, 0, stream>>>(mu, muh, HID, IDIM);
  wsplit_th_kernel<<<dim3(16, 44, 8), 256, 0, stream>>>(md, mdh, IDIM, HID);
  esplit_kernel<<<16000, 256, 0, stream>>>(embed, eh);

  tables_kernel<<<256, 256, 0, stream>>>(ct, st);
  embed_kernel<<<SEQ, 256, 0, stream>>>(ids, embed, h);

  for (int li = 0; li < 4; ++li) {
    const bool comp = (li <= 2);
    rmsnorm_kernel<<<SEQ, 256, 0, stream>>>(h, ln1 + li * HID, hn, hnh, hnl);
    size_t wofs = (size_t)li * HID * HID;
    if (comp)
      gemm_bt_kernel<true, false, false, 64, false><<<dim3(8, 32, 3), 256, 0, stream>>>(
          hnh, hnl, wqh + wofs, wql + wofs, wkh + wofs, wkl + wofs,
          wvh + wofs, wvl + wofs, q, k, v, SEQ, HID, HID);
    else
      gemm_bt_kernel<false, false, false, 64, false><<<dim3(8, 32, 3), 256, 0, stream>>>(
          hnh, hnh, wqh + wofs, wqh + wofs, wkh + wofs, wkh + wofs,
          wvh + wofs, wvh + wofs, q, k, v, SEQ, HID, HID);

    rope_split_kernel<<<4096, 256, 0, stream>>>(q, k, qh, ql, kbh, kbl, ct, st);
    vtsplit_kernel<<<dim3(32, 16), 256, 0, stream>>>(v, vth, vtl);

    attn_flash_kernel<<<dim3(32, 16), 256, 0, stream>>>(
        qh, ql, kbh, kbl, vth, vtl, oh, ol);

    if (comp)
      gemm_bt_kernel<true, true, false, 64, false><<<dim3(8, 32, 1), 256, 0, stream>>>(
          oh, ol, woh + wofs, wol + wofs, woh + wofs, wol + wofs,
          woh + wofs, wol + wofs, h, h, h, SEQ, HID, HID);
    else
      gemm_bt_kernel<false, true, false, 64, false><<<dim3(8, 32, 1), 256, 0, stream>>>(
          oh, oh, woh + wofs, woh + wofs, woh + wofs, woh + wofs,
          woh + wofs, woh + wofs, h, h, h, SEQ, HID, HID);

    rmsnorm_kernel<<<SEQ, 256, 0, stream>>>(h, ln2 + li * HID, hn, hnh, hnl);
    if (li == 2) {
      router_kernel<<<512, 256, 0, stream>>>(hn, rw, rl);
      zero_kernel<<<1, 32, 0, stream>>>(aux, 17);
      topk_kernel<<<8, 256, 0, stream>>>(rl, wmoe, aux);
      aux_kernel<<<1, 1, 0, stream>>>(aux, out);
      zeroi_kernel<<<1, 32, 0, stream>>>(cnt, 8);
      build_list_kernel<<<8, 256, 0, stream>>>(wmoe, cnt, list, tokp);
      prefix_kernel<<<1, 64, 0, stream>>>(cnt, off8);
      gemm_moe_guf_kernel<<<dim3(44, 16, 8), 256, 0, stream>>>(
          hnh, mgh, muh, a2, wmoe, list, cnt, off8);
      gemm_moe_down2_kernel<<<dim3(16, 16, 8), 256, 0, stream>>>(
          a2, mdh, y2, cnt, off8);
      moe_scatter_kernel<<<SEQ, 256, 0, stream>>>(tokp, off8, y2, h);
    } else {
      int d = (li < 2) ? li : li - 1;
      size_t go = (size_t)d * HID * IDIM;
      if (comp) {
        gemm_bt_kernel<true, false, false, 128, false><<<dim3(22, 16, 2), 256, 0, stream>>>(
            hnh, hnl, dgh + go, dgl + go, duh + go, dul + go,
            duh + go, dul + go, g, u, u, SEQ, IDIM, HID);
        silu_kernel<<<dim3(11, SEQ), 256, 0, stream>>>(g, u, gh, gl);
        gemm_bt_kernel<true, true, false, 64, false><<<dim3(8, 32, 1), 256, 0, stream>>>(
            gh, gl, ddh + go, ddl + go, ddh + go, ddl + go,
            ddh + go, ddl + go, h, h, h, SEQ, HID, IDIM);
      } else {
        gemm_bt_kernel<false, false, false, 128, false><<<dim3(22, 16, 2), 256, 0, stream>>>(
            hnh, hnh, dgh + go, dgh + go, duh + go, duh + go,
            duh + go, duh + go, g, u, u, SEQ, IDIM, HID);
        silu_kernel<<<dim3(11, SEQ), 256, 0, stream>>>(g, u, gh, gl);
        gemm_bt_kernel<false, true, false, 64, false><<<dim3(8, 32, 1), 256, 0, stream>>>(
            gh, gh, ddh + go, ddh + go, ddh + go, ddh + go,
            ddh + go, ddh + go, h, h, h, SEQ, HID, IDIM);
      }
    }
  }
  rmsnorm_kernel<<<SEQ, 256, 0, stream>>>(h, fin, hn, hnh, hnl);
  // logits: XCD-aware bijective swizzle (padded 1D grid; bn>=250 exits)
  gemm_bt_kernel<false, false, false, 128, true><<<dim3(4096, 1, 1), 256, 0, stream>>>(
      hnh, hnh, eh, eh, eh, eh, eh, eh, out, out, out, SEQ, VOCAB, HID);
}

// Round 16
// 1954.698 us; speedup vs baseline: 1.1823x; 1.0480x over previous
//
#include <hip/hip_runtime.h>
#include <hip/hip_bf16.h>
#include <math.h>

#define SEQ 2048
#define HID 1024
#define NHEAD 16
#define HDIM 64
#define IDIM 2816
#define NEXP 8
#define VOCAB 32000

#define ASTRIDE 144  // padded rows (attention)

typedef float f32x4v __attribute__((ext_vector_type(4)));
typedef __bf16 bf16x8v __attribute__((ext_vector_type(8)));
typedef __bf16 bf16x4v __attribute__((ext_vector_type(4)));

__device__ __forceinline__ bf16x8v cvt8(const float4& a, const float4& b) {
  bf16x8v r;
  r[0] = (__bf16)a.x; r[1] = (__bf16)a.y; r[2] = (__bf16)a.z; r[3] = (__bf16)a.w;
  r[4] = (__bf16)b.x; r[5] = (__bf16)b.y; r[6] = (__bf16)b.z; r[7] = (__bf16)b.w;
  return r;
}

#define MFMA(a, b, c) __builtin_amdgcn_mfma_f32_16x16x32_bf16(a, b, c, 0, 0, 0)

// async global->LDS DMA, 16B per lane; lds base must be wave-uniform
__device__ __forceinline__ void gld_lds16(const void* g, void* l) {
  __builtin_amdgcn_global_load_lds(
      (const __attribute__((address_space(1))) unsigned int*)(unsigned long long)g,
      (__attribute__((address_space(3))) unsigned int*)(unsigned int)(unsigned long long)l,
      16, 0, 0);
}

// ---------------------------------------------------------------------------
// Weight preprocessing: W[K,N] f32 -> WH,WL [N,K] bf16 (transposed hi/lo).
// ---------------------------------------------------------------------------
__global__ __launch_bounds__(256) void wsplit_t_kernel(
    const float* __restrict__ W, __bf16* __restrict__ WH, __bf16* __restrict__ WL,
    int K, int N)
{
  __shared__ float tile[64][65];
  const int tid = threadIdx.x;
  const size_t zofs = (size_t)blockIdx.z * K * N;
  const int n0 = blockIdx.x * 64, k0 = blockIdx.y * 64;
#pragma unroll
  for (int r = 0; r < 4; ++r) {
    int kk = (tid >> 4) + r * 16;
    int nn = (tid & 15) * 4;
    float4 v = *(const float4*)(W + zofs + (size_t)(k0 + kk) * N + n0 + nn);
    tile[kk][nn] = v.x; tile[kk][nn + 1] = v.y;
    tile[kk][nn + 2] = v.z; tile[kk][nn + 3] = v.w;
  }
  __syncthreads();
  const int nn = tid >> 2;
  const int kk = (tid & 3) * 16;
  __bf16* dh = WH + zofs + (size_t)(n0 + nn) * K + k0 + kk;
  __bf16* dl = WL + zofs + (size_t)(n0 + nn) * K + k0 + kk;
  bf16x8v h0, l0, h1, l1;
#pragma unroll
  for (int j = 0; j < 8; ++j) {
    float f = tile[kk + j][nn];
    __bf16 hb = (__bf16)f; h0[j] = hb; l0[j] = (__bf16)(f - (float)hb);
    f = tile[kk + 8 + j][nn];
    hb = (__bf16)f; h1[j] = hb; l1[j] = (__bf16)(f - (float)hb);
  }
  *(bf16x8v*)dh = h0; *(bf16x8v*)(dh + 8) = h1;
  *(bf16x8v*)dl = l0; *(bf16x8v*)(dl + 8) = l1;
}

// hi-only variant (MoE weights; plain-bf16 path needs no lo)
__global__ __launch_bounds__(256) void wsplit_th_kernel(
    const float* __restrict__ W, __bf16* __restrict__ WH, int K, int N)
{
  __shared__ float tile[64][65];
  const int tid = threadIdx.x;
  const size_t zofs = (size_t)blockIdx.z * K * N;
  const int n0 = blockIdx.x * 64, k0 = blockIdx.y * 64;
#pragma unroll
  for (int r = 0; r < 4; ++r) {
    int kk = (tid >> 4) + r * 16;
    int nn = (tid & 15) * 4;
    float4 v = *(const float4*)(W + zofs + (size_t)(k0 + kk) * N + n0 + nn);
    tile[kk][nn] = v.x; tile[kk][nn + 1] = v.y;
    tile[kk][nn + 2] = v.z; tile[kk][nn + 3] = v.w;
  }
  __syncthreads();
  const int nn = tid >> 2;
  const int kk = (tid & 3) * 16;
  __bf16* dh = WH + zofs + (size_t)(n0 + nn) * K + k0 + kk;
  bf16x8v h0, h1;
#pragma unroll
  for (int j = 0; j < 8; ++j) {
    h0[j] = (__bf16)tile[kk + j][nn];
    h1[j] = (__bf16)tile[kk + 8 + j][nn];
  }
  *(bf16x8v*)dh = h0; *(bf16x8v*)(dh + 8) = h1;
}

__global__ __launch_bounds__(256) void esplit_kernel(
    const float* __restrict__ E, __bf16* __restrict__ EH)
{
  size_t i = ((size_t)blockIdx.x * 256 + threadIdx.x) * 8;
  float4 a = *(const float4*)(E + i);
  float4 b = *(const float4*)(E + i + 4);
  *(bf16x8v*)(EH + i) = cvt8(a, b);
}

// ---------------------------------------------------------------------------
// Unified BT GEMM. A,B pre-split bf16. Staging = global_load_lds DMA (16B),
// LINEAR LDS rows (64B/row). XSWZ: XCD-aware bijective 1D grid (logits).
// ---------------------------------------------------------------------------
template<bool COMP, bool ACCUM, bool SWAP, int BM, bool XSWZ>
__global__ __launch_bounds__(256) void gemm_bt_kernel(
    const __bf16* __restrict__ Ah, const __bf16* __restrict__ Al,
    const __bf16* __restrict__ B0h, const __bf16* __restrict__ B0l,
    const __bf16* __restrict__ B1h, const __bf16* __restrict__ B1l,
    const __bf16* __restrict__ B2h, const __bf16* __restrict__ B2l,
    float* __restrict__ C0, float* __restrict__ C1, float* __restrict__ C2,
    int M, int N, int Kd)
{
  const __bf16* __restrict__ Bh = (blockIdx.z == 0) ? B0h : (blockIdx.z == 1 ? B1h : B2h);
  const __bf16* __restrict__ Bl = (blockIdx.z == 0) ? B0l : (blockIdx.z == 1 ? B1l : B2l);
  float* __restrict__ C         = (blockIdx.z == 0) ? C0 : (blockIdx.z == 1 ? C1 : C2);
  constexpr int ATILE = BM * 64;
  constexpr int BTILE = 128 * 64;
  constexpr int MFR = BM / 32;
  __shared__ __align__(16) char smem[COMP ? 2 * (ATILE + BTILE) : (ATILE + BTILE)];
  char* AsH = smem;
  char* BsH = smem + ATILE;
  char* AsL = COMP ? smem + ATILE + BTILE : smem;
  char* BsL = COMP ? smem + 2 * ATILE + BTILE : smem + ATILE;
  const int tid = threadIdx.x;
  int bm, bn;
  if (XSWZ) {
    int id = blockIdx.x;            // padded grid (e.g. 4096)
    int xcd = id & 7;
    int j = id >> 3;
    bm = j & 15;
    bn = xcd * 32 + (j >> 4);
    if (bn >= N / 128) return;
  } else {
    bm = SWAP ? blockIdx.x : blockIdx.y;
    bn = SWAP ? blockIdx.y : blockIdx.x;
  }
  const int wid = tid >> 6, lane = tid & 63;
  const int wm = (wid >> 1) * (BM / 2), wn = (wid & 1) << 6;
  const int lr = lane & 15, kh = lane >> 4;
  const int lrow = lane >> 2;
  const int lcol = (lane & 3) << 3;

  f32x4v acc[MFR][4];
  const f32x4v z4 = {0.f, 0.f, 0.f, 0.f};
#pragma unroll
  for (int i = 0; i < MFR; ++i)
#pragma unroll
    for (int j2 = 0; j2 < 4; ++j2) acc[i][j2] = z4;

  for (int k0 = 0; k0 < Kd; k0 += 32) {
    __syncthreads();
#pragma unroll
    for (int c = wid; c < BM / 16; c += 4) {
      size_t gofs = (size_t)(bm * BM + c * 16 + lrow) * Kd + k0 + lcol;
      gld_lds16(Ah + gofs, AsH + c * 1024);
      if (COMP) gld_lds16(Al + gofs, AsL + c * 1024);
    }
#pragma unroll
    for (int c = wid; c < 8; c += 4) {
      size_t gofs = (size_t)(bn * 128 + c * 16 + lrow) * Kd + k0 + lcol;
      gld_lds16(Bh + gofs, BsH + c * 1024);
      if (COMP) gld_lds16(Bl + gofs, BsL + c * 1024);
    }
    __syncthreads();

    bf16x8v ah[MFR], al[MFR], bh4[4], bl4[4];
#pragma unroll
    for (int i = 0; i < MFR; ++i) {
      int r = wm + (i << 4) + lr;
      int off = r * 64 + (kh << 4);
      ah[i] = *(const bf16x8v*)(AsH + off);
      if (COMP) al[i] = *(const bf16x8v*)(AsL + off);
    }
#pragma unroll
    for (int i = 0; i < 4; ++i) {
      int r = wn + (i << 4) + lr;
      int off = r * 64 + (kh << 4);
      bh4[i] = *(const bf16x8v*)(BsH + off);
      if (COMP) bl4[i] = *(const bf16x8v*)(BsL + off);
    }
#pragma unroll
    for (int mi = 0; mi < MFR; ++mi)
#pragma unroll
      for (int ni = 0; ni < 4; ++ni) {
        if (COMP) {
          acc[mi][ni] = MFMA(al[mi], bh4[ni], acc[mi][ni]);
          acc[mi][ni] = MFMA(ah[mi], bl4[ni], acc[mi][ni]);
        }
        acc[mi][ni] = MFMA(ah[mi], bh4[ni], acc[mi][ni]);
      }
  }

  const int cr0 = kh << 2;
#pragma unroll
  for (int mi = 0; mi < MFR; ++mi)
#pragma unroll
    for (int ni = 0; ni < 4; ++ni)
#pragma unroll
      for (int r = 0; r < 4; ++r) {
        int row = bm * BM + wm + (mi << 4) + cr0 + r;
        int col = bn * 128 + wn + (ni << 4) + lr;
        size_t idx = (size_t)row * N + col;
        if (ACCUM) C[idx] += acc[mi][ni][r];
        else       C[idx] = acc[mi][ni][r];
      }
}

// ---------------------------------------------------------------------------
// rope + hi/lo split for Q (scale 1/8) and K
// ---------------------------------------------------------------------------
__global__ __launch_bounds__(256) void rope_split_kernel(
    const float* __restrict__ Q, const float* __restrict__ K,
    __bf16* __restrict__ QH, __bf16* __restrict__ QL,
    __bf16* __restrict__ KH, __bf16* __restrict__ KL,
    const float* __restrict__ CT, const float* __restrict__ ST)
{
  int idx = blockIdx.x * 256 + threadIdx.x;
  int s = idx >> 9;
  int rr = idx & 511;
  int hd = rr >> 5;
  int i = rr & 31;
  float c = CT[(s << 5) + i], sn = ST[(s << 5) + i];
  size_t base = (size_t)s * HID + hd * 64 + i;
  {
    float x1 = Q[base], x2 = Q[base + 32];
    float o1 = (x1 * c - x2 * sn) * 0.125f;
    float o2 = (x2 * c + x1 * sn) * 0.125f;
    __bf16 h1 = (__bf16)o1, h2 = (__bf16)o2;
    QH[base] = h1;      QL[base] = (__bf16)(o1 - (float)h1);
    QH[base + 32] = h2; QL[base + 32] = (__bf16)(o2 - (float)h2);
  }
  {
    float x1 = K[base], x2 = K[base + 32];
    float o1 = x1 * c - x2 * sn;
    float o2 = x2 * c + x1 * sn;
    __bf16 h1 = (__bf16)o1, h2 = (__bf16)o2;
    KH[base] = h1;      KL[base] = (__bf16)(o1 - (float)h1);
    KH[base + 32] = h2; KL[base + 32] = (__bf16)(o2 - (float)h2);
  }
}

// V f32 [S][HID] -> per-head transposed hi/lo bf16 [NHEAD][HDIM][SEQ]
__global__ __launch_bounds__(256) void vtsplit_kernel(
    const float* __restrict__ V, __bf16* __restrict__ VTH, __bf16* __restrict__ VTL)
{
  __shared__ float tile[64][65];
  const int tid = threadIdx.x;
  const int s0 = blockIdx.x * 64;
  const int head = blockIdx.y;
#pragma unroll
  for (int r = 0; r < 4; ++r) {
    int ss = (tid >> 4) + r * 16;
    int dd = (tid & 15) * 4;
    float4 v = *(const float4*)(V + (size_t)(s0 + ss) * HID + head * 64 + dd);
    tile[ss][dd] = v.x; tile[ss][dd + 1] = v.y;
    tile[ss][dd + 2] = v.z; tile[ss][dd + 3] = v.w;
  }
  __syncthreads();
#pragma unroll
  for (int half = 0; half < 2; ++half) {
    const int d = (tid >> 3) + (half << 5);
    const int c = tid & 7;
    bf16x8v hv, lv;
#pragma unroll
    for (int j = 0; j < 8; ++j) {
      float f = tile[c * 8 + j][d];
      __bf16 hb = (__bf16)f;
      hv[j] = hb; lv[j] = (__bf16)(f - (float)hb);
    }
    size_t dst = (size_t)(head * 64 + d) * SEQ + s0 + c * 8;
    *(bf16x8v*)(VTH + dst) = hv;
    *(bf16x8v*)(VTL + dst) = lv;
  }
}

// ---------------------------------------------------------------------------
// Compensated flash attention; padded LDS; O -> bf16 hi/lo.
// Load-balanced: grid (16,16); block processes qt = bx and qt = 31-bx
// (work = (bx+1) + (32-bx) = 33 iters, uniform across all 256 blocks).
// ---------------------------------------------------------------------------
__global__ __launch_bounds__(256) void attn_flash_kernel(
    const __bf16* __restrict__ QH, const __bf16* __restrict__ QL,
    const __bf16* __restrict__ KH, const __bf16* __restrict__ KL,
    const __bf16* __restrict__ VTH, const __bf16* __restrict__ VTL,
    __bf16* __restrict__ OH, __bf16* __restrict__ OL)
{
  const int head = blockIdx.y;
  const int tid = threadIdx.x, wid = tid >> 6, lane = tid & 63;
  const int lr = lane & 15, kh = lane >> 4;
  __shared__ __align__(16) char KsH[64 * ASTRIDE], KsL[64 * ASTRIDE];
  __shared__ __align__(16) char VtH[64 * ASTRIDE], VtL[64 * ASTRIDE];
  __shared__ __align__(16) char PsH[4][16 * ASTRIDE], PsL[4][16 * ASTRIDE];

#pragma unroll
  for (int seg = 0; seg < 2; ++seg) {
    const int qt = seg ? (31 - (int)blockIdx.x) : (int)blockIdx.x;

    const size_t qofs = (size_t)(qt * 64 + wid * 16 + lr) * HID + head * HDIM;
    const bf16x8v qfh0 = *(const bf16x8v*)(QH + qofs + (kh << 3));
    const bf16x8v qfh1 = *(const bf16x8v*)(QH + qofs + 32 + (kh << 3));
    const bf16x8v qfl0 = *(const bf16x8v*)(QL + qofs + (kh << 3));
    const bf16x8v qfl1 = *(const bf16x8v*)(QL + qofs + 32 + (kh << 3));

    float m_run[4], l_run[4];
    f32x4v oacc[4];
    const f32x4v z4 = {0.f, 0.f, 0.f, 0.f};
#pragma unroll
    for (int i = 0; i < 4; ++i) { m_run[i] = -1e30f; l_run[i] = 0.f; oacc[i] = z4; }

    for (int kt = 0; kt <= qt; ++kt) {
      __syncthreads();
#pragma unroll
      for (int p = 0; p < 2; ++p) {
        int g = tid + (p << 8);
        int r = g >> 3;
        int c = g & 7;
        int off = r * ASTRIDE + (c << 4);
        const size_t kofs = (size_t)(kt * 64 + r) * HID + head * HDIM + (c << 3);
        *(bf16x8v*)(KsH + off) = *(const bf16x8v*)(KH + kofs);
        *(bf16x8v*)(KsL + off) = *(const bf16x8v*)(KL + kofs);
        const size_t vofs = (size_t)(head * 64 + r) * SEQ + kt * 64 + (c << 3);
        *(bf16x8v*)(VtH + off) = *(const bf16x8v*)(VTH + vofs);
        *(bf16x8v*)(VtL + off) = *(const bf16x8v*)(VTL + vofs);
      }
      __syncthreads();

      float sv[4][4];
#pragma unroll
      for (int stt = 0; stt < 4; ++stt) {
        int r = (stt << 4) + lr;
        int off0 = r * ASTRIDE + (kh << 4);
        int off1 = off0 + 64;
        bf16x8v kfh0 = *(const bf16x8v*)(KsH + off0);
        bf16x8v kfl0 = *(const bf16x8v*)(KsL + off0);
        bf16x8v kfh1 = *(const bf16x8v*)(KsH + off1);
        bf16x8v kfl1 = *(const bf16x8v*)(KsL + off1);
        f32x4v s = z4;
        s = MFMA(qfl0, kfh0, s);
        s = MFMA(qfh0, kfl0, s);
        s = MFMA(qfh0, kfh0, s);
        s = MFMA(qfl1, kfh1, s);
        s = MFMA(qfh1, kfl1, s);
        s = MFMA(qfh1, kfh1, s);
        int key = kt * 64 + (stt << 4) + lr;
#pragma unroll
        for (int rr = 0; rr < 4; ++rr) {
          int qr = qt * 64 + wid * 16 + (kh << 2) + rr;
          sv[stt][rr] = (key <= qr) ? s[rr] : -1e30f;
        }
      }

#pragma unroll
      for (int rr = 0; rr < 4; ++rr) {
        float mx = fmaxf(fmaxf(sv[0][rr], sv[1][rr]), fmaxf(sv[2][rr], sv[3][rr]));
#pragma unroll
        for (int d = 1; d < 16; d <<= 1) mx = fmaxf(mx, __shfl_xor(mx, d));
        float mnew = fmaxf(m_run[rr], mx);
        float scl = __expf(m_run[rr] - mnew);
        float pv[4];
#pragma unroll
        for (int stt = 0; stt < 4; ++stt) pv[stt] = __expf(sv[stt][rr] - mnew);
        float rs = pv[0] + pv[1] + pv[2] + pv[3];
#pragma unroll
        for (int d = 1; d < 16; d <<= 1) rs += __shfl_xor(rs, d);
        l_run[rr] = l_run[rr] * scl + rs;
        m_run[rr] = mnew;
#pragma unroll
        for (int n = 0; n < 4; ++n) oacc[n][rr] *= scl;
        int qlr = (kh << 2) + rr;
#pragma unroll
        for (int stt = 0; stt < 4; ++stt) {
          __bf16 hb = (__bf16)pv[stt];
          __bf16 lb = (__bf16)(pv[stt] - (float)hb);
          int off = qlr * ASTRIDE + (((stt << 4) + lr) << 1);
          *(__bf16*)(PsH[wid] + off) = hb;
          *(__bf16*)(PsL[wid] + off) = lb;
        }
      }

      int poff0 = lr * ASTRIDE + (kh << 4);
      int poff1 = poff0 + 64;
      bf16x8v pah0 = *(const bf16x8v*)(PsH[wid] + poff0);
      bf16x8v pal0 = *(const bf16x8v*)(PsL[wid] + poff0);
      bf16x8v pah1 = *(const bf16x8v*)(PsH[wid] + poff1);
      bf16x8v pal1 = *(const bf16x8v*)(PsL[wid] + poff1);
#pragma unroll
      for (int n = 0; n < 4; ++n) {
        int vr = (n << 4) + lr;
        int voff0 = vr * ASTRIDE + (kh << 4);
        int voff1 = voff0 + 64;
        bf16x8v vfh0 = *(const bf16x8v*)(VtH + voff0);
        bf16x8v vfl0 = *(const bf16x8v*)(VtL + voff0);
        bf16x8v vfh1 = *(const bf16x8v*)(VtH + voff1);
        bf16x8v vfl1 = *(const bf16x8v*)(VtL + voff1);
        oacc[n] = MFMA(pal0, vfh0, oacc[n]);
        oacc[n] = MFMA(pah0, vfl0, oacc[n]);
        oacc[n] = MFMA(pah0, vfh0, oacc[n]);
        oacc[n] = MFMA(pal1, vfh1, oacc[n]);
        oacc[n] = MFMA(pah1, vfl1, oacc[n]);
        oacc[n] = MFMA(pah1, vfh1, oacc[n]);
      }
    }

#pragma unroll
    for (int n = 0; n < 4; ++n)
#pragma unroll
      for (int rr = 0; rr < 4; ++rr) {
        int qr = qt * 64 + wid * 16 + (kh << 2) + rr;
        size_t ofs = (size_t)qr * HID + head * HDIM + (n << 4) + lr;
        float val = oacc[n][rr] / l_run[rr];
        __bf16 hb = (__bf16)val;
        OH[ofs] = hb;
        OL[ofs] = (__bf16)(val - (float)hb);
      }
  }
}

// ---------------------------------------------------------------------------
// MoE: fused gate+up+silu. BM=128, BN=64. DMA staging, pre-split weights.
// ---------------------------------------------------------------------------
__global__ __launch_bounds__(256) void gemm_moe_guf_kernel(
    const __bf16* __restrict__ Xh,
    const __bf16* __restrict__ MGH, const __bf16* __restrict__ MUH,
    __bf16* __restrict__ A2, const float* __restrict__ W,
    const int* __restrict__ list, const int* __restrict__ cnt8,
    const int* __restrict__ off8)
{
  const int e = blockIdx.z;
  const int cnt = cnt8[e];
  const int bn = blockIdx.x, bm = blockIdx.y;
  if (bm * 128 >= cnt) return;
  const int base = off8[e];
  __shared__ __align__(16) char AsB[8192];
  __shared__ __align__(16) char BgB[4096];
  __shared__ __align__(16) char BuB[4096];
  const int tid = threadIdx.x;
  const int wid = tid >> 6, lane = tid & 63;
  const int wm = (wid >> 1) << 6, wn = (wid & 1) << 5;
  const int lr = lane & 15, kh = lane >> 4;
  const int lrow = lane >> 2;
  const int lcol = (lane & 3) << 3;

  f32x4v accg[4][2], accu[4][2];
  const f32x4v z4 = {0.f, 0.f, 0.f, 0.f};
#pragma unroll
  for (int i = 0; i < 4; ++i)
#pragma unroll
    for (int j = 0; j < 2; ++j) { accg[i][j] = z4; accu[i][j] = z4; }

  for (int k0 = 0; k0 < HID; k0 += 32) {
    __syncthreads();
#pragma unroll
    for (int c = wid; c < 8; c += 4) {     // A: 128 rows
      int rg = bm * 128 + c * 16 + lrow;
      int tok = list[e * SEQ + (rg < cnt ? rg : cnt - 1)];
      gld_lds16(Xh + (size_t)tok * HID + k0 + lcol, AsB + c * 1024);
    }
    {                                       // B: 64 rows each (g,u)
      int c = wid;
      size_t wofs = (size_t)(e * IDIM + bn * 64 + c * 16 + lrow) * HID + k0 + lcol;
      gld_lds16(MGH + wofs, BgB + c * 1024);
      gld_lds16(MUH + wofs, BuB + c * 1024);
    }
    __syncthreads();

    bf16x8v af[4], bg4[2], bu4[2];
#pragma unroll
    for (int i = 0; i < 4; ++i) {
      int r = wm + (i << 4) + lr;
      af[i] = *(const bf16x8v*)(AsB + r * 64 + (kh << 4));
    }
#pragma unroll
    for (int i = 0; i < 2; ++i) {
      int r = wn + (i << 4) + lr;
      bg4[i] = *(const bf16x8v*)(BgB + r * 64 + (kh << 4));
      bu4[i] = *(const bf16x8v*)(BuB + r * 64 + (kh << 4));
    }
#pragma unroll
    for (int mi = 0; mi < 4; ++mi)
#pragma unroll
      for (int ni = 0; ni < 2; ++ni) {
        accg[mi][ni] = MFMA(af[mi], bg4[ni], accg[mi][ni]);
        accu[mi][ni] = MFMA(af[mi], bu4[ni], accu[mi][ni]);
      }
  }

  const int cr0 = kh << 2;
#pragma unroll
  for (int mi = 0; mi < 4; ++mi)
#pragma unroll
    for (int ni = 0; ni < 2; ++ni)
#pragma unroll
      for (int r = 0; r < 4; ++r) {
        int row = bm * 128 + wm + (mi << 4) + cr0 + r;
        if (row < cnt) {
          int col = bn * 64 + wn + (ni << 4) + lr;
          int tok = list[e * SEQ + row];
          float w = W[tok * 8 + e];
          float gval = accg[mi][ni][r];
          float uval = accu[mi][ni][r];
          float a = gval / (1.f + __expf(-gval)) * uval * w;
          A2[(size_t)(base + row) * IDIM + col] = (__bf16)a;
        }
      }
}

__global__ __launch_bounds__(256) void gemm_moe_down2_kernel(
    const __bf16* __restrict__ A2, const __bf16* __restrict__ MDH,
    float* __restrict__ Y2,
    const int* __restrict__ cnt8, const int* __restrict__ off8)
{
  const int e = blockIdx.z;
  const int cnt = cnt8[e];
  const int bn = blockIdx.x, bm = blockIdx.y;
  if (bm * 128 >= cnt) return;
  const int base = off8[e];
  __shared__ __align__(16) char AsB[8192];
  __shared__ __align__(16) char BsB[4096];
  const int tid = threadIdx.x;
  const int wid = tid >> 6, lane = tid & 63;
  const int wm = (wid >> 1) << 6, wn = (wid & 1) << 5;
  const int lr = lane & 15, kh = lane >> 4;
  const int lrow = lane >> 2;
  const int lcol = (lane & 3) << 3;

  f32x4v acc[4][2];
  const f32x4v z4 = {0.f, 0.f, 0.f, 0.f};
#pragma unroll
  for (int i = 0; i < 4; ++i)
#pragma unroll
    for (int j = 0; j < 2; ++j) acc[i][j] = z4;

  for (int k0 = 0; k0 < IDIM; k0 += 32) {
    __syncthreads();
#pragma unroll
    for (int c = wid; c < 8; c += 4) {
      int rg = bm * 128 + c * 16 + lrow;
      int row = (rg < cnt ? rg : cnt - 1);
      gld_lds16(A2 + (size_t)(base + row) * IDIM + k0 + lcol, AsB + c * 1024);
    }
    {
      int c = wid;
      gld_lds16(MDH + (size_t)(e * HID + bn * 64 + c * 16 + lrow) * IDIM + k0 + lcol,
                BsB + c * 1024);
    }
    __syncthreads();

    bf16x8v af[4], bfv[2];
#pragma unroll
    for (int i = 0; i < 4; ++i) {
      int r = wm + (i << 4) + lr;
      af[i] = *(const bf16x8v*)(AsB + r * 64 + (kh << 4));
    }
#pragma unroll
    for (int i = 0; i < 2; ++i) {
      int r = wn + (i << 4) + lr;
      bfv[i] = *(const bf16x8v*)(BsB + r * 64 + (kh << 4));
    }
#pragma unroll
    for (int mi = 0; mi < 4; ++mi)
#pragma unroll
      for (int ni = 0; ni < 2; ++ni)
        acc[mi][ni] = MFMA(af[mi], bfv[ni], acc[mi][ni]);
  }

  const int cr0 = kh << 2;
#pragma unroll
  for (int mi = 0; mi < 4; ++mi)
#pragma unroll
    for (int ni = 0; ni < 2; ++ni)
#pragma unroll
      for (int r = 0; r < 4; ++r) {
        int row = bm * 128 + wm + (mi << 4) + cr0 + r;
        if (row < cnt) {
          int col = bn * 64 + wn + (ni << 4) + lr;
          Y2[(size_t)(base + row) * HID + col] = acc[mi][ni][r];
        }
      }
}

// h[t] += y(e_lo) + y(e_hi)  (ascending-e order == old serial order)
__global__ __launch_bounds__(256) void moe_scatter_kernel(
    const int* __restrict__ tokpair, const int* __restrict__ off8,
    const float* __restrict__ Y2, float* __restrict__ H)
{
  const int t = blockIdx.x;
  const int i = threadIdx.x;
  int p0 = tokpair[t * 2], p1 = tokpair[t * 2 + 1];
  size_t r0 = off8[p0 >> 16] + (p0 & 0xffff);
  size_t r1 = off8[p1 >> 16] + (p1 & 0xffff);
  float4 a = ((const float4*)(Y2 + r0 * HID))[i];
  float4 b = ((const float4*)(Y2 + r1 * HID))[i];
  float4 hv = ((float4*)(H + (size_t)t * HID))[i];
  hv.x = (hv.x + a.x) + b.x;
  hv.y = (hv.y + a.y) + b.y;
  hv.z = (hv.z + a.z) + b.z;
  hv.w = (hv.w + a.w) + b.w;
  ((float4*)(H + (size_t)t * HID))[i] = hv;
}

// ---------------------------------------------------------------------------
// Small kernels
// ---------------------------------------------------------------------------
__global__ void tables_kernel(float* __restrict__ CT, float* __restrict__ ST)
{
  int idx = blockIdx.x * 256 + threadIdx.x;
  int s = idx >> 5, i = idx & 31;
  double inv = exp(-log(10000.0) * (double)i / 32.0);
  double ang = (double)s * inv;
  CT[idx] = (float)cos(ang);
  ST[idx] = (float)sin(ang);
}

__global__ __launch_bounds__(256) void embed_kernel(
    const int* __restrict__ ids, const float* __restrict__ E, float* __restrict__ H)
{
  int t = blockIdx.x;
  int id = ids[t];
  ((float4*)(H + (size_t)t * HID))[threadIdx.x] =
      ((const float4*)(E + (size_t)id * HID))[threadIdx.x];
}

__global__ __launch_bounds__(256) void rmsnorm_kernel(
    const float* __restrict__ X, const float* __restrict__ W,
    float* __restrict__ O, __bf16* __restrict__ OHb, __bf16* __restrict__ OLb)
{
  int t = blockIdx.x;
  int tid = threadIdx.x;
  float4 v = ((const float4*)(X + (size_t)t * HID))[tid];
  float ss = v.x * v.x + v.y * v.y + v.z * v.z + v.w * v.w;
#pragma unroll
  for (int d = 1; d < 64; d <<= 1) ss += __shfl_xor(ss, d);
  __shared__ float red[4];
  if ((tid & 63) == 0) red[tid >> 6] = ss;
  __syncthreads();
  float tot = red[0] + red[1] + red[2] + red[3];
  float inv = 1.0f / sqrtf(tot * (1.0f / 1024.0f) + 1e-6f);
  float4 w = ((const float4*)W)[tid];
  float4 r;
  r.x = v.x * inv * w.x; r.y = v.y * inv * w.y;
  r.z = v.z * inv * w.z; r.w = v.w * inv * w.w;
  ((float4*)(O + (size_t)t * HID))[tid] = r;
  float f[4] = {r.x, r.y, r.z, r.w};
  bf16x4v hv, lv;
#pragma unroll
  for (int j = 0; j < 4; ++j) {
    __bf16 hb = (__bf16)f[j];
    hv[j] = hb; lv[j] = (__bf16)(f[j] - (float)hb);
  }
  *(bf16x4v*)(OHb + (size_t)t * HID + tid * 4) = hv;
  *(bf16x4v*)(OLb + (size_t)t * HID + tid * 4) = lv;
}

__global__ __launch_bounds__(256) void silu_kernel(
    const float* __restrict__ G, const float* __restrict__ U,
    __bf16* __restrict__ AH, __bf16* __restrict__ AL)
{
  int t = blockIdx.y;
  int i = blockIdx.x * 256 + threadIdx.x;
  size_t idx = (size_t)t * IDIM + i;
  float gv = G[idx], uv = U[idx];
  float a = gv / (1.f + __expf(-gv)) * uv;
  __bf16 hb = (__bf16)a;
  AH[idx] = hb;
  AL[idx] = (__bf16)(a - (float)hb);
}

__global__ __launch_bounds__(256) void router_kernel(
    const float* __restrict__ X, const float* __restrict__ RW, float* __restrict__ RL)
{
  int wid = threadIdx.x >> 6, lane = threadIdx.x & 63;
  int t = blockIdx.x * 4 + wid;
  const float* x = X + (size_t)t * HID;
  float a0 = 0, a1 = 0, a2 = 0, a3 = 0, a4 = 0, a5 = 0, a6 = 0, a7 = 0;
  for (int hh = lane; hh < HID; hh += 64) {
    float xv = x[hh];
    float4 f0 = *(const float4*)(RW + hh * 8);
    float4 f1 = *(const float4*)(RW + hh * 8 + 4);
    a0 += xv * f0.x; a1 += xv * f0.y; a2 += xv * f0.z; a3 += xv * f0.w;
    a4 += xv * f1.x; a5 += xv * f1.y; a6 += xv * f1.z; a7 += xv * f1.w;
  }
#pragma unroll
  for (int d = 1; d < 64; d <<= 1) {
    a0 += __shfl_xor(a0, d); a1 += __shfl_xor(a1, d);
    a2 += __shfl_xor(a2, d); a3 += __shfl_xor(a3, d);
    a4 += __shfl_xor(a4, d); a5 += __shfl_xor(a5, d);
    a6 += __shfl_xor(a6, d); a7 += __shfl_xor(a7, d);
  }
  if (lane == 0) {
    float* dst = RL + (size_t)t * 8;
    dst[0] = a0; dst[1] = a1; dst[2] = a2; dst[3] = a3;
    dst[4] = a4; dst[5] = a5; dst[6] = a6; dst[7] = a7;
  }
}

__global__ void zero_kernel(float* __restrict__ p, int n)
{
  int i = threadIdx.x;
  if (i < n) p[i] = 0.f;
}

__global__ void zeroi_kernel(int* __restrict__ p, int n)
{
  int i = threadIdx.x;
  if (i < n) p[i] = 0;
}

__global__ __launch_bounds__(256) void topk_kernel(
    const float* __restrict__ RL, float* __restrict__ W, float* __restrict__ AUX)
{
  int t = blockIdx.x * 256 + threadIdx.x;
  int lane = threadIdx.x & 63;
  float r[8];
#pragma unroll
  for (int e = 0; e < 8; ++e) r[e] = RL[t * 8 + e];
  float mx = r[0];
#pragma unroll
  for (int e = 1; e < 8; ++e) mx = fmaxf(mx, r[e]);
  float p[8];
  float se = 0.f;
#pragma unroll
  for (int e = 0; e < 8; ++e) { p[e] = __expf(r[e] - mx); se += p[e]; }
  float inv = 1.f / se;
#pragma unroll
  for (int e = 0; e < 8; ++e) p[e] *= inv;
  float lse = logf(se) + mx;
  int i1 = 0; float v1 = p[0];
#pragma unroll
  for (int e = 1; e < 8; ++e) if (p[e] > v1) { v1 = p[e]; i1 = e; }
  int i2 = -1; float v2 = -1.f;
#pragma unroll
  for (int e = 0; e < 8; ++e) if (e != i1 && p[e] > v2) { v2 = p[e]; i2 = e; }
  float s12 = v1 + v2;
#pragma unroll
  for (int e = 0; e < 8; ++e)
    W[t * 8 + e] = (e == i1) ? v1 / s12 : ((e == i2) ? v2 / s12 : 0.f);
#pragma unroll
  for (int e = 0; e < 8; ++e) {
    float fe = ((i1 == e) ? 1.f : 0.f) + ((i2 == e) ? 1.f : 0.f);
    float pe = p[e];
#pragma unroll
    for (int d = 1; d < 64; d <<= 1) { fe += __shfl_xor(fe, d); pe += __shfl_xor(pe, d); }
    if (lane == 0) { atomicAdd(&AUX[e], fe); atomicAdd(&AUX[8 + e], pe); }
  }
  float zz = lse * lse;
#pragma unroll
  for (int d = 1; d < 64; d <<= 1) zz += __shfl_xor(zz, d);
  if (lane == 0) atomicAdd(&AUX[16], zz);
}

__global__ void aux_kernel(const float* __restrict__ AUX, float* __restrict__ OUT)
{
  float s = 0.f;
#pragma unroll
  for (int e = 0; e < 8; ++e)
    s += (AUX[e] * (1.f / 2048.f)) * (AUX[8 + e] * (1.f / 2048.f));
  float auxv = 0.01f * 8.f * s;
  float z = 0.001f * (AUX[16] * (1.f / 2048.f));
  OUT[(size_t)SEQ * VOCAB] = auxv + z;
}

// records per-token (expert, pos) pairs in ascending-e order
__global__ __launch_bounds__(256) void build_list_kernel(
    const float* __restrict__ W, int* __restrict__ cnt, int* __restrict__ list,
    int* __restrict__ tokpair)
{
  int t = blockIdx.x * 256 + threadIdx.x;
  int j = 0;
#pragma unroll
  for (int e = 0; e < 8; ++e) {
    if (W[t * 8 + e] > 0.f) {
      int p = atomicAdd(&cnt[e], 1);
      list[e * SEQ + p] = t;
      tokpair[t * 2 + j] = (e << 16) | p;
      ++j;
    }
  }
}

__global__ void prefix_kernel(const int* __restrict__ cnt, int* __restrict__ off)
{
  if (threadIdx.x == 0) {
    int s = 0;
    for (int e = 0; e < 8; ++e) { off[e] = s; s += cnt[e]; }
  }
}

// ---------------------------------------------------------------------------
extern "C" void kernel_launch(void* const* d_in, const int* in_sizes, int n_in,
                              void* d_out, int out_size, void* d_ws, size_t ws_size,
                              hipStream_t stream)
{
  const int*   ids   = (const int*)d_in[0];
  const float* embed = (const float*)d_in[1];
  const float* ln1   = (const float*)d_in[2];
  const float* ln2   = (const float*)d_in[3];
  const float* wq    = (const float*)d_in[4];
  const float* wk    = (const float*)d_in[5];
  const float* wv    = (const float*)d_in[6];
  const float* wo    = (const float*)d_in[7];
  const float* dg    = (const float*)d_in[8];
  const float* du    = (const float*)d_in[9];
  const float* dd    = (const float*)d_in[10];
  const float* rw    = (const float*)d_in[11];
  const float* mg    = (const float*)d_in[12];
  const float* mu    = (const float*)d_in[13];
  const float* md    = (const float*)d_in[14];
  const float* fin   = (const float*)d_in[15];
  float* out = (float*)d_out;

  char* ws = (char*)d_ws;
  float* h    = (float*)(ws + 0);
  float* hn   = (float*)(ws + 8388608);
  float* q    = (float*)(ws + 16777216);
  float* k    = (float*)(ws + 25165824);
  float* v    = (float*)(ws + 33554432);
  __bf16* oh  = (__bf16*)(ws + 41943040);
  __bf16* ol  = (__bf16*)(ws + 46137344);
  float* g    = (float*)(ws + 50331648);
  float* u    = (float*)(ws + 73400320);
  float* ct   = (float*)(ws + 96468992);
  float* st   = (float*)(ws + 96731136);
  float* rl   = (float*)(ws + 96993280);
  float* wmoe = (float*)(ws + 97058816);
  float* aux  = (float*)(ws + 97124352);
  int*   cnt  = (int*)  (ws + 97124608);
  int*   list = (int*)  (ws + 97124864);
  int*   tokp = (int*)  (ws + 97190400);
  int*   off8 = (int*)  (ws + 97206784);
  __bf16* wqh = (__bf16*)(ws + 97320960);
  __bf16* wql = (__bf16*)(ws + 105709568);
  __bf16* wkh = (__bf16*)(ws + 114098176);
  __bf16* wkl = (__bf16*)(ws + 122486784);
  __bf16* wvh = (__bf16*)(ws + 130875392);
  __bf16* wvl = (__bf16*)(ws + 139264000);
  __bf16* woh = (__bf16*)(ws + 147652608);
  __bf16* wol = (__bf16*)(ws + 156041216);
  __bf16* dgh = (__bf16*)(ws + 164429824);
  __bf16* dgl = (__bf16*)(ws + 181731328);
  __bf16* duh = (__bf16*)(ws + 199032832);
  __bf16* dul = (__bf16*)(ws + 216334336);
  __bf16* ddh = (__bf16*)(ws + 233635840);
  __bf16* ddl = (__bf16*)(ws + 250937344);
  __bf16* eh  = (__bf16*)(ws + 268238848);
  __bf16* hnh = (__bf16*)(ws + 333774848);
  __bf16* hnl = (__bf16*)(ws + 337969152);
  __bf16* gh  = (__bf16*)(ws + 342163456);
  __bf16* gl  = (__bf16*)(ws + 353697792);
  __bf16* mgh = (__bf16*)(ws + 365232128);
  __bf16* muh = (__bf16*)(ws + 411369472);
  __bf16* mdh = (__bf16*)(ws + 457506816);
  // end: 503,644,160 bytes
  __bf16* qh  = (__bf16*)g;
  __bf16* ql  = (__bf16*)((char*)g + 4194304);
  __bf16* kbh = (__bf16*)((char*)g + 8388608);
  __bf16* kbl = (__bf16*)((char*)g + 12582912);
  __bf16* vth = (__bf16*)u;
  __bf16* vtl = (__bf16*)((char*)u + 4194304);
  __bf16* a2  = (__bf16*)g;
  float*  y2  = u;

  wsplit_t_kernel<<<dim3(16, 16, 4), 256, 0, stream>>>(wq, wqh, wql, HID, HID);
  wsplit_t_kernel<<<dim3(16, 16, 4), 256, 0, stream>>>(wk, wkh, wkl, HID, HID);
  wsplit_t_kernel<<<dim3(16, 16, 4), 256, 0, stream>>>(wv, wvh, wvl, HID, HID);
  wsplit_t_kernel<<<dim3(16, 16, 4), 256, 0, stream>>>(wo, woh, wol, HID, HID);
  wsplit_t_kernel<<<dim3(44, 16, 3), 256, 0, stream>>>(dg, dgh, dgl, HID, IDIM);
  wsplit_t_kernel<<<dim3(44, 16, 3), 256, 0, stream>>>(du, duh, dul, HID, IDIM);
  wsplit_t_kernel<<<dim3(16, 44, 3), 256, 0, stream>>>(dd, ddh, ddl, IDIM, HID);
  wsplit_th_kernel<<<dim3(44, 16, 8), 256, 0, stream>>>(mg, mgh, HID, IDIM);
  wsplit_th_kernel<<<dim3(44, 16, 8), 256, 0, stream>>>(mu, muh, HID, IDIM);
  wsplit_th_kernel<<<dim3(16, 44, 8), 256, 0, stream>>>(md, mdh, IDIM, HID);
  esplit_kernel<<<16000, 256, 0, stream>>>(embed, eh);

  tables_kernel<<<256, 256, 0, stream>>>(ct, st);
  embed_kernel<<<SEQ, 256, 0, stream>>>(ids, embed, h);

  for (int li = 0; li < 4; ++li) {
    const bool comp = (li <= 2);
    rmsnorm_kernel<<<SEQ, 256, 0, stream>>>(h, ln1 + li * HID, hn, hnh, hnl);
    size_t wofs = (size_t)li * HID * HID;
    if (comp)
      gemm_bt_kernel<true, false, false, 64, false><<<dim3(8, 32, 3), 256, 0, stream>>>(
          hnh, hnl, wqh + wofs, wql + wofs, wkh + wofs, wkl + wofs,
          wvh + wofs, wvl + wofs, q, k, v, SEQ, HID, HID);
    else
      gemm_bt_kernel<false, false, false, 64, false><<<dim3(8, 32, 3), 256, 0, stream>>>(
          hnh, hnh, wqh + wofs, wqh + wofs, wkh + wofs, wkh + wofs,
          wvh + wofs, wvh + wofs, q, k, v, SEQ, HID, HID);

    rope_split_kernel<<<4096, 256, 0, stream>>>(q, k, qh, ql, kbh, kbl, ct, st);
    vtsplit_kernel<<<dim3(32, 16), 256, 0, stream>>>(v, vth, vtl);

    attn_flash_kernel<<<dim3(16, 16), 256, 0, stream>>>(
        qh, ql, kbh, kbl, vth, vtl, oh, ol);

    if (comp)
      gemm_bt_kernel<true, true, false, 64, false><<<dim3(8, 32, 1), 256, 0, stream>>>(
          oh, ol, woh + wofs, wol + wofs, woh + wofs, wol + wofs,
          woh + wofs, wol + wofs, h, h, h, SEQ, HID, HID);
    else
      gemm_bt_kernel<false, true, false, 64, false><<<dim3(8, 32, 1), 256, 0, stream>>>(
          oh, oh, woh + wofs, woh + wofs, woh + wofs, woh + wofs,
          woh + wofs, woh + wofs, h, h, h, SEQ, HID, HID);

    rmsnorm_kernel<<<SEQ, 256, 0, stream>>>(h, ln2 + li * HID, hn, hnh, hnl);
    if (li == 2) {
      router_kernel<<<512, 256, 0, stream>>>(hn, rw, rl);
      zero_kernel<<<1, 32, 0, stream>>>(aux, 17);
      topk_kernel<<<8, 256, 0, stream>>>(rl, wmoe, aux);
      aux_kernel<<<1, 1, 0, stream>>>(aux, out);
      zeroi_kernel<<<1, 32, 0, stream>>>(cnt, 8);
      build_list_kernel<<<8, 256, 0, stream>>>(wmoe, cnt, list, tokp);
      prefix_kernel<<<1, 64, 0, stream>>>(cnt, off8);
      gemm_moe_guf_kernel<<<dim3(44, 16, 8), 256, 0, stream>>>(
          hnh, mgh, muh, a2, wmoe, list, cnt, off8);
      gemm_moe_down2_kernel<<<dim3(16, 16, 8), 256, 0, stream>>>(
          a2, mdh, y2, cnt, off8);
      moe_scatter_kernel<<<SEQ, 256, 0, stream>>>(tokp, off8, y2, h);
    } else {
      int d = (li < 2) ? li : li - 1;
      size_t go = (size_t)d * HID * IDIM;
      if (comp) {
        gemm_bt_kernel<true, false, false, 128, false><<<dim3(22, 16, 2), 256, 0, stream>>>(
            hnh, hnl, dgh + go, dgl + go, duh + go, dul + go,
            duh + go, dul + go, g, u, u, SEQ, IDIM, HID);
        silu_kernel<<<dim3(11, SEQ), 256, 0, stream>>>(g, u, gh, gl);
        gemm_bt_kernel<true, true, false, 64, false><<<dim3(8, 32, 1), 256, 0, stream>>>(
            gh, gl, ddh + go, ddl + go, ddh + go, ddl + go,
            ddh + go, ddl + go, h, h, h, SEQ, HID, IDIM);
      } else {
        gemm_bt_kernel<false, false, false, 128, false><<<dim3(22, 16, 2), 256, 0, stream>>>(
            hnh, hnh, dgh + go, dgh + go, duh + go, duh + go,
            duh + go, duh + go, g, u, u, SEQ, IDIM, HID);
        silu_kernel<<<dim3(11, SEQ), 256, 0, stream>>>(g, u, gh, gl);
        gemm_bt_kernel<false, true, false, 64, false><<<dim3(8, 32, 1), 256, 0, stream>>>(
            gh, gh, ddh + go, ddh + go, ddh + go, ddh + go,
            ddh + go, ddh + go, h, h, h, SEQ, HID, IDIM);
      }
    }
  }
  rmsnorm_kernel<<<SEQ, 256, 0, stream>>>(h, fin, hn, hnh, hnl);
  // logits: XCD-aware bijective swizzle (padded 1D grid; bn>=250 exits)
  gemm_bt_kernel<false, false, false, 128, true><<<dim3(4096, 1, 1), 256, 0, stream>>>(
      hnh, hnh, eh, eh, eh, eh, eh, eh, out, out, out, SEQ, VOCAB, HID);
}

// Round 17
// 1928.406 us; speedup vs baseline: 1.1984x; 1.0136x over previous
//
#include <hip/hip_runtime.h>
#include <hip/hip_bf16.h>
#include <math.h>

#define SEQ 2048
#define HID 1024
#define NHEAD 16
#define HDIM 64
#define IDIM 2816
#define NEXP 8
#define VOCAB 32000

#define ASTRIDE 144  // padded rows (attention)

typedef float f32x4v __attribute__((ext_vector_type(4)));
typedef __bf16 bf16x8v __attribute__((ext_vector_type(8)));
typedef __bf16 bf16x4v __attribute__((ext_vector_type(4)));

__device__ __forceinline__ bf16x8v cvt8(const float4& a, const float4& b) {
  bf16x8v r;
  r[0] = (__bf16)a.x; r[1] = (__bf16)a.y; r[2] = (__bf16)a.z; r[3] = (__bf16)a.w;
  r[4] = (__bf16)b.x; r[5] = (__bf16)b.y; r[6] = (__bf16)b.z; r[7] = (__bf16)b.w;
  return r;
}

#define MFMA(a, b, c) __builtin_amdgcn_mfma_f32_16x16x32_bf16(a, b, c, 0, 0, 0)

// async global->LDS DMA, 16B per lane; lds base must be wave-uniform
__device__ __forceinline__ void gld_lds16(const void* g, void* l) {
  __builtin_amdgcn_global_load_lds(
      (const __attribute__((address_space(1))) unsigned int*)(unsigned long long)g,
      (__attribute__((address_space(3))) unsigned int*)(unsigned int)(unsigned long long)l,
      16, 0, 0);
}

// ---------------------------------------------------------------------------
// Weight preprocessing: W[K,N] f32 -> WH,WL [N,K] bf16 (transposed hi/lo).
// ---------------------------------------------------------------------------
__global__ __launch_bounds__(256) void wsplit_t_kernel(
    const float* __restrict__ W, __bf16* __restrict__ WH, __bf16* __restrict__ WL,
    int K, int N)
{
  __shared__ float tile[64][65];
  const int tid = threadIdx.x;
  const size_t zofs = (size_t)blockIdx.z * K * N;
  const int n0 = blockIdx.x * 64, k0 = blockIdx.y * 64;
#pragma unroll
  for (int r = 0; r < 4; ++r) {
    int kk = (tid >> 4) + r * 16;
    int nn = (tid & 15) * 4;
    float4 v = *(const float4*)(W + zofs + (size_t)(k0 + kk) * N + n0 + nn);
    tile[kk][nn] = v.x; tile[kk][nn + 1] = v.y;
    tile[kk][nn + 2] = v.z; tile[kk][nn + 3] = v.w;
  }
  __syncthreads();
  const int nn = tid >> 2;
  const int kk = (tid & 3) * 16;
  __bf16* dh = WH + zofs + (size_t)(n0 + nn) * K + k0 + kk;
  __bf16* dl = WL + zofs + (size_t)(n0 + nn) * K + k0 + kk;
  bf16x8v h0, l0, h1, l1;
#pragma unroll
  for (int j = 0; j < 8; ++j) {
    float f = tile[kk + j][nn];
    __bf16 hb = (__bf16)f; h0[j] = hb; l0[j] = (__bf16)(f - (float)hb);
    f = tile[kk + 8 + j][nn];
    hb = (__bf16)f; h1[j] = hb; l1[j] = (__bf16)(f - (float)hb);
  }
  *(bf16x8v*)dh = h0; *(bf16x8v*)(dh + 8) = h1;
  *(bf16x8v*)dl = l0; *(bf16x8v*)(dl + 8) = l1;
}

// hi-only variant (MoE weights; plain-bf16 path needs no lo)
__global__ __launch_bounds__(256) void wsplit_th_kernel(
    const float* __restrict__ W, __bf16* __restrict__ WH, int K, int N)
{
  __shared__ float tile[64][65];
  const int tid = threadIdx.x;
  const size_t zofs = (size_t)blockIdx.z * K * N;
  const int n0 = blockIdx.x * 64, k0 = blockIdx.y * 64;
#pragma unroll
  for (int r = 0; r < 4; ++r) {
    int kk = (tid >> 4) + r * 16;
    int nn = (tid & 15) * 4;
    float4 v = *(const float4*)(W + zofs + (size_t)(k0 + kk) * N + n0 + nn);
    tile[kk][nn] = v.x; tile[kk][nn + 1] = v.y;
    tile[kk][nn + 2] = v.z; tile[kk][nn + 3] = v.w;
  }
  __syncthreads();
  const int nn = tid >> 2;
  const int kk = (tid & 3) * 16;
  __bf16* dh = WH + zofs + (size_t)(n0 + nn) * K + k0 + kk;
  bf16x8v h0, h1;
#pragma unroll
  for (int j = 0; j < 8; ++j) {
    h0[j] = (__bf16)tile[kk + j][nn];
    h1[j] = (__bf16)tile[kk + 8 + j][nn];
  }
  *(bf16x8v*)dh = h0; *(bf16x8v*)(dh + 8) = h1;
}

__global__ __launch_bounds__(256) void esplit_kernel(
    const float* __restrict__ E, __bf16* __restrict__ EH)
{
  size_t i = ((size_t)blockIdx.x * 256 + threadIdx.x) * 8;
  float4 a = *(const float4*)(E + i);
  float4 b = *(const float4*)(E + i + 4);
  *(bf16x8v*)(EH + i) = cvt8(a, b);
}

// ---------------------------------------------------------------------------
// Unified BT GEMM. A,B pre-split bf16. Staging = global_load_lds DMA (16B),
// LINEAR LDS rows (64B/row). XSWZ: XCD-aware bijective 1D grid (logits).
// ---------------------------------------------------------------------------
template<bool COMP, bool ACCUM, bool SWAP, int BM, bool XSWZ>
__global__ __launch_bounds__(256) void gemm_bt_kernel(
    const __bf16* __restrict__ Ah, const __bf16* __restrict__ Al,
    const __bf16* __restrict__ B0h, const __bf16* __restrict__ B0l,
    const __bf16* __restrict__ B1h, const __bf16* __restrict__ B1l,
    const __bf16* __restrict__ B2h, const __bf16* __restrict__ B2l,
    float* __restrict__ C0, float* __restrict__ C1, float* __restrict__ C2,
    int M, int N, int Kd)
{
  const __bf16* __restrict__ Bh = (blockIdx.z == 0) ? B0h : (blockIdx.z == 1 ? B1h : B2h);
  const __bf16* __restrict__ Bl = (blockIdx.z == 0) ? B0l : (blockIdx.z == 1 ? B1l : B2l);
  float* __restrict__ C         = (blockIdx.z == 0) ? C0 : (blockIdx.z == 1 ? C1 : C2);
  constexpr int ATILE = BM * 64;
  constexpr int BTILE = 128 * 64;
  constexpr int MFR = BM / 32;
  __shared__ __align__(16) char smem[COMP ? 2 * (ATILE + BTILE) : (ATILE + BTILE)];
  char* AsH = smem;
  char* BsH = smem + ATILE;
  char* AsL = COMP ? smem + ATILE + BTILE : smem;
  char* BsL = COMP ? smem + 2 * ATILE + BTILE : smem + ATILE;
  const int tid = threadIdx.x;
  int bm, bn;
  if (XSWZ) {
    int id = blockIdx.x;            // padded grid (e.g. 4096)
    int xcd = id & 7;
    int j = id >> 3;
    bm = j & 15;
    bn = xcd * 32 + (j >> 4);
    if (bn >= N / 128) return;
  } else {
    bm = SWAP ? blockIdx.x : blockIdx.y;
    bn = SWAP ? blockIdx.y : blockIdx.x;
  }
  const int wid = tid >> 6, lane = tid & 63;
  const int wm = (wid >> 1) * (BM / 2), wn = (wid & 1) << 6;
  const int lr = lane & 15, kh = lane >> 4;
  const int lrow = lane >> 2;
  const int lcol = (lane & 3) << 3;

  f32x4v acc[MFR][4];
  const f32x4v z4 = {0.f, 0.f, 0.f, 0.f};
#pragma unroll
  for (int i = 0; i < MFR; ++i)
#pragma unroll
    for (int j2 = 0; j2 < 4; ++j2) acc[i][j2] = z4;

  for (int k0 = 0; k0 < Kd; k0 += 32) {
    __syncthreads();
#pragma unroll
    for (int c = wid; c < BM / 16; c += 4) {
      size_t gofs = (size_t)(bm * BM + c * 16 + lrow) * Kd + k0 + lcol;
      gld_lds16(Ah + gofs, AsH + c * 1024);
      if (COMP) gld_lds16(Al + gofs, AsL + c * 1024);
    }
#pragma unroll
    for (int c = wid; c < 8; c += 4) {
      size_t gofs = (size_t)(bn * 128 + c * 16 + lrow) * Kd + k0 + lcol;
      gld_lds16(Bh + gofs, BsH + c * 1024);
      if (COMP) gld_lds16(Bl + gofs, BsL + c * 1024);
    }
    __syncthreads();

    bf16x8v ah[MFR], al[MFR], bh4[4], bl4[4];
#pragma unroll
    for (int i = 0; i < MFR; ++i) {
      int r = wm + (i << 4) + lr;
      int off = r * 64 + (kh << 4);
      ah[i] = *(const bf16x8v*)(AsH + off);
      if (COMP) al[i] = *(const bf16x8v*)(AsL + off);
    }
#pragma unroll
    for (int i = 0; i < 4; ++i) {
      int r = wn + (i << 4) + lr;
      int off = r * 64 + (kh << 4);
      bh4[i] = *(const bf16x8v*)(BsH + off);
      if (COMP) bl4[i] = *(const bf16x8v*)(BsL + off);
    }
#pragma unroll
    for (int mi = 0; mi < MFR; ++mi)
#pragma unroll
      for (int ni = 0; ni < 4; ++ni) {
        if (COMP) {
          acc[mi][ni] = MFMA(al[mi], bh4[ni], acc[mi][ni]);
          acc[mi][ni] = MFMA(ah[mi], bl4[ni], acc[mi][ni]);
        }
        acc[mi][ni] = MFMA(ah[mi], bh4[ni], acc[mi][ni]);
      }
  }

  const int cr0 = kh << 2;
#pragma unroll
  for (int mi = 0; mi < MFR; ++mi)
#pragma unroll
    for (int ni = 0; ni < 4; ++ni)
#pragma unroll
      for (int r = 0; r < 4; ++r) {
        int row = bm * BM + wm + (mi << 4) + cr0 + r;
        int col = bn * 128 + wn + (ni << 4) + lr;
        size_t idx = (size_t)row * N + col;
        if (ACCUM) C[idx] += acc[mi][ni][r];
        else       C[idx] = acc[mi][ni][r];
      }
}

// ---------------------------------------------------------------------------
// QKV GEMM with fused rope + hi/lo split epilogue (z=0 q scale 1/8, z=1 k),
// z=2 writes f32 v (for vtsplit). BM=64, N=K=HID. Bit-exact vs GEMM+rope_split.
// ---------------------------------------------------------------------------
template<bool COMP>
__global__ __launch_bounds__(256) void gemm_qkv_kernel(
    const __bf16* __restrict__ Ah, const __bf16* __restrict__ Al,
    const __bf16* __restrict__ Bqh, const __bf16* __restrict__ Bql,
    const __bf16* __restrict__ Bkh, const __bf16* __restrict__ Bkl,
    const __bf16* __restrict__ Bvh, const __bf16* __restrict__ Bvl,
    __bf16* __restrict__ QH, __bf16* __restrict__ QL,
    __bf16* __restrict__ KH, __bf16* __restrict__ KL,
    float* __restrict__ Vout,
    const float* __restrict__ CT, const float* __restrict__ ST)
{
  const __bf16* __restrict__ Bh = (blockIdx.z == 0) ? Bqh : (blockIdx.z == 1 ? Bkh : Bvh);
  const __bf16* __restrict__ Bl = (blockIdx.z == 0) ? Bql : (blockIdx.z == 1 ? Bkl : Bvl);
  constexpr int ATILE = 64 * 64;
  constexpr int BTILE = 128 * 64;
  __shared__ __align__(16) char smem[COMP ? 2 * (ATILE + BTILE) : (ATILE + BTILE)];
  char* AsH = smem;
  char* BsH = smem + ATILE;
  char* AsL = COMP ? smem + ATILE + BTILE : smem;
  char* BsL = COMP ? smem + 2 * ATILE + BTILE : smem + ATILE;
  const int tid = threadIdx.x;
  const int bm = blockIdx.y, bn = blockIdx.x;
  const int wid = tid >> 6, lane = tid & 63;
  const int wm = (wid >> 1) << 5, wn = (wid & 1) << 6;
  const int lr = lane & 15, kh = lane >> 4;
  const int lrow = lane >> 2;
  const int lcol = (lane & 3) << 3;

  f32x4v acc[2][4];
  const f32x4v z4 = {0.f, 0.f, 0.f, 0.f};
#pragma unroll
  for (int i = 0; i < 2; ++i)
#pragma unroll
    for (int j2 = 0; j2 < 4; ++j2) acc[i][j2] = z4;

  for (int k0 = 0; k0 < HID; k0 += 32) {
    __syncthreads();
    {
      int c = wid;   // A: 4 chunks
      size_t gofs = (size_t)(bm * 64 + c * 16 + lrow) * HID + k0 + lcol;
      gld_lds16(Ah + gofs, AsH + c * 1024);
      if (COMP) gld_lds16(Al + gofs, AsL + c * 1024);
    }
#pragma unroll
    for (int c = wid; c < 8; c += 4) {
      size_t gofs = (size_t)(bn * 128 + c * 16 + lrow) * HID + k0 + lcol;
      gld_lds16(Bh + gofs, BsH + c * 1024);
      if (COMP) gld_lds16(Bl + gofs, BsL + c * 1024);
    }
    __syncthreads();

    bf16x8v ah2[2], al2[2], bh4[4], bl4[4];
#pragma unroll
    for (int i = 0; i < 2; ++i) {
      int r = wm + (i << 4) + lr;
      int off = r * 64 + (kh << 4);
      ah2[i] = *(const bf16x8v*)(AsH + off);
      if (COMP) al2[i] = *(const bf16x8v*)(AsL + off);
    }
#pragma unroll
    for (int i = 0; i < 4; ++i) {
      int r = wn + (i << 4) + lr;
      int off = r * 64 + (kh << 4);
      bh4[i] = *(const bf16x8v*)(BsH + off);
      if (COMP) bl4[i] = *(const bf16x8v*)(BsL + off);
    }
#pragma unroll
    for (int mi = 0; mi < 2; ++mi)
#pragma unroll
      for (int ni = 0; ni < 4; ++ni) {
        if (COMP) {
          acc[mi][ni] = MFMA(al2[mi], bh4[ni], acc[mi][ni]);
          acc[mi][ni] = MFMA(ah2[mi], bl4[ni], acc[mi][ni]);
        }
        acc[mi][ni] = MFMA(ah2[mi], bh4[ni], acc[mi][ni]);
      }
  }

  const int cr0 = kh << 2;
  if (blockIdx.z == 2) {
#pragma unroll
    for (int mi = 0; mi < 2; ++mi)
#pragma unroll
      for (int ni = 0; ni < 4; ++ni)
#pragma unroll
        for (int r = 0; r < 4; ++r) {
          int row = bm * 64 + wm + (mi << 4) + cr0 + r;
          int col = bn * 128 + wn + (ni << 4) + lr;
          Vout[(size_t)row * HID + col] = acc[mi][ni][r];
        }
  } else {
    const float scale = (blockIdx.z == 0) ? 0.125f : 1.0f;
    __bf16* OH = (blockIdx.z == 0) ? QH : KH;
    __bf16* OL = (blockIdx.z == 0) ? QL : KL;
#pragma unroll
    for (int mi = 0; mi < 2; ++mi)
#pragma unroll
      for (int ni = 0; ni < 2; ++ni)
#pragma unroll
        for (int r = 0; r < 4; ++r) {
          int row = bm * 64 + wm + (mi << 4) + cr0 + r;
          int col = bn * 128 + wn + (ni << 4) + lr;   // (col&63) < 32
          int i = col & 31;
          float c = CT[row * 32 + i], sn = ST[row * 32 + i];
          float x1 = acc[mi][ni][r];
          float x2 = acc[mi][ni + 2][r];
          float o1 = (x1 * c - x2 * sn) * scale;
          float o2 = (x2 * c + x1 * sn) * scale;
          size_t ofs = (size_t)row * HID + col;
          __bf16 h1 = (__bf16)o1;
          OH[ofs] = h1; OL[ofs] = (__bf16)(o1 - (float)h1);
          __bf16 h2 = (__bf16)o2;
          OH[ofs + 32] = h2; OL[ofs + 32] = (__bf16)(o2 - (float)h2);
        }
  }
}

// ---------------------------------------------------------------------------
// Dense gate+up GEMM with fused silu + hi/lo split epilogue. BM=64, BN=64.
// Bit-exact vs separate gate/up GEMMs + silu kernel (same MFMA chains).
// ---------------------------------------------------------------------------
template<bool COMP>
__global__ __launch_bounds__(256) void gemm_dgu_kernel(
    const __bf16* __restrict__ Ah, const __bf16* __restrict__ Al,
    const __bf16* __restrict__ BGh, const __bf16* __restrict__ BGl,
    const __bf16* __restrict__ BUh, const __bf16* __restrict__ BUl,
    __bf16* __restrict__ GH, __bf16* __restrict__ GL)
{
  __shared__ __align__(16) char AsH[4096], AsL[4096];
  __shared__ __align__(16) char BgH[4096], BgL[4096];
  __shared__ __align__(16) char BuH[4096], BuL[4096];
  const int tid = threadIdx.x;
  const int bn = blockIdx.x, bm = blockIdx.y;
  const int wid = tid >> 6, lane = tid & 63;
  const int wm = (wid >> 1) << 5, wn = (wid & 1) << 5;
  const int lr = lane & 15, kh = lane >> 4;
  const int lrow = lane >> 2;
  const int lcol = (lane & 3) << 3;

  f32x4v accg[2][2], accu[2][2];
  const f32x4v z4 = {0.f, 0.f, 0.f, 0.f};
#pragma unroll
  for (int i = 0; i < 2; ++i)
#pragma unroll
    for (int j = 0; j < 2; ++j) { accg[i][j] = z4; accu[i][j] = z4; }

  for (int k0 = 0; k0 < HID; k0 += 32) {
    __syncthreads();
    {
      int c = wid;   // 4 chunks each buffer
      size_t aofs = (size_t)(bm * 64 + c * 16 + lrow) * HID + k0 + lcol;
      gld_lds16(Ah + aofs, AsH + c * 1024);
      if (COMP) gld_lds16(Al + aofs, AsL + c * 1024);
      size_t bofs = (size_t)(bn * 64 + c * 16 + lrow) * HID + k0 + lcol;
      gld_lds16(BGh + bofs, BgH + c * 1024);
      gld_lds16(BUh + bofs, BuH + c * 1024);
      if (COMP) {
        gld_lds16(BGl + bofs, BgL + c * 1024);
        gld_lds16(BUl + bofs, BuL + c * 1024);
      }
    }
    __syncthreads();

    bf16x8v af[2], afl[2], bg4[2], bgl4[2], bu4[2], bul4[2];
#pragma unroll
    for (int i = 0; i < 2; ++i) {
      int r = wm + (i << 4) + lr;
      int off = r * 64 + (kh << 4);
      af[i] = *(const bf16x8v*)(AsH + off);
      if (COMP) afl[i] = *(const bf16x8v*)(AsL + off);
    }
#pragma unroll
    for (int i = 0; i < 2; ++i) {
      int r = wn + (i << 4) + lr;
      int off = r * 64 + (kh << 4);
      bg4[i] = *(const bf16x8v*)(BgH + off);
      bu4[i] = *(const bf16x8v*)(BuH + off);
      if (COMP) {
        bgl4[i] = *(const bf16x8v*)(BgL + off);
        bul4[i] = *(const bf16x8v*)(BuL + off);
      }
    }
#pragma unroll
    for (int mi = 0; mi < 2; ++mi)
#pragma unroll
      for (int ni = 0; ni < 2; ++ni) {
        if (COMP) {
          accg[mi][ni] = MFMA(afl[mi], bg4[ni], accg[mi][ni]);
          accg[mi][ni] = MFMA(af[mi], bgl4[ni], accg[mi][ni]);
        }
        accg[mi][ni] = MFMA(af[mi], bg4[ni], accg[mi][ni]);
        if (COMP) {
          accu[mi][ni] = MFMA(afl[mi], bu4[ni], accu[mi][ni]);
          accu[mi][ni] = MFMA(af[mi], bul4[ni], accu[mi][ni]);
        }
        accu[mi][ni] = MFMA(af[mi], bu4[ni], accu[mi][ni]);
      }
  }

  const int cr0 = kh << 2;
#pragma unroll
  for (int mi = 0; mi < 2; ++mi)
#pragma unroll
    for (int ni = 0; ni < 2; ++ni)
#pragma unroll
      for (int r = 0; r < 4; ++r) {
        int row = bm * 64 + wm + (mi << 4) + cr0 + r;
        int col = bn * 64 + wn + (ni << 4) + lr;
        float gv = accg[mi][ni][r];
        float uv = accu[mi][ni][r];
        float a = gv / (1.f + __expf(-gv)) * uv;
        size_t idx = (size_t)row * IDIM + col;
        __bf16 hb = (__bf16)a;
        GH[idx] = hb;
        GL[idx] = (__bf16)(a - (float)hb);
      }
}

// V f32 [S][HID] -> per-head transposed hi/lo bf16 [NHEAD][HDIM][SEQ]
__global__ __launch_bounds__(256) void vtsplit_kernel(
    const float* __restrict__ V, __bf16* __restrict__ VTH, __bf16* __restrict__ VTL)
{
  __shared__ float tile[64][65];
  const int tid = threadIdx.x;
  const int s0 = blockIdx.x * 64;
  const int head = blockIdx.y;
#pragma unroll
  for (int r = 0; r < 4; ++r) {
    int ss = (tid >> 4) + r * 16;
    int dd = (tid & 15) * 4;
    float4 v = *(const float4*)(V + (size_t)(s0 + ss) * HID + head * 64 + dd);
    tile[ss][dd] = v.x; tile[ss][dd + 1] = v.y;
    tile[ss][dd + 2] = v.z; tile[ss][dd + 3] = v.w;
  }
  __syncthreads();
#pragma unroll
  for (int half = 0; half < 2; ++half) {
    const int d = (tid >> 3) + (half << 5);
    const int c = tid & 7;
    bf16x8v hv, lv;
#pragma unroll
    for (int j = 0; j < 8; ++j) {
      float f = tile[c * 8 + j][d];
      __bf16 hb = (__bf16)f;
      hv[j] = hb; lv[j] = (__bf16)(f - (float)hb);
    }
    size_t dst = (size_t)(head * 64 + d) * SEQ + s0 + c * 8;
    *(bf16x8v*)(VTH + dst) = hv;
    *(bf16x8v*)(VTL + dst) = lv;
  }
}

// ---------------------------------------------------------------------------
// Compensated flash attention; padded LDS; O -> bf16 hi/lo.
// Load-balanced: grid (16,16); block processes qt = bx and qt = 31-bx.
// ---------------------------------------------------------------------------
__global__ __launch_bounds__(256) void attn_flash_kernel(
    const __bf16* __restrict__ QH, const __bf16* __restrict__ QL,
    const __bf16* __restrict__ KH, const __bf16* __restrict__ KL,
    const __bf16* __restrict__ VTH, const __bf16* __restrict__ VTL,
    __bf16* __restrict__ OH, __bf16* __restrict__ OL)
{
  const int head = blockIdx.y;
  const int tid = threadIdx.x, wid = tid >> 6, lane = tid & 63;
  const int lr = lane & 15, kh = lane >> 4;
  __shared__ __align__(16) char KsH[64 * ASTRIDE], KsL[64 * ASTRIDE];
  __shared__ __align__(16) char VtH[64 * ASTRIDE], VtL[64 * ASTRIDE];
  __shared__ __align__(16) char PsH[4][16 * ASTRIDE], PsL[4][16 * ASTRIDE];

#pragma unroll
  for (int seg = 0; seg < 2; ++seg) {
    const int qt = seg ? (31 - (int)blockIdx.x) : (int)blockIdx.x;

    const size_t qofs = (size_t)(qt * 64 + wid * 16 + lr) * HID + head * HDIM;
    const bf16x8v qfh0 = *(const bf16x8v*)(QH + qofs + (kh << 3));
    const bf16x8v qfh1 = *(const bf16x8v*)(QH + qofs + 32 + (kh << 3));
    const bf16x8v qfl0 = *(const bf16x8v*)(QL + qofs + (kh << 3));
    const bf16x8v qfl1 = *(const bf16x8v*)(QL + qofs + 32 + (kh << 3));

    float m_run[4], l_run[4];
    f32x4v oacc[4];
    const f32x4v z4 = {0.f, 0.f, 0.f, 0.f};
#pragma unroll
    for (int i = 0; i < 4; ++i) { m_run[i] = -1e30f; l_run[i] = 0.f; oacc[i] = z4; }

    for (int kt = 0; kt <= qt; ++kt) {
      __syncthreads();
#pragma unroll
      for (int p = 0; p < 2; ++p) {
        int g = tid + (p << 8);
        int r = g >> 3;
        int c = g & 7;
        int off = r * ASTRIDE + (c << 4);
        const size_t kofs = (size_t)(kt * 64 + r) * HID + head * HDIM + (c << 3);
        *(bf16x8v*)(KsH + off) = *(const bf16x8v*)(KH + kofs);
        *(bf16x8v*)(KsL + off) = *(const bf16x8v*)(KL + kofs);
        const size_t vofs = (size_t)(head * 64 + r) * SEQ + kt * 64 + (c << 3);
        *(bf16x8v*)(VtH + off) = *(const bf16x8v*)(VTH + vofs);
        *(bf16x8v*)(VtL + off) = *(const bf16x8v*)(VTL + vofs);
      }
      __syncthreads();

      float sv[4][4];
#pragma unroll
      for (int stt = 0; stt < 4; ++stt) {
        int r = (stt << 4) + lr;
        int off0 = r * ASTRIDE + (kh << 4);
        int off1 = off0 + 64;
        bf16x8v kfh0 = *(const bf16x8v*)(KsH + off0);
        bf16x8v kfl0 = *(const bf16x8v*)(KsL + off0);
        bf16x8v kfh1 = *(const bf16x8v*)(KsH + off1);
        bf16x8v kfl1 = *(const bf16x8v*)(KsL + off1);
        f32x4v s = z4;
        s = MFMA(qfl0, kfh0, s);
        s = MFMA(qfh0, kfl0, s);
        s = MFMA(qfh0, kfh0, s);
        s = MFMA(qfl1, kfh1, s);
        s = MFMA(qfh1, kfl1, s);
        s = MFMA(qfh1, kfh1, s);
        int key = kt * 64 + (stt << 4) + lr;
#pragma unroll
        for (int rr = 0; rr < 4; ++rr) {
          int qr = qt * 64 + wid * 16 + (kh << 2) + rr;
          sv[stt][rr] = (key <= qr) ? s[rr] : -1e30f;
        }
      }

#pragma unroll
      for (int rr = 0; rr < 4; ++rr) {
        float mx = fmaxf(fmaxf(sv[0][rr], sv[1][rr]), fmaxf(sv[2][rr], sv[3][rr]));
#pragma unroll
        for (int d = 1; d < 16; d <<= 1) mx = fmaxf(mx, __shfl_xor(mx, d));
        float mnew = fmaxf(m_run[rr], mx);
        float scl = __expf(m_run[rr] - mnew);
        float pv[4];
#pragma unroll
        for (int stt = 0; stt < 4; ++stt) pv[stt] = __expf(sv[stt][rr] - mnew);
        float rs = pv[0] + pv[1] + pv[2] + pv[3];
#pragma unroll
        for (int d = 1; d < 16; d <<= 1) rs += __shfl_xor(rs, d);
        l_run[rr] = l_run[rr] * scl + rs;
        m_run[rr] = mnew;
#pragma unroll
        for (int n = 0; n < 4; ++n) oacc[n][rr] *= scl;
        int qlr = (kh << 2) + rr;
#pragma unroll
        for (int stt = 0; stt < 4; ++stt) {
          __bf16 hb = (__bf16)pv[stt];
          __bf16 lb = (__bf16)(pv[stt] - (float)hb);
          int off = qlr * ASTRIDE + (((stt << 4) + lr) << 1);
          *(__bf16*)(PsH[wid] + off) = hb;
          *(__bf16*)(PsL[wid] + off) = lb;
        }
      }

      int poff0 = lr * ASTRIDE + (kh << 4);
      int poff1 = poff0 + 64;
      bf16x8v pah0 = *(const bf16x8v*)(PsH[wid] + poff0);
      bf16x8v pal0 = *(const bf16x8v*)(PsL[wid] + poff0);
      bf16x8v pah1 = *(const bf16x8v*)(PsH[wid] + poff1);
      bf16x8v pal1 = *(const bf16x8v*)(PsL[wid] + poff1);
#pragma unroll
      for (int n = 0; n < 4; ++n) {
        int vr = (n << 4) + lr;
        int voff0 = vr * ASTRIDE + (kh << 4);
        int voff1 = voff0 + 64;
        bf16x8v vfh0 = *(const bf16x8v*)(VtH + voff0);
        bf16x8v vfl0 = *(const bf16x8v*)(VtL + voff0);
        bf16x8v vfh1 = *(const bf16x8v*)(VtH + voff1);
        bf16x8v vfl1 = *(const bf16x8v*)(VtL + voff1);
        oacc[n] = MFMA(pal0, vfh0, oacc[n]);
        oacc[n] = MFMA(pah0, vfl0, oacc[n]);
        oacc[n] = MFMA(pah0, vfh0, oacc[n]);
        oacc[n] = MFMA(pal1, vfh1, oacc[n]);
        oacc[n] = MFMA(pah1, vfl1, oacc[n]);
        oacc[n] = MFMA(pah1, vfh1, oacc[n]);
      }
    }

#pragma unroll
    for (int n = 0; n < 4; ++n)
#pragma unroll
      for (int rr = 0; rr < 4; ++rr) {
        int qr = qt * 64 + wid * 16 + (kh << 2) + rr;
        size_t ofs = (size_t)qr * HID + head * HDIM + (n << 4) + lr;
        float val = oacc[n][rr] / l_run[rr];
        __bf16 hb = (__bf16)val;
        OH[ofs] = hb;
        OL[ofs] = (__bf16)(val - (float)hb);
      }
  }
}

// ---------------------------------------------------------------------------
// MoE: fused gate+up+silu. BM=128, BN=64. DMA staging, pre-split weights.
// ---------------------------------------------------------------------------
__global__ __launch_bounds__(256) void gemm_moe_guf_kernel(
    const __bf16* __restrict__ Xh,
    const __bf16* __restrict__ MGH, const __bf16* __restrict__ MUH,
    __bf16* __restrict__ A2, const float* __restrict__ W,
    const int* __restrict__ list, const int* __restrict__ cnt8,
    const int* __restrict__ off8)
{
  const int e = blockIdx.z;
  const int cnt = cnt8[e];
  const int bn = blockIdx.x, bm = blockIdx.y;
  if (bm * 128 >= cnt) return;
  const int base = off8[e];
  __shared__ __align__(16) char AsB[8192];
  __shared__ __align__(16) char BgB[4096];
  __shared__ __align__(16) char BuB[4096];
  const int tid = threadIdx.x;
  const int wid = tid >> 6, lane = tid & 63;
  const int wm = (wid >> 1) << 6, wn = (wid & 1) << 5;
  const int lr = lane & 15, kh = lane >> 4;
  const int lrow = lane >> 2;
  const int lcol = (lane & 3) << 3;

  f32x4v accg[4][2], accu[4][2];
  const f32x4v z4 = {0.f, 0.f, 0.f, 0.f};
#pragma unroll
  for (int i = 0; i < 4; ++i)
#pragma unroll
    for (int j = 0; j < 2; ++j) { accg[i][j] = z4; accu[i][j] = z4; }

  for (int k0 = 0; k0 < HID; k0 += 32) {
    __syncthreads();
#pragma unroll
    for (int c = wid; c < 8; c += 4) {     // A: 128 rows
      int rg = bm * 128 + c * 16 + lrow;
      int tok = list[e * SEQ + (rg < cnt ? rg : cnt - 1)];
      gld_lds16(Xh + (size_t)tok * HID + k0 + lcol, AsB + c * 1024);
    }
    {                                       // B: 64 rows each (g,u)
      int c = wid;
      size_t wofs = (size_t)(e * IDIM + bn * 64 + c * 16 + lrow) * HID + k0 + lcol;
      gld_lds16(MGH + wofs, BgB + c * 1024);
      gld_lds16(MUH + wofs, BuB + c * 1024);
    }
    __syncthreads();

    bf16x8v af[4], bg4[2], bu4[2];
#pragma unroll
    for (int i = 0; i < 4; ++i) {
      int r = wm + (i << 4) + lr;
      af[i] = *(const bf16x8v*)(AsB + r * 64 + (kh << 4));
    }
#pragma unroll
    for (int i = 0; i < 2; ++i) {
      int r = wn + (i << 4) + lr;
      bg4[i] = *(const bf16x8v*)(BgB + r * 64 + (kh << 4));
      bu4[i] = *(const bf16x8v*)(BuB + r * 64 + (kh << 4));
    }
#pragma unroll
    for (int mi = 0; mi < 4; ++mi)
#pragma unroll
      for (int ni = 0; ni < 2; ++ni) {
        accg[mi][ni] = MFMA(af[mi], bg4[ni], accg[mi][ni]);
        accu[mi][ni] = MFMA(af[mi], bu4[ni], accu[mi][ni]);
      }
  }

  const int cr0 = kh << 2;
#pragma unroll
  for (int mi = 0; mi < 4; ++mi)
#pragma unroll
    for (int ni = 0; ni < 2; ++ni)
#pragma unroll
      for (int r = 0; r < 4; ++r) {
        int row = bm * 128 + wm + (mi << 4) + cr0 + r;
        if (row < cnt) {
          int col = bn * 64 + wn + (ni << 4) + lr;
          int tok = list[e * SEQ + row];
          float w = W[tok * 8 + e];
          float gval = accg[mi][ni][r];
          float uval = accu[mi][ni][r];
          float a = gval / (1.f + __expf(-gval)) * uval * w;
          A2[(size_t)(base + row) * IDIM + col] = (__bf16)a;
        }
      }
}

__global__ __launch_bounds__(256) void gemm_moe_down2_kernel(
    const __bf16* __restrict__ A2, const __bf16* __restrict__ MDH,
    float* __restrict__ Y2,
    const int* __restrict__ cnt8, const int* __restrict__ off8)
{
  const int e = blockIdx.z;
  const int cnt = cnt8[e];
  const int bn = blockIdx.x, bm = blockIdx.y;
  if (bm * 128 >= cnt) return;
  const int base = off8[e];
  __shared__ __align__(16) char AsB[8192];
  __shared__ __align__(16) char BsB[4096];
  const int tid = threadIdx.x;
  const int wid = tid >> 6, lane = tid & 63;
  const int wm = (wid >> 1) << 6, wn = (wid & 1) << 5;
  const int lr = lane & 15, kh = lane >> 4;
  const int lrow = lane >> 2;
  const int lcol = (lane & 3) << 3;

  f32x4v acc[4][2];
  const f32x4v z4 = {0.f, 0.f, 0.f, 0.f};
#pragma unroll
  for (int i = 0; i < 4; ++i)
#pragma unroll
    for (int j = 0; j < 2; ++j) acc[i][j] = z4;

  for (int k0 = 0; k0 < IDIM; k0 += 32) {
    __syncthreads();
#pragma unroll
    for (int c = wid; c < 8; c += 4) {
      int rg = bm * 128 + c * 16 + lrow;
      int row = (rg < cnt ? rg : cnt - 1);
      gld_lds16(A2 + (size_t)(base + row) * IDIM + k0 + lcol, AsB + c * 1024);
    }
    {
      int c = wid;
      gld_lds16(MDH + (size_t)(e * HID + bn * 64 + c * 16 + lrow) * IDIM + k0 + lcol,
                BsB + c * 1024);
    }
    __syncthreads();

    bf16x8v af[4], bfv[2];
#pragma unroll
    for (int i = 0; i < 4; ++i) {
      int r = wm + (i << 4) + lr;
      af[i] = *(const bf16x8v*)(AsB + r * 64 + (kh << 4));
    }
#pragma unroll
    for (int i = 0; i < 2; ++i) {
      int r = wn + (i << 4) + lr;
      bfv[i] = *(const bf16x8v*)(BsB + r * 64 + (kh << 4));
    }
#pragma unroll
    for (int mi = 0; mi < 4; ++mi)
#pragma unroll
      for (int ni = 0; ni < 2; ++ni)
        acc[mi][ni] = MFMA(af[mi], bfv[ni], acc[mi][ni]);
  }

  const int cr0 = kh << 2;
#pragma unroll
  for (int mi = 0; mi < 4; ++mi)
#pragma unroll
    for (int ni = 0; ni < 2; ++ni)
#pragma unroll
      for (int r = 0; r < 4; ++r) {
        int row = bm * 128 + wm + (mi << 4) + cr0 + r;
        if (row < cnt) {
          int col = bn * 64 + wn + (ni << 4) + lr;
          Y2[(size_t)(base + row) * HID + col] = acc[mi][ni][r];
        }
      }
}

// h[t] += y(e_lo) + y(e_hi)  (ascending-e order == old serial order)
__global__ __launch_bounds__(256) void moe_scatter_kernel(
    const int* __restrict__ tokpair, const int* __restrict__ off8,
    const float* __restrict__ Y2, float* __restrict__ H)
{
  const int t = blockIdx.x;
  const int i = threadIdx.x;
  int p0 = tokpair[t * 2], p1 = tokpair[t * 2 + 1];
  size_t r0 = off8[p0 >> 16] + (p0 & 0xffff);
  size_t r1 = off8[p1 >> 16] + (p1 & 0xffff);
  float4 a = ((const float4*)(Y2 + r0 * HID))[i];
  float4 b = ((const float4*)(Y2 + r1 * HID))[i];
  float4 hv = ((float4*)(H + (size_t)t * HID))[i];
  hv.x = (hv.x + a.x) + b.x;
  hv.y = (hv.y + a.y) + b.y;
  hv.z = (hv.z + a.z) + b.z;
  hv.w = (hv.w + a.w) + b.w;
  ((float4*)(H + (size_t)t * HID))[i] = hv;
}

// ---------------------------------------------------------------------------
// Small kernels
// ---------------------------------------------------------------------------
__global__ void tables_kernel(float* __restrict__ CT, float* __restrict__ ST)
{
  int idx = blockIdx.x * 256 + threadIdx.x;
  int s = idx >> 5, i = idx & 31;
  double inv = exp(-log(10000.0) * (double)i / 32.0);
  double ang = (double)s * inv;
  CT[idx] = (float)cos(ang);
  ST[idx] = (float)sin(ang);
}

__global__ __launch_bounds__(256) void embed_kernel(
    const int* __restrict__ ids, const float* __restrict__ E, float* __restrict__ H)
{
  int t = blockIdx.x;
  int id = ids[t];
  ((float4*)(H + (size_t)t * HID))[threadIdx.x] =
      ((const float4*)(E + (size_t)id * HID))[threadIdx.x];
}

__global__ __launch_bounds__(256) void rmsnorm_kernel(
    const float* __restrict__ X, const float* __restrict__ W,
    float* __restrict__ O, __bf16* __restrict__ OHb, __bf16* __restrict__ OLb)
{
  int t = blockIdx.x;
  int tid = threadIdx.x;
  float4 v = ((const float4*)(X + (size_t)t * HID))[tid];
  float ss = v.x * v.x + v.y * v.y + v.z * v.z + v.w * v.w;
#pragma unroll
  for (int d = 1; d < 64; d <<= 1) ss += __shfl_xor(ss, d);
  __shared__ float red[4];
  if ((tid & 63) == 0) red[tid >> 6] = ss;
  __syncthreads();
  float tot = red[0] + red[1] + red[2] + red[3];
  float inv = 1.0f / sqrtf(tot * (1.0f / 1024.0f) + 1e-6f);
  float4 w = ((const float4*)W)[tid];
  float4 r;
  r.x = v.x * inv * w.x; r.y = v.y * inv * w.y;
  r.z = v.z * inv * w.z; r.w = v.w * inv * w.w;
  ((float4*)(O + (size_t)t * HID))[tid] = r;
  float f[4] = {r.x, r.y, r.z, r.w};
  bf16x4v hv, lv;
#pragma unroll
  for (int j = 0; j < 4; ++j) {
    __bf16 hb = (__bf16)f[j];
    hv[j] = hb; lv[j] = (__bf16)(f[j] - (float)hb);
  }
  *(bf16x4v*)(OHb + (size_t)t * HID + tid * 4) = hv;
  *(bf16x4v*)(OLb + (size_t)t * HID + tid * 4) = lv;
}

__global__ __launch_bounds__(256) void router_kernel(
    const float* __restrict__ X, const float* __restrict__ RW, float* __restrict__ RL)
{
  int wid = threadIdx.x >> 6, lane = threadIdx.x & 63;
  int t = blockIdx.x * 4 + wid;
  const float* x = X + (size_t)t * HID;
  float a0 = 0, a1 = 0, a2 = 0, a3 = 0, a4 = 0, a5 = 0, a6 = 0, a7 = 0;
  for (int hh = lane; hh < HID; hh += 64) {
    float xv = x[hh];
    float4 f0 = *(const float4*)(RW + hh * 8);
    float4 f1 = *(const float4*)(RW + hh * 8 + 4);
    a0 += xv * f0.x; a1 += xv * f0.y; a2 += xv * f0.z; a3 += xv * f0.w;
    a4 += xv * f1.x; a5 += xv * f1.y; a6 += xv * f1.z; a7 += xv * f1.w;
  }
#pragma unroll
  for (int d = 1; d < 64; d <<= 1) {
    a0 += __shfl_xor(a0, d); a1 += __shfl_xor(a1, d);
    a2 += __shfl_xor(a2, d); a3 += __shfl_xor(a3, d);
    a4 += __shfl_xor(a4, d); a5 += __shfl_xor(a5, d);
    a6 += __shfl_xor(a6, d); a7 += __shfl_xor(a7, d);
  }
  if (lane == 0) {
    float* dst = RL + (size_t)t * 8;
    dst[0] = a0; dst[1] = a1; dst[2] = a2; dst[3] = a3;
    dst[4] = a4; dst[5] = a5; dst[6] = a6; dst[7] = a7;
  }
}

__global__ void zero_kernel(float* __restrict__ p, int n)
{
  int i = threadIdx.x;
  if (i < n) p[i] = 0.f;
}

__global__ void zeroi_kernel(int* __restrict__ p, int n)
{
  int i = threadIdx.x;
  if (i < n) p[i] = 0;
}

__global__ __launch_bounds__(256) void topk_kernel(
    const float* __restrict__ RL, float* __restrict__ W, float* __restrict__ AUX)
{
  int t = blockIdx.x * 256 + threadIdx.x;
  int lane = threadIdx.x & 63;
  float r[8];
#pragma unroll
  for (int e = 0; e < 8; ++e) r[e] = RL[t * 8 + e];
  float mx = r[0];
#pragma unroll
  for (int e = 1; e < 8; ++e) mx = fmaxf(mx, r[e]);
  float p[8];
  float se = 0.f;
#pragma unroll
  for (int e = 0; e < 8; ++e) { p[e] = __expf(r[e] - mx); se += p[e]; }
  float inv = 1.f / se;
#pragma unroll
  for (int e = 0; e < 8; ++e) p[e] *= inv;
  float lse = logf(se) + mx;
  int i1 = 0; float v1 = p[0];
#pragma unroll
  for (int e = 1; e < 8; ++e) if (p[e] > v1) { v1 = p[e]; i1 = e; }
  int i2 = -1; float v2 = -1.f;
#pragma unroll
  for (int e = 0; e < 8; ++e) if (e != i1 && p[e] > v2) { v2 = p[e]; i2 = e; }
  float s12 = v1 + v2;
#pragma unroll
  for (int e = 0; e < 8; ++e)
    W[t * 8 + e] = (e == i1) ? v1 / s12 : ((e == i2) ? v2 / s12 : 0.f);
#pragma unroll
  for (int e = 0; e < 8; ++e) {
    float fe = ((i1 == e) ? 1.f : 0.f) + ((i2 == e) ? 1.f : 0.f);
    float pe = p[e];
#pragma unroll
    for (int d = 1; d < 64; d <<= 1) { fe += __shfl_xor(fe, d); pe += __shfl_xor(pe, d); }
    if (lane == 0) { atomicAdd(&AUX[e], fe); atomicAdd(&AUX[8 + e], pe); }
  }
  float zz = lse * lse;
#pragma unroll
  for (int d = 1; d < 64; d <<= 1) zz += __shfl_xor(zz, d);
  if (lane == 0) atomicAdd(&AUX[16], zz);
}

__global__ void aux_kernel(const float* __restrict__ AUX, float* __restrict__ OUT)
{
  float s = 0.f;
#pragma unroll
  for (int e = 0; e < 8; ++e)
    s += (AUX[e] * (1.f / 2048.f)) * (AUX[8 + e] * (1.f / 2048.f));
  float auxv = 0.01f * 8.f * s;
  float z = 0.001f * (AUX[16] * (1.f / 2048.f));
  OUT[(size_t)SEQ * VOCAB] = auxv + z;
}

// records per-token (expert, pos) pairs in ascending-e order
__global__ __launch_bounds__(256) void build_list_kernel(
    const float* __restrict__ W, int* __restrict__ cnt, int* __restrict__ list,
    int* __restrict__ tokpair)
{
  int t = blockIdx.x * 256 + threadIdx.x;
  int j = 0;
#pragma unroll
  for (int e = 0; e < 8; ++e) {
    if (W[t * 8 + e] > 0.f) {
      int p = atomicAdd(&cnt[e], 1);
      list[e * SEQ + p] = t;
      tokpair[t * 2 + j] = (e << 16) | p;
      ++j;
    }
  }
}

__global__ void prefix_kernel(const int* __restrict__ cnt, int* __restrict__ off)
{
  if (threadIdx.x == 0) {
    int s = 0;
    for (int e = 0; e < 8; ++e) { off[e] = s; s += cnt[e]; }
  }
}

// ---------------------------------------------------------------------------
extern "C" void kernel_launch(void* const* d_in, const int* in_sizes, int n_in,
                              void* d_out, int out_size, void* d_ws, size_t ws_size,
                              hipStream_t stream)
{
  const int*   ids   = (const int*)d_in[0];
  const float* embed = (const float*)d_in[1];
  const float* ln1   = (const float*)d_in[2];
  const float* ln2   = (const float*)d_in[3];
  const float* wq    = (const float*)d_in[4];
  const float* wk    = (const float*)d_in[5];
  const float* wv    = (const float*)d_in[6];
  const float* wo    = (const float*)d_in[7];
  const float* dg    = (const float*)d_in[8];
  const float* du    = (const float*)d_in[9];
  const float* dd    = (const float*)d_in[10];
  const float* rw    = (const float*)d_in[11];
  const float* mg    = (const float*)d_in[12];
  const float* mu    = (const float*)d_in[13];
  const float* md    = (const float*)d_in[14];
  const float* fin   = (const float*)d_in[15];
  float* out = (float*)d_out;

  char* ws = (char*)d_ws;
  float* h    = (float*)(ws + 0);
  float* hn   = (float*)(ws + 8388608);
  float* q    = (float*)(ws + 16777216);
  float* k    = (float*)(ws + 25165824);
  float* v    = (float*)(ws + 33554432);
  __bf16* oh  = (__bf16*)(ws + 41943040);
  __bf16* ol  = (__bf16*)(ws + 46137344);
  float* g    = (float*)(ws + 50331648);
  float* u    = (float*)(ws + 73400320);
  float* ct   = (float*)(ws + 96468992);
  float* st   = (float*)(ws + 96731136);
  float* rl   = (float*)(ws + 96993280);
  float* wmoe = (float*)(ws + 97058816);
  float* aux  = (float*)(ws + 97124352);
  int*   cnt  = (int*)  (ws + 97124608);
  int*   list = (int*)  (ws + 97124864);
  int*   tokp = (int*)  (ws + 97190400);
  int*   off8 = (int*)  (ws + 97206784);
  __bf16* wqh = (__bf16*)(ws + 97320960);
  __bf16* wql = (__bf16*)(ws + 105709568);
  __bf16* wkh = (__bf16*)(ws + 114098176);
  __bf16* wkl = (__bf16*)(ws + 122486784);
  __bf16* wvh = (__bf16*)(ws + 130875392);
  __bf16* wvl = (__bf16*)(ws + 139264000);
  __bf16* woh = (__bf16*)(ws + 147652608);
  __bf16* wol = (__bf16*)(ws + 156041216);
  __bf16* dgh = (__bf16*)(ws + 164429824);
  __bf16* dgl = (__bf16*)(ws + 181731328);
  __bf16* duh = (__bf16*)(ws + 199032832);
  __bf16* dul = (__bf16*)(ws + 216334336);
  __bf16* ddh = (__bf16*)(ws + 233635840);
  __bf16* ddl = (__bf16*)(ws + 250937344);
  __bf16* eh  = (__bf16*)(ws + 268238848);
  __bf16* hnh = (__bf16*)(ws + 333774848);
  __bf16* hnl = (__bf16*)(ws + 337969152);
  __bf16* gh  = (__bf16*)(ws + 342163456);
  __bf16* gl  = (__bf16*)(ws + 353697792);
  __bf16* mgh = (__bf16*)(ws + 365232128);
  __bf16* muh = (__bf16*)(ws + 411369472);
  __bf16* mdh = (__bf16*)(ws + 457506816);
  // end: 503,644,160 bytes
  __bf16* qh  = (__bf16*)g;
  __bf16* ql  = (__bf16*)((char*)g + 4194304);
  __bf16* kbh = (__bf16*)((char*)g + 8388608);
  __bf16* kbl = (__bf16*)((char*)g + 12582912);
  __bf16* vth = (__bf16*)u;
  __bf16* vtl = (__bf16*)((char*)u + 4194304);
  __bf16* a2  = (__bf16*)g;
  float*  y2  = u;

  wsplit_t_kernel<<<dim3(16, 16, 4), 256, 0, stream>>>(wq, wqh, wql, HID, HID);
  wsplit_t_kernel<<<dim3(16, 16, 4), 256, 0, stream>>>(wk, wkh, wkl, HID, HID);
  wsplit_t_kernel<<<dim3(16, 16, 4), 256, 0, stream>>>(wv, wvh, wvl, HID, HID);
  wsplit_t_kernel<<<dim3(16, 16, 4), 256, 0, stream>>>(wo, woh, wol, HID, HID);
  wsplit_t_kernel<<<dim3(44, 16, 3), 256, 0, stream>>>(dg, dgh, dgl, HID, IDIM);
  wsplit_t_kernel<<<dim3(44, 16, 3), 256, 0, stream>>>(du, duh, dul, HID, IDIM);
  wsplit_t_kernel<<<dim3(16, 44, 3), 256, 0, stream>>>(dd, ddh, ddl, IDIM, HID);
  wsplit_th_kernel<<<dim3(44, 16, 8), 256, 0, stream>>>(mg, mgh, HID, IDIM);
  wsplit_th_kernel<<<dim3(44, 16, 8), 256, 0, stream>>>(mu, muh, HID, IDIM);
  wsplit_th_kernel<<<dim3(16, 44, 8), 256, 0, stream>>>(md, mdh, IDIM, HID);
  esplit_kernel<<<16000, 256, 0, stream>>>(embed, eh);

  tables_kernel<<<256, 256, 0, stream>>>(ct, st);
  embed_kernel<<<SEQ, 256, 0, stream>>>(ids, embed, h);

  for (int li = 0; li < 4; ++li) {
    const bool comp = (li <= 2);
    rmsnorm_kernel<<<SEQ, 256, 0, stream>>>(h, ln1 + li * HID, hn, hnh, hnl);
    size_t wofs = (size_t)li * HID * HID;
    // QKV GEMM with fused rope+split epilogue (q,k) and f32 v output
    if (comp)
      gemm_qkv_kernel<true><<<dim3(8, 32, 3), 256, 0, stream>>>(
          hnh, hnl, wqh + wofs, wql + wofs, wkh + wofs, wkl + wofs,
          wvh + wofs, wvl + wofs, qh, ql, kbh, kbl, v, ct, st);
    else
      gemm_qkv_kernel<false><<<dim3(8, 32, 3), 256, 0, stream>>>(
          hnh, hnh, wqh + wofs, wqh + wofs, wkh + wofs, wkh + wofs,
          wvh + wofs, wvh + wofs, qh, ql, kbh, kbl, v, ct, st);

    vtsplit_kernel<<<dim3(32, 16), 256, 0, stream>>>(v, vth, vtl);

    attn_flash_kernel<<<dim3(16, 16), 256, 0, stream>>>(
        qh, ql, kbh, kbl, vth, vtl, oh, ol);

    if (comp)
      gemm_bt_kernel<true, true, false, 64, false><<<dim3(8, 32, 1), 256, 0, stream>>>(
          oh, ol, woh + wofs, wol + wofs, woh + wofs, wol + wofs,
          woh + wofs, wol + wofs, h, h, h, SEQ, HID, HID);
    else
      gemm_bt_kernel<false, true, false, 64, false><<<dim3(8, 32, 1), 256, 0, stream>>>(
          oh, oh, woh + wofs, woh + wofs, woh + wofs, woh + wofs,
          woh + wofs, woh + wofs, h, h, h, SEQ, HID, HID);

    rmsnorm_kernel<<<SEQ, 256, 0, stream>>>(h, ln2 + li * HID, hn, hnh, hnl);
    if (li == 2) {
      router_kernel<<<512, 256, 0, stream>>>(hn, rw, rl);
      zero_kernel<<<1, 32, 0, stream>>>(aux, 17);
      topk_kernel<<<8, 256, 0, stream>>>(rl, wmoe, aux);
      aux_kernel<<<1, 1, 0, stream>>>(aux, out);
      zeroi_kernel<<<1, 32, 0, stream>>>(cnt, 8);
      build_list_kernel<<<8, 256, 0, stream>>>(wmoe, cnt, list, tokp);
      prefix_kernel<<<1, 64, 0, stream>>>(cnt, off8);
      gemm_moe_guf_kernel<<<dim3(44, 16, 8), 256, 0, stream>>>(
          hnh, mgh, muh, a2, wmoe, list, cnt, off8);
      gemm_moe_down2_kernel<<<dim3(16, 16, 8), 256, 0, stream>>>(
          a2, mdh, y2, cnt, off8);
      moe_scatter_kernel<<<SEQ, 256, 0, stream>>>(tokp, off8, y2, h);
    } else {
      int d = (li < 2) ? li : li - 1;
      size_t go = (size_t)d * HID * IDIM;
      // dense gate+up GEMM with fused silu + hi/lo split epilogue
      if (comp)
        gemm_dgu_kernel<true><<<dim3(44, 32), 256, 0, stream>>>(
            hnh, hnl, dgh + go, dgl + go, duh + go, dul + go, gh, gl);
      else
        gemm_dgu_kernel<false><<<dim3(44, 32), 256, 0, stream>>>(
            hnh, hnh, dgh + go, dgh + go, duh + go, duh + go, gh, gl);
      if (comp)
        gemm_bt_kernel<true, true, false, 64, false><<<dim3(8, 32, 1), 256, 0, stream>>>(
            gh, gl, ddh + go, ddl + go, ddh + go, ddl + go,
            ddh + go, ddl + go, h, h, h, SEQ, HID, IDIM);
      else
        gemm_bt_kernel<false, true, false, 64, false><<<dim3(8, 32, 1), 256, 0, stream>>>(
            gh, gh, ddh + go, ddh + go, ddh + go, ddh + go,
            ddh + go, ddh + go, h, h, h, SEQ, HID, IDIM);
    }
  }
  rmsnorm_kernel<<<SEQ, 256, 0, stream>>>(h, fin, hn, hnh, hnl);
  // logits: XCD-aware bijective swizzle (padded 1D grid; bn>=250 exits)
  gemm_bt_kernel<false, false, false, 128, true><<<dim3(4096, 1, 1), 256, 0, stream>>>(
      hnh, hnh, eh, eh, eh, eh, eh, eh, out, out, out, SEQ, VOCAB, HID);
}

// Round 18
// 1845.557 us; speedup vs baseline: 1.2522x; 1.0449x over previous
//
#include <hip/hip_runtime.h>
#include <hip/hip_bf16.h>
#include <math.h>

#define SEQ 2048
#define HID 1024
#define NHEAD 16
#define HDIM 64
#define IDIM 2816
#define NEXP 8
#define VOCAB 32000

#define ASTRIDE 144  // padded rows (attention)

typedef float f32x4v __attribute__((ext_vector_type(4)));
typedef __bf16 bf16x8v __attribute__((ext_vector_type(8)));
typedef __bf16 bf16x4v __attribute__((ext_vector_type(4)));

__device__ __forceinline__ bf16x8v cvt8(const float4& a, const float4& b) {
  bf16x8v r;
  r[0] = (__bf16)a.x; r[1] = (__bf16)a.y; r[2] = (__bf16)a.z; r[3] = (__bf16)a.w;
  r[4] = (__bf16)b.x; r[5] = (__bf16)b.y; r[6] = (__bf16)b.z; r[7] = (__bf16)b.w;
  return r;
}

#define MFMA(a, b, c) __builtin_amdgcn_mfma_f32_16x16x32_bf16(a, b, c, 0, 0, 0)

// async global->LDS DMA, 16B per lane; lds base must be wave-uniform
__device__ __forceinline__ void gld_lds16(const void* g, void* l) {
  __builtin_amdgcn_global_load_lds(
      (const __attribute__((address_space(1))) unsigned int*)(unsigned long long)g,
      (__attribute__((address_space(3))) unsigned int*)(unsigned int)(unsigned long long)l,
      16, 0, 0);
}

// ---------------------------------------------------------------------------
// Weight preprocessing: W[K,N] f32 -> WH,WL [N,K] bf16 (transposed hi/lo).
// ---------------------------------------------------------------------------
__global__ __launch_bounds__(256) void wsplit_t_kernel(
    const float* __restrict__ W, __bf16* __restrict__ WH, __bf16* __restrict__ WL,
    int K, int N)
{
  __shared__ float tile[64][65];
  const int tid = threadIdx.x;
  const size_t zofs = (size_t)blockIdx.z * K * N;
  const int n0 = blockIdx.x * 64, k0 = blockIdx.y * 64;
#pragma unroll
  for (int r = 0; r < 4; ++r) {
    int kk = (tid >> 4) + r * 16;
    int nn = (tid & 15) * 4;
    float4 v = *(const float4*)(W + zofs + (size_t)(k0 + kk) * N + n0 + nn);
    tile[kk][nn] = v.x; tile[kk][nn + 1] = v.y;
    tile[kk][nn + 2] = v.z; tile[kk][nn + 3] = v.w;
  }
  __syncthreads();
  const int nn = tid >> 2;
  const int kk = (tid & 3) * 16;
  __bf16* dh = WH + zofs + (size_t)(n0 + nn) * K + k0 + kk;
  __bf16* dl = WL + zofs + (size_t)(n0 + nn) * K + k0 + kk;
  bf16x8v h0, l0, h1, l1;
#pragma unroll
  for (int j = 0; j < 8; ++j) {
    float f = tile[kk + j][nn];
    __bf16 hb = (__bf16)f; h0[j] = hb; l0[j] = (__bf16)(f - (float)hb);
    f = tile[kk + 8 + j][nn];
    hb = (__bf16)f; h1[j] = hb; l1[j] = (__bf16)(f - (float)hb);
  }
  *(bf16x8v*)dh = h0; *(bf16x8v*)(dh + 8) = h1;
  *(bf16x8v*)dl = l0; *(bf16x8v*)(dl + 8) = l1;
}

// hi-only variant (MoE weights; plain-bf16 path needs no lo)
__global__ __launch_bounds__(256) void wsplit_th_kernel(
    const float* __restrict__ W, __bf16* __restrict__ WH, int K, int N)
{
  __shared__ float tile[64][65];
  const int tid = threadIdx.x;
  const size_t zofs = (size_t)blockIdx.z * K * N;
  const int n0 = blockIdx.x * 64, k0 = blockIdx.y * 64;
#pragma unroll
  for (int r = 0; r < 4; ++r) {
    int kk = (tid >> 4) + r * 16;
    int nn = (tid & 15) * 4;
    float4 v = *(const float4*)(W + zofs + (size_t)(k0 + kk) * N + n0 + nn);
    tile[kk][nn] = v.x; tile[kk][nn + 1] = v.y;
    tile[kk][nn + 2] = v.z; tile[kk][nn + 3] = v.w;
  }
  __syncthreads();
  const int nn = tid >> 2;
  const int kk = (tid & 3) * 16;
  __bf16* dh = WH + zofs + (size_t)(n0 + nn) * K + k0 + kk;
  bf16x8v h0, h1;
#pragma unroll
  for (int j = 0; j < 8; ++j) {
    h0[j] = (__bf16)tile[kk + j][nn];
    h1[j] = (__bf16)tile[kk + 8 + j][nn];
  }
  *(bf16x8v*)dh = h0; *(bf16x8v*)(dh + 8) = h1;
}

__global__ __launch_bounds__(256) void esplit_kernel(
    const float* __restrict__ E, __bf16* __restrict__ EH)
{
  size_t i = ((size_t)blockIdx.x * 256 + threadIdx.x) * 8;
  float4 a = *(const float4*)(E + i);
  float4 b = *(const float4*)(E + i + 4);
  *(bf16x8v*)(EH + i) = cvt8(a, b);
}

// ---------------------------------------------------------------------------
// Unified BT GEMM. A,B pre-split bf16. Staging = global_load_lds DMA (16B),
// LINEAR LDS rows (64B/row). BM/BN tile params. XSWZ: XCD-aware 1D grid
// (logits; requires BM=64: bm=j&31, bn=xcd*32+(j>>5)).
// ---------------------------------------------------------------------------
template<bool COMP, bool ACCUM, int BM, int BN, bool XSWZ>
__global__ __launch_bounds__(256) void gemm_bt_kernel(
    const __bf16* __restrict__ Ah, const __bf16* __restrict__ Al,
    const __bf16* __restrict__ B0h, const __bf16* __restrict__ B0l,
    const __bf16* __restrict__ B1h, const __bf16* __restrict__ B1l,
    const __bf16* __restrict__ B2h, const __bf16* __restrict__ B2l,
    float* __restrict__ C0, float* __restrict__ C1, float* __restrict__ C2,
    int M, int N, int Kd)
{
  const __bf16* __restrict__ Bh = (blockIdx.z == 0) ? B0h : (blockIdx.z == 1 ? B1h : B2h);
  const __bf16* __restrict__ Bl = (blockIdx.z == 0) ? B0l : (blockIdx.z == 1 ? B1l : B2l);
  float* __restrict__ C         = (blockIdx.z == 0) ? C0 : (blockIdx.z == 1 ? C1 : C2);
  constexpr int ATILE = BM * 64;
  constexpr int BTILE = BN * 64;
  constexpr int MFR = BM / 32;
  constexpr int NFR = BN / 32;
  __shared__ __align__(16) char smem[COMP ? 2 * (ATILE + BTILE) : (ATILE + BTILE)];
  char* AsH = smem;
  char* BsH = smem + ATILE;
  char* AsL = COMP ? smem + ATILE + BTILE : smem;
  char* BsL = COMP ? smem + 2 * ATILE + BTILE : smem + ATILE;
  const int tid = threadIdx.x;
  int bm, bn;
  if (XSWZ) {
    int id = blockIdx.x;            // padded 1D grid (8192)
    int xcd = id & 7;
    int j = id >> 3;
    bm = j & 31;                    // BM must be 64 (M=2048 -> 32 bm-blocks)
    bn = xcd * 32 + (j >> 5);
    if (bn >= N / BN) return;
  } else {
    bm = blockIdx.y;
    bn = blockIdx.x;
  }
  const int wid = tid >> 6, lane = tid & 63;
  const int wm = (wid >> 1) * (BM / 2), wn = (wid & 1) * (BN / 2);
  const int lr = lane & 15, kh = lane >> 4;
  const int lrow = lane >> 2;
  const int lcol = (lane & 3) << 3;

  f32x4v acc[MFR][NFR];
  const f32x4v z4 = {0.f, 0.f, 0.f, 0.f};
#pragma unroll
  for (int i = 0; i < MFR; ++i)
#pragma unroll
    for (int j2 = 0; j2 < NFR; ++j2) acc[i][j2] = z4;

  for (int k0 = 0; k0 < Kd; k0 += 32) {
    __syncthreads();
#pragma unroll
    for (int c = wid; c < BM / 16; c += 4) {
      size_t gofs = (size_t)(bm * BM + c * 16 + lrow) * Kd + k0 + lcol;
      gld_lds16(Ah + gofs, AsH + c * 1024);
      if (COMP) gld_lds16(Al + gofs, AsL + c * 1024);
    }
#pragma unroll
    for (int c = wid; c < BN / 16; c += 4) {
      size_t gofs = (size_t)(bn * BN + c * 16 + lrow) * Kd + k0 + lcol;
      gld_lds16(Bh + gofs, BsH + c * 1024);
      if (COMP) gld_lds16(Bl + gofs, BsL + c * 1024);
    }
    __syncthreads();

    bf16x8v ah[MFR], al[MFR], bh4[NFR], bl4[NFR];
#pragma unroll
    for (int i = 0; i < MFR; ++i) {
      int r = wm + (i << 4) + lr;
      int off = r * 64 + (kh << 4);
      ah[i] = *(const bf16x8v*)(AsH + off);
      if (COMP) al[i] = *(const bf16x8v*)(AsL + off);
    }
#pragma unroll
    for (int i = 0; i < NFR; ++i) {
      int r = wn + (i << 4) + lr;
      int off = r * 64 + (kh << 4);
      bh4[i] = *(const bf16x8v*)(BsH + off);
      if (COMP) bl4[i] = *(const bf16x8v*)(BsL + off);
    }
#pragma unroll
    for (int mi = 0; mi < MFR; ++mi)
#pragma unroll
      for (int ni = 0; ni < NFR; ++ni) {
        if (COMP) {
          acc[mi][ni] = MFMA(al[mi], bh4[ni], acc[mi][ni]);
          acc[mi][ni] = MFMA(ah[mi], bl4[ni], acc[mi][ni]);
        }
        acc[mi][ni] = MFMA(ah[mi], bh4[ni], acc[mi][ni]);
      }
  }

  const int cr0 = kh << 2;
#pragma unroll
  for (int mi = 0; mi < MFR; ++mi)
#pragma unroll
    for (int ni = 0; ni < NFR; ++ni)
#pragma unroll
      for (int r = 0; r < 4; ++r) {
        int row = bm * BM + wm + (mi << 4) + cr0 + r;
        int col = bn * BN + wn + (ni << 4) + lr;
        size_t idx = (size_t)row * N + col;
        if (ACCUM) C[idx] += acc[mi][ni][r];
        else       C[idx] = acc[mi][ni][r];
      }
}

// ---------------------------------------------------------------------------
// QKV GEMM with fused rope + hi/lo split epilogue (z=0 q scale 1/8, z=1 k),
// z=2 writes f32 v (for vtsplit). BM=64, N=K=HID. Bit-exact vs GEMM+rope_split.
// ---------------------------------------------------------------------------
template<bool COMP>
__global__ __launch_bounds__(256) void gemm_qkv_kernel(
    const __bf16* __restrict__ Ah, const __bf16* __restrict__ Al,
    const __bf16* __restrict__ Bqh, const __bf16* __restrict__ Bql,
    const __bf16* __restrict__ Bkh, const __bf16* __restrict__ Bkl,
    const __bf16* __restrict__ Bvh, const __bf16* __restrict__ Bvl,
    __bf16* __restrict__ QH, __bf16* __restrict__ QL,
    __bf16* __restrict__ KH, __bf16* __restrict__ KL,
    float* __restrict__ Vout,
    const float* __restrict__ CT, const float* __restrict__ ST)
{
  const __bf16* __restrict__ Bh = (blockIdx.z == 0) ? Bqh : (blockIdx.z == 1 ? Bkh : Bvh);
  const __bf16* __restrict__ Bl = (blockIdx.z == 0) ? Bql : (blockIdx.z == 1 ? Bkl : Bvl);
  constexpr int ATILE = 64 * 64;
  constexpr int BTILE = 128 * 64;
  __shared__ __align__(16) char smem[COMP ? 2 * (ATILE + BTILE) : (ATILE + BTILE)];
  char* AsH = smem;
  char* BsH = smem + ATILE;
  char* AsL = COMP ? smem + ATILE + BTILE : smem;
  char* BsL = COMP ? smem + 2 * ATILE + BTILE : smem + ATILE;
  const int tid = threadIdx.x;
  const int bm = blockIdx.y, bn = blockIdx.x;
  const int wid = tid >> 6, lane = tid & 63;
  const int wm = (wid >> 1) << 5, wn = (wid & 1) << 6;
  const int lr = lane & 15, kh = lane >> 4;
  const int lrow = lane >> 2;
  const int lcol = (lane & 3) << 3;

  f32x4v acc[2][4];
  const f32x4v z4 = {0.f, 0.f, 0.f, 0.f};
#pragma unroll
  for (int i = 0; i < 2; ++i)
#pragma unroll
    for (int j2 = 0; j2 < 4; ++j2) acc[i][j2] = z4;

  for (int k0 = 0; k0 < HID; k0 += 32) {
    __syncthreads();
    {
      int c = wid;   // A: 4 chunks
      size_t gofs = (size_t)(bm * 64 + c * 16 + lrow) * HID + k0 + lcol;
      gld_lds16(Ah + gofs, AsH + c * 1024);
      if (COMP) gld_lds16(Al + gofs, AsL + c * 1024);
    }
#pragma unroll
    for (int c = wid; c < 8; c += 4) {
      size_t gofs = (size_t)(bn * 128 + c * 16 + lrow) * HID + k0 + lcol;
      gld_lds16(Bh + gofs, BsH + c * 1024);
      if (COMP) gld_lds16(Bl + gofs, BsL + c * 1024);
    }
    __syncthreads();

    bf16x8v ah2[2], al2[2], bh4[4], bl4[4];
#pragma unroll
    for (int i = 0; i < 2; ++i) {
      int r = wm + (i << 4) + lr;
      int off = r * 64 + (kh << 4);
      ah2[i] = *(const bf16x8v*)(AsH + off);
      if (COMP) al2[i] = *(const bf16x8v*)(AsL + off);
    }
#pragma unroll
    for (int i = 0; i < 4; ++i) {
      int r = wn + (i << 4) + lr;
      int off = r * 64 + (kh << 4);
      bh4[i] = *(const bf16x8v*)(BsH + off);
      if (COMP) bl4[i] = *(const bf16x8v*)(BsL + off);
    }
#pragma unroll
    for (int mi = 0; mi < 2; ++mi)
#pragma unroll
      for (int ni = 0; ni < 4; ++ni) {
        if (COMP) {
          acc[mi][ni] = MFMA(al2[mi], bh4[ni], acc[mi][ni]);
          acc[mi][ni] = MFMA(ah2[mi], bl4[ni], acc[mi][ni]);
        }
        acc[mi][ni] = MFMA(ah2[mi], bh4[ni], acc[mi][ni]);
      }
  }

  const int cr0 = kh << 2;
  if (blockIdx.z == 2) {
#pragma unroll
    for (int mi = 0; mi < 2; ++mi)
#pragma unroll
      for (int ni = 0; ni < 4; ++ni)
#pragma unroll
        for (int r = 0; r < 4; ++r) {
          int row = bm * 64 + wm + (mi << 4) + cr0 + r;
          int col = bn * 128 + wn + (ni << 4) + lr;
          Vout[(size_t)row * HID + col] = acc[mi][ni][r];
        }
  } else {
    const float scale = (blockIdx.z == 0) ? 0.125f : 1.0f;
    __bf16* OH = (blockIdx.z == 0) ? QH : KH;
    __bf16* OL = (blockIdx.z == 0) ? QL : KL;
#pragma unroll
    for (int mi = 0; mi < 2; ++mi)
#pragma unroll
      for (int ni = 0; ni < 2; ++ni)
#pragma unroll
        for (int r = 0; r < 4; ++r) {
          int row = bm * 64 + wm + (mi << 4) + cr0 + r;
          int col = bn * 128 + wn + (ni << 4) + lr;   // (col&63) < 32
          int i = col & 31;
          float c = CT[row * 32 + i], sn = ST[row * 32 + i];
          float x1 = acc[mi][ni][r];
          float x2 = acc[mi][ni + 2][r];
          float o1 = (x1 * c - x2 * sn) * scale;
          float o2 = (x2 * c + x1 * sn) * scale;
          size_t ofs = (size_t)row * HID + col;
          __bf16 h1 = (__bf16)o1;
          OH[ofs] = h1; OL[ofs] = (__bf16)(o1 - (float)h1);
          __bf16 h2 = (__bf16)o2;
          OH[ofs + 32] = h2; OL[ofs + 32] = (__bf16)(o2 - (float)h2);
        }
  }
}

// ---------------------------------------------------------------------------
// Dense gate+up GEMM with fused silu + hi/lo split epilogue. BM=64, BN=64.
// ---------------------------------------------------------------------------
template<bool COMP>
__global__ __launch_bounds__(256) void gemm_dgu_kernel(
    const __bf16* __restrict__ Ah, const __bf16* __restrict__ Al,
    const __bf16* __restrict__ BGh, const __bf16* __restrict__ BGl,
    const __bf16* __restrict__ BUh, const __bf16* __restrict__ BUl,
    __bf16* __restrict__ GH, __bf16* __restrict__ GL)
{
  __shared__ __align__(16) char AsH[4096], AsL[4096];
  __shared__ __align__(16) char BgH[4096], BgL[4096];
  __shared__ __align__(16) char BuH[4096], BuL[4096];
  const int tid = threadIdx.x;
  const int bn = blockIdx.x, bm = blockIdx.y;
  const int wid = tid >> 6, lane = tid & 63;
  const int wm = (wid >> 1) << 5, wn = (wid & 1) << 5;
  const int lr = lane & 15, kh = lane >> 4;
  const int lrow = lane >> 2;
  const int lcol = (lane & 3) << 3;

  f32x4v accg[2][2], accu[2][2];
  const f32x4v z4 = {0.f, 0.f, 0.f, 0.f};
#pragma unroll
  for (int i = 0; i < 2; ++i)
#pragma unroll
    for (int j = 0; j < 2; ++j) { accg[i][j] = z4; accu[i][j] = z4; }

  for (int k0 = 0; k0 < HID; k0 += 32) {
    __syncthreads();
    {
      int c = wid;   // 4 chunks each buffer
      size_t aofs = (size_t)(bm * 64 + c * 16 + lrow) * HID + k0 + lcol;
      gld_lds16(Ah + aofs, AsH + c * 1024);
      if (COMP) gld_lds16(Al + aofs, AsL + c * 1024);
      size_t bofs = (size_t)(bn * 64 + c * 16 + lrow) * HID + k0 + lcol;
      gld_lds16(BGh + bofs, BgH + c * 1024);
      gld_lds16(BUh + bofs, BuH + c * 1024);
      if (COMP) {
        gld_lds16(BGl + bofs, BgL + c * 1024);
        gld_lds16(BUl + bofs, BuL + c * 1024);
      }
    }
    __syncthreads();

    bf16x8v af[2], afl[2], bg4[2], bgl4[2], bu4[2], bul4[2];
#pragma unroll
    for (int i = 0; i < 2; ++i) {
      int r = wm + (i << 4) + lr;
      int off = r * 64 + (kh << 4);
      af[i] = *(const bf16x8v*)(AsH + off);
      if (COMP) afl[i] = *(const bf16x8v*)(AsL + off);
    }
#pragma unroll
    for (int i = 0; i < 2; ++i) {
      int r = wn + (i << 4) + lr;
      int off = r * 64 + (kh << 4);
      bg4[i] = *(const bf16x8v*)(BgH + off);
      bu4[i] = *(const bf16x8v*)(BuH + off);
      if (COMP) {
        bgl4[i] = *(const bf16x8v*)(BgL + off);
        bul4[i] = *(const bf16x8v*)(BuL + off);
      }
    }
#pragma unroll
    for (int mi = 0; mi < 2; ++mi)
#pragma unroll
      for (int ni = 0; ni < 2; ++ni) {
        if (COMP) {
          accg[mi][ni] = MFMA(afl[mi], bg4[ni], accg[mi][ni]);
          accg[mi][ni] = MFMA(af[mi], bgl4[ni], accg[mi][ni]);
        }
        accg[mi][ni] = MFMA(af[mi], bg4[ni], accg[mi][ni]);
        if (COMP) {
          accu[mi][ni] = MFMA(afl[mi], bu4[ni], accu[mi][ni]);
          accu[mi][ni] = MFMA(af[mi], bul4[ni], accu[mi][ni]);
        }
        accu[mi][ni] = MFMA(af[mi], bu4[ni], accu[mi][ni]);
      }
  }

  const int cr0 = kh << 2;
#pragma unroll
  for (int mi = 0; mi < 2; ++mi)
#pragma unroll
    for (int ni = 0; ni < 2; ++ni)
#pragma unroll
      for (int r = 0; r < 4; ++r) {
        int row = bm * 64 + wm + (mi << 4) + cr0 + r;
        int col = bn * 64 + wn + (ni << 4) + lr;
        float gv = accg[mi][ni][r];
        float uv = accu[mi][ni][r];
        float a = gv / (1.f + __expf(-gv)) * uv;
        size_t idx = (size_t)row * IDIM + col;
        __bf16 hb = (__bf16)a;
        GH[idx] = hb;
        GL[idx] = (__bf16)(a - (float)hb);
      }
}

// V f32 [S][HID] -> per-head transposed hi/lo bf16 [NHEAD][HDIM][SEQ]
__global__ __launch_bounds__(256) void vtsplit_kernel(
    const float* __restrict__ V, __bf16* __restrict__ VTH, __bf16* __restrict__ VTL)
{
  __shared__ float tile[64][65];
  const int tid = threadIdx.x;
  const int s0 = blockIdx.x * 64;
  const int head = blockIdx.y;
#pragma unroll
  for (int r = 0; r < 4; ++r) {
    int ss = (tid >> 4) + r * 16;
    int dd = (tid & 15) * 4;
    float4 v = *(const float4*)(V + (size_t)(s0 + ss) * HID + head * 64 + dd);
    tile[ss][dd] = v.x; tile[ss][dd + 1] = v.y;
    tile[ss][dd + 2] = v.z; tile[ss][dd + 3] = v.w;
  }
  __syncthreads();
#pragma unroll
  for (int half = 0; half < 2; ++half) {
    const int d = (tid >> 3) + (half << 5);
    const int c = tid & 7;
    bf16x8v hv, lv;
#pragma unroll
    for (int j = 0; j < 8; ++j) {
      float f = tile[c * 8 + j][d];
      __bf16 hb = (__bf16)f;
      hv[j] = hb; lv[j] = (__bf16)(f - (float)hb);
    }
    size_t dst = (size_t)(head * 64 + d) * SEQ + s0 + c * 8;
    *(bf16x8v*)(VTH + dst) = hv;
    *(bf16x8v*)(VTL + dst) = lv;
  }
}

// ---------------------------------------------------------------------------
// Compensated flash attention; padded LDS; O -> bf16 hi/lo.
// Load-balanced: grid (16,16); block processes qt = bx and qt = 31-bx.
// ---------------------------------------------------------------------------
__global__ __launch_bounds__(256) void attn_flash_kernel(
    const __bf16* __restrict__ QH, const __bf16* __restrict__ QL,
    const __bf16* __restrict__ KH, const __bf16* __restrict__ KL,
    const __bf16* __restrict__ VTH, const __bf16* __restrict__ VTL,
    __bf16* __restrict__ OH, __bf16* __restrict__ OL)
{
  const int head = blockIdx.y;
  const int tid = threadIdx.x, wid = tid >> 6, lane = tid & 63;
  const int lr = lane & 15, kh = lane >> 4;
  __shared__ __align__(16) char KsH[64 * ASTRIDE], KsL[64 * ASTRIDE];
  __shared__ __align__(16) char VtH[64 * ASTRIDE], VtL[64 * ASTRIDE];
  __shared__ __align__(16) char PsH[4][16 * ASTRIDE], PsL[4][16 * ASTRIDE];

#pragma unroll
  for (int seg = 0; seg < 2; ++seg) {
    const int qt = seg ? (31 - (int)blockIdx.x) : (int)blockIdx.x;

    const size_t qofs = (size_t)(qt * 64 + wid * 16 + lr) * HID + head * HDIM;
    const bf16x8v qfh0 = *(const bf16x8v*)(QH + qofs + (kh << 3));
    const bf16x8v qfh1 = *(const bf16x8v*)(QH + qofs + 32 + (kh << 3));
    const bf16x8v qfl0 = *(const bf16x8v*)(QL + qofs + (kh << 3));
    const bf16x8v qfl1 = *(const bf16x8v*)(QL + qofs + 32 + (kh << 3));

    float m_run[4], l_run[4];
    f32x4v oacc[4];
    const f32x4v z4 = {0.f, 0.f, 0.f, 0.f};
#pragma unroll
    for (int i = 0; i < 4; ++i) { m_run[i] = -1e30f; l_run[i] = 0.f; oacc[i] = z4; }

    for (int kt = 0; kt <= qt; ++kt) {
      __syncthreads();
#pragma unroll
      for (int p = 0; p < 2; ++p) {
        int g = tid + (p << 8);
        int r = g >> 3;
        int c = g & 7;
        int off = r * ASTRIDE + (c << 4);
        const size_t kofs = (size_t)(kt * 64 + r) * HID + head * HDIM + (c << 3);
        *(bf16x8v*)(KsH + off) = *(const bf16x8v*)(KH + kofs);
        *(bf16x8v*)(KsL + off) = *(const bf16x8v*)(KL + kofs);
        const size_t vofs = (size_t)(head * 64 + r) * SEQ + kt * 64 + (c << 3);
        *(bf16x8v*)(VtH + off) = *(const bf16x8v*)(VTH + vofs);
        *(bf16x8v*)(VtL + off) = *(const bf16x8v*)(VTL + vofs);
      }
      __syncthreads();

      float sv[4][4];
#pragma unroll
      for (int stt = 0; stt < 4; ++stt) {
        int r = (stt << 4) + lr;
        int off0 = r * ASTRIDE + (kh << 4);
        int off1 = off0 + 64;
        bf16x8v kfh0 = *(const bf16x8v*)(KsH + off0);
        bf16x8v kfl0 = *(const bf16x8v*)(KsL + off0);
        bf16x8v kfh1 = *(const bf16x8v*)(KsH + off1);
        bf16x8v kfl1 = *(const bf16x8v*)(KsL + off1);
        f32x4v s = z4;
        s = MFMA(qfl0, kfh0, s);
        s = MFMA(qfh0, kfl0, s);
        s = MFMA(qfh0, kfh0, s);
        s = MFMA(qfl1, kfh1, s);
        s = MFMA(qfh1, kfl1, s);
        s = MFMA(qfh1, kfh1, s);
        int key = kt * 64 + (stt << 4) + lr;
#pragma unroll
        for (int rr = 0; rr < 4; ++rr) {
          int qr = qt * 64 + wid * 16 + (kh << 2) + rr;
          sv[stt][rr] = (key <= qr) ? s[rr] : -1e30f;
        }
      }

#pragma unroll
      for (int rr = 0; rr < 4; ++rr) {
        float mx = fmaxf(fmaxf(sv[0][rr], sv[1][rr]), fmaxf(sv[2][rr], sv[3][rr]));
#pragma unroll
        for (int d = 1; d < 16; d <<= 1) mx = fmaxf(mx, __shfl_xor(mx, d));
        float mnew = fmaxf(m_run[rr], mx);
        float scl = __expf(m_run[rr] - mnew);
        float pv[4];
#pragma unroll
        for (int stt = 0; stt < 4; ++stt) pv[stt] = __expf(sv[stt][rr] - mnew);
        float rs = pv[0] + pv[1] + pv[2] + pv[3];
#pragma unroll
        for (int d = 1; d < 16; d <<= 1) rs += __shfl_xor(rs, d);
        l_run[rr] = l_run[rr] * scl + rs;
        m_run[rr] = mnew;
#pragma unroll
        for (int n = 0; n < 4; ++n) oacc[n][rr] *= scl;
        int qlr = (kh << 2) + rr;
#pragma unroll
        for (int stt = 0; stt < 4; ++stt) {
          __bf16 hb = (__bf16)pv[stt];
          __bf16 lb = (__bf16)(pv[stt] - (float)hb);
          int off = qlr * ASTRIDE + (((stt << 4) + lr) << 1);
          *(__bf16*)(PsH[wid] + off) = hb;
          *(__bf16*)(PsL[wid] + off) = lb;
        }
      }

      int poff0 = lr * ASTRIDE + (kh << 4);
      int poff1 = poff0 + 64;
      bf16x8v pah0 = *(const bf16x8v*)(PsH[wid] + poff0);
      bf16x8v pal0 = *(const bf16x8v*)(PsL[wid] + poff0);
      bf16x8v pah1 = *(const bf16x8v*)(PsH[wid] + poff1);
      bf16x8v pal1 = *(const bf16x8v*)(PsL[wid] + poff1);
#pragma unroll
      for (int n = 0; n < 4; ++n) {
        int vr = (n << 4) + lr;
        int voff0 = vr * ASTRIDE + (kh << 4);
        int voff1 = voff0 + 64;
        bf16x8v vfh0 = *(const bf16x8v*)(VtH + voff0);
        bf16x8v vfl0 = *(const bf16x8v*)(VtL + voff0);
        bf16x8v vfh1 = *(const bf16x8v*)(VtH + voff1);
        bf16x8v vfl1 = *(const bf16x8v*)(VtL + voff1);
        oacc[n] = MFMA(pal0, vfh0, oacc[n]);
        oacc[n] = MFMA(pah0, vfl0, oacc[n]);
        oacc[n] = MFMA(pah0, vfh0, oacc[n]);
        oacc[n] = MFMA(pal1, vfh1, oacc[n]);
        oacc[n] = MFMA(pah1, vfl1, oacc[n]);
        oacc[n] = MFMA(pah1, vfh1, oacc[n]);
      }
    }

#pragma unroll
    for (int n = 0; n < 4; ++n)
#pragma unroll
      for (int rr = 0; rr < 4; ++rr) {
        int qr = qt * 64 + wid * 16 + (kh << 2) + rr;
        size_t ofs = (size_t)qr * HID + head * HDIM + (n << 4) + lr;
        float val = oacc[n][rr] / l_run[rr];
        __bf16 hb = (__bf16)val;
        OH[ofs] = hb;
        OL[ofs] = (__bf16)(val - (float)hb);
      }
  }
}

// ---------------------------------------------------------------------------
// MoE: fused gate+up+silu. BM=128, BN=64. DMA staging, pre-split weights.
// ---------------------------------------------------------------------------
__global__ __launch_bounds__(256) void gemm_moe_guf_kernel(
    const __bf16* __restrict__ Xh,
    const __bf16* __restrict__ MGH, const __bf16* __restrict__ MUH,
    __bf16* __restrict__ A2, const float* __restrict__ W,
    const int* __restrict__ list, const int* __restrict__ cnt8,
    const int* __restrict__ off8)
{
  const int e = blockIdx.z;
  const int cnt = cnt8[e];
  const int bn = blockIdx.x, bm = blockIdx.y;
  if (bm * 128 >= cnt) return;
  const int base = off8[e];
  __shared__ __align__(16) char AsB[8192];
  __shared__ __align__(16) char BgB[4096];
  __shared__ __align__(16) char BuB[4096];
  const int tid = threadIdx.x;
  const int wid = tid >> 6, lane = tid & 63;
  const int wm = (wid >> 1) << 6, wn = (wid & 1) << 5;
  const int lr = lane & 15, kh = lane >> 4;
  const int lrow = lane >> 2;
  const int lcol = (lane & 3) << 3;

  f32x4v accg[4][2], accu[4][2];
  const f32x4v z4 = {0.f, 0.f, 0.f, 0.f};
#pragma unroll
  for (int i = 0; i < 4; ++i)
#pragma unroll
    for (int j = 0; j < 2; ++j) { accg[i][j] = z4; accu[i][j] = z4; }

  for (int k0 = 0; k0 < HID; k0 += 32) {
    __syncthreads();
#pragma unroll
    for (int c = wid; c < 8; c += 4) {     // A: 128 rows
      int rg = bm * 128 + c * 16 + lrow;
      int tok = list[e * SEQ + (rg < cnt ? rg : cnt - 1)];
      gld_lds16(Xh + (size_t)tok * HID + k0 + lcol, AsB + c * 1024);
    }
    {                                       // B: 64 rows each (g,u)
      int c = wid;
      size_t wofs = (size_t)(e * IDIM + bn * 64 + c * 16 + lrow) * HID + k0 + lcol;
      gld_lds16(MGH + wofs, BgB + c * 1024);
      gld_lds16(MUH + wofs, BuB + c * 1024);
    }
    __syncthreads();

    bf16x8v af[4], bg4[2], bu4[2];
#pragma unroll
    for (int i = 0; i < 4; ++i) {
      int r = wm + (i << 4) + lr;
      af[i] = *(const bf16x8v*)(AsB + r * 64 + (kh << 4));
    }
#pragma unroll
    for (int i = 0; i < 2; ++i) {
      int r = wn + (i << 4) + lr;
      bg4[i] = *(const bf16x8v*)(BgB + r * 64 + (kh << 4));
      bu4[i] = *(const bf16x8v*)(BuB + r * 64 + (kh << 4));
    }
#pragma unroll
    for (int mi = 0; mi < 4; ++mi)
#pragma unroll
      for (int ni = 0; ni < 2; ++ni) {
        accg[mi][ni] = MFMA(af[mi], bg4[ni], accg[mi][ni]);
        accu[mi][ni] = MFMA(af[mi], bu4[ni], accu[mi][ni]);
      }
  }

  const int cr0 = kh << 2;
#pragma unroll
  for (int mi = 0; mi < 4; ++mi)
#pragma unroll
    for (int ni = 0; ni < 2; ++ni)
#pragma unroll
      for (int r = 0; r < 4; ++r) {
        int row = bm * 128 + wm + (mi << 4) + cr0 + r;
        if (row < cnt) {
          int col = bn * 64 + wn + (ni << 4) + lr;
          int tok = list[e * SEQ + row];
          float w = W[tok * 8 + e];
          float gval = accg[mi][ni][r];
          float uval = accu[mi][ni][r];
          float a = gval / (1.f + __expf(-gval)) * uval * w;
          A2[(size_t)(base + row) * IDIM + col] = (__bf16)a;
        }
      }
}

__global__ __launch_bounds__(256) void gemm_moe_down2_kernel(
    const __bf16* __restrict__ A2, const __bf16* __restrict__ MDH,
    float* __restrict__ Y2,
    const int* __restrict__ cnt8, const int* __restrict__ off8)
{
  const int e = blockIdx.z;
  const int cnt = cnt8[e];
  const int bn = blockIdx.x, bm = blockIdx.y;
  if (bm * 128 >= cnt) return;
  const int base = off8[e];
  __shared__ __align__(16) char AsB[8192];
  __shared__ __align__(16) char BsB[4096];
  const int tid = threadIdx.x;
  const int wid = tid >> 6, lane = tid & 63;
  const int wm = (wid >> 1) << 6, wn = (wid & 1) << 5;
  const int lr = lane & 15, kh = lane >> 4;
  const int lrow = lane >> 2;
  const int lcol = (lane & 3) << 3;

  f32x4v acc[4][2];
  const f32x4v z4 = {0.f, 0.f, 0.f, 0.f};
#pragma unroll
  for (int i = 0; i < 4; ++i)
#pragma unroll
    for (int j = 0; j < 2; ++j) acc[i][j] = z4;

  for (int k0 = 0; k0 < IDIM; k0 += 32) {
    __syncthreads();
#pragma unroll
    for (int c = wid; c < 8; c += 4) {
      int rg = bm * 128 + c * 16 + lrow;
      int row = (rg < cnt ? rg : cnt - 1);
      gld_lds16(A2 + (size_t)(base + row) * IDIM + k0 + lcol, AsB + c * 1024);
    }
    {
      int c = wid;
      gld_lds16(MDH + (size_t)(e * HID + bn * 64 + c * 16 + lrow) * IDIM + k0 + lcol,
                BsB + c * 1024);
    }
    __syncthreads();

    bf16x8v af[4], bfv[2];
#pragma unroll
    for (int i = 0; i < 4; ++i) {
      int r = wm + (i << 4) + lr;
      af[i] = *(const bf16x8v*)(AsB + r * 64 + (kh << 4));
    }
#pragma unroll
    for (int i = 0; i < 2; ++i) {
      int r = wn + (i << 4) + lr;
      bfv[i] = *(const bf16x8v*)(BsB + r * 64 + (kh << 4));
    }
#pragma unroll
    for (int mi = 0; mi < 4; ++mi)
#pragma unroll
      for (int ni = 0; ni < 2; ++ni)
        acc[mi][ni] = MFMA(af[mi], bfv[ni], acc[mi][ni]);
  }

  const int cr0 = kh << 2;
#pragma unroll
  for (int mi = 0; mi < 4; ++mi)
#pragma unroll
    for (int ni = 0; ni < 2; ++ni)
#pragma unroll
      for (int r = 0; r < 4; ++r) {
        int row = bm * 128 + wm + (mi << 4) + cr0 + r;
        if (row < cnt) {
          int col = bn * 64 + wn + (ni << 4) + lr;
          Y2[(size_t)(base + row) * HID + col] = acc[mi][ni][r];
        }
      }
}

// h[t] += y(e_lo) + y(e_hi)  (ascending-e order == old serial order)
__global__ __launch_bounds__(256) void moe_scatter_kernel(
    const int* __restrict__ tokpair, const int* __restrict__ off8,
    const float* __restrict__ Y2, float* __restrict__ H)
{
  const int t = blockIdx.x;
  const int i = threadIdx.x;
  int p0 = tokpair[t * 2], p1 = tokpair[t * 2 + 1];
  size_t r0 = off8[p0 >> 16] + (p0 & 0xffff);
  size_t r1 = off8[p1 >> 16] + (p1 & 0xffff);
  float4 a = ((const float4*)(Y2 + r0 * HID))[i];
  float4 b = ((const float4*)(Y2 + r1 * HID))[i];
  float4 hv = ((float4*)(H + (size_t)t * HID))[i];
  hv.x = (hv.x + a.x) + b.x;
  hv.y = (hv.y + a.y) + b.y;
  hv.z = (hv.z + a.z) + b.z;
  hv.w = (hv.w + a.w) + b.w;
  ((float4*)(H + (size_t)t * HID))[i] = hv;
}

// ---------------------------------------------------------------------------
// Small kernels
// ---------------------------------------------------------------------------
__global__ void tables_kernel(float* __restrict__ CT, float* __restrict__ ST)
{
  int idx = blockIdx.x * 256 + threadIdx.x;
  int s = idx >> 5, i = idx & 31;
  double inv = exp(-log(10000.0) * (double)i / 32.0);
  double ang = (double)s * inv;
  CT[idx] = (float)cos(ang);
  ST[idx] = (float)sin(ang);
}

__global__ __launch_bounds__(256) void embed_kernel(
    const int* __restrict__ ids, const float* __restrict__ E, float* __restrict__ H)
{
  int t = blockIdx.x;
  int id = ids[t];
  ((float4*)(H + (size_t)t * HID))[threadIdx.x] =
      ((const float4*)(E + (size_t)id * HID))[threadIdx.x];
}

__global__ __launch_bounds__(256) void rmsnorm_kernel(
    const float* __restrict__ X, const float* __restrict__ W,
    float* __restrict__ O, __bf16* __restrict__ OHb, __bf16* __restrict__ OLb)
{
  int t = blockIdx.x;
  int tid = threadIdx.x;
  float4 v = ((const float4*)(X + (size_t)t * HID))[tid];
  float ss = v.x * v.x + v.y * v.y + v.z * v.z + v.w * v.w;
#pragma unroll
  for (int d = 1; d < 64; d <<= 1) ss += __shfl_xor(ss, d);
  __shared__ float red[4];
  if ((tid & 63) == 0) red[tid >> 6] = ss;
  __syncthreads();
  float tot = red[0] + red[1] + red[2] + red[3];
  float inv = 1.0f / sqrtf(tot * (1.0f / 1024.0f) + 1e-6f);
  float4 w = ((const float4*)W)[tid];
  float4 r;
  r.x = v.x * inv * w.x; r.y = v.y * inv * w.y;
  r.z = v.z * inv * w.z; r.w = v.w * inv * w.w;
  ((float4*)(O + (size_t)t * HID))[tid] = r;
  float f[4] = {r.x, r.y, r.z, r.w};
  bf16x4v hv, lv;
#pragma unroll
  for (int j = 0; j < 4; ++j) {
    __bf16 hb = (__bf16)f[j];
    hv[j] = hb; lv[j] = (__bf16)(f[j] - (float)hb);
  }
  *(bf16x4v*)(OHb + (size_t)t * HID + tid * 4) = hv;
  *(bf16x4v*)(OLb + (size_t)t * HID + tid * 4) = lv;
}

__global__ __launch_bounds__(256) void router_kernel(
    const float* __restrict__ X, const float* __restrict__ RW, float* __restrict__ RL)
{
  int wid = threadIdx.x >> 6, lane = threadIdx.x & 63;
  int t = blockIdx.x * 4 + wid;
  const float* x = X + (size_t)t * HID;
  float a0 = 0, a1 = 0, a2 = 0, a3 = 0, a4 = 0, a5 = 0, a6 = 0, a7 = 0;
  for (int hh = lane; hh < HID; hh += 64) {
    float xv = x[hh];
    float4 f0 = *(const float4*)(RW + hh * 8);
    float4 f1 = *(const float4*)(RW + hh * 8 + 4);
    a0 += xv * f0.x; a1 += xv * f0.y; a2 += xv * f0.z; a3 += xv * f0.w;
    a4 += xv * f1.x; a5 += xv * f1.y; a6 += xv * f1.z; a7 += xv * f1.w;
  }
#pragma unroll
  for (int d = 1; d < 64; d <<= 1) {
    a0 += __shfl_xor(a0, d); a1 += __shfl_xor(a1, d);
    a2 += __shfl_xor(a2, d); a3 += __shfl_xor(a3, d);
    a4 += __shfl_xor(a4, d); a5 += __shfl_xor(a5, d);
    a6 += __shfl_xor(a6, d); a7 += __shfl_xor(a7, d);
  }
  if (lane == 0) {
    float* dst = RL + (size_t)t * 8;
    dst[0] = a0; dst[1] = a1; dst[2] = a2; dst[3] = a3;
    dst[4] = a4; dst[5] = a5; dst[6] = a6; dst[7] = a7;
  }
}

__global__ void zero_kernel(float* __restrict__ p, int n)
{
  int i = threadIdx.x;
  if (i < n) p[i] = 0.f;
}

__global__ void zeroi_kernel(int* __restrict__ p, int n)
{
  int i = threadIdx.x;
  if (i < n) p[i] = 0;
}

__global__ __launch_bounds__(256) void topk_kernel(
    const float* __restrict__ RL, float* __restrict__ W, float* __restrict__ AUX)
{
  int t = blockIdx.x * 256 + threadIdx.x;
  int lane = threadIdx.x & 63;
  float r[8];
#pragma unroll
  for (int e = 0; e < 8; ++e) r[e] = RL[t * 8 + e];
  float mx = r[0];
#pragma unroll
  for (int e = 1; e < 8; ++e) mx = fmaxf(mx, r[e]);
  float p[8];
  float se = 0.f;
#pragma unroll
  for (int e = 0; e < 8; ++e) { p[e] = __expf(r[e] - mx); se += p[e]; }
  float inv = 1.f / se;
#pragma unroll
  for (int e = 0; e < 8; ++e) p[e] *= inv;
  float lse = logf(se) + mx;
  int i1 = 0; float v1 = p[0];
#pragma unroll
  for (int e = 1; e < 8; ++e) if (p[e] > v1) { v1 = p[e]; i1 = e; }
  int i2 = -1; float v2 = -1.f;
#pragma unroll
  for (int e = 0; e < 8; ++e) if (e != i1 && p[e] > v2) { v2 = p[e]; i2 = e; }
  float s12 = v1 + v2;
#pragma unroll
  for (int e = 0; e < 8; ++e)
    W[t * 8 + e] = (e == i1) ? v1 / s12 : ((e == i2) ? v2 / s12 : 0.f);
#pragma unroll
  for (int e = 0; e < 8; ++e) {
    float fe = ((i1 == e) ? 1.f : 0.f) + ((i2 == e) ? 1.f : 0.f);
    float pe = p[e];
#pragma unroll
    for (int d = 1; d < 64; d <<= 1) { fe += __shfl_xor(fe, d); pe += __shfl_xor(pe, d); }
    if (lane == 0) { atomicAdd(&AUX[e], fe); atomicAdd(&AUX[8 + e], pe); }
  }
  float zz = lse * lse;
#pragma unroll
  for (int d = 1; d < 64; d <<= 1) zz += __shfl_xor(zz, d);
  if (lane == 0) atomicAdd(&AUX[16], zz);
}

__global__ void aux_kernel(const float* __restrict__ AUX, float* __restrict__ OUT)
{
  float s = 0.f;
#pragma unroll
  for (int e = 0; e < 8; ++e)
    s += (AUX[e] * (1.f / 2048.f)) * (AUX[8 + e] * (1.f / 2048.f));
  float auxv = 0.01f * 8.f * s;
  float z = 0.001f * (AUX[16] * (1.f / 2048.f));
  OUT[(size_t)SEQ * VOCAB] = auxv + z;
}

// records per-token (expert, pos) pairs in ascending-e order
__global__ __launch_bounds__(256) void build_list_kernel(
    const float* __restrict__ W, int* __restrict__ cnt, int* __restrict__ list,
    int* __restrict__ tokpair)
{
  int t = blockIdx.x * 256 + threadIdx.x;
  int j = 0;
#pragma unroll
  for (int e = 0; e < 8; ++e) {
    if (W[t * 8 + e] > 0.f) {
      int p = atomicAdd(&cnt[e], 1);
      list[e * SEQ + p] = t;
      tokpair[t * 2 + j] = (e << 16) | p;
      ++j;
    }
  }
}

__global__ void prefix_kernel(const int* __restrict__ cnt, int* __restrict__ off)
{
  if (threadIdx.x == 0) {
    int s = 0;
    for (int e = 0; e < 8; ++e) { off[e] = s; s += cnt[e]; }
  }
}

// ---------------------------------------------------------------------------
extern "C" void kernel_launch(void* const* d_in, const int* in_sizes, int n_in,
                              void* d_out, int out_size, void* d_ws, size_t ws_size,
                              hipStream_t stream)
{
  const int*   ids   = (const int*)d_in[0];
  const float* embed = (const float*)d_in[1];
  const float* ln1   = (const float*)d_in[2];
  const float* ln2   = (const float*)d_in[3];
  const float* wq    = (const float*)d_in[4];
  const float* wk    = (const float*)d_in[5];
  const float* wv    = (const float*)d_in[6];
  const float* wo    = (const float*)d_in[7];
  const float* dg    = (const float*)d_in[8];
  const float* du    = (const float*)d_in[9];
  const float* dd    = (const float*)d_in[10];
  const float* rw    = (const float*)d_in[11];
  const float* mg    = (const float*)d_in[12];
  const float* mu    = (const float*)d_in[13];
  const float* md    = (const float*)d_in[14];
  const float* fin   = (const float*)d_in[15];
  float* out = (float*)d_out;

  char* ws = (char*)d_ws;
  float* h    = (float*)(ws + 0);
  float* hn   = (float*)(ws + 8388608);
  float* q    = (float*)(ws + 16777216);
  float* k    = (float*)(ws + 25165824);
  float* v    = (float*)(ws + 33554432);
  __bf16* oh  = (__bf16*)(ws + 41943040);
  __bf16* ol  = (__bf16*)(ws + 46137344);
  float* g    = (float*)(ws + 50331648);
  float* u    = (float*)(ws + 73400320);
  float* ct   = (float*)(ws + 96468992);
  float* st   = (float*)(ws + 96731136);
  float* rl   = (float*)(ws + 96993280);
  float* wmoe = (float*)(ws + 97058816);
  float* aux  = (float*)(ws + 97124352);
  int*   cnt  = (int*)  (ws + 97124608);
  int*   list = (int*)  (ws + 97124864);
  int*   tokp = (int*)  (ws + 97190400);
  int*   off8 = (int*)  (ws + 97206784);
  __bf16* wqh = (__bf16*)(ws + 97320960);
  __bf16* wql = (__bf16*)(ws + 105709568);
  __bf16* wkh = (__bf16*)(ws + 114098176);
  __bf16* wkl = (__bf16*)(ws + 122486784);
  __bf16* wvh = (__bf16*)(ws + 130875392);
  __bf16* wvl = (__bf16*)(ws + 139264000);
  __bf16* woh = (__bf16*)(ws + 147652608);
  __bf16* wol = (__bf16*)(ws + 156041216);
  __bf16* dgh = (__bf16*)(ws + 164429824);
  __bf16* dgl = (__bf16*)(ws + 181731328);
  __bf16* duh = (__bf16*)(ws + 199032832);
  __bf16* dul = (__bf16*)(ws + 216334336);
  __bf16* ddh = (__bf16*)(ws + 233635840);
  __bf16* ddl = (__bf16*)(ws + 250937344);
  __bf16* eh  = (__bf16*)(ws + 268238848);
  __bf16* hnh = (__bf16*)(ws + 333774848);
  __bf16* hnl = (__bf16*)(ws + 337969152);
  __bf16* gh  = (__bf16*)(ws + 342163456);
  __bf16* gl  = (__bf16*)(ws + 353697792);
  __bf16* mgh = (__bf16*)(ws + 365232128);
  __bf16* muh = (__bf16*)(ws + 411369472);
  __bf16* mdh = (__bf16*)(ws + 457506816);
  // end: 503,644,160 bytes
  __bf16* qh  = (__bf16*)g;
  __bf16* ql  = (__bf16*)((char*)g + 4194304);
  __bf16* kbh = (__bf16*)((char*)g + 8388608);
  __bf16* kbl = (__bf16*)((char*)g + 12582912);
  __bf16* vth = (__bf16*)u;
  __bf16* vtl = (__bf16*)((char*)u + 4194304);
  __bf16* a2  = (__bf16*)g;
  float*  y2  = u;

  wsplit_t_kernel<<<dim3(16, 16, 4), 256, 0, stream>>>(wq, wqh, wql, HID, HID);
  wsplit_t_kernel<<<dim3(16, 16, 4), 256, 0, stream>>>(wk, wkh, wkl, HID, HID);
  wsplit_t_kernel<<<dim3(16, 16, 4), 256, 0, stream>>>(wv, wvh, wvl, HID, HID);
  wsplit_t_kernel<<<dim3(16, 16, 4), 256, 0, stream>>>(wo, woh, wol, HID, HID);
  wsplit_t_kernel<<<dim3(44, 16, 3), 256, 0, stream>>>(dg, dgh, dgl, HID, IDIM);
  wsplit_t_kernel<<<dim3(44, 16, 3), 256, 0, stream>>>(du, duh, dul, HID, IDIM);
  wsplit_t_kernel<<<dim3(16, 44, 3), 256, 0, stream>>>(dd, ddh, ddl, IDIM, HID);
  wsplit_th_kernel<<<dim3(44, 16, 8), 256, 0, stream>>>(mg, mgh, HID, IDIM);
  wsplit_th_kernel<<<dim3(44, 16, 8), 256, 0, stream>>>(mu, muh, HID, IDIM);
  wsplit_th_kernel<<<dim3(16, 44, 8), 256, 0, stream>>>(md, mdh, IDIM, HID);
  esplit_kernel<<<16000, 256, 0, stream>>>(embed, eh);

  tables_kernel<<<256, 256, 0, stream>>>(ct, st);
  embed_kernel<<<SEQ, 256, 0, stream>>>(ids, embed, h);

  for (int li = 0; li < 4; ++li) {
    const bool comp = (li <= 2);
    rmsnorm_kernel<<<SEQ, 256, 0, stream>>>(h, ln1 + li * HID, hn, hnh, hnl);
    size_t wofs = (size_t)li * HID * HID;
    // QKV GEMM with fused rope+split epilogue (q,k) and f32 v output
    if (comp)
      gemm_qkv_kernel<true><<<dim3(8, 32, 3), 256, 0, stream>>>(
          hnh, hnl, wqh + wofs, wql + wofs, wkh + wofs, wkl + wofs,
          wvh + wofs, wvl + wofs, qh, ql, kbh, kbl, v, ct, st);
    else
      gemm_qkv_kernel<false><<<dim3(8, 32, 3), 256, 0, stream>>>(
          hnh, hnh, wqh + wofs, wqh + wofs, wkh + wofs, wkh + wofs,
          wvh + wofs, wvh + wofs, qh, ql, kbh, kbl, v, ct, st);

    vtsplit_kernel<<<dim3(32, 16), 256, 0, stream>>>(v, vth, vtl);

    attn_flash_kernel<<<dim3(16, 16), 256, 0, stream>>>(
        qh, ql, kbh, kbl, vth, vtl, oh, ol);

    // wo GEMM: BN=64 -> 512 blocks (2/CU)
    if (comp)
      gemm_bt_kernel<true, true, 64, 64, false><<<dim3(16, 32, 1), 256, 0, stream>>>(
          oh, ol, woh + wofs, wol + wofs, woh + wofs, wol + wofs,
          woh + wofs, wol + wofs, h, h, h, SEQ, HID, HID);
    else
      gemm_bt_kernel<false, true, 64, 64, false><<<dim3(16, 32, 1), 256, 0, stream>>>(
          oh, oh, woh + wofs, woh + wofs, woh + wofs, woh + wofs,
          woh + wofs, woh + wofs, h, h, h, SEQ, HID, HID);

    rmsnorm_kernel<<<SEQ, 256, 0, stream>>>(h, ln2 + li * HID, hn, hnh, hnl);
    if (li == 2) {
      router_kernel<<<512, 256, 0, stream>>>(hn, rw, rl);
      zero_kernel<<<1, 32, 0, stream>>>(aux, 17);
      topk_kernel<<<8, 256, 0, stream>>>(rl, wmoe, aux);
      aux_kernel<<<1, 1, 0, stream>>>(aux, out);
      zeroi_kernel<<<1, 32, 0, stream>>>(cnt, 8);
      build_list_kernel<<<8, 256, 0, stream>>>(wmoe, cnt, list, tokp);
      prefix_kernel<<<1, 64, 0, stream>>>(cnt, off8);
      gemm_moe_guf_kernel<<<dim3(44, 16, 8), 256, 0, stream>>>(
          hnh, mgh, muh, a2, wmoe, list, cnt, off8);
      gemm_moe_down2_kernel<<<dim3(16, 16, 8), 256, 0, stream>>>(
          a2, mdh, y2, cnt, off8);
      moe_scatter_kernel<<<SEQ, 256, 0, stream>>>(tokp, off8, y2, h);
    } else {
      int d = (li < 2) ? li : li - 1;
      size_t go = (size_t)d * HID * IDIM;
      // dense gate+up GEMM with fused silu + hi/lo split epilogue
      if (comp)
        gemm_dgu_kernel<true><<<dim3(44, 32), 256, 0, stream>>>(
            hnh, hnl, dgh + go, dgl + go, duh + go, dul + go, gh, gl);
      else
        gemm_dgu_kernel<false><<<dim3(44, 32), 256, 0, stream>>>(
            hnh, hnh, dgh + go, dgh + go, duh + go, duh + go, gh, gl);
      // down GEMM: BN=64 -> 512 blocks
      if (comp)
        gemm_bt_kernel<true, true, 64, 64, false><<<dim3(16, 32, 1), 256, 0, stream>>>(
            gh, gl, ddh + go, ddl + go, ddh + go, ddl + go,
            ddh + go, ddl + go, h, h, h, SEQ, HID, IDIM);
      else
        gemm_bt_kernel<false, true, 64, 64, false><<<dim3(16, 32, 1), 256, 0, stream>>>(
            gh, gh, ddh + go, ddh + go, ddh + go, ddh + go,
            ddh + go, ddh + go, h, h, h, SEQ, HID, IDIM);
    }
  }
  rmsnorm_kernel<<<SEQ, 256, 0, stream>>>(h, fin, hn, hnh, hnl);
  // logits: BM=64 + XCD-aware bijective swizzle (8192-block 1D grid)
  gemm_bt_kernel<false, false, 64, 128, true><<<dim3(8192, 1, 1), 256, 0, stream>>>(
      hnh, hnh, eh, eh, eh, eh, eh, eh, out, out, out, SEQ, VOCAB, HID);
}

// Round 19
// 1783.276 us; speedup vs baseline: 1.2959x; 1.0349x over previous
//
#include <hip/hip_runtime.h>
#include <hip/hip_bf16.h>
#include <math.h>

#define SEQ 2048
#define HID 1024
#define NHEAD 16
#define HDIM 64
#define IDIM 2816
#define NEXP 8
#define VOCAB 32000

#define ASTRIDE 144  // padded rows (attention)

typedef float f32x4v __attribute__((ext_vector_type(4)));
typedef __bf16 bf16x8v __attribute__((ext_vector_type(8)));
typedef __bf16 bf16x4v __attribute__((ext_vector_type(4)));

__device__ __forceinline__ bf16x8v cvt8(const float4& a, const float4& b) {
  bf16x8v r;
  r[0] = (__bf16)a.x; r[1] = (__bf16)a.y; r[2] = (__bf16)a.z; r[3] = (__bf16)a.w;
  r[4] = (__bf16)b.x; r[5] = (__bf16)b.y; r[6] = (__bf16)b.z; r[7] = (__bf16)b.w;
  return r;
}

#define MFMA(a, b, c) __builtin_amdgcn_mfma_f32_16x16x32_bf16(a, b, c, 0, 0, 0)

// async global->LDS DMA, 16B per lane; lds base must be wave-uniform
__device__ __forceinline__ void gld_lds16(const void* g, void* l) {
  __builtin_amdgcn_global_load_lds(
      (const __attribute__((address_space(1))) unsigned int*)(unsigned long long)g,
      (__attribute__((address_space(3))) unsigned int*)(unsigned int)(unsigned long long)l,
      16, 0, 0);
}

// ---------------------------------------------------------------------------
// Weight preprocessing: W[K,N] f32 -> WH,WL [N,K] bf16 (transposed hi/lo).
// ---------------------------------------------------------------------------
__global__ __launch_bounds__(256) void wsplit_t_kernel(
    const float* __restrict__ W, __bf16* __restrict__ WH, __bf16* __restrict__ WL,
    int K, int N)
{
  __shared__ float tile[64][65];
  const int tid = threadIdx.x;
  const size_t zofs = (size_t)blockIdx.z * K * N;
  const int n0 = blockIdx.x * 64, k0 = blockIdx.y * 64;
#pragma unroll
  for (int r = 0; r < 4; ++r) {
    int kk = (tid >> 4) + r * 16;
    int nn = (tid & 15) * 4;
    float4 v = *(const float4*)(W + zofs + (size_t)(k0 + kk) * N + n0 + nn);
    tile[kk][nn] = v.x; tile[kk][nn + 1] = v.y;
    tile[kk][nn + 2] = v.z; tile[kk][nn + 3] = v.w;
  }
  __syncthreads();
  const int nn = tid >> 2;
  const int kk = (tid & 3) * 16;
  __bf16* dh = WH + zofs + (size_t)(n0 + nn) * K + k0 + kk;
  __bf16* dl = WL + zofs + (size_t)(n0 + nn) * K + k0 + kk;
  bf16x8v h0, l0, h1, l1;
#pragma unroll
  for (int j = 0; j < 8; ++j) {
    float f = tile[kk + j][nn];
    __bf16 hb = (__bf16)f; h0[j] = hb; l0[j] = (__bf16)(f - (float)hb);
    f = tile[kk + 8 + j][nn];
    hb = (__bf16)f; h1[j] = hb; l1[j] = (__bf16)(f - (float)hb);
  }
  *(bf16x8v*)dh = h0; *(bf16x8v*)(dh + 8) = h1;
  *(bf16x8v*)dl = l0; *(bf16x8v*)(dl + 8) = l1;
}

// hi-only variant (MoE weights; plain-bf16 path needs no lo)
__global__ __launch_bounds__(256) void wsplit_th_kernel(
    const float* __restrict__ W, __bf16* __restrict__ WH, int K, int N)
{
  __shared__ float tile[64][65];
  const int tid = threadIdx.x;
  const size_t zofs = (size_t)blockIdx.z * K * N;
  const int n0 = blockIdx.x * 64, k0 = blockIdx.y * 64;
#pragma unroll
  for (int r = 0; r < 4; ++r) {
    int kk = (tid >> 4) + r * 16;
    int nn = (tid & 15) * 4;
    float4 v = *(const float4*)(W + zofs + (size_t)(k0 + kk) * N + n0 + nn);
    tile[kk][nn] = v.x; tile[kk][nn + 1] = v.y;
    tile[kk][nn + 2] = v.z; tile[kk][nn + 3] = v.w;
  }
  __syncthreads();
  const int nn = tid >> 2;
  const int kk = (tid & 3) * 16;
  __bf16* dh = WH + zofs + (size_t)(n0 + nn) * K + k0 + kk;
  bf16x8v h0, h1;
#pragma unroll
  for (int j = 0; j < 8; ++j) {
    h0[j] = (__bf16)tile[kk + j][nn];
    h1[j] = (__bf16)tile[kk + 8 + j][nn];
  }
  *(bf16x8v*)dh = h0; *(bf16x8v*)(dh + 8) = h1;
}

__global__ __launch_bounds__(256) void esplit_kernel(
    const float* __restrict__ E, __bf16* __restrict__ EH)
{
  size_t i = ((size_t)blockIdx.x * 256 + threadIdx.x) * 8;
  float4 a = *(const float4*)(E + i);
  float4 b = *(const float4*)(E + i + 4);
  *(bf16x8v*)(EH + i) = cvt8(a, b);
}

// ---------------------------------------------------------------------------
// Unified BT GEMM. A,B pre-split bf16. Staging = global_load_lds DMA (16B),
// LINEAR LDS rows (64B/row). BM/BN tile params. XSWZ: XCD-aware bijective
// 1D grid (logits): BM=128 -> bm=j&15, bn=xcd*32+(j>>4), grid 4096.
// ---------------------------------------------------------------------------
template<bool COMP, bool ACCUM, int BM, int BN, bool XSWZ>
__global__ __launch_bounds__(256) void gemm_bt_kernel(
    const __bf16* __restrict__ Ah, const __bf16* __restrict__ Al,
    const __bf16* __restrict__ B0h, const __bf16* __restrict__ B0l,
    const __bf16* __restrict__ B1h, const __bf16* __restrict__ B1l,
    const __bf16* __restrict__ B2h, const __bf16* __restrict__ B2l,
    float* __restrict__ C0, float* __restrict__ C1, float* __restrict__ C2,
    int M, int N, int Kd)
{
  const __bf16* __restrict__ Bh = (blockIdx.z == 0) ? B0h : (blockIdx.z == 1 ? B1h : B2h);
  const __bf16* __restrict__ Bl = (blockIdx.z == 0) ? B0l : (blockIdx.z == 1 ? B1l : B2l);
  float* __restrict__ C         = (blockIdx.z == 0) ? C0 : (blockIdx.z == 1 ? C1 : C2);
  constexpr int ATILE = BM * 64;
  constexpr int BTILE = BN * 64;
  constexpr int MFR = BM / 32;
  constexpr int NFR = BN / 32;
  __shared__ __align__(16) char smem[COMP ? 2 * (ATILE + BTILE) : (ATILE + BTILE)];
  char* AsH = smem;
  char* BsH = smem + ATILE;
  char* AsL = COMP ? smem + ATILE + BTILE : smem;
  char* BsL = COMP ? smem + 2 * ATILE + BTILE : smem + ATILE;
  const int tid = threadIdx.x;
  int bm, bn;
  if (XSWZ) {
    int id = blockIdx.x;            // padded 1D grid
    int xcd = id & 7;
    int j = id >> 3;
    if (BM == 128) {                // M=2048 -> 16 bm-blocks
      bm = j & 15;
      bn = xcd * 32 + (j >> 4);
    } else {                        // BM=64 -> 32 bm-blocks
      bm = j & 31;
      bn = xcd * 32 + (j >> 5);
    }
    if (bn >= N / BN) return;
  } else {
    bm = blockIdx.y;
    bn = blockIdx.x;
  }
  const int wid = tid >> 6, lane = tid & 63;
  const int wm = (wid >> 1) * (BM / 2), wn = (wid & 1) * (BN / 2);
  const int lr = lane & 15, kh = lane >> 4;
  const int lrow = lane >> 2;
  const int lcol = (lane & 3) << 3;

  f32x4v acc[MFR][NFR];
  const f32x4v z4 = {0.f, 0.f, 0.f, 0.f};
#pragma unroll
  for (int i = 0; i < MFR; ++i)
#pragma unroll
    for (int j2 = 0; j2 < NFR; ++j2) acc[i][j2] = z4;

  for (int k0 = 0; k0 < Kd; k0 += 32) {
    __syncthreads();
#pragma unroll
    for (int c = wid; c < BM / 16; c += 4) {
      size_t gofs = (size_t)(bm * BM + c * 16 + lrow) * Kd + k0 + lcol;
      gld_lds16(Ah + gofs, AsH + c * 1024);
      if (COMP) gld_lds16(Al + gofs, AsL + c * 1024);
    }
#pragma unroll
    for (int c = wid; c < BN / 16; c += 4) {
      size_t gofs = (size_t)(bn * BN + c * 16 + lrow) * Kd + k0 + lcol;
      gld_lds16(Bh + gofs, BsH + c * 1024);
      if (COMP) gld_lds16(Bl + gofs, BsL + c * 1024);
    }
    __syncthreads();

    bf16x8v ah[MFR], al[MFR], bh4[NFR], bl4[NFR];
#pragma unroll
    for (int i = 0; i < MFR; ++i) {
      int r = wm + (i << 4) + lr;
      int off = r * 64 + (kh << 4);
      ah[i] = *(const bf16x8v*)(AsH + off);
      if (COMP) al[i] = *(const bf16x8v*)(AsL + off);
    }
#pragma unroll
    for (int i = 0; i < NFR; ++i) {
      int r = wn + (i << 4) + lr;
      int off = r * 64 + (kh << 4);
      bh4[i] = *(const bf16x8v*)(BsH + off);
      if (COMP) bl4[i] = *(const bf16x8v*)(BsL + off);
    }
#pragma unroll
    for (int mi = 0; mi < MFR; ++mi)
#pragma unroll
      for (int ni = 0; ni < NFR; ++ni) {
        if (COMP) {
          acc[mi][ni] = MFMA(al[mi], bh4[ni], acc[mi][ni]);
          acc[mi][ni] = MFMA(ah[mi], bl4[ni], acc[mi][ni]);
        }
        acc[mi][ni] = MFMA(ah[mi], bh4[ni], acc[mi][ni]);
      }
  }

  const int cr0 = kh << 2;
#pragma unroll
  for (int mi = 0; mi < MFR; ++mi)
#pragma unroll
    for (int ni = 0; ni < NFR; ++ni)
#pragma unroll
      for (int r = 0; r < 4; ++r) {
        int row = bm * BM + wm + (mi << 4) + cr0 + r;
        int col = bn * BN + wn + (ni << 4) + lr;
        size_t idx = (size_t)row * N + col;
        if (ACCUM) C[idx] += acc[mi][ni][r];
        else       C[idx] = acc[mi][ni][r];
      }
}

// ---------------------------------------------------------------------------
// QKV GEMM with fused rope + hi/lo split epilogue (z=0 q scale 1/8, z=1 k),
// z=2 writes f32 v (for vtsplit). BM=64, N=K=HID. Bit-exact vs GEMM+rope_split.
// ---------------------------------------------------------------------------
template<bool COMP>
__global__ __launch_bounds__(256) void gemm_qkv_kernel(
    const __bf16* __restrict__ Ah, const __bf16* __restrict__ Al,
    const __bf16* __restrict__ Bqh, const __bf16* __restrict__ Bql,
    const __bf16* __restrict__ Bkh, const __bf16* __restrict__ Bkl,
    const __bf16* __restrict__ Bvh, const __bf16* __restrict__ Bvl,
    __bf16* __restrict__ QH, __bf16* __restrict__ QL,
    __bf16* __restrict__ KH, __bf16* __restrict__ KL,
    float* __restrict__ Vout,
    const float* __restrict__ CT, const float* __restrict__ ST)
{
  const __bf16* __restrict__ Bh = (blockIdx.z == 0) ? Bqh : (blockIdx.z == 1 ? Bkh : Bvh);
  const __bf16* __restrict__ Bl = (blockIdx.z == 0) ? Bql : (blockIdx.z == 1 ? Bkl : Bvl);
  constexpr int ATILE = 64 * 64;
  constexpr int BTILE = 128 * 64;
  __shared__ __align__(16) char smem[COMP ? 2 * (ATILE + BTILE) : (ATILE + BTILE)];
  char* AsH = smem;
  char* BsH = smem + ATILE;
  char* AsL = COMP ? smem + ATILE + BTILE : smem;
  char* BsL = COMP ? smem + 2 * ATILE + BTILE : smem + ATILE;
  const int tid = threadIdx.x;
  const int bm = blockIdx.y, bn = blockIdx.x;
  const int wid = tid >> 6, lane = tid & 63;
  const int wm = (wid >> 1) << 5, wn = (wid & 1) << 6;
  const int lr = lane & 15, kh = lane >> 4;
  const int lrow = lane >> 2;
  const int lcol = (lane & 3) << 3;

  f32x4v acc[2][4];
  const f32x4v z4 = {0.f, 0.f, 0.f, 0.f};
#pragma unroll
  for (int i = 0; i < 2; ++i)
#pragma unroll
    for (int j2 = 0; j2 < 4; ++j2) acc[i][j2] = z4;

  for (int k0 = 0; k0 < HID; k0 += 32) {
    __syncthreads();
    {
      int c = wid;   // A: 4 chunks
      size_t gofs = (size_t)(bm * 64 + c * 16 + lrow) * HID + k0 + lcol;
      gld_lds16(Ah + gofs, AsH + c * 1024);
      if (COMP) gld_lds16(Al + gofs, AsL + c * 1024);
    }
#pragma unroll
    for (int c = wid; c < 8; c += 4) {
      size_t gofs = (size_t)(bn * 128 + c * 16 + lrow) * HID + k0 + lcol;
      gld_lds16(Bh + gofs, BsH + c * 1024);
      if (COMP) gld_lds16(Bl + gofs, BsL + c * 1024);
    }
    __syncthreads();

    bf16x8v ah2[2], al2[2], bh4[4], bl4[4];
#pragma unroll
    for (int i = 0; i < 2; ++i) {
      int r = wm + (i << 4) + lr;
      int off = r * 64 + (kh << 4);
      ah2[i] = *(const bf16x8v*)(AsH + off);
      if (COMP) al2[i] = *(const bf16x8v*)(AsL + off);
    }
#pragma unroll
    for (int i = 0; i < 4; ++i) {
      int r = wn + (i << 4) + lr;
      int off = r * 64 + (kh << 4);
      bh4[i] = *(const bf16x8v*)(BsH + off);
      if (COMP) bl4[i] = *(const bf16x8v*)(BsL + off);
    }
#pragma unroll
    for (int mi = 0; mi < 2; ++mi)
#pragma unroll
      for (int ni = 0; ni < 4; ++ni) {
        if (COMP) {
          acc[mi][ni] = MFMA(al2[mi], bh4[ni], acc[mi][ni]);
          acc[mi][ni] = MFMA(ah2[mi], bl4[ni], acc[mi][ni]);
        }
        acc[mi][ni] = MFMA(ah2[mi], bh4[ni], acc[mi][ni]);
      }
  }

  const int cr0 = kh << 2;
  if (blockIdx.z == 2) {
#pragma unroll
    for (int mi = 0; mi < 2; ++mi)
#pragma unroll
      for (int ni = 0; ni < 4; ++ni)
#pragma unroll
        for (int r = 0; r < 4; ++r) {
          int row = bm * 64 + wm + (mi << 4) + cr0 + r;
          int col = bn * 128 + wn + (ni << 4) + lr;
          Vout[(size_t)row * HID + col] = acc[mi][ni][r];
        }
  } else {
    const float scale = (blockIdx.z == 0) ? 0.125f : 1.0f;
    __bf16* OH = (blockIdx.z == 0) ? QH : KH;
    __bf16* OL = (blockIdx.z == 0) ? QL : KL;
#pragma unroll
    for (int mi = 0; mi < 2; ++mi)
#pragma unroll
      for (int ni = 0; ni < 2; ++ni)
#pragma unroll
        for (int r = 0; r < 4; ++r) {
          int row = bm * 64 + wm + (mi << 4) + cr0 + r;
          int col = bn * 128 + wn + (ni << 4) + lr;   // (col&63) < 32
          int i = col & 31;
          float c = CT[row * 32 + i], sn = ST[row * 32 + i];
          float x1 = acc[mi][ni][r];
          float x2 = acc[mi][ni + 2][r];
          float o1 = (x1 * c - x2 * sn) * scale;
          float o2 = (x2 * c + x1 * sn) * scale;
          size_t ofs = (size_t)row * HID + col;
          __bf16 h1 = (__bf16)o1;
          OH[ofs] = h1; OL[ofs] = (__bf16)(o1 - (float)h1);
          __bf16 h2 = (__bf16)o2;
          OH[ofs + 32] = h2; OL[ofs + 32] = (__bf16)(o2 - (float)h2);
        }
  }
}

// ---------------------------------------------------------------------------
// Dense gate+up GEMM with fused silu + hi/lo split epilogue. BM=64, BN=64.
// ---------------------------------------------------------------------------
template<bool COMP>
__global__ __launch_bounds__(256) void gemm_dgu_kernel(
    const __bf16* __restrict__ Ah, const __bf16* __restrict__ Al,
    const __bf16* __restrict__ BGh, const __bf16* __restrict__ BGl,
    const __bf16* __restrict__ BUh, const __bf16* __restrict__ BUl,
    __bf16* __restrict__ GH, __bf16* __restrict__ GL)
{
  __shared__ __align__(16) char AsH[4096], AsL[4096];
  __shared__ __align__(16) char BgH[4096], BgL[4096];
  __shared__ __align__(16) char BuH[4096], BuL[4096];
  const int tid = threadIdx.x;
  const int bn = blockIdx.x, bm = blockIdx.y;
  const int wid = tid >> 6, lane = tid & 63;
  const int wm = (wid >> 1) << 5, wn = (wid & 1) << 5;
  const int lr = lane & 15, kh = lane >> 4;
  const int lrow = lane >> 2;
  const int lcol = (lane & 3) << 3;

  f32x4v accg[2][2], accu[2][2];
  const f32x4v z4 = {0.f, 0.f, 0.f, 0.f};
#pragma unroll
  for (int i = 0; i < 2; ++i)
#pragma unroll
    for (int j = 0; j < 2; ++j) { accg[i][j] = z4; accu[i][j] = z4; }

  for (int k0 = 0; k0 < HID; k0 += 32) {
    __syncthreads();
    {
      int c = wid;   // 4 chunks each buffer
      size_t aofs = (size_t)(bm * 64 + c * 16 + lrow) * HID + k0 + lcol;
      gld_lds16(Ah + aofs, AsH + c * 1024);
      if (COMP) gld_lds16(Al + aofs, AsL + c * 1024);
      size_t bofs = (size_t)(bn * 64 + c * 16 + lrow) * HID + k0 + lcol;
      gld_lds16(BGh + bofs, BgH + c * 1024);
      gld_lds16(BUh + bofs, BuH + c * 1024);
      if (COMP) {
        gld_lds16(BGl + bofs, BgL + c * 1024);
        gld_lds16(BUl + bofs, BuL + c * 1024);
      }
    }
    __syncthreads();

    bf16x8v af[2], afl[2], bg4[2], bgl4[2], bu4[2], bul4[2];
#pragma unroll
    for (int i = 0; i < 2; ++i) {
      int r = wm + (i << 4) + lr;
      int off = r * 64 + (kh << 4);
      af[i] = *(const bf16x8v*)(AsH + off);
      if (COMP) afl[i] = *(const bf16x8v*)(AsL + off);
    }
#pragma unroll
    for (int i = 0; i < 2; ++i) {
      int r = wn + (i << 4) + lr;
      int off = r * 64 + (kh << 4);
      bg4[i] = *(const bf16x8v*)(BgH + off);
      bu4[i] = *(const bf16x8v*)(BuH + off);
      if (COMP) {
        bgl4[i] = *(const bf16x8v*)(BgL + off);
        bul4[i] = *(const bf16x8v*)(BuL + off);
      }
    }
#pragma unroll
    for (int mi = 0; mi < 2; ++mi)
#pragma unroll
      for (int ni = 0; ni < 2; ++ni) {
        if (COMP) {
          accg[mi][ni] = MFMA(afl[mi], bg4[ni], accg[mi][ni]);
          accg[mi][ni] = MFMA(af[mi], bgl4[ni], accg[mi][ni]);
        }
        accg[mi][ni] = MFMA(af[mi], bg4[ni], accg[mi][ni]);
        if (COMP) {
          accu[mi][ni] = MFMA(afl[mi], bu4[ni], accu[mi][ni]);
          accu[mi][ni] = MFMA(af[mi], bul4[ni], accu[mi][ni]);
        }
        accu[mi][ni] = MFMA(af[mi], bu4[ni], accu[mi][ni]);
      }
  }

  const int cr0 = kh << 2;
#pragma unroll
  for (int mi = 0; mi < 2; ++mi)
#pragma unroll
    for (int ni = 0; ni < 2; ++ni)
#pragma unroll
      for (int r = 0; r < 4; ++r) {
        int row = bm * 64 + wm + (mi << 4) + cr0 + r;
        int col = bn * 64 + wn + (ni << 4) + lr;
        float gv = accg[mi][ni][r];
        float uv = accu[mi][ni][r];
        float a = gv / (1.f + __expf(-gv)) * uv;
        size_t idx = (size_t)row * IDIM + col;
        __bf16 hb = (__bf16)a;
        GH[idx] = hb;
        GL[idx] = (__bf16)(a - (float)hb);
      }
}

// V f32 [S][HID] -> per-head transposed hi/lo bf16 [NHEAD][HDIM][SEQ]
__global__ __launch_bounds__(256) void vtsplit_kernel(
    const float* __restrict__ V, __bf16* __restrict__ VTH, __bf16* __restrict__ VTL)
{
  __shared__ float tile[64][65];
  const int tid = threadIdx.x;
  const int s0 = blockIdx.x * 64;
  const int head = blockIdx.y;
#pragma unroll
  for (int r = 0; r < 4; ++r) {
    int ss = (tid >> 4) + r * 16;
    int dd = (tid & 15) * 4;
    float4 v = *(const float4*)(V + (size_t)(s0 + ss) * HID + head * 64 + dd);
    tile[ss][dd] = v.x; tile[ss][dd + 1] = v.y;
    tile[ss][dd + 2] = v.z; tile[ss][dd + 3] = v.w;
  }
  __syncthreads();
#pragma unroll
  for (int half = 0; half < 2; ++half) {
    const int d = (tid >> 3) + (half << 5);
    const int c = tid & 7;
    bf16x8v hv, lv;
#pragma unroll
    for (int j = 0; j < 8; ++j) {
      float f = tile[c * 8 + j][d];
      __bf16 hb = (__bf16)f;
      hv[j] = hb; lv[j] = (__bf16)(f - (float)hb);
    }
    size_t dst = (size_t)(head * 64 + d) * SEQ + s0 + c * 8;
    *(bf16x8v*)(VTH + dst) = hv;
    *(bf16x8v*)(VTL + dst) = lv;
  }
}

// ---------------------------------------------------------------------------
// Compensated flash attention; padded LDS; O -> bf16 hi/lo.
// Load-balanced: grid (16,16); block processes qt = bx and qt = 31-bx.
// ---------------------------------------------------------------------------
__global__ __launch_bounds__(256) void attn_flash_kernel(
    const __bf16* __restrict__ QH, const __bf16* __restrict__ QL,
    const __bf16* __restrict__ KH, const __bf16* __restrict__ KL,
    const __bf16* __restrict__ VTH, const __bf16* __restrict__ VTL,
    __bf16* __restrict__ OH, __bf16* __restrict__ OL)
{
  const int head = blockIdx.y;
  const int tid = threadIdx.x, wid = tid >> 6, lane = tid & 63;
  const int lr = lane & 15, kh = lane >> 4;
  __shared__ __align__(16) char KsH[64 * ASTRIDE], KsL[64 * ASTRIDE];
  __shared__ __align__(16) char VtH[64 * ASTRIDE], VtL[64 * ASTRIDE];
  __shared__ __align__(16) char PsH[4][16 * ASTRIDE], PsL[4][16 * ASTRIDE];

#pragma unroll
  for (int seg = 0; seg < 2; ++seg) {
    const int qt = seg ? (31 - (int)blockIdx.x) : (int)blockIdx.x;

    const size_t qofs = (size_t)(qt * 64 + wid * 16 + lr) * HID + head * HDIM;
    const bf16x8v qfh0 = *(const bf16x8v*)(QH + qofs + (kh << 3));
    const bf16x8v qfh1 = *(const bf16x8v*)(QH + qofs + 32 + (kh << 3));
    const bf16x8v qfl0 = *(const bf16x8v*)(QL + qofs + (kh << 3));
    const bf16x8v qfl1 = *(const bf16x8v*)(QL + qofs + 32 + (kh << 3));

    float m_run[4], l_run[4];
    f32x4v oacc[4];
    const f32x4v z4 = {0.f, 0.f, 0.f, 0.f};
#pragma unroll
    for (int i = 0; i < 4; ++i) { m_run[i] = -1e30f; l_run[i] = 0.f; oacc[i] = z4; }

    for (int kt = 0; kt <= qt; ++kt) {
      __syncthreads();
#pragma unroll
      for (int p = 0; p < 2; ++p) {
        int g = tid + (p << 8);
        int r = g >> 3;
        int c = g & 7;
        int off = r * ASTRIDE + (c << 4);
        const size_t kofs = (size_t)(kt * 64 + r) * HID + head * HDIM + (c << 3);
        *(bf16x8v*)(KsH + off) = *(const bf16x8v*)(KH + kofs);
        *(bf16x8v*)(KsL + off) = *(const bf16x8v*)(KL + kofs);
        const size_t vofs = (size_t)(head * 64 + r) * SEQ + kt * 64 + (c << 3);
        *(bf16x8v*)(VtH + off) = *(const bf16x8v*)(VTH + vofs);
        *(bf16x8v*)(VtL + off) = *(const bf16x8v*)(VTL + vofs);
      }
      __syncthreads();

      float sv[4][4];
#pragma unroll
      for (int stt = 0; stt < 4; ++stt) {
        int r = (stt << 4) + lr;
        int off0 = r * ASTRIDE + (kh << 4);
        int off1 = off0 + 64;
        bf16x8v kfh0 = *(const bf16x8v*)(KsH + off0);
        bf16x8v kfl0 = *(const bf16x8v*)(KsL + off0);
        bf16x8v kfh1 = *(const bf16x8v*)(KsH + off1);
        bf16x8v kfl1 = *(const bf16x8v*)(KsL + off1);
        f32x4v s = z4;
        s = MFMA(qfl0, kfh0, s);
        s = MFMA(qfh0, kfl0, s);
        s = MFMA(qfh0, kfh0, s);
        s = MFMA(qfl1, kfh1, s);
        s = MFMA(qfh1, kfl1, s);
        s = MFMA(qfh1, kfh1, s);
        int key = kt * 64 + (stt << 4) + lr;
#pragma unroll
        for (int rr = 0; rr < 4; ++rr) {
          int qr = qt * 64 + wid * 16 + (kh << 2) + rr;
          sv[stt][rr] = (key <= qr) ? s[rr] : -1e30f;
        }
      }

#pragma unroll
      for (int rr = 0; rr < 4; ++rr) {
        float mx = fmaxf(fmaxf(sv[0][rr], sv[1][rr]), fmaxf(sv[2][rr], sv[3][rr]));
#pragma unroll
        for (int d = 1; d < 16; d <<= 1) mx = fmaxf(mx, __shfl_xor(mx, d));
        float mnew = fmaxf(m_run[rr], mx);
        float scl = __expf(m_run[rr] - mnew);
        float pv[4];
#pragma unroll
        for (int stt = 0; stt < 4; ++stt) pv[stt] = __expf(sv[stt][rr] - mnew);
        float rs = pv[0] + pv[1] + pv[2] + pv[3];
#pragma unroll
        for (int d = 1; d < 16; d <<= 1) rs += __shfl_xor(rs, d);
        l_run[rr] = l_run[rr] * scl + rs;
        m_run[rr] = mnew;
#pragma unroll
        for (int n = 0; n < 4; ++n) oacc[n][rr] *= scl;
        int qlr = (kh << 2) + rr;
#pragma unroll
        for (int stt = 0; stt < 4; ++stt) {
          __bf16 hb = (__bf16)pv[stt];
          __bf16 lb = (__bf16)(pv[stt] - (float)hb);
          int off = qlr * ASTRIDE + (((stt << 4) + lr) << 1);
          *(__bf16*)(PsH[wid] + off) = hb;
          *(__bf16*)(PsL[wid] + off) = lb;
        }
      }

      int poff0 = lr * ASTRIDE + (kh << 4);
      int poff1 = poff0 + 64;
      bf16x8v pah0 = *(const bf16x8v*)(PsH[wid] + poff0);
      bf16x8v pal0 = *(const bf16x8v*)(PsL[wid] + poff0);
      bf16x8v pah1 = *(const bf16x8v*)(PsH[wid] + poff1);
      bf16x8v pal1 = *(const bf16x8v*)(PsL[wid] + poff1);
#pragma unroll
      for (int n = 0; n < 4; ++n) {
        int vr = (n << 4) + lr;
        int voff0 = vr * ASTRIDE + (kh << 4);
        int voff1 = voff0 + 64;
        bf16x8v vfh0 = *(const bf16x8v*)(VtH + voff0);
        bf16x8v vfl0 = *(const bf16x8v*)(VtL + voff0);
        bf16x8v vfh1 = *(const bf16x8v*)(VtH + voff1);
        bf16x8v vfl1 = *(const bf16x8v*)(VtL + voff1);
        oacc[n] = MFMA(pal0, vfh0, oacc[n]);
        oacc[n] = MFMA(pah0, vfl0, oacc[n]);
        oacc[n] = MFMA(pah0, vfh0, oacc[n]);
        oacc[n] = MFMA(pal1, vfh1, oacc[n]);
        oacc[n] = MFMA(pah1, vfl1, oacc[n]);
        oacc[n] = MFMA(pah1, vfh1, oacc[n]);
      }
    }

#pragma unroll
    for (int n = 0; n < 4; ++n)
#pragma unroll
      for (int rr = 0; rr < 4; ++rr) {
        int qr = qt * 64 + wid * 16 + (kh << 2) + rr;
        size_t ofs = (size_t)qr * HID + head * HDIM + (n << 4) + lr;
        float val = oacc[n][rr] / l_run[rr];
        __bf16 hb = (__bf16)val;
        OH[ofs] = hb;
        OL[ofs] = (__bf16)(val - (float)hb);
      }
  }
}

// ---------------------------------------------------------------------------
// MoE: fused gate+up+silu. BM=128, BN=64. DMA staging, pre-split weights.
// ---------------------------------------------------------------------------
__global__ __launch_bounds__(256) void gemm_moe_guf_kernel(
    const __bf16* __restrict__ Xh,
    const __bf16* __restrict__ MGH, const __bf16* __restrict__ MUH,
    __bf16* __restrict__ A2, const float* __restrict__ W,
    const int* __restrict__ list, const int* __restrict__ cnt8,
    const int* __restrict__ off8)
{
  const int e = blockIdx.z;
  const int cnt = cnt8[e];
  const int bn = blockIdx.x, bm = blockIdx.y;
  if (bm * 128 >= cnt) return;
  const int base = off8[e];
  __shared__ __align__(16) char AsB[8192];
  __shared__ __align__(16) char BgB[4096];
  __shared__ __align__(16) char BuB[4096];
  const int tid = threadIdx.x;
  const int wid = tid >> 6, lane = tid & 63;
  const int wm = (wid >> 1) << 6, wn = (wid & 1) << 5;
  const int lr = lane & 15, kh = lane >> 4;
  const int lrow = lane >> 2;
  const int lcol = (lane & 3) << 3;

  f32x4v accg[4][2], accu[4][2];
  const f32x4v z4 = {0.f, 0.f, 0.f, 0.f};
#pragma unroll
  for (int i = 0; i < 4; ++i)
#pragma unroll
    for (int j = 0; j < 2; ++j) { accg[i][j] = z4; accu[i][j] = z4; }

  for (int k0 = 0; k0 < HID; k0 += 32) {
    __syncthreads();
#pragma unroll
    for (int c = wid; c < 8; c += 4) {     // A: 128 rows
      int rg = bm * 128 + c * 16 + lrow;
      int tok = list[e * SEQ + (rg < cnt ? rg : cnt - 1)];
      gld_lds16(Xh + (size_t)tok * HID + k0 + lcol, AsB + c * 1024);
    }
    {                                       // B: 64 rows each (g,u)
      int c = wid;
      size_t wofs = (size_t)(e * IDIM + bn * 64 + c * 16 + lrow) * HID + k0 + lcol;
      gld_lds16(MGH + wofs, BgB + c * 1024);
      gld_lds16(MUH + wofs, BuB + c * 1024);
    }
    __syncthreads();

    bf16x8v af[4], bg4[2], bu4[2];
#pragma unroll
    for (int i = 0; i < 4; ++i) {
      int r = wm + (i << 4) + lr;
      af[i] = *(const bf16x8v*)(AsB + r * 64 + (kh << 4));
    }
#pragma unroll
    for (int i = 0; i < 2; ++i) {
      int r = wn + (i << 4) + lr;
      bg4[i] = *(const bf16x8v*)(BgB + r * 64 + (kh << 4));
      bu4[i] = *(const bf16x8v*)(BuB + r * 64 + (kh << 4));
    }
#pragma unroll
    for (int mi = 0; mi < 4; ++mi)
#pragma unroll
      for (int ni = 0; ni < 2; ++ni) {
        accg[mi][ni] = MFMA(af[mi], bg4[ni], accg[mi][ni]);
        accu[mi][ni] = MFMA(af[mi], bu4[ni], accu[mi][ni]);
      }
  }

  const int cr0 = kh << 2;
#pragma unroll
  for (int mi = 0; mi < 4; ++mi)
#pragma unroll
    for (int ni = 0; ni < 2; ++ni)
#pragma unroll
      for (int r = 0; r < 4; ++r) {
        int row = bm * 128 + wm + (mi << 4) + cr0 + r;
        if (row < cnt) {
          int col = bn * 64 + wn + (ni << 4) + lr;
          int tok = list[e * SEQ + row];
          float w = W[tok * 8 + e];
          float gval = accg[mi][ni][r];
          float uval = accu[mi][ni][r];
          float a = gval / (1.f + __expf(-gval)) * uval * w;
          A2[(size_t)(base + row) * IDIM + col] = (__bf16)a;
        }
      }
}

__global__ __launch_bounds__(256) void gemm_moe_down2_kernel(
    const __bf16* __restrict__ A2, const __bf16* __restrict__ MDH,
    float* __restrict__ Y2,
    const int* __restrict__ cnt8, const int* __restrict__ off8)
{
  const int e = blockIdx.z;
  const int cnt = cnt8[e];
  const int bn = blockIdx.x, bm = blockIdx.y;
  if (bm * 128 >= cnt) return;
  const int base = off8[e];
  __shared__ __align__(16) char AsB[8192];
  __shared__ __align__(16) char BsB[4096];
  const int tid = threadIdx.x;
  const int wid = tid >> 6, lane = tid & 63;
  const int wm = (wid >> 1) << 6, wn = (wid & 1) << 5;
  const int lr = lane & 15, kh = lane >> 4;
  const int lrow = lane >> 2;
  const int lcol = (lane & 3) << 3;

  f32x4v acc[4][2];
  const f32x4v z4 = {0.f, 0.f, 0.f, 0.f};
#pragma unroll
  for (int i = 0; i < 4; ++i)
#pragma unroll
    for (int j = 0; j < 2; ++j) acc[i][j] = z4;

  for (int k0 = 0; k0 < IDIM; k0 += 32) {
    __syncthreads();
#pragma unroll
    for (int c = wid; c < 8; c += 4) {
      int rg = bm * 128 + c * 16 + lrow;
      int row = (rg < cnt ? rg : cnt - 1);
      gld_lds16(A2 + (size_t)(base + row) * IDIM + k0 + lcol, AsB + c * 1024);
    }
    {
      int c = wid;
      gld_lds16(MDH + (size_t)(e * HID + bn * 64 + c * 16 + lrow) * IDIM + k0 + lcol,
                BsB + c * 1024);
    }
    __syncthreads();

    bf16x8v af[4], bfv[2];
#pragma unroll
    for (int i = 0; i < 4; ++i) {
      int r = wm + (i << 4) + lr;
      af[i] = *(const bf16x8v*)(AsB + r * 64 + (kh << 4));
    }
#pragma unroll
    for (int i = 0; i < 2; ++i) {
      int r = wn + (i << 4) + lr;
      bfv[i] = *(const bf16x8v*)(BsB + r * 64 + (kh << 4));
    }
#pragma unroll
    for (int mi = 0; mi < 4; ++mi)
#pragma unroll
      for (int ni = 0; ni < 2; ++ni)
        acc[mi][ni] = MFMA(af[mi], bfv[ni], acc[mi][ni]);
  }

  const int cr0 = kh << 2;
#pragma unroll
  for (int mi = 0; mi < 4; ++mi)
#pragma unroll
    for (int ni = 0; ni < 2; ++ni)
#pragma unroll
      for (int r = 0; r < 4; ++r) {
        int row = bm * 128 + wm + (mi << 4) + cr0 + r;
        if (row < cnt) {
          int col = bn * 64 + wn + (ni << 4) + lr;
          Y2[(size_t)(base + row) * HID + col] = acc[mi][ni][r];
        }
      }
}

// h[t] += y(e_lo) + y(e_hi)  (ascending-e order == old serial order)
__global__ __launch_bounds__(256) void moe_scatter_kernel(
    const int* __restrict__ tokpair, const int* __restrict__ off8,
    const float* __restrict__ Y2, float* __restrict__ H)
{
  const int t = blockIdx.x;
  const int i = threadIdx.x;
  int p0 = tokpair[t * 2], p1 = tokpair[t * 2 + 1];
  size_t r0 = off8[p0 >> 16] + (p0 & 0xffff);
  size_t r1 = off8[p1 >> 16] + (p1 & 0xffff);
  float4 a = ((const float4*)(Y2 + r0 * HID))[i];
  float4 b = ((const float4*)(Y2 + r1 * HID))[i];
  float4 hv = ((float4*)(H + (size_t)t * HID))[i];
  hv.x = (hv.x + a.x) + b.x;
  hv.y = (hv.y + a.y) + b.y;
  hv.z = (hv.z + a.z) + b.z;
  hv.w = (hv.w + a.w) + b.w;
  ((float4*)(H + (size_t)t * HID))[i] = hv;
}

// ---------------------------------------------------------------------------
// Small kernels
// ---------------------------------------------------------------------------
__global__ void tables_kernel(float* __restrict__ CT, float* __restrict__ ST)
{
  int idx = blockIdx.x * 256 + threadIdx.x;
  int s = idx >> 5, i = idx & 31;
  double inv = exp(-log(10000.0) * (double)i / 32.0);
  double ang = (double)s * inv;
  CT[idx] = (float)cos(ang);
  ST[idx] = (float)sin(ang);
}

__global__ __launch_bounds__(256) void embed_kernel(
    const int* __restrict__ ids, const float* __restrict__ E, float* __restrict__ H)
{
  int t = blockIdx.x;
  int id = ids[t];
  ((float4*)(H + (size_t)t * HID))[threadIdx.x] =
      ((const float4*)(E + (size_t)id * HID))[threadIdx.x];
}

__global__ __launch_bounds__(256) void rmsnorm_kernel(
    const float* __restrict__ X, const float* __restrict__ W,
    float* __restrict__ O, __bf16* __restrict__ OHb, __bf16* __restrict__ OLb)
{
  int t = blockIdx.x;
  int tid = threadIdx.x;
  float4 v = ((const float4*)(X + (size_t)t * HID))[tid];
  float ss = v.x * v.x + v.y * v.y + v.z * v.z + v.w * v.w;
#pragma unroll
  for (int d = 1; d < 64; d <<= 1) ss += __shfl_xor(ss, d);
  __shared__ float red[4];
  if ((tid & 63) == 0) red[tid >> 6] = ss;
  __syncthreads();
  float tot = red[0] + red[1] + red[2] + red[3];
  float inv = 1.0f / sqrtf(tot * (1.0f / 1024.0f) + 1e-6f);
  float4 w = ((const float4*)W)[tid];
  float4 r;
  r.x = v.x * inv * w.x; r.y = v.y * inv * w.y;
  r.z = v.z * inv * w.z; r.w = v.w * inv * w.w;
  ((float4*)(O + (size_t)t * HID))[tid] = r;
  float f[4] = {r.x, r.y, r.z, r.w};
  bf16x4v hv, lv;
#pragma unroll
  for (int j = 0; j < 4; ++j) {
    __bf16 hb = (__bf16)f[j];
    hv[j] = hb; lv[j] = (__bf16)(f[j] - (float)hb);
  }
  *(bf16x4v*)(OHb + (size_t)t * HID + tid * 4) = hv;
  *(bf16x4v*)(OLb + (size_t)t * HID + tid * 4) = lv;
}

__global__ __launch_bounds__(256) void router_kernel(
    const float* __restrict__ X, const float* __restrict__ RW, float* __restrict__ RL)
{
  int wid = threadIdx.x >> 6, lane = threadIdx.x & 63;
  int t = blockIdx.x * 4 + wid;
  const float* x = X + (size_t)t * HID;
  float a0 = 0, a1 = 0, a2 = 0, a3 = 0, a4 = 0, a5 = 0, a6 = 0, a7 = 0;
  for (int hh = lane; hh < HID; hh += 64) {
    float xv = x[hh];
    float4 f0 = *(const float4*)(RW + hh * 8);
    float4 f1 = *(const float4*)(RW + hh * 8 + 4);
    a0 += xv * f0.x; a1 += xv * f0.y; a2 += xv * f0.z; a3 += xv * f0.w;
    a4 += xv * f1.x; a5 += xv * f1.y; a6 += xv * f1.z; a7 += xv * f1.w;
  }
#pragma unroll
  for (int d = 1; d < 64; d <<= 1) {
    a0 += __shfl_xor(a0, d); a1 += __shfl_xor(a1, d);
    a2 += __shfl_xor(a2, d); a3 += __shfl_xor(a3, d);
    a4 += __shfl_xor(a4, d); a5 += __shfl_xor(a5, d);
    a6 += __shfl_xor(a6, d); a7 += __shfl_xor(a7, d);
  }
  if (lane == 0) {
    float* dst = RL + (size_t)t * 8;
    dst[0] = a0; dst[1] = a1; dst[2] = a2; dst[3] = a3;
    dst[4] = a4; dst[5] = a5; dst[6] = a6; dst[7] = a7;
  }
}

__global__ void zero_kernel(float* __restrict__ p, int n)
{
  int i = threadIdx.x;
  if (i < n) p[i] = 0.f;
}

__global__ void zeroi_kernel(int* __restrict__ p, int n)
{
  int i = threadIdx.x;
  if (i < n) p[i] = 0;
}

__global__ __launch_bounds__(256) void topk_kernel(
    const float* __restrict__ RL, float* __restrict__ W, float* __restrict__ AUX)
{
  int t = blockIdx.x * 256 + threadIdx.x;
  int lane = threadIdx.x & 63;
  float r[8];
#pragma unroll
  for (int e = 0; e < 8; ++e) r[e] = RL[t * 8 + e];
  float mx = r[0];
#pragma unroll
  for (int e = 1; e < 8; ++e) mx = fmaxf(mx, r[e]);
  float p[8];
  float se = 0.f;
#pragma unroll
  for (int e = 0; e < 8; ++e) { p[e] = __expf(r[e] - mx); se += p[e]; }
  float inv = 1.f / se;
#pragma unroll
  for (int e = 0; e < 8; ++e) p[e] *= inv;
  float lse = logf(se) + mx;
  int i1 = 0; float v1 = p[0];
#pragma unroll
  for (int e = 1; e < 8; ++e) if (p[e] > v1) { v1 = p[e]; i1 = e; }
  int i2 = -1; float v2 = -1.f;
#pragma unroll
  for (int e = 0; e < 8; ++e) if (e != i1 && p[e] > v2) { v2 = p[e]; i2 = e; }
  float s12 = v1 + v2;
#pragma unroll
  for (int e = 0; e < 8; ++e)
    W[t * 8 + e] = (e == i1) ? v1 / s12 : ((e == i2) ? v2 / s12 : 0.f);
#pragma unroll
  for (int e = 0; e < 8; ++e) {
    float fe = ((i1 == e) ? 1.f : 0.f) + ((i2 == e) ? 1.f : 0.f);
    float pe = p[e];
#pragma unroll
    for (int d = 1; d < 64; d <<= 1) { fe += __shfl_xor(fe, d); pe += __shfl_xor(pe, d); }
    if (lane == 0) { atomicAdd(&AUX[e], fe); atomicAdd(&AUX[8 + e], pe); }
  }
  float zz = lse * lse;
#pragma unroll
  for (int d = 1; d < 64; d <<= 1) zz += __shfl_xor(zz, d);
  if (lane == 0) atomicAdd(&AUX[16], zz);
}

__global__ void aux_kernel(const float* __restrict__ AUX, float* __restrict__ OUT)
{
  float s = 0.f;
#pragma unroll
  for (int e = 0; e < 8; ++e)
    s += (AUX[e] * (1.f / 2048.f)) * (AUX[8 + e] * (1.f / 2048.f));
  float auxv = 0.01f * 8.f * s;
  float z = 0.001f * (AUX[16] * (1.f / 2048.f));
  OUT[(size_t)SEQ * VOCAB] = auxv + z;
}

// records per-token (expert, pos) pairs in ascending-e order
__global__ __launch_bounds__(256) void build_list_kernel(
    const float* __restrict__ W, int* __restrict__ cnt, int* __restrict__ list,
    int* __restrict__ tokpair)
{
  int t = blockIdx.x * 256 + threadIdx.x;
  int j = 0;
#pragma unroll
  for (int e = 0; e < 8; ++e) {
    if (W[t * 8 + e] > 0.f) {
      int p = atomicAdd(&cnt[e], 1);
      list[e * SEQ + p] = t;
      tokpair[t * 2 + j] = (e << 16) | p;
      ++j;
    }
  }
}

__global__ void prefix_kernel(const int* __restrict__ cnt, int* __restrict__ off)
{
  if (threadIdx.x == 0) {
    int s = 0;
    for (int e = 0; e < 8; ++e) { off[e] = s; s += cnt[e]; }
  }
}

// ---------------------------------------------------------------------------
extern "C" void kernel_launch(void* const* d_in, const int* in_sizes, int n_in,
                              void* d_out, int out_size, void* d_ws, size_t ws_size,
                              hipStream_t stream)
{
  const int*   ids   = (const int*)d_in[0];
  const float* embed = (const float*)d_in[1];
  const float* ln1   = (const float*)d_in[2];
  const float* ln2   = (const float*)d_in[3];
  const float* wq    = (const float*)d_in[4];
  const float* wk    = (const float*)d_in[5];
  const float* wv    = (const float*)d_in[6];
  const float* wo    = (const float*)d_in[7];
  const float* dg    = (const float*)d_in[8];
  const float* du    = (const float*)d_in[9];
  const float* dd    = (const float*)d_in[10];
  const float* rw    = (const float*)d_in[11];
  const float* mg    = (const float*)d_in[12];
  const float* mu    = (const float*)d_in[13];
  const float* md    = (const float*)d_in[14];
  const float* fin   = (const float*)d_in[15];
  float* out = (float*)d_out;

  char* ws = (char*)d_ws;
  float* h    = (float*)(ws + 0);
  float* hn   = (float*)(ws + 8388608);
  float* q    = (float*)(ws + 16777216);
  float* k    = (float*)(ws + 25165824);
  float* v    = (float*)(ws + 33554432);
  __bf16* oh  = (__bf16*)(ws + 41943040);
  __bf16* ol  = (__bf16*)(ws + 46137344);
  float* g    = (float*)(ws + 50331648);
  float* u    = (float*)(ws + 73400320);
  float* ct   = (float*)(ws + 96468992);
  float* st   = (float*)(ws + 96731136);
  float* rl   = (float*)(ws + 96993280);
  float* wmoe = (float*)(ws + 97058816);
  float* aux  = (float*)(ws + 97124352);
  int*   cnt  = (int*)  (ws + 97124608);
  int*   list = (int*)  (ws + 97124864);
  int*   tokp = (int*)  (ws + 97190400);
  int*   off8 = (int*)  (ws + 97206784);
  __bf16* wqh = (__bf16*)(ws + 97320960);
  __bf16* wql = (__bf16*)(ws + 105709568);
  __bf16* wkh = (__bf16*)(ws + 114098176);
  __bf16* wkl = (__bf16*)(ws + 122486784);
  __bf16* wvh = (__bf16*)(ws + 130875392);
  __bf16* wvl = (__bf16*)(ws + 139264000);
  __bf16* woh = (__bf16*)(ws + 147652608);
  __bf16* wol = (__bf16*)(ws + 156041216);
  __bf16* dgh = (__bf16*)(ws + 164429824);
  __bf16* dgl = (__bf16*)(ws + 181731328);
  __bf16* duh = (__bf16*)(ws + 199032832);
  __bf16* dul = (__bf16*)(ws + 216334336);
  __bf16* ddh = (__bf16*)(ws + 233635840);
  __bf16* ddl = (__bf16*)(ws + 250937344);
  __bf16* eh  = (__bf16*)(ws + 268238848);
  __bf16* hnh = (__bf16*)(ws + 333774848);
  __bf16* hnl = (__bf16*)(ws + 337969152);
  __bf16* gh  = (__bf16*)(ws + 342163456);
  __bf16* gl  = (__bf16*)(ws + 353697792);
  __bf16* mgh = (__bf16*)(ws + 365232128);
  __bf16* muh = (__bf16*)(ws + 411369472);
  __bf16* mdh = (__bf16*)(ws + 457506816);
  // end: 503,644,160 bytes
  __bf16* qh  = (__bf16*)g;
  __bf16* ql  = (__bf16*)((char*)g + 4194304);
  __bf16* kbh = (__bf16*)((char*)g + 8388608);
  __bf16* kbl = (__bf16*)((char*)g + 12582912);
  __bf16* vth = (__bf16*)u;
  __bf16* vtl = (__bf16*)((char*)u + 4194304);
  __bf16* a2  = (__bf16*)g;
  float*  y2  = u;

  wsplit_t_kernel<<<dim3(16, 16, 4), 256, 0, stream>>>(wq, wqh, wql, HID, HID);
  wsplit_t_kernel<<<dim3(16, 16, 4), 256, 0, stream>>>(wk, wkh, wkl, HID, HID);
  wsplit_t_kernel<<<dim3(16, 16, 4), 256, 0, stream>>>(wv, wvh, wvl, HID, HID);
  wsplit_t_kernel<<<dim3(16, 16, 4), 256, 0, stream>>>(wo, woh, wol, HID, HID);
  wsplit_t_kernel<<<dim3(44, 16, 3), 256, 0, stream>>>(dg, dgh, dgl, HID, IDIM);
  wsplit_t_kernel<<<dim3(44, 16, 3), 256, 0, stream>>>(du, duh, dul, HID, IDIM);
  wsplit_t_kernel<<<dim3(16, 44, 3), 256, 0, stream>>>(dd, ddh, ddl, IDIM, HID);
  wsplit_th_kernel<<<dim3(44, 16, 8), 256, 0, stream>>>(mg, mgh, HID, IDIM);
  wsplit_th_kernel<<<dim3(44, 16, 8), 256, 0, stream>>>(mu, muh, HID, IDIM);
  wsplit_th_kernel<<<dim3(16, 44, 8), 256, 0, stream>>>(md, mdh, IDIM, HID);
  esplit_kernel<<<16000, 256, 0, stream>>>(embed, eh);

  tables_kernel<<<256, 256, 0, stream>>>(ct, st);
  embed_kernel<<<SEQ, 256, 0, stream>>>(ids, embed, h);

  for (int li = 0; li < 4; ++li) {
    const bool comp = (li <= 2);
    rmsnorm_kernel<<<SEQ, 256, 0, stream>>>(h, ln1 + li * HID, hn, hnh, hnl);
    size_t wofs = (size_t)li * HID * HID;
    // QKV GEMM with fused rope+split epilogue (q,k) and f32 v output
    if (comp)
      gemm_qkv_kernel<true><<<dim3(8, 32, 3), 256, 0, stream>>>(
          hnh, hnl, wqh + wofs, wql + wofs, wkh + wofs, wkl + wofs,
          wvh + wofs, wvl + wofs, qh, ql, kbh, kbl, v, ct, st);
    else
      gemm_qkv_kernel<false><<<dim3(8, 32, 3), 256, 0, stream>>>(
          hnh, hnh, wqh + wofs, wqh + wofs, wkh + wofs, wkh + wofs,
          wvh + wofs, wvh + wofs, qh, ql, kbh, kbl, v, ct, st);

    vtsplit_kernel<<<dim3(32, 16), 256, 0, stream>>>(v, vth, vtl);

    attn_flash_kernel<<<dim3(16, 16), 256, 0, stream>>>(
        qh, ql, kbh, kbl, vth, vtl, oh, ol);

    // wo GEMM: BN=64 -> 512 blocks (2/CU)
    if (comp)
      gemm_bt_kernel<true, true, 64, 64, false><<<dim3(16, 32, 1), 256, 0, stream>>>(
          oh, ol, woh + wofs, wol + wofs, woh + wofs, wol + wofs,
          woh + wofs, wol + wofs, h, h, h, SEQ, HID, HID);
    else
      gemm_bt_kernel<false, true, 64, 64, false><<<dim3(16, 32, 1), 256, 0, stream>>>(
          oh, oh, woh + wofs, woh + wofs, woh + wofs, woh + wofs,
          woh + wofs, woh + wofs, h, h, h, SEQ, HID, HID);

    rmsnorm_kernel<<<SEQ, 256, 0, stream>>>(h, ln2 + li * HID, hn, hnh, hnl);
    if (li == 2) {
      router_kernel<<<512, 256, 0, stream>>>(hn, rw, rl);
      zero_kernel<<<1, 32, 0, stream>>>(aux, 17);
      topk_kernel<<<8, 256, 0, stream>>>(rl, wmoe, aux);
      aux_kernel<<<1, 1, 0, stream>>>(aux, out);
      zeroi_kernel<<<1, 32, 0, stream>>>(cnt, 8);
      build_list_kernel<<<8, 256, 0, stream>>>(wmoe, cnt, list, tokp);
      prefix_kernel<<<1, 64, 0, stream>>>(cnt, off8);
      gemm_moe_guf_kernel<<<dim3(44, 16, 8), 256, 0, stream>>>(
          hnh, mgh, muh, a2, wmoe, list, cnt, off8);
      gemm_moe_down2_kernel<<<dim3(16, 16, 8), 256, 0, stream>>>(
          a2, mdh, y2, cnt, off8);
      moe_scatter_kernel<<<SEQ, 256, 0, stream>>>(tokp, off8, y2, h);
    } else {
      int d = (li < 2) ? li : li - 1;
      size_t go = (size_t)d * HID * IDIM;
      // dense gate+up GEMM with fused silu + hi/lo split epilogue
      if (comp)
        gemm_dgu_kernel<true><<<dim3(44, 32), 256, 0, stream>>>(
            hnh, hnl, dgh + go, dgl + go, duh + go, dul + go, gh, gl);
      else
        gemm_dgu_kernel<false><<<dim3(44, 32), 256, 0, stream>>>(
            hnh, hnh, dgh + go, dgh + go, duh + go, duh + go, gh, gl);
      // down GEMM: BN=64 -> 512 blocks
      if (comp)
        gemm_bt_kernel<true, true, 64, 64, false><<<dim3(16, 32, 1), 256, 0, stream>>>(
            gh, gl, ddh + go, ddl + go, ddh + go, ddl + go,
            ddh + go, ddl + go, h, h, h, SEQ, HID, IDIM);
      else
        gemm_bt_kernel<false, true, 64, 64, false><<<dim3(16, 32, 1), 256, 0, stream>>>(
            gh, gh, ddh + go, ddh + go, ddh + go, ddh + go,
            ddh + go, ddh + go, h, h, h, SEQ, HID, IDIM);
    }
  }
  rmsnorm_kernel<<<SEQ, 256, 0, stream>>>(h, fin, hn, hnh, hnl);
  // logits: BM=128 + XCD-aware bijective swizzle (4096-block 1D grid)
  gemm_bt_kernel<false, false, 128, 128, true><<<dim3(4096, 1, 1), 256, 0, stream>>>(
      hnh, hnh, eh, eh, eh, eh, eh, eh, out, out, out, SEQ, VOCAB, HID);
}

// Round 20
// 1710.801 us; speedup vs baseline: 1.3508x; 1.0424x over previous
//
#include <hip/hip_runtime.h>
#include <hip/hip_bf16.h>
#include <math.h>

#define SEQ 2048
#define HID 1024
#define NHEAD 16
#define HDIM 64
#define IDIM 2816
#define NEXP 8
#define VOCAB 32000

#define ASTRIDE 144  // padded rows (attention)

typedef float f32x4v __attribute__((ext_vector_type(4)));
typedef __bf16 bf16x8v __attribute__((ext_vector_type(8)));
typedef __bf16 bf16x4v __attribute__((ext_vector_type(4)));

__device__ __forceinline__ bf16x8v cvt8(const float4& a, const float4& b) {
  bf16x8v r;
  r[0] = (__bf16)a.x; r[1] = (__bf16)a.y; r[2] = (__bf16)a.z; r[3] = (__bf16)a.w;
  r[4] = (__bf16)b.x; r[5] = (__bf16)b.y; r[6] = (__bf16)b.z; r[7] = (__bf16)b.w;
  return r;
}

#define MFMA(a, b, c) __builtin_amdgcn_mfma_f32_16x16x32_bf16(a, b, c, 0, 0, 0)

// async global->LDS DMA, 16B per lane; lds base must be wave-uniform
__device__ __forceinline__ void gld_lds16(const void* g, void* l) {
  __builtin_amdgcn_global_load_lds(
      (const __attribute__((address_space(1))) unsigned int*)(unsigned long long)g,
      (__attribute__((address_space(3))) unsigned int*)(unsigned int)(unsigned long long)l,
      16, 0, 0);
}

// ---------------------------------------------------------------------------
// Weight preprocessing: W[K,N] f32 -> WH,WL [N,K] bf16 (transposed hi/lo).
// ---------------------------------------------------------------------------
__global__ __launch_bounds__(256) void wsplit_t_kernel(
    const float* __restrict__ W, __bf16* __restrict__ WH, __bf16* __restrict__ WL,
    int K, int N)
{
  __shared__ float tile[64][65];
  const int tid = threadIdx.x;
  const size_t zofs = (size_t)blockIdx.z * K * N;
  const int n0 = blockIdx.x * 64, k0 = blockIdx.y * 64;
#pragma unroll
  for (int r = 0; r < 4; ++r) {
    int kk = (tid >> 4) + r * 16;
    int nn = (tid & 15) * 4;
    float4 v = *(const float4*)(W + zofs + (size_t)(k0 + kk) * N + n0 + nn);
    tile[kk][nn] = v.x; tile[kk][nn + 1] = v.y;
    tile[kk][nn + 2] = v.z; tile[kk][nn + 3] = v.w;
  }
  __syncthreads();
  const int nn = tid >> 2;
  const int kk = (tid & 3) * 16;
  __bf16* dh = WH + zofs + (size_t)(n0 + nn) * K + k0 + kk;
  __bf16* dl = WL + zofs + (size_t)(n0 + nn) * K + k0 + kk;
  bf16x8v h0, l0, h1, l1;
#pragma unroll
  for (int j = 0; j < 8; ++j) {
    float f = tile[kk + j][nn];
    __bf16 hb = (__bf16)f; h0[j] = hb; l0[j] = (__bf16)(f - (float)hb);
    f = tile[kk + 8 + j][nn];
    hb = (__bf16)f; h1[j] = hb; l1[j] = (__bf16)(f - (float)hb);
  }
  *(bf16x8v*)dh = h0; *(bf16x8v*)(dh + 8) = h1;
  *(bf16x8v*)dl = l0; *(bf16x8v*)(dl + 8) = l1;
}

// hi-only variant (MoE weights; plain-bf16 path needs no lo)
__global__ __launch_bounds__(256) void wsplit_th_kernel(
    const float* __restrict__ W, __bf16* __restrict__ WH, int K, int N)
{
  __shared__ float tile[64][65];
  const int tid = threadIdx.x;
  const size_t zofs = (size_t)blockIdx.z * K * N;
  const int n0 = blockIdx.x * 64, k0 = blockIdx.y * 64;
#pragma unroll
  for (int r = 0; r < 4; ++r) {
    int kk = (tid >> 4) + r * 16;
    int nn = (tid & 15) * 4;
    float4 v = *(const float4*)(W + zofs + (size_t)(k0 + kk) * N + n0 + nn);
    tile[kk][nn] = v.x; tile[kk][nn + 1] = v.y;
    tile[kk][nn + 2] = v.z; tile[kk][nn + 3] = v.w;
  }
  __syncthreads();
  const int nn = tid >> 2;
  const int kk = (tid & 3) * 16;
  __bf16* dh = WH + zofs + (size_t)(n0 + nn) * K + k0 + kk;
  bf16x8v h0, h1;
#pragma unroll
  for (int j = 0; j < 8; ++j) {
    h0[j] = (__bf16)tile[kk + j][nn];
    h1[j] = (__bf16)tile[kk + 8 + j][nn];
  }
  *(bf16x8v*)dh = h0; *(bf16x8v*)(dh + 8) = h1;
}

__global__ __launch_bounds__(256) void esplit_kernel(
    const float* __restrict__ E, __bf16* __restrict__ EH)
{
  size_t i = ((size_t)blockIdx.x * 256 + threadIdx.x) * 8;
  float4 a = *(const float4*)(E + i);
  float4 b = *(const float4*)(E + i + 4);
  *(bf16x8v*)(EH + i) = cvt8(a, b);
}

// ---------------------------------------------------------------------------
// Unified BT GEMM, 2-phase double-buffered LDS (T3 minimum recipe):
// one __syncthreads per K-step; next-tile global_load_lds issued BEFORE the
// current tile's ds_read+MFMA. Bit-exact (MFMA chains unchanged).
// ---------------------------------------------------------------------------
template<bool COMP, bool ACCUM, int BM, int BN, bool XSWZ>
__global__ __launch_bounds__(256) void gemm_bt_kernel(
    const __bf16* __restrict__ Ah, const __bf16* __restrict__ Al,
    const __bf16* __restrict__ B0h, const __bf16* __restrict__ B0l,
    const __bf16* __restrict__ B1h, const __bf16* __restrict__ B1l,
    const __bf16* __restrict__ B2h, const __bf16* __restrict__ B2l,
    float* __restrict__ C0, float* __restrict__ C1, float* __restrict__ C2,
    int M, int N, int Kd)
{
  const __bf16* __restrict__ Bh = (blockIdx.z == 0) ? B0h : (blockIdx.z == 1 ? B1h : B2h);
  const __bf16* __restrict__ Bl = (blockIdx.z == 0) ? B0l : (blockIdx.z == 1 ? B1l : B2l);
  float* __restrict__ C         = (blockIdx.z == 0) ? C0 : (blockIdx.z == 1 ? C1 : C2);
  constexpr int ATILE = BM * 64;
  constexpr int BTILE = BN * 64;
  constexpr int MFR = BM / 32;
  constexpr int NFR = BN / 32;
  constexpr int SBUF = COMP ? 2 * (ATILE + BTILE) : (ATILE + BTILE);
  __shared__ __align__(16) char smem[2 * SBUF];
  const int tid = threadIdx.x;
  int bm, bn;
  if (XSWZ) {
    int id = blockIdx.x;            // padded 1D grid
    int xcd = id & 7;
    int j = id >> 3;
    if (BM == 128) {                // M=2048 -> 16 bm-blocks
      bm = j & 15;
      bn = xcd * 32 + (j >> 4);
    } else {                        // BM=64 -> 32 bm-blocks
      bm = j & 31;
      bn = xcd * 32 + (j >> 5);
    }
    if (bn >= N / BN) return;
  } else {
    bm = blockIdx.y;
    bn = blockIdx.x;
  }
  const int wid = tid >> 6, lane = tid & 63;
  const int wm = (wid >> 1) * (BM / 2), wn = (wid & 1) * (BN / 2);
  const int lr = lane & 15, kh = lane >> 4;
  const int lrow = lane >> 2;
  const int lcol = (lane & 3) << 3;

  auto stage = [&](char* buf, int k0) {
    char* AsH = buf;
    char* BsH = buf + ATILE;
    char* AsL = COMP ? buf + ATILE + BTILE : buf;
    char* BsL = COMP ? buf + 2 * ATILE + BTILE : buf + ATILE;
#pragma unroll
    for (int c = wid; c < BM / 16; c += 4) {
      size_t gofs = (size_t)(bm * BM + c * 16 + lrow) * Kd + k0 + lcol;
      gld_lds16(Ah + gofs, AsH + c * 1024);
      if (COMP) gld_lds16(Al + gofs, AsL + c * 1024);
    }
#pragma unroll
    for (int c = wid; c < BN / 16; c += 4) {
      size_t gofs = (size_t)(bn * BN + c * 16 + lrow) * Kd + k0 + lcol;
      gld_lds16(Bh + gofs, BsH + c * 1024);
      if (COMP) gld_lds16(Bl + gofs, BsL + c * 1024);
    }
  };

  f32x4v acc[MFR][NFR];
  const f32x4v z4 = {0.f, 0.f, 0.f, 0.f};
#pragma unroll
  for (int i = 0; i < MFR; ++i)
#pragma unroll
    for (int j2 = 0; j2 < NFR; ++j2) acc[i][j2] = z4;

  stage(smem, 0);
  int cur = 0;
  for (int k0 = 0; k0 < Kd; k0 += 32) {
    __syncthreads();                     // drains glds into buf[cur]
    char* buf = smem + cur * SBUF;
    if (k0 + 32 < Kd) stage(smem + (cur ^ 1) * SBUF, k0 + 32);
    char* AsH = buf;
    char* BsH = buf + ATILE;
    char* AsL = COMP ? buf + ATILE + BTILE : buf;
    char* BsL = COMP ? buf + 2 * ATILE + BTILE : buf + ATILE;

    bf16x8v ah[MFR], al[MFR], bh4[NFR], bl4[NFR];
#pragma unroll
    for (int i = 0; i < MFR; ++i) {
      int r = wm + (i << 4) + lr;
      int off = r * 64 + (kh << 4);
      ah[i] = *(const bf16x8v*)(AsH + off);
      if (COMP) al[i] = *(const bf16x8v*)(AsL + off);
    }
#pragma unroll
    for (int i = 0; i < NFR; ++i) {
      int r = wn + (i << 4) + lr;
      int off = r * 64 + (kh << 4);
      bh4[i] = *(const bf16x8v*)(BsH + off);
      if (COMP) bl4[i] = *(const bf16x8v*)(BsL + off);
    }
#pragma unroll
    for (int mi = 0; mi < MFR; ++mi)
#pragma unroll
      for (int ni = 0; ni < NFR; ++ni) {
        if (COMP) {
          acc[mi][ni] = MFMA(al[mi], bh4[ni], acc[mi][ni]);
          acc[mi][ni] = MFMA(ah[mi], bl4[ni], acc[mi][ni]);
        }
        acc[mi][ni] = MFMA(ah[mi], bh4[ni], acc[mi][ni]);
      }
    cur ^= 1;
  }

  const int cr0 = kh << 2;
#pragma unroll
  for (int mi = 0; mi < MFR; ++mi)
#pragma unroll
    for (int ni = 0; ni < NFR; ++ni)
#pragma unroll
      for (int r = 0; r < 4; ++r) {
        int row = bm * BM + wm + (mi << 4) + cr0 + r;
        int col = bn * BN + wn + (ni << 4) + lr;
        size_t idx = (size_t)row * N + col;
        if (ACCUM) C[idx] += acc[mi][ni][r];
        else       C[idx] = acc[mi][ni][r];
      }
}

// ---------------------------------------------------------------------------
// QKV GEMM with fused rope + hi/lo split epilogue (z=0 q scale 1/8, z=1 k),
// z=2 writes f32 v. 2-phase double-buffered. Bit-exact.
// ---------------------------------------------------------------------------
template<bool COMP>
__global__ __launch_bounds__(256) void gemm_qkv_kernel(
    const __bf16* __restrict__ Ah, const __bf16* __restrict__ Al,
    const __bf16* __restrict__ Bqh, const __bf16* __restrict__ Bql,
    const __bf16* __restrict__ Bkh, const __bf16* __restrict__ Bkl,
    const __bf16* __restrict__ Bvh, const __bf16* __restrict__ Bvl,
    __bf16* __restrict__ QH, __bf16* __restrict__ QL,
    __bf16* __restrict__ KH, __bf16* __restrict__ KL,
    float* __restrict__ Vout,
    const float* __restrict__ CT, const float* __restrict__ ST)
{
  const __bf16* __restrict__ Bh = (blockIdx.z == 0) ? Bqh : (blockIdx.z == 1 ? Bkh : Bvh);
  const __bf16* __restrict__ Bl = (blockIdx.z == 0) ? Bql : (blockIdx.z == 1 ? Bkl : Bvl);
  constexpr int ATILE = 64 * 64;
  constexpr int BTILE = 128 * 64;
  constexpr int SBUF = COMP ? 2 * (ATILE + BTILE) : (ATILE + BTILE);
  __shared__ __align__(16) char smem[2 * SBUF];
  const int tid = threadIdx.x;
  const int bm = blockIdx.y, bn = blockIdx.x;
  const int wid = tid >> 6, lane = tid & 63;
  const int wm = (wid >> 1) << 5, wn = (wid & 1) << 6;
  const int lr = lane & 15, kh = lane >> 4;
  const int lrow = lane >> 2;
  const int lcol = (lane & 3) << 3;

  auto stage = [&](char* buf, int k0) {
    char* AsH = buf;
    char* BsH = buf + ATILE;
    char* AsL = COMP ? buf + ATILE + BTILE : buf;
    char* BsL = COMP ? buf + 2 * ATILE + BTILE : buf + ATILE;
    {
      int c = wid;   // A: 4 chunks
      size_t gofs = (size_t)(bm * 64 + c * 16 + lrow) * HID + k0 + lcol;
      gld_lds16(Ah + gofs, AsH + c * 1024);
      if (COMP) gld_lds16(Al + gofs, AsL + c * 1024);
    }
#pragma unroll
    for (int c = wid; c < 8; c += 4) {
      size_t gofs = (size_t)(bn * 128 + c * 16 + lrow) * HID + k0 + lcol;
      gld_lds16(Bh + gofs, BsH + c * 1024);
      if (COMP) gld_lds16(Bl + gofs, BsL + c * 1024);
    }
  };

  f32x4v acc[2][4];
  const f32x4v z4 = {0.f, 0.f, 0.f, 0.f};
#pragma unroll
  for (int i = 0; i < 2; ++i)
#pragma unroll
    for (int j2 = 0; j2 < 4; ++j2) acc[i][j2] = z4;

  stage(smem, 0);
  int cur = 0;
  for (int k0 = 0; k0 < HID; k0 += 32) {
    __syncthreads();
    char* buf = smem + cur * SBUF;
    if (k0 + 32 < HID) stage(smem + (cur ^ 1) * SBUF, k0 + 32);
    char* AsH = buf;
    char* BsH = buf + ATILE;
    char* AsL = COMP ? buf + ATILE + BTILE : buf;
    char* BsL = COMP ? buf + 2 * ATILE + BTILE : buf + ATILE;

    bf16x8v ah2[2], al2[2], bh4[4], bl4[4];
#pragma unroll
    for (int i = 0; i < 2; ++i) {
      int r = wm + (i << 4) + lr;
      int off = r * 64 + (kh << 4);
      ah2[i] = *(const bf16x8v*)(AsH + off);
      if (COMP) al2[i] = *(const bf16x8v*)(AsL + off);
    }
#pragma unroll
    for (int i = 0; i < 4; ++i) {
      int r = wn + (i << 4) + lr;
      int off = r * 64 + (kh << 4);
      bh4[i] = *(const bf16x8v*)(BsH + off);
      if (COMP) bl4[i] = *(const bf16x8v*)(BsL + off);
    }
#pragma unroll
    for (int mi = 0; mi < 2; ++mi)
#pragma unroll
      for (int ni = 0; ni < 4; ++ni) {
        if (COMP) {
          acc[mi][ni] = MFMA(al2[mi], bh4[ni], acc[mi][ni]);
          acc[mi][ni] = MFMA(ah2[mi], bl4[ni], acc[mi][ni]);
        }
        acc[mi][ni] = MFMA(ah2[mi], bh4[ni], acc[mi][ni]);
      }
    cur ^= 1;
  }

  const int cr0 = kh << 2;
  if (blockIdx.z == 2) {
#pragma unroll
    for (int mi = 0; mi < 2; ++mi)
#pragma unroll
      for (int ni = 0; ni < 4; ++ni)
#pragma unroll
        for (int r = 0; r < 4; ++r) {
          int row = bm * 64 + wm + (mi << 4) + cr0 + r;
          int col = bn * 128 + wn + (ni << 4) + lr;
          Vout[(size_t)row * HID + col] = acc[mi][ni][r];
        }
  } else {
    const float scale = (blockIdx.z == 0) ? 0.125f : 1.0f;
    __bf16* OH = (blockIdx.z == 0) ? QH : KH;
    __bf16* OL = (blockIdx.z == 0) ? QL : KL;
#pragma unroll
    for (int mi = 0; mi < 2; ++mi)
#pragma unroll
      for (int ni = 0; ni < 2; ++ni)
#pragma unroll
        for (int r = 0; r < 4; ++r) {
          int row = bm * 64 + wm + (mi << 4) + cr0 + r;
          int col = bn * 128 + wn + (ni << 4) + lr;   // (col&63) < 32
          int i = col & 31;
          float c = CT[row * 32 + i], sn = ST[row * 32 + i];
          float x1 = acc[mi][ni][r];
          float x2 = acc[mi][ni + 2][r];
          float o1 = (x1 * c - x2 * sn) * scale;
          float o2 = (x2 * c + x1 * sn) * scale;
          size_t ofs = (size_t)row * HID + col;
          __bf16 h1 = (__bf16)o1;
          OH[ofs] = h1; OL[ofs] = (__bf16)(o1 - (float)h1);
          __bf16 h2 = (__bf16)o2;
          OH[ofs + 32] = h2; OL[ofs + 32] = (__bf16)(o2 - (float)h2);
        }
  }
}

// ---------------------------------------------------------------------------
// Dense gate+up GEMM with fused silu + hi/lo split epilogue. BM=64, BN=64.
// 2-phase double-buffered. Bit-exact.
// ---------------------------------------------------------------------------
template<bool COMP>
__global__ __launch_bounds__(256) void gemm_dgu_kernel(
    const __bf16* __restrict__ Ah, const __bf16* __restrict__ Al,
    const __bf16* __restrict__ BGh, const __bf16* __restrict__ BGl,
    const __bf16* __restrict__ BUh, const __bf16* __restrict__ BUl,
    __bf16* __restrict__ GH, __bf16* __restrict__ GL)
{
  constexpr int SBUF = COMP ? 24576 : 12288;
  __shared__ __align__(16) char smem[2 * SBUF];
  const int tid = threadIdx.x;
  const int bn = blockIdx.x, bm = blockIdx.y;
  const int wid = tid >> 6, lane = tid & 63;
  const int wm = (wid >> 1) << 5, wn = (wid & 1) << 5;
  const int lr = lane & 15, kh = lane >> 4;
  const int lrow = lane >> 2;
  const int lcol = (lane & 3) << 3;

  auto stage = [&](char* buf, int k0) {
    char* AsH = buf;
    char* BgH = buf + 4096;
    char* BuH = buf + 8192;
    char* AsL = COMP ? buf + 12288 : buf;
    char* BgL = COMP ? buf + 16384 : buf;
    char* BuL = COMP ? buf + 20480 : buf;
    int c = wid;   // 4 chunks each buffer
    size_t aofs = (size_t)(bm * 64 + c * 16 + lrow) * HID + k0 + lcol;
    gld_lds16(Ah + aofs, AsH + c * 1024);
    if (COMP) gld_lds16(Al + aofs, AsL + c * 1024);
    size_t bofs = (size_t)(bn * 64 + c * 16 + lrow) * HID + k0 + lcol;
    gld_lds16(BGh + bofs, BgH + c * 1024);
    gld_lds16(BUh + bofs, BuH + c * 1024);
    if (COMP) {
      gld_lds16(BGl + bofs, BgL + c * 1024);
      gld_lds16(BUl + bofs, BuL + c * 1024);
    }
  };

  f32x4v accg[2][2], accu[2][2];
  const f32x4v z4 = {0.f, 0.f, 0.f, 0.f};
#pragma unroll
  for (int i = 0; i < 2; ++i)
#pragma unroll
    for (int j = 0; j < 2; ++j) { accg[i][j] = z4; accu[i][j] = z4; }

  stage(smem, 0);
  int cur = 0;
  for (int k0 = 0; k0 < HID; k0 += 32) {
    __syncthreads();
    char* buf = smem + cur * SBUF;
    if (k0 + 32 < HID) stage(smem + (cur ^ 1) * SBUF, k0 + 32);
    char* AsH = buf;
    char* BgH = buf + 4096;
    char* BuH = buf + 8192;
    char* AsL = COMP ? buf + 12288 : buf;
    char* BgL = COMP ? buf + 16384 : buf;
    char* BuL = COMP ? buf + 20480 : buf;

    bf16x8v af[2], afl[2], bg4[2], bgl4[2], bu4[2], bul4[2];
#pragma unroll
    for (int i = 0; i < 2; ++i) {
      int r = wm + (i << 4) + lr;
      int off = r * 64 + (kh << 4);
      af[i] = *(const bf16x8v*)(AsH + off);
      if (COMP) afl[i] = *(const bf16x8v*)(AsL + off);
    }
#pragma unroll
    for (int i = 0; i < 2; ++i) {
      int r = wn + (i << 4) + lr;
      int off = r * 64 + (kh << 4);
      bg4[i] = *(const bf16x8v*)(BgH + off);
      bu4[i] = *(const bf16x8v*)(BuH + off);
      if (COMP) {
        bgl4[i] = *(const bf16x8v*)(BgL + off);
        bul4[i] = *(const bf16x8v*)(BuL + off);
      }
    }
#pragma unroll
    for (int mi = 0; mi < 2; ++mi)
#pragma unroll
      for (int ni = 0; ni < 2; ++ni) {
        if (COMP) {
          accg[mi][ni] = MFMA(afl[mi], bg4[ni], accg[mi][ni]);
          accg[mi][ni] = MFMA(af[mi], bgl4[ni], accg[mi][ni]);
        }
        accg[mi][ni] = MFMA(af[mi], bg4[ni], accg[mi][ni]);
        if (COMP) {
          accu[mi][ni] = MFMA(afl[mi], bu4[ni], accu[mi][ni]);
          accu[mi][ni] = MFMA(af[mi], bul4[ni], accu[mi][ni]);
        }
        accu[mi][ni] = MFMA(af[mi], bu4[ni], accu[mi][ni]);
      }
    cur ^= 1;
  }

  const int cr0 = kh << 2;
#pragma unroll
  for (int mi = 0; mi < 2; ++mi)
#pragma unroll
    for (int ni = 0; ni < 2; ++ni)
#pragma unroll
      for (int r = 0; r < 4; ++r) {
        int row = bm * 64 + wm + (mi << 4) + cr0 + r;
        int col = bn * 64 + wn + (ni << 4) + lr;
        float gv = accg[mi][ni][r];
        float uv = accu[mi][ni][r];
        float a = gv / (1.f + __expf(-gv)) * uv;
        size_t idx = (size_t)row * IDIM + col;
        __bf16 hb = (__bf16)a;
        GH[idx] = hb;
        GL[idx] = (__bf16)(a - (float)hb);
      }
}

// V f32 [S][HID] -> per-head transposed hi/lo bf16 [NHEAD][HDIM][SEQ]
__global__ __launch_bounds__(256) void vtsplit_kernel(
    const float* __restrict__ V, __bf16* __restrict__ VTH, __bf16* __restrict__ VTL)
{
  __shared__ float tile[64][65];
  const int tid = threadIdx.x;
  const int s0 = blockIdx.x * 64;
  const int head = blockIdx.y;
#pragma unroll
  for (int r = 0; r < 4; ++r) {
    int ss = (tid >> 4) + r * 16;
    int dd = (tid & 15) * 4;
    float4 v = *(const float4*)(V + (size_t)(s0 + ss) * HID + head * 64 + dd);
    tile[ss][dd] = v.x; tile[ss][dd + 1] = v.y;
    tile[ss][dd + 2] = v.z; tile[ss][dd + 3] = v.w;
  }
  __syncthreads();
#pragma unroll
  for (int half = 0; half < 2; ++half) {
    const int d = (tid >> 3) + (half << 5);
    const int c = tid & 7;
    bf16x8v hv, lv;
#pragma unroll
    for (int j = 0; j < 8; ++j) {
      float f = tile[c * 8 + j][d];
      __bf16 hb = (__bf16)f;
      hv[j] = hb; lv[j] = (__bf16)(f - (float)hb);
    }
    size_t dst = (size_t)(head * 64 + d) * SEQ + s0 + c * 8;
    *(bf16x8v*)(VTH + dst) = hv;
    *(bf16x8v*)(VTL + dst) = lv;
  }
}

// ---------------------------------------------------------------------------
// Compensated flash attention; padded LDS; O -> bf16 hi/lo.
// Load-balanced: grid (16,16); block processes qt = bx and qt = 31-bx.
// ---------------------------------------------------------------------------
__global__ __launch_bounds__(256) void attn_flash_kernel(
    const __bf16* __restrict__ QH, const __bf16* __restrict__ QL,
    const __bf16* __restrict__ KH, const __bf16* __restrict__ KL,
    const __bf16* __restrict__ VTH, const __bf16* __restrict__ VTL,
    __bf16* __restrict__ OH, __bf16* __restrict__ OL)
{
  const int head = blockIdx.y;
  const int tid = threadIdx.x, wid = tid >> 6, lane = tid & 63;
  const int lr = lane & 15, kh = lane >> 4;
  __shared__ __align__(16) char KsH[64 * ASTRIDE], KsL[64 * ASTRIDE];
  __shared__ __align__(16) char VtH[64 * ASTRIDE], VtL[64 * ASTRIDE];
  __shared__ __align__(16) char PsH[4][16 * ASTRIDE], PsL[4][16 * ASTRIDE];

#pragma unroll
  for (int seg = 0; seg < 2; ++seg) {
    const int qt = seg ? (31 - (int)blockIdx.x) : (int)blockIdx.x;

    const size_t qofs = (size_t)(qt * 64 + wid * 16 + lr) * HID + head * HDIM;
    const bf16x8v qfh0 = *(const bf16x8v*)(QH + qofs + (kh << 3));
    const bf16x8v qfh1 = *(const bf16x8v*)(QH + qofs + 32 + (kh << 3));
    const bf16x8v qfl0 = *(const bf16x8v*)(QL + qofs + (kh << 3));
    const bf16x8v qfl1 = *(const bf16x8v*)(QL + qofs + 32 + (kh << 3));

    float m_run[4], l_run[4];
    f32x4v oacc[4];
    const f32x4v z4 = {0.f, 0.f, 0.f, 0.f};
#pragma unroll
    for (int i = 0; i < 4; ++i) { m_run[i] = -1e30f; l_run[i] = 0.f; oacc[i] = z4; }

    for (int kt = 0; kt <= qt; ++kt) {
      __syncthreads();
#pragma unroll
      for (int p = 0; p < 2; ++p) {
        int g = tid + (p << 8);
        int r = g >> 3;
        int c = g & 7;
        int off = r * ASTRIDE + (c << 4);
        const size_t kofs = (size_t)(kt * 64 + r) * HID + head * HDIM + (c << 3);
        *(bf16x8v*)(KsH + off) = *(const bf16x8v*)(KH + kofs);
        *(bf16x8v*)(KsL + off) = *(const bf16x8v*)(KL + kofs);
        const size_t vofs = (size_t)(head * 64 + r) * SEQ + kt * 64 + (c << 3);
        *(bf16x8v*)(VtH + off) = *(const bf16x8v*)(VTH + vofs);
        *(bf16x8v*)(VtL + off) = *(const bf16x8v*)(VTL + vofs);
      }
      __syncthreads();

      float sv[4][4];
#pragma unroll
      for (int stt = 0; stt < 4; ++stt) {
        int r = (stt << 4) + lr;
        int off0 = r * ASTRIDE + (kh << 4);
        int off1 = off0 + 64;
        bf16x8v kfh0 = *(const bf16x8v*)(KsH + off0);
        bf16x8v kfl0 = *(const bf16x8v*)(KsL + off0);
        bf16x8v kfh1 = *(const bf16x8v*)(KsH + off1);
        bf16x8v kfl1 = *(const bf16x8v*)(KsL + off1);
        f32x4v s = z4;
        s = MFMA(qfl0, kfh0, s);
        s = MFMA(qfh0, kfl0, s);
        s = MFMA(qfh0, kfh0, s);
        s = MFMA(qfl1, kfh1, s);
        s = MFMA(qfh1, kfl1, s);
        s = MFMA(qfh1, kfh1, s);
        int key = kt * 64 + (stt << 4) + lr;
#pragma unroll
        for (int rr = 0; rr < 4; ++rr) {
          int qr = qt * 64 + wid * 16 + (kh << 2) + rr;
          sv[stt][rr] = (key <= qr) ? s[rr] : -1e30f;
        }
      }

#pragma unroll
      for (int rr = 0; rr < 4; ++rr) {
        float mx = fmaxf(fmaxf(sv[0][rr], sv[1][rr]), fmaxf(sv[2][rr], sv[3][rr]));
#pragma unroll
        for (int d = 1; d < 16; d <<= 1) mx = fmaxf(mx, __shfl_xor(mx, d));
        float mnew = fmaxf(m_run[rr], mx);
        float scl = __expf(m_run[rr] - mnew);
        float pv[4];
#pragma unroll
        for (int stt = 0; stt < 4; ++stt) pv[stt] = __expf(sv[stt][rr] - mnew);
        float rs = pv[0] + pv[1] + pv[2] + pv[3];
#pragma unroll
        for (int d = 1; d < 16; d <<= 1) rs += __shfl_xor(rs, d);
        l_run[rr] = l_run[rr] * scl + rs;
        m_run[rr] = mnew;
#pragma unroll
        for (int n = 0; n < 4; ++n) oacc[n][rr] *= scl;
        int qlr = (kh << 2) + rr;
#pragma unroll
        for (int stt = 0; stt < 4; ++stt) {
          __bf16 hb = (__bf16)pv[stt];
          __bf16 lb = (__bf16)(pv[stt] - (float)hb);
          int off = qlr * ASTRIDE + (((stt << 4) + lr) << 1);
          *(__bf16*)(PsH[wid] + off) = hb;
          *(__bf16*)(PsL[wid] + off) = lb;
        }
      }

      int poff0 = lr * ASTRIDE + (kh << 4);
      int poff1 = poff0 + 64;
      bf16x8v pah0 = *(const bf16x8v*)(PsH[wid] + poff0);
      bf16x8v pal0 = *(const bf16x8v*)(PsL[wid] + poff0);
      bf16x8v pah1 = *(const bf16x8v*)(PsH[wid] + poff1);
      bf16x8v pal1 = *(const bf16x8v*)(PsL[wid] + poff1);
#pragma unroll
      for (int n = 0; n < 4; ++n) {
        int vr = (n << 4) + lr;
        int voff0 = vr * ASTRIDE + (kh << 4);
        int voff1 = voff0 + 64;
        bf16x8v vfh0 = *(const bf16x8v*)(VtH + voff0);
        bf16x8v vfl0 = *(const bf16x8v*)(VtL + voff0);
        bf16x8v vfh1 = *(const bf16x8v*)(VtH + voff1);
        bf16x8v vfl1 = *(const bf16x8v*)(VtL + voff1);
        oacc[n] = MFMA(pal0, vfh0, oacc[n]);
        oacc[n] = MFMA(pah0, vfl0, oacc[n]);
        oacc[n] = MFMA(pah0, vfh0, oacc[n]);
        oacc[n] = MFMA(pal1, vfh1, oacc[n]);
        oacc[n] = MFMA(pah1, vfl1, oacc[n]);
        oacc[n] = MFMA(pah1, vfh1, oacc[n]);
      }
    }

#pragma unroll
    for (int n = 0; n < 4; ++n)
#pragma unroll
      for (int rr = 0; rr < 4; ++rr) {
        int qr = qt * 64 + wid * 16 + (kh << 2) + rr;
        size_t ofs = (size_t)qr * HID + head * HDIM + (n << 4) + lr;
        float val = oacc[n][rr] / l_run[rr];
        __bf16 hb = (__bf16)val;
        OH[ofs] = hb;
        OL[ofs] = (__bf16)(val - (float)hb);
      }
  }
}

// ---------------------------------------------------------------------------
// MoE: fused gate+up+silu. BM=128, BN=64. 2-phase double-buffered.
// ---------------------------------------------------------------------------
__global__ __launch_bounds__(256) void gemm_moe_guf_kernel(
    const __bf16* __restrict__ Xh,
    const __bf16* __restrict__ MGH, const __bf16* __restrict__ MUH,
    __bf16* __restrict__ A2, const float* __restrict__ W,
    const int* __restrict__ list, const int* __restrict__ cnt8,
    const int* __restrict__ off8)
{
  const int e = blockIdx.z;
  const int cnt = cnt8[e];
  const int bn = blockIdx.x, bm = blockIdx.y;
  if (bm * 128 >= cnt) return;
  const int base = off8[e];
  constexpr int SBUF = 16384;   // AsB 8192 | BgB 4096 | BuB 4096
  __shared__ __align__(16) char smem[2 * SBUF];
  const int tid = threadIdx.x;
  const int wid = tid >> 6, lane = tid & 63;
  const int wm = (wid >> 1) << 6, wn = (wid & 1) << 5;
  const int lr = lane & 15, kh = lane >> 4;
  const int lrow = lane >> 2;
  const int lcol = (lane & 3) << 3;

  auto stage = [&](char* buf, int k0) {
    char* AsB = buf;
    char* BgB = buf + 8192;
    char* BuB = buf + 12288;
#pragma unroll
    for (int c = wid; c < 8; c += 4) {     // A: 128 rows
      int rg = bm * 128 + c * 16 + lrow;
      int tok = list[e * SEQ + (rg < cnt ? rg : cnt - 1)];
      gld_lds16(Xh + (size_t)tok * HID + k0 + lcol, AsB + c * 1024);
    }
    {                                       // B: 64 rows each (g,u)
      int c = wid;
      size_t wofs = (size_t)(e * IDIM + bn * 64 + c * 16 + lrow) * HID + k0 + lcol;
      gld_lds16(MGH + wofs, BgB + c * 1024);
      gld_lds16(MUH + wofs, BuB + c * 1024);
    }
  };

  f32x4v accg[4][2], accu[4][2];
  const f32x4v z4 = {0.f, 0.f, 0.f, 0.f};
#pragma unroll
  for (int i = 0; i < 4; ++i)
#pragma unroll
    for (int j = 0; j < 2; ++j) { accg[i][j] = z4; accu[i][j] = z4; }

  stage(smem, 0);
  int cur = 0;
  for (int k0 = 0; k0 < HID; k0 += 32) {
    __syncthreads();
    char* buf = smem + cur * SBUF;
    if (k0 + 32 < HID) stage(smem + (cur ^ 1) * SBUF, k0 + 32);
    char* AsB = buf;
    char* BgB = buf + 8192;
    char* BuB = buf + 12288;

    bf16x8v af[4], bg4[2], bu4[2];
#pragma unroll
    for (int i = 0; i < 4; ++i) {
      int r = wm + (i << 4) + lr;
      af[i] = *(const bf16x8v*)(AsB + r * 64 + (kh << 4));
    }
#pragma unroll
    for (int i = 0; i < 2; ++i) {
      int r = wn + (i << 4) + lr;
      bg4[i] = *(const bf16x8v*)(BgB + r * 64 + (kh << 4));
      bu4[i] = *(const bf16x8v*)(BuB + r * 64 + (kh << 4));
    }
#pragma unroll
    for (int mi = 0; mi < 4; ++mi)
#pragma unroll
      for (int ni = 0; ni < 2; ++ni) {
        accg[mi][ni] = MFMA(af[mi], bg4[ni], accg[mi][ni]);
        accu[mi][ni] = MFMA(af[mi], bu4[ni], accu[mi][ni]);
      }
    cur ^= 1;
  }

  const int cr0 = kh << 2;
#pragma unroll
  for (int mi = 0; mi < 4; ++mi)
#pragma unroll
    for (int ni = 0; ni < 2; ++ni)
#pragma unroll
      for (int r = 0; r < 4; ++r) {
        int row = bm * 128 + wm + (mi << 4) + cr0 + r;
        if (row < cnt) {
          int col = bn * 64 + wn + (ni << 4) + lr;
          int tok = list[e * SEQ + row];
          float w = W[tok * 8 + e];
          float gval = accg[mi][ni][r];
          float uval = accu[mi][ni][r];
          float a = gval / (1.f + __expf(-gval)) * uval * w;
          A2[(size_t)(base + row) * IDIM + col] = (__bf16)a;
        }
      }
}

__global__ __launch_bounds__(256) void gemm_moe_down2_kernel(
    const __bf16* __restrict__ A2, const __bf16* __restrict__ MDH,
    float* __restrict__ Y2,
    const int* __restrict__ cnt8, const int* __restrict__ off8)
{
  const int e = blockIdx.z;
  const int cnt = cnt8[e];
  const int bn = blockIdx.x, bm = blockIdx.y;
  if (bm * 128 >= cnt) return;
  const int base = off8[e];
  constexpr int SBUF = 12288;   // AsB 8192 | BsB 4096
  __shared__ __align__(16) char smem[2 * SBUF];
  const int tid = threadIdx.x;
  const int wid = tid >> 6, lane = tid & 63;
  const int wm = (wid >> 1) << 6, wn = (wid & 1) << 5;
  const int lr = lane & 15, kh = lane >> 4;
  const int lrow = lane >> 2;
  const int lcol = (lane & 3) << 3;

  auto stage = [&](char* buf, int k0) {
    char* AsB = buf;
    char* BsB = buf + 8192;
#pragma unroll
    for (int c = wid; c < 8; c += 4) {
      int rg = bm * 128 + c * 16 + lrow;
      int row = (rg < cnt ? rg : cnt - 1);
      gld_lds16(A2 + (size_t)(base + row) * IDIM + k0 + lcol, AsB + c * 1024);
    }
    {
      int c = wid;
      gld_lds16(MDH + (size_t)(e * HID + bn * 64 + c * 16 + lrow) * IDIM + k0 + lcol,
                BsB + c * 1024);
    }
  };

  f32x4v acc[4][2];
  const f32x4v z4 = {0.f, 0.f, 0.f, 0.f};
#pragma unroll
  for (int i = 0; i < 4; ++i)
#pragma unroll
    for (int j = 0; j < 2; ++j) acc[i][j] = z4;

  stage(smem, 0);
  int cur = 0;
  for (int k0 = 0; k0 < IDIM; k0 += 32) {
    __syncthreads();
    char* buf = smem + cur * SBUF;
    if (k0 + 32 < IDIM) stage(smem + (cur ^ 1) * SBUF, k0 + 32);
    char* AsB = buf;
    char* BsB = buf + 8192;

    bf16x8v af[4], bfv[2];
#pragma unroll
    for (int i = 0; i < 4; ++i) {
      int r = wm + (i << 4) + lr;
      af[i] = *(const bf16x8v*)(AsB + r * 64 + (kh << 4));
    }
#pragma unroll
    for (int i = 0; i < 2; ++i) {
      int r = wn + (i << 4) + lr;
      bfv[i] = *(const bf16x8v*)(BsB + r * 64 + (kh << 4));
    }
#pragma unroll
    for (int mi = 0; mi < 4; ++mi)
#pragma unroll
      for (int ni = 0; ni < 2; ++ni)
        acc[mi][ni] = MFMA(af[mi], bfv[ni], acc[mi][ni]);
    cur ^= 1;
  }

  const int cr0 = kh << 2;
#pragma unroll
  for (int mi = 0; mi < 4; ++mi)
#pragma unroll
    for (int ni = 0; ni < 2; ++ni)
#pragma unroll
      for (int r = 0; r < 4; ++r) {
        int row = bm * 128 + wm + (mi << 4) + cr0 + r;
        if (row < cnt) {
          int col = bn * 64 + wn + (ni << 4) + lr;
          Y2[(size_t)(base + row) * HID + col] = acc[mi][ni][r];
        }
      }
}

// h[t] += y(e_lo) + y(e_hi)  (ascending-e order == old serial order)
__global__ __launch_bounds__(256) void moe_scatter_kernel(
    const int* __restrict__ tokpair, const int* __restrict__ off8,
    const float* __restrict__ Y2, float* __restrict__ H)
{
  const int t = blockIdx.x;
  const int i = threadIdx.x;
  int p0 = tokpair[t * 2], p1 = tokpair[t * 2 + 1];
  size_t r0 = off8[p0 >> 16] + (p0 & 0xffff);
  size_t r1 = off8[p1 >> 16] + (p1 & 0xffff);
  float4 a = ((const float4*)(Y2 + r0 * HID))[i];
  float4 b = ((const float4*)(Y2 + r1 * HID))[i];
  float4 hv = ((float4*)(H + (size_t)t * HID))[i];
  hv.x = (hv.x + a.x) + b.x;
  hv.y = (hv.y + a.y) + b.y;
  hv.z = (hv.z + a.z) + b.z;
  hv.w = (hv.w + a.w) + b.w;
  ((float4*)(H + (size_t)t * HID))[i] = hv;
}

// ---------------------------------------------------------------------------
// Small kernels
// ---------------------------------------------------------------------------
__global__ void tables_kernel(float* __restrict__ CT, float* __restrict__ ST)
{
  int idx = blockIdx.x * 256 + threadIdx.x;
  int s = idx >> 5, i = idx & 31;
  double inv = exp(-log(10000.0) * (double)i / 32.0);
  double ang = (double)s * inv;
  CT[idx] = (float)cos(ang);
  ST[idx] = (float)sin(ang);
}

__global__ __launch_bounds__(256) void embed_kernel(
    const int* __restrict__ ids, const float* __restrict__ E, float* __restrict__ H)
{
  int t = blockIdx.x;
  int id = ids[t];
  ((float4*)(H + (size_t)t * HID))[threadIdx.x] =
      ((const float4*)(E + (size_t)id * HID))[threadIdx.x];
}

__global__ __launch_bounds__(256) void rmsnorm_kernel(
    const float* __restrict__ X, const float* __restrict__ W,
    float* __restrict__ O, __bf16* __restrict__ OHb, __bf16* __restrict__ OLb)
{
  int t = blockIdx.x;
  int tid = threadIdx.x;
  float4 v = ((const float4*)(X + (size_t)t * HID))[tid];
  float ss = v.x * v.x + v.y * v.y + v.z * v.z + v.w * v.w;
#pragma unroll
  for (int d = 1; d < 64; d <<= 1) ss += __shfl_xor(ss, d);
  __shared__ float red[4];
  if ((tid & 63) == 0) red[tid >> 6] = ss;
  __syncthreads();
  float tot = red[0] + red[1] + red[2] + red[3];
  float inv = 1.0f / sqrtf(tot * (1.0f / 1024.0f) + 1e-6f);
  float4 w = ((const float4*)W)[tid];
  float4 r;
  r.x = v.x * inv * w.x; r.y = v.y * inv * w.y;
  r.z = v.z * inv * w.z; r.w = v.w * inv * w.w;
  ((float4*)(O + (size_t)t * HID))[tid] = r;
  float f[4] = {r.x, r.y, r.z, r.w};
  bf16x4v hv, lv;
#pragma unroll
  for (int j = 0; j < 4; ++j) {
    __bf16 hb = (__bf16)f[j];
    hv[j] = hb; lv[j] = (__bf16)(f[j] - (float)hb);
  }
  *(bf16x4v*)(OHb + (size_t)t * HID + tid * 4) = hv;
  *(bf16x4v*)(OLb + (size_t)t * HID + tid * 4) = lv;
}

__global__ __launch_bounds__(256) void router_kernel(
    const float* __restrict__ X, const float* __restrict__ RW, float* __restrict__ RL)
{
  int wid = threadIdx.x >> 6, lane = threadIdx.x & 63;
  int t = blockIdx.x * 4 + wid;
  const float* x = X + (size_t)t * HID;
  float a0 = 0, a1 = 0, a2 = 0, a3 = 0, a4 = 0, a5 = 0, a6 = 0, a7 = 0;
  for (int hh = lane; hh < HID; hh += 64) {
    float xv = x[hh];
    float4 f0 = *(const float4*)(RW + hh * 8);
    float4 f1 = *(const float4*)(RW + hh * 8 + 4);
    a0 += xv * f0.x; a1 += xv * f0.y; a2 += xv * f0.z; a3 += xv * f0.w;
    a4 += xv * f1.x; a5 += xv * f1.y; a6 += xv * f1.z; a7 += xv * f1.w;
  }
#pragma unroll
  for (int d = 1; d < 64; d <<= 1) {
    a0 += __shfl_xor(a0, d); a1 += __shfl_xor(a1, d);
    a2 += __shfl_xor(a2, d); a3 += __shfl_xor(a3, d);
    a4 += __shfl_xor(a4, d); a5 += __shfl_xor(a5, d);
    a6 += __shfl_xor(a6, d); a7 += __shfl_xor(a7, d);
  }
  if (lane == 0) {
    float* dst = RL + (size_t)t * 8;
    dst[0] = a0; dst[1] = a1; dst[2] = a2; dst[3] = a3;
    dst[4] = a4; dst[5] = a5; dst[6] = a6; dst[7] = a7;
  }
}

__global__ void zero_kernel(float* __restrict__ p, int n)
{
  int i = threadIdx.x;
  if (i < n) p[i] = 0.f;
}

__global__ void zeroi_kernel(int* __restrict__ p, int n)
{
  int i = threadIdx.x;
  if (i < n) p[i] = 0;
}

__global__ __launch_bounds__(256) void topk_kernel(
    const float* __restrict__ RL, float* __restrict__ W, float* __restrict__ AUX)
{
  int t = blockIdx.x * 256 + threadIdx.x;
  int lane = threadIdx.x & 63;
  float r[8];
#pragma unroll
  for (int e = 0; e < 8; ++e) r[e] = RL[t * 8 + e];
  float mx = r[0];
#pragma unroll
  for (int e = 1; e < 8; ++e) mx = fmaxf(mx, r[e]);
  float p[8];
  float se = 0.f;
#pragma unroll
  for (int e = 0; e < 8; ++e) { p[e] = __expf(r[e] - mx); se += p[e]; }
  float inv = 1.f / se;
#pragma unroll
  for (int e = 0; e < 8; ++e) p[e] *= inv;
  float lse = logf(se) + mx;
  int i1 = 0; float v1 = p[0];
#pragma unroll
  for (int e = 1; e < 8; ++e) if (p[e] > v1) { v1 = p[e]; i1 = e; }
  int i2 = -1; float v2 = -1.f;
#pragma unroll
  for (int e = 0; e < 8; ++e) if (e != i1 && p[e] > v2) { v2 = p[e]; i2 = e; }
  float s12 = v1 + v2;
#pragma unroll
  for (int e = 0; e < 8; ++e)
    W[t * 8 + e] = (e == i1) ? v1 / s12 : ((e == i2) ? v2 / s12 : 0.f);
#pragma unroll
  for (int e = 0; e < 8; ++e) {
    float fe = ((i1 == e) ? 1.f : 0.f) + ((i2 == e) ? 1.f : 0.f);
    float pe = p[e];
#pragma unroll
    for (int d = 1; d < 64; d <<= 1) { fe += __shfl_xor(fe, d); pe += __shfl_xor(pe, d); }
    if (lane == 0) { atomicAdd(&AUX[e], fe); atomicAdd(&AUX[8 + e], pe); }
  }
  float zz = lse * lse;
#pragma unroll
  for (int d = 1; d < 64; d <<= 1) zz += __shfl_xor(zz, d);
  if (lane == 0) atomicAdd(&AUX[16], zz);
}

__global__ void aux_kernel(const float* __restrict__ AUX, float* __restrict__ OUT)
{
  float s = 0.f;
#pragma unroll
  for (int e = 0; e < 8; ++e)
    s += (AUX[e] * (1.f / 2048.f)) * (AUX[8 + e] * (1.f / 2048.f));
  float auxv = 0.01f * 8.f * s;
  float z = 0.001f * (AUX[16] * (1.f / 2048.f));
  OUT[(size_t)SEQ * VOCAB] = auxv + z;
}

// records per-token (expert, pos) pairs in ascending-e order
__global__ __launch_bounds__(256) void build_list_kernel(
    const float* __restrict__ W, int* __restrict__ cnt, int* __restrict__ list,
    int* __restrict__ tokpair)
{
  int t = blockIdx.x * 256 + threadIdx.x;
  int j = 0;
#pragma unroll
  for (int e = 0; e < 8; ++e) {
    if (W[t * 8 + e] > 0.f) {
      int p = atomicAdd(&cnt[e], 1);
      list[e * SEQ + p] = t;
      tokpair[t * 2 + j] = (e << 16) | p;
      ++j;
    }
  }
}

__global__ void prefix_kernel(const int* __restrict__ cnt, int* __restrict__ off)
{
  if (threadIdx.x == 0) {
    int s = 0;
    for (int e = 0; e < 8; ++e) { off[e] = s; s += cnt[e]; }
  }
}

// ---------------------------------------------------------------------------
extern "C" void kernel_launch(void* const* d_in, const int* in_sizes, int n_in,
                              void* d_out, int out_size, void* d_ws, size_t ws_size,
                              hipStream_t stream)
{
  const int*   ids   = (const int*)d_in[0];
  const float* embed = (const float*)d_in[1];
  const float* ln1   = (const float*)d_in[2];
  const float* ln2   = (const float*)d_in[3];
  const float* wq    = (const float*)d_in[4];
  const float* wk    = (const float*)d_in[5];
  const float* wv    = (const float*)d_in[6];
  const float* wo    = (const float*)d_in[7];
  const float* dg    = (const float*)d_in[8];
  const float* du    = (const float*)d_in[9];
  const float* dd    = (const float*)d_in[10];
  const float* rw    = (const float*)d_in[11];
  const float* mg    = (const float*)d_in[12];
  const float* mu    = (const float*)d_in[13];
  const float* md    = (const float*)d_in[14];
  const float* fin   = (const float*)d_in[15];
  float* out = (float*)d_out;

  char* ws = (char*)d_ws;
  float* h    = (float*)(ws + 0);
  float* hn   = (float*)(ws + 8388608);
  float* q    = (float*)(ws + 16777216);
  float* k    = (float*)(ws + 25165824);
  float* v    = (float*)(ws + 33554432);
  __bf16* oh  = (__bf16*)(ws + 41943040);
  __bf16* ol  = (__bf16*)(ws + 46137344);
  float* g    = (float*)(ws + 50331648);
  float* u    = (float*)(ws + 73400320);
  float* ct   = (float*)(ws + 96468992);
  float* st   = (float*)(ws + 96731136);
  float* rl   = (float*)(ws + 96993280);
  float* wmoe = (float*)(ws + 97058816);
  float* aux  = (float*)(ws + 97124352);
  int*   cnt  = (int*)  (ws + 97124608);
  int*   list = (int*)  (ws + 97124864);
  int*   tokp = (int*)  (ws + 97190400);
  int*   off8 = (int*)  (ws + 97206784);
  __bf16* wqh = (__bf16*)(ws + 97320960);
  __bf16* wql = (__bf16*)(ws + 105709568);
  __bf16* wkh = (__bf16*)(ws + 114098176);
  __bf16* wkl = (__bf16*)(ws + 122486784);
  __bf16* wvh = (__bf16*)(ws + 130875392);
  __bf16* wvl = (__bf16*)(ws + 139264000);
  __bf16* woh = (__bf16*)(ws + 147652608);
  __bf16* wol = (__bf16*)(ws + 156041216);
  __bf16* dgh = (__bf16*)(ws + 164429824);
  __bf16* dgl = (__bf16*)(ws + 181731328);
  __bf16* duh = (__bf16*)(ws + 199032832);
  __bf16* dul = (__bf16*)(ws + 216334336);
  __bf16* ddh = (__bf16*)(ws + 233635840);
  __bf16* ddl = (__bf16*)(ws + 250937344);
  __bf16* eh  = (__bf16*)(ws + 268238848);
  __bf16* hnh = (__bf16*)(ws + 333774848);
  __bf16* hnl = (__bf16*)(ws + 337969152);
  __bf16* gh  = (__bf16*)(ws + 342163456);
  __bf16* gl  = (__bf16*)(ws + 353697792);
  __bf16* mgh = (__bf16*)(ws + 365232128);
  __bf16* muh = (__bf16*)(ws + 411369472);
  __bf16* mdh = (__bf16*)(ws + 457506816);
  // end: 503,644,160 bytes
  __bf16* qh  = (__bf16*)g;
  __bf16* ql  = (__bf16*)((char*)g + 4194304);
  __bf16* kbh = (__bf16*)((char*)g + 8388608);
  __bf16* kbl = (__bf16*)((char*)g + 12582912);
  __bf16* vth = (__bf16*)u;
  __bf16* vtl = (__bf16*)((char*)u + 4194304);
  __bf16* a2  = (__bf16*)g;
  float*  y2  = u;

  wsplit_t_kernel<<<dim3(16, 16, 4), 256, 0, stream>>>(wq, wqh, wql, HID, HID);
  wsplit_t_kernel<<<dim3(16, 16, 4), 256, 0, stream>>>(wk, wkh, wkl, HID, HID);
  wsplit_t_kernel<<<dim3(16, 16, 4), 256, 0, stream>>>(wv, wvh, wvl, HID, HID);
  wsplit_t_kernel<<<dim3(16, 16, 4), 256, 0, stream>>>(wo, woh, wol, HID, HID);
  wsplit_t_kernel<<<dim3(44, 16, 3), 256, 0, stream>>>(dg, dgh, dgl, HID, IDIM);
  wsplit_t_kernel<<<dim3(44, 16, 3), 256, 0, stream>>>(du, duh, dul, HID, IDIM);
  wsplit_t_kernel<<<dim3(16, 44, 3), 256, 0, stream>>>(dd, ddh, ddl, IDIM, HID);
  wsplit_th_kernel<<<dim3(44, 16, 8), 256, 0, stream>>>(mg, mgh, HID, IDIM);
  wsplit_th_kernel<<<dim3(44, 16, 8), 256, 0, stream>>>(mu, muh, HID, IDIM);
  wsplit_th_kernel<<<dim3(16, 44, 8), 256, 0, stream>>>(md, mdh, IDIM, HID);
  esplit_kernel<<<16000, 256, 0, stream>>>(embed, eh);

  tables_kernel<<<256, 256, 0, stream>>>(ct, st);
  embed_kernel<<<SEQ, 256, 0, stream>>>(ids, embed, h);

  for (int li = 0; li < 4; ++li) {
    const bool comp = (li <= 2);
    rmsnorm_kernel<<<SEQ, 256, 0, stream>>>(h, ln1 + li * HID, hn, hnh, hnl);
    size_t wofs = (size_t)li * HID * HID;
    // QKV GEMM with fused rope+split epilogue (q,k) and f32 v output
    if (comp)
      gemm_qkv_kernel<true><<<dim3(8, 32, 3), 256, 0, stream>>>(
          hnh, hnl, wqh + wofs, wql + wofs, wkh + wofs, wkl + wofs,
          wvh + wofs, wvl + wofs, qh, ql, kbh, kbl, v, ct, st);
    else
      gemm_qkv_kernel<false><<<dim3(8, 32, 3), 256, 0, stream>>>(
          hnh, hnh, wqh + wofs, wqh + wofs, wkh + wofs, wkh + wofs,
          wvh + wofs, wvh + wofs, qh, ql, kbh, kbl, v, ct, st);

    vtsplit_kernel<<<dim3(32, 16), 256, 0, stream>>>(v, vth, vtl);

    attn_flash_kernel<<<dim3(16, 16), 256, 0, stream>>>(
        qh, ql, kbh, kbl, vth, vtl, oh, ol);

    // wo GEMM: BN=64 -> 512 blocks (2/CU)
    if (comp)
      gemm_bt_kernel<true, true, 64, 64, false><<<dim3(16, 32, 1), 256, 0, stream>>>(
          oh, ol, woh + wofs, wol + wofs, woh + wofs, wol + wofs,
          woh + wofs, wol + wofs, h, h, h, SEQ, HID, HID);
    else
      gemm_bt_kernel<false, true, 64, 64, false><<<dim3(16, 32, 1), 256, 0, stream>>>(
          oh, oh, woh + wofs, woh + wofs, woh + wofs, woh + wofs,
          woh + wofs, woh + wofs, h, h, h, SEQ, HID, HID);

    rmsnorm_kernel<<<SEQ, 256, 0, stream>>>(h, ln2 + li * HID, hn, hnh, hnl);
    if (li == 2) {
      router_kernel<<<512, 256, 0, stream>>>(hn, rw, rl);
      zero_kernel<<<1, 32, 0, stream>>>(aux, 17);
      topk_kernel<<<8, 256, 0, stream>>>(rl, wmoe, aux);
      aux_kernel<<<1, 1, 0, stream>>>(aux, out);
      zeroi_kernel<<<1, 32, 0, stream>>>(cnt, 8);
      build_list_kernel<<<8, 256, 0, stream>>>(wmoe, cnt, list, tokp);
      prefix_kernel<<<1, 64, 0, stream>>>(cnt, off8);
      gemm_moe_guf_kernel<<<dim3(44, 16, 8), 256, 0, stream>>>(
          hnh, mgh, muh, a2, wmoe, list, cnt, off8);
      gemm_moe_down2_kernel<<<dim3(16, 16, 8), 256, 0, stream>>>(
          a2, mdh, y2, cnt, off8);
      moe_scatter_kernel<<<SEQ, 256, 0, stream>>>(tokp, off8, y2, h);
    } else {
      int d = (li < 2) ? li : li - 1;
      size_t go = (size_t)d * HID * IDIM;
      // dense gate+up GEMM with fused silu + hi/lo split epilogue
      if (comp)
        gemm_dgu_kernel<true><<<dim3(44, 32), 256, 0, stream>>>(
            hnh, hnl, dgh + go, dgl + go, duh + go, dul + go, gh, gl);
      else
        gemm_dgu_kernel<false><<<dim3(44, 32), 256, 0, stream>>>(
            hnh, hnh, dgh + go, dgh + go, duh + go, duh + go, gh, gl);
      // down GEMM: BN=64 -> 512 blocks
      if (comp)
        gemm_bt_kernel<true, true, 64, 64, false><<<dim3(16, 32, 1), 256, 0, stream>>>(
            gh, gl, ddh + go, ddl + go, ddh + go, ddl + go,
            ddh + go, ddl + go, h, h, h, SEQ, HID, IDIM);
      else
        gemm_bt_kernel<false, true, 64, 64, false><<<dim3(16, 32, 1), 256, 0, stream>>>(
            gh, gh, ddh + go, ddh + go, ddh + go, ddh + go,
            ddh + go, ddh + go, h, h, h, SEQ, HID, IDIM);
    }
  }
  rmsnorm_kernel<<<SEQ, 256, 0, stream>>>(h, fin, hn, hnh, hnl);
  // logits: BM=128 + XCD-aware bijective swizzle (4096-block 1D grid)
  gemm_bt_kernel<false, false, 128, 128, true><<<dim3(4096, 1, 1), 256, 0, stream>>>(
      hnh, hnh, eh, eh, eh, eh, eh, eh, out, out, out, SEQ, VOCAB, HID);
}

// Round 21
// 1667.518 us; speedup vs baseline: 1.3859x; 1.0260x over previous
//
#include <hip/hip_runtime.h>
#include <hip/hip_bf16.h>
#include <math.h>

#define SEQ 2048
#define HID 1024
#define NHEAD 16
#define HDIM 64
#define IDIM 2816
#define NEXP 8
#define VOCAB 32000

#define ASTRIDE 144  // padded rows (attention)

typedef float f32x4v __attribute__((ext_vector_type(4)));
typedef __bf16 bf16x8v __attribute__((ext_vector_type(8)));
typedef __bf16 bf16x4v __attribute__((ext_vector_type(4)));

__device__ __forceinline__ bf16x8v cvt8(const float4& a, const float4& b) {
  bf16x8v r;
  r[0] = (__bf16)a.x; r[1] = (__bf16)a.y; r[2] = (__bf16)a.z; r[3] = (__bf16)a.w;
  r[4] = (__bf16)b.x; r[5] = (__bf16)b.y; r[6] = (__bf16)b.z; r[7] = (__bf16)b.w;
  return r;
}

#define MFMA(a, b, c) __builtin_amdgcn_mfma_f32_16x16x32_bf16(a, b, c, 0, 0, 0)

// async global->LDS DMA, 16B per lane; lds base must be wave-uniform
__device__ __forceinline__ void gld_lds16(const void* g, void* l) {
  __builtin_amdgcn_global_load_lds(
      (const __attribute__((address_space(1))) unsigned int*)(unsigned long long)g,
      (__attribute__((address_space(3))) unsigned int*)(unsigned int)(unsigned long long)l,
      16, 0, 0);
}

// ---------------------------------------------------------------------------
// Weight preprocessing: W[K,N] f32 -> WH,WL [N,K] bf16 (transposed hi/lo).
// ---------------------------------------------------------------------------
__global__ __launch_bounds__(256) void wsplit_t_kernel(
    const float* __restrict__ W, __bf16* __restrict__ WH, __bf16* __restrict__ WL,
    int K, int N)
{
  __shared__ float tile[64][65];
  const int tid = threadIdx.x;
  const size_t zofs = (size_t)blockIdx.z * K * N;
  const int n0 = blockIdx.x * 64, k0 = blockIdx.y * 64;
#pragma unroll
  for (int r = 0; r < 4; ++r) {
    int kk = (tid >> 4) + r * 16;
    int nn = (tid & 15) * 4;
    float4 v = *(const float4*)(W + zofs + (size_t)(k0 + kk) * N + n0 + nn);
    tile[kk][nn] = v.x; tile[kk][nn + 1] = v.y;
    tile[kk][nn + 2] = v.z; tile[kk][nn + 3] = v.w;
  }
  __syncthreads();
  const int nn = tid >> 2;
  const int kk = (tid & 3) * 16;
  __bf16* dh = WH + zofs + (size_t)(n0 + nn) * K + k0 + kk;
  __bf16* dl = WL + zofs + (size_t)(n0 + nn) * K + k0 + kk;
  bf16x8v h0, l0, h1, l1;
#pragma unroll
  for (int j = 0; j < 8; ++j) {
    float f = tile[kk + j][nn];
    __bf16 hb = (__bf16)f; h0[j] = hb; l0[j] = (__bf16)(f - (float)hb);
    f = tile[kk + 8 + j][nn];
    hb = (__bf16)f; h1[j] = hb; l1[j] = (__bf16)(f - (float)hb);
  }
  *(bf16x8v*)dh = h0; *(bf16x8v*)(dh + 8) = h1;
  *(bf16x8v*)dl = l0; *(bf16x8v*)(dl + 8) = l1;
}

// merged QKVO wsplit: z = weight(0..3) * 4 + layer(0..3); dst stride 16MB/weight
__global__ __launch_bounds__(256) void wsplit_qkvo_kernel(
    const float* __restrict__ W0, const float* __restrict__ W1,
    const float* __restrict__ W2, const float* __restrict__ W3,
    __bf16* __restrict__ WHbase)
{
  const int z = blockIdx.z;
  const int li = z & 3, sel = z >> 2;
  const float* W = (sel == 0) ? W0 : (sel == 1) ? W1 : (sel == 2) ? W2 : W3;
  const size_t lofs = (size_t)li * HID * HID;
  __bf16* WH = (__bf16*)((char*)WHbase + (size_t)sel * 16777216) + lofs;
  __bf16* WL = (__bf16*)((char*)WHbase + (size_t)sel * 16777216 + 8388608) + lofs;
  __shared__ float tile[64][65];
  const int tid = threadIdx.x;
  const int n0 = blockIdx.x * 64, k0 = blockIdx.y * 64;
#pragma unroll
  for (int r = 0; r < 4; ++r) {
    int kk = (tid >> 4) + r * 16;
    int nn = (tid & 15) * 4;
    float4 v = *(const float4*)(W + lofs + (size_t)(k0 + kk) * HID + n0 + nn);
    tile[kk][nn] = v.x; tile[kk][nn + 1] = v.y;
    tile[kk][nn + 2] = v.z; tile[kk][nn + 3] = v.w;
  }
  __syncthreads();
  const int nn = tid >> 2;
  const int kk = (tid & 3) * 16;
  __bf16* dh = WH + (size_t)(n0 + nn) * HID + k0 + kk;
  __bf16* dl = WL + (size_t)(n0 + nn) * HID + k0 + kk;
  bf16x8v h0, l0, h1, l1;
#pragma unroll
  for (int j = 0; j < 8; ++j) {
    float f = tile[kk + j][nn];
    __bf16 hb = (__bf16)f; h0[j] = hb; l0[j] = (__bf16)(f - (float)hb);
    f = tile[kk + 8 + j][nn];
    hb = (__bf16)f; h1[j] = hb; l1[j] = (__bf16)(f - (float)hb);
  }
  *(bf16x8v*)dh = h0; *(bf16x8v*)(dh + 8) = h1;
  *(bf16x8v*)dl = l0; *(bf16x8v*)(dl + 8) = l1;
}

// hi-only variant (MoE weights; plain-bf16 path needs no lo)
__global__ __launch_bounds__(256) void wsplit_th_kernel(
    const float* __restrict__ W, __bf16* __restrict__ WH, int K, int N)
{
  __shared__ float tile[64][65];
  const int tid = threadIdx.x;
  const size_t zofs = (size_t)blockIdx.z * K * N;
  const int n0 = blockIdx.x * 64, k0 = blockIdx.y * 64;
#pragma unroll
  for (int r = 0; r < 4; ++r) {
    int kk = (tid >> 4) + r * 16;
    int nn = (tid & 15) * 4;
    float4 v = *(const float4*)(W + zofs + (size_t)(k0 + kk) * N + n0 + nn);
    tile[kk][nn] = v.x; tile[kk][nn + 1] = v.y;
    tile[kk][nn + 2] = v.z; tile[kk][nn + 3] = v.w;
  }
  __syncthreads();
  const int nn = tid >> 2;
  const int kk = (tid & 3) * 16;
  __bf16* dh = WH + zofs + (size_t)(n0 + nn) * K + k0 + kk;
  bf16x8v h0, h1;
#pragma unroll
  for (int j = 0; j < 8; ++j) {
    h0[j] = (__bf16)tile[kk + j][nn];
    h1[j] = (__bf16)tile[kk + 8 + j][nn];
  }
  *(bf16x8v*)dh = h0; *(bf16x8v*)(dh + 8) = h1;
}

__global__ __launch_bounds__(256) void esplit_kernel(
    const float* __restrict__ E, __bf16* __restrict__ EH)
{
  size_t i = ((size_t)blockIdx.x * 256 + threadIdx.x) * 8;
  float4 a = *(const float4*)(E + i);
  float4 b = *(const float4*)(E + i + 4);
  *(bf16x8v*)(EH + i) = cvt8(a, b);
}

// ---------------------------------------------------------------------------
// Unified BT GEMM, 2-phase double-buffered LDS. Bit-exact MFMA chains.
// XSWZ: XCD-aware bijective 1D grid (logits, BM=128).
// ---------------------------------------------------------------------------
template<bool COMP, bool ACCUM, int BM, int BN, bool XSWZ>
__global__ __launch_bounds__(256) void gemm_bt_kernel(
    const __bf16* __restrict__ Ah, const __bf16* __restrict__ Al,
    const __bf16* __restrict__ B0h, const __bf16* __restrict__ B0l,
    const __bf16* __restrict__ B1h, const __bf16* __restrict__ B1l,
    const __bf16* __restrict__ B2h, const __bf16* __restrict__ B2l,
    float* __restrict__ C0, float* __restrict__ C1, float* __restrict__ C2,
    int M, int N, int Kd)
{
  const __bf16* __restrict__ Bh = (blockIdx.z == 0) ? B0h : (blockIdx.z == 1 ? B1h : B2h);
  const __bf16* __restrict__ Bl = (blockIdx.z == 0) ? B0l : (blockIdx.z == 1 ? B1l : B2l);
  float* __restrict__ C         = (blockIdx.z == 0) ? C0 : (blockIdx.z == 1 ? C1 : C2);
  constexpr int ATILE = BM * 64;
  constexpr int BTILE = BN * 64;
  constexpr int MFR = BM / 32;
  constexpr int NFR = BN / 32;
  constexpr int SBUF = COMP ? 2 * (ATILE + BTILE) : (ATILE + BTILE);
  __shared__ __align__(16) char smem[2 * SBUF];
  const int tid = threadIdx.x;
  int bm, bn;
  if (XSWZ) {
    int id = blockIdx.x;            // padded 1D grid
    int xcd = id & 7;
    int j = id >> 3;
    if (BM == 128) {                // M=2048 -> 16 bm-blocks
      bm = j & 15;
      bn = xcd * 32 + (j >> 4);
    } else {                        // BM=64 -> 32 bm-blocks
      bm = j & 31;
      bn = xcd * 32 + (j >> 5);
    }
    if (bn >= N / BN) return;
  } else {
    bm = blockIdx.y;
    bn = blockIdx.x;
  }
  const int wid = tid >> 6, lane = tid & 63;
  const int wm = (wid >> 1) * (BM / 2), wn = (wid & 1) * (BN / 2);
  const int lr = lane & 15, kh = lane >> 4;
  const int lrow = lane >> 2;
  const int lcol = (lane & 3) << 3;

  auto stage = [&](char* buf, int k0) {
    char* AsH = buf;
    char* BsH = buf + ATILE;
    char* AsL = COMP ? buf + ATILE + BTILE : buf;
    char* BsL = COMP ? buf + 2 * ATILE + BTILE : buf + ATILE;
#pragma unroll
    for (int c = wid; c < BM / 16; c += 4) {
      size_t gofs = (size_t)(bm * BM + c * 16 + lrow) * Kd + k0 + lcol;
      gld_lds16(Ah + gofs, AsH + c * 1024);
      if (COMP) gld_lds16(Al + gofs, AsL + c * 1024);
    }
#pragma unroll
    for (int c = wid; c < BN / 16; c += 4) {
      size_t gofs = (size_t)(bn * BN + c * 16 + lrow) * Kd + k0 + lcol;
      gld_lds16(Bh + gofs, BsH + c * 1024);
      if (COMP) gld_lds16(Bl + gofs, BsL + c * 1024);
    }
  };

  f32x4v acc[MFR][NFR];
  const f32x4v z4 = {0.f, 0.f, 0.f, 0.f};
#pragma unroll
  for (int i = 0; i < MFR; ++i)
#pragma unroll
    for (int j2 = 0; j2 < NFR; ++j2) acc[i][j2] = z4;

  stage(smem, 0);
  int cur = 0;
  for (int k0 = 0; k0 < Kd; k0 += 32) {
    __syncthreads();                     // drains glds into buf[cur]
    char* buf = smem + cur * SBUF;
    if (k0 + 32 < Kd) stage(smem + (cur ^ 1) * SBUF, k0 + 32);
    char* AsH = buf;
    char* BsH = buf + ATILE;
    char* AsL = COMP ? buf + ATILE + BTILE : buf;
    char* BsL = COMP ? buf + 2 * ATILE + BTILE : buf + ATILE;

    bf16x8v ah[MFR], al[MFR], bh4[NFR], bl4[NFR];
#pragma unroll
    for (int i = 0; i < MFR; ++i) {
      int r = wm + (i << 4) + lr;
      int off = r * 64 + (kh << 4);
      ah[i] = *(const bf16x8v*)(AsH + off);
      if (COMP) al[i] = *(const bf16x8v*)(AsL + off);
    }
#pragma unroll
    for (int i = 0; i < NFR; ++i) {
      int r = wn + (i << 4) + lr;
      int off = r * 64 + (kh << 4);
      bh4[i] = *(const bf16x8v*)(BsH + off);
      if (COMP) bl4[i] = *(const bf16x8v*)(BsL + off);
    }
#pragma unroll
    for (int mi = 0; mi < MFR; ++mi)
#pragma unroll
      for (int ni = 0; ni < NFR; ++ni) {
        if (COMP) {
          acc[mi][ni] = MFMA(al[mi], bh4[ni], acc[mi][ni]);
          acc[mi][ni] = MFMA(ah[mi], bl4[ni], acc[mi][ni]);
        }
        acc[mi][ni] = MFMA(ah[mi], bh4[ni], acc[mi][ni]);
      }
    cur ^= 1;
  }

  const int cr0 = kh << 2;
#pragma unroll
  for (int mi = 0; mi < MFR; ++mi)
#pragma unroll
    for (int ni = 0; ni < NFR; ++ni)
#pragma unroll
      for (int r = 0; r < 4; ++r) {
        int row = bm * BM + wm + (mi << 4) + cr0 + r;
        int col = bn * BN + wn + (ni << 4) + lr;
        size_t idx = (size_t)row * N + col;
        if (ACCUM) C[idx] += acc[mi][ni][r];
        else       C[idx] = acc[mi][ni][r];
      }
}

// ---------------------------------------------------------------------------
// QKV GEMM. z=0 q (rope+split, scale 1/8), z=1 k (rope+split), z=2 v:
// fused in-LDS f32 transpose -> VTH/VTL [NHEAD][HDIM][SEQ] hi/lo (bit-exact
// vs old f32-roundtrip + vtsplit). 2-phase double-buffered.
// ---------------------------------------------------------------------------
template<bool COMP>
__global__ __launch_bounds__(256) void gemm_qkv_kernel(
    const __bf16* __restrict__ Ah, const __bf16* __restrict__ Al,
    const __bf16* __restrict__ Bqh, const __bf16* __restrict__ Bql,
    const __bf16* __restrict__ Bkh, const __bf16* __restrict__ Bkl,
    const __bf16* __restrict__ Bvh, const __bf16* __restrict__ Bvl,
    __bf16* __restrict__ QH, __bf16* __restrict__ QL,
    __bf16* __restrict__ KH, __bf16* __restrict__ KL,
    __bf16* __restrict__ VTH, __bf16* __restrict__ VTL,
    const float* __restrict__ CT, const float* __restrict__ ST)
{
  const __bf16* __restrict__ Bh = (blockIdx.z == 0) ? Bqh : (blockIdx.z == 1 ? Bkh : Bvh);
  const __bf16* __restrict__ Bl = (blockIdx.z == 0) ? Bql : (blockIdx.z == 1 ? Bkl : Bvl);
  constexpr int ATILE = 64 * 64;
  constexpr int BTILE = 128 * 64;
  constexpr int SBUF = COMP ? 2 * (ATILE + BTILE) : (ATILE + BTILE);
  constexpr int SMEMSZ = (2 * SBUF > 32768) ? 2 * SBUF : 32768;  // >=32KB for f32 transpose
  __shared__ __align__(16) char smem[SMEMSZ];
  const int tid = threadIdx.x;
  const int bm = blockIdx.y, bn = blockIdx.x;
  const int wid = tid >> 6, lane = tid & 63;
  const int wm = (wid >> 1) << 5, wn = (wid & 1) << 6;
  const int lr = lane & 15, kh = lane >> 4;
  const int lrow = lane >> 2;
  const int lcol = (lane & 3) << 3;

  auto stage = [&](char* buf, int k0) {
    char* AsH = buf;
    char* BsH = buf + ATILE;
    char* AsL = COMP ? buf + ATILE + BTILE : buf;
    char* BsL = COMP ? buf + 2 * ATILE + BTILE : buf + ATILE;
    {
      int c = wid;   // A: 4 chunks
      size_t gofs = (size_t)(bm * 64 + c * 16 + lrow) * HID + k0 + lcol;
      gld_lds16(Ah + gofs, AsH + c * 1024);
      if (COMP) gld_lds16(Al + gofs, AsL + c * 1024);
    }
#pragma unroll
    for (int c = wid; c < 8; c += 4) {
      size_t gofs = (size_t)(bn * 128 + c * 16 + lrow) * HID + k0 + lcol;
      gld_lds16(Bh + gofs, BsH + c * 1024);
      if (COMP) gld_lds16(Bl + gofs, BsL + c * 1024);
    }
  };

  f32x4v acc[2][4];
  const f32x4v z4 = {0.f, 0.f, 0.f, 0.f};
#pragma unroll
  for (int i = 0; i < 2; ++i)
#pragma unroll
    for (int j2 = 0; j2 < 4; ++j2) acc[i][j2] = z4;

  stage(smem, 0);
  int cur = 0;
  for (int k0 = 0; k0 < HID; k0 += 32) {
    __syncthreads();
    char* buf = smem + cur * SBUF;
    if (k0 + 32 < HID) stage(smem + (cur ^ 1) * SBUF, k0 + 32);
    char* AsH = buf;
    char* BsH = buf + ATILE;
    char* AsL = COMP ? buf + ATILE + BTILE : buf;
    char* BsL = COMP ? buf + 2 * ATILE + BTILE : buf + ATILE;

    bf16x8v ah2[2], al2[2], bh4[4], bl4[4];
#pragma unroll
    for (int i = 0; i < 2; ++i) {
      int r = wm + (i << 4) + lr;
      int off = r * 64 + (kh << 4);
      ah2[i] = *(const bf16x8v*)(AsH + off);
      if (COMP) al2[i] = *(const bf16x8v*)(AsL + off);
    }
#pragma unroll
    for (int i = 0; i < 4; ++i) {
      int r = wn + (i << 4) + lr;
      int off = r * 64 + (kh << 4);
      bh4[i] = *(const bf16x8v*)(BsH + off);
      if (COMP) bl4[i] = *(const bf16x8v*)(BsL + off);
    }
#pragma unroll
    for (int mi = 0; mi < 2; ++mi)
#pragma unroll
      for (int ni = 0; ni < 4; ++ni) {
        if (COMP) {
          acc[mi][ni] = MFMA(al2[mi], bh4[ni], acc[mi][ni]);
          acc[mi][ni] = MFMA(ah2[mi], bl4[ni], acc[mi][ni]);
        }
        acc[mi][ni] = MFMA(ah2[mi], bh4[ni], acc[mi][ni]);
      }
    cur ^= 1;
  }

  const int cr0 = kh << 2;
  if (blockIdx.z == 2) {
    // in-LDS f32 transpose, then hi/lo split writes (== old vtsplit, bit-exact)
    float* tf = (float*)smem;   // [64][128] f32 = 32KB
    __syncthreads();            // K-loop LDS reads complete in all waves
#pragma unroll
    for (int mi = 0; mi < 2; ++mi)
#pragma unroll
      for (int ni = 0; ni < 4; ++ni)
#pragma unroll
        for (int r = 0; r < 4; ++r) {
          int rrow = wm + (mi << 4) + cr0 + r;   // 0..63 (seq within tile)
          int ccol = wn + (ni << 4) + lr;        // 0..127 (d within tile)
          tf[rrow * 128 + ccol] = acc[mi][ni][r];
        }
    __syncthreads();
#pragma unroll
    for (int t4 = 0; t4 < 4; ++t4) {
      int idx = tid + (t4 << 8);   // 0..1023 = 128 d x 8 chunks
      int d = idx >> 3;
      int c = idx & 7;
      bf16x8v hv, lv;
#pragma unroll
      for (int j = 0; j < 8; ++j) {
        float f = tf[(c * 8 + j) * 128 + d];
        __bf16 hb = (__bf16)f;
        hv[j] = hb; lv[j] = (__bf16)(f - (float)hb);
      }
      size_t dst = (size_t)(bn * 128 + d) * SEQ + bm * 64 + c * 8;
      *(bf16x8v*)(VTH + dst) = hv;
      *(bf16x8v*)(VTL + dst) = lv;
    }
  } else {
    const float scale = (blockIdx.z == 0) ? 0.125f : 1.0f;
    __bf16* OH = (blockIdx.z == 0) ? QH : KH;
    __bf16* OL = (blockIdx.z == 0) ? QL : KL;
#pragma unroll
    for (int mi = 0; mi < 2; ++mi)
#pragma unroll
      for (int ni = 0; ni < 2; ++ni)
#pragma unroll
        for (int r = 0; r < 4; ++r) {
          int row = bm * 64 + wm + (mi << 4) + cr0 + r;
          int col = bn * 128 + wn + (ni << 4) + lr;   // (col&63) < 32
          int i = col & 31;
          float c = CT[row * 32 + i], sn = ST[row * 32 + i];
          float x1 = acc[mi][ni][r];
          float x2 = acc[mi][ni + 2][r];
          float o1 = (x1 * c - x2 * sn) * scale;
          float o2 = (x2 * c + x1 * sn) * scale;
          size_t ofs = (size_t)row * HID + col;
          __bf16 h1 = (__bf16)o1;
          OH[ofs] = h1; OL[ofs] = (__bf16)(o1 - (float)h1);
          __bf16 h2 = (__bf16)o2;
          OH[ofs + 32] = h2; OL[ofs + 32] = (__bf16)(o2 - (float)h2);
        }
  }
}

// ---------------------------------------------------------------------------
// Dense gate+up GEMM with fused silu + hi/lo split epilogue. BM=64, BN=64.
// 2-phase double-buffered. Bit-exact.
// ---------------------------------------------------------------------------
template<bool COMP>
__global__ __launch_bounds__(256) void gemm_dgu_kernel(
    const __bf16* __restrict__ Ah, const __bf16* __restrict__ Al,
    const __bf16* __restrict__ BGh, const __bf16* __restrict__ BGl,
    const __bf16* __restrict__ BUh, const __bf16* __restrict__ BUl,
    __bf16* __restrict__ GH, __bf16* __restrict__ GL)
{
  constexpr int SBUF = COMP ? 24576 : 12288;
  __shared__ __align__(16) char smem[2 * SBUF];
  const int tid = threadIdx.x;
  const int bn = blockIdx.x, bm = blockIdx.y;
  const int wid = tid >> 6, lane = tid & 63;
  const int wm = (wid >> 1) << 5, wn = (wid & 1) << 5;
  const int lr = lane & 15, kh = lane >> 4;
  const int lrow = lane >> 2;
  const int lcol = (lane & 3) << 3;

  auto stage = [&](char* buf, int k0) {
    char* AsH = buf;
    char* BgH = buf + 4096;
    char* BuH = buf + 8192;
    char* AsL = COMP ? buf + 12288 : buf;
    char* BgL = COMP ? buf + 16384 : buf;
    char* BuL = COMP ? buf + 20480 : buf;
    int c = wid;   // 4 chunks each buffer
    size_t aofs = (size_t)(bm * 64 + c * 16 + lrow) * HID + k0 + lcol;
    gld_lds16(Ah + aofs, AsH + c * 1024);
    if (COMP) gld_lds16(Al + aofs, AsL + c * 1024);
    size_t bofs = (size_t)(bn * 64 + c * 16 + lrow) * HID + k0 + lcol;
    gld_lds16(BGh + bofs, BgH + c * 1024);
    gld_lds16(BUh + bofs, BuH + c * 1024);
    if (COMP) {
      gld_lds16(BGl + bofs, BgL + c * 1024);
      gld_lds16(BUl + bofs, BuL + c * 1024);
    }
  };

  f32x4v accg[2][2], accu[2][2];
  const f32x4v z4 = {0.f, 0.f, 0.f, 0.f};
#pragma unroll
  for (int i = 0; i < 2; ++i)
#pragma unroll
    for (int j = 0; j < 2; ++j) { accg[i][j] = z4; accu[i][j] = z4; }

  stage(smem, 0);
  int cur = 0;
  for (int k0 = 0; k0 < HID; k0 += 32) {
    __syncthreads();
    char* buf = smem + cur * SBUF;
    if (k0 + 32 < HID) stage(smem + (cur ^ 1) * SBUF, k0 + 32);
    char* AsH = buf;
    char* BgH = buf + 4096;
    char* BuH = buf + 8192;
    char* AsL = COMP ? buf + 12288 : buf;
    char* BgL = COMP ? buf + 16384 : buf;
    char* BuL = COMP ? buf + 20480 : buf;

    bf16x8v af[2], afl[2], bg4[2], bgl4[2], bu4[2], bul4[2];
#pragma unroll
    for (int i = 0; i < 2; ++i) {
      int r = wm + (i << 4) + lr;
      int off = r * 64 + (kh << 4);
      af[i] = *(const bf16x8v*)(AsH + off);
      if (COMP) afl[i] = *(const bf16x8v*)(AsL + off);
    }
#pragma unroll
    for (int i = 0; i < 2; ++i) {
      int r = wn + (i << 4) + lr;
      int off = r * 64 + (kh << 4);
      bg4[i] = *(const bf16x8v*)(BgH + off);
      bu4[i] = *(const bf16x8v*)(BuH + off);
      if (COMP) {
        bgl4[i] = *(const bf16x8v*)(BgL + off);
        bul4[i] = *(const bf16x8v*)(BuL + off);
      }
    }
#pragma unroll
    for (int mi = 0; mi < 2; ++mi)
#pragma unroll
      for (int ni = 0; ni < 2; ++ni) {
        if (COMP) {
          accg[mi][ni] = MFMA(afl[mi], bg4[ni], accg[mi][ni]);
          accg[mi][ni] = MFMA(af[mi], bgl4[ni], accg[mi][ni]);
        }
        accg[mi][ni] = MFMA(af[mi], bg4[ni], accg[mi][ni]);
        if (COMP) {
          accu[mi][ni] = MFMA(afl[mi], bu4[ni], accu[mi][ni]);
          accu[mi][ni] = MFMA(af[mi], bul4[ni], accu[mi][ni]);
        }
        accu[mi][ni] = MFMA(af[mi], bu4[ni], accu[mi][ni]);
      }
    cur ^= 1;
  }

  const int cr0 = kh << 2;
#pragma unroll
  for (int mi = 0; mi < 2; ++mi)
#pragma unroll
    for (int ni = 0; ni < 2; ++ni)
#pragma unroll
      for (int r = 0; r < 4; ++r) {
        int row = bm * 64 + wm + (mi << 4) + cr0 + r;
        int col = bn * 64 + wn + (ni << 4) + lr;
        float gv = accg[mi][ni][r];
        float uv = accu[mi][ni][r];
        float a = gv / (1.f + __expf(-gv)) * uv;
        size_t idx = (size_t)row * IDIM + col;
        __bf16 hb = (__bf16)a;
        GH[idx] = hb;
        GL[idx] = (__bf16)(a - (float)hb);
      }
}

// ---------------------------------------------------------------------------
// Compensated flash attention; padded LDS; O -> bf16 hi/lo.
// Load-balanced: grid (16,16); block processes qt = bx and qt = 31-bx.
// s_setprio(1) around MFMA clusters (T5).
// ---------------------------------------------------------------------------
__global__ __launch_bounds__(256) void attn_flash_kernel(
    const __bf16* __restrict__ QH, const __bf16* __restrict__ QL,
    const __bf16* __restrict__ KH, const __bf16* __restrict__ KL,
    const __bf16* __restrict__ VTH, const __bf16* __restrict__ VTL,
    __bf16* __restrict__ OH, __bf16* __restrict__ OL)
{
  const int head = blockIdx.y;
  const int tid = threadIdx.x, wid = tid >> 6, lane = tid & 63;
  const int lr = lane & 15, kh = lane >> 4;
  __shared__ __align__(16) char KsH[64 * ASTRIDE], KsL[64 * ASTRIDE];
  __shared__ __align__(16) char VtH[64 * ASTRIDE], VtL[64 * ASTRIDE];
  __shared__ __align__(16) char PsH[4][16 * ASTRIDE], PsL[4][16 * ASTRIDE];

#pragma unroll
  for (int seg = 0; seg < 2; ++seg) {
    const int qt = seg ? (31 - (int)blockIdx.x) : (int)blockIdx.x;

    const size_t qofs = (size_t)(qt * 64 + wid * 16 + lr) * HID + head * HDIM;
    const bf16x8v qfh0 = *(const bf16x8v*)(QH + qofs + (kh << 3));
    const bf16x8v qfh1 = *(const bf16x8v*)(QH + qofs + 32 + (kh << 3));
    const bf16x8v qfl0 = *(const bf16x8v*)(QL + qofs + (kh << 3));
    const bf16x8v qfl1 = *(const bf16x8v*)(QL + qofs + 32 + (kh << 3));

    float m_run[4], l_run[4];
    f32x4v oacc[4];
    const f32x4v z4 = {0.f, 0.f, 0.f, 0.f};
#pragma unroll
    for (int i = 0; i < 4; ++i) { m_run[i] = -1e30f; l_run[i] = 0.f; oacc[i] = z4; }

    for (int kt = 0; kt <= qt; ++kt) {
      __syncthreads();
#pragma unroll
      for (int p = 0; p < 2; ++p) {
        int g = tid + (p << 8);
        int r = g >> 3;
        int c = g & 7;
        int off = r * ASTRIDE + (c << 4);
        const size_t kofs = (size_t)(kt * 64 + r) * HID + head * HDIM + (c << 3);
        *(bf16x8v*)(KsH + off) = *(const bf16x8v*)(KH + kofs);
        *(bf16x8v*)(KsL + off) = *(const bf16x8v*)(KL + kofs);
        const size_t vofs = (size_t)(head * 64 + r) * SEQ + kt * 64 + (c << 3);
        *(bf16x8v*)(VtH + off) = *(const bf16x8v*)(VTH + vofs);
        *(bf16x8v*)(VtL + off) = *(const bf16x8v*)(VTL + vofs);
      }
      __syncthreads();

      float sv[4][4];
      __builtin_amdgcn_s_setprio(1);
#pragma unroll
      for (int stt = 0; stt < 4; ++stt) {
        int r = (stt << 4) + lr;
        int off0 = r * ASTRIDE + (kh << 4);
        int off1 = off0 + 64;
        bf16x8v kfh0 = *(const bf16x8v*)(KsH + off0);
        bf16x8v kfl0 = *(const bf16x8v*)(KsL + off0);
        bf16x8v kfh1 = *(const bf16x8v*)(KsH + off1);
        bf16x8v kfl1 = *(const bf16x8v*)(KsL + off1);
        f32x4v s = z4;
        s = MFMA(qfl0, kfh0, s);
        s = MFMA(qfh0, kfl0, s);
        s = MFMA(qfh0, kfh0, s);
        s = MFMA(qfl1, kfh1, s);
        s = MFMA(qfh1, kfl1, s);
        s = MFMA(qfh1, kfh1, s);
        int key = kt * 64 + (stt << 4) + lr;
#pragma unroll
        for (int rr = 0; rr < 4; ++rr) {
          int qr = qt * 64 + wid * 16 + (kh << 2) + rr;
          sv[stt][rr] = (key <= qr) ? s[rr] : -1e30f;
        }
      }
      __builtin_amdgcn_s_setprio(0);

#pragma unroll
      for (int rr = 0; rr < 4; ++rr) {
        float mx = fmaxf(fmaxf(sv[0][rr], sv[1][rr]), fmaxf(sv[2][rr], sv[3][rr]));
#pragma unroll
        for (int d = 1; d < 16; d <<= 1) mx = fmaxf(mx, __shfl_xor(mx, d));
        float mnew = fmaxf(m_run[rr], mx);
        float scl = __expf(m_run[rr] - mnew);
        float pv[4];
#pragma unroll
        for (int stt = 0; stt < 4; ++stt) pv[stt] = __expf(sv[stt][rr] - mnew);
        float rs = pv[0] + pv[1] + pv[2] + pv[3];
#pragma unroll
        for (int d = 1; d < 16; d <<= 1) rs += __shfl_xor(rs, d);
        l_run[rr] = l_run[rr] * scl + rs;
        m_run[rr] = mnew;
#pragma unroll
        for (int n = 0; n < 4; ++n) oacc[n][rr] *= scl;
        int qlr = (kh << 2) + rr;
#pragma unroll
        for (int stt = 0; stt < 4; ++stt) {
          __bf16 hb = (__bf16)pv[stt];
          __bf16 lb = (__bf16)(pv[stt] - (float)hb);
          int off = qlr * ASTRIDE + (((stt << 4) + lr) << 1);
          *(__bf16*)(PsH[wid] + off) = hb;
          *(__bf16*)(PsL[wid] + off) = lb;
        }
      }

      int poff0 = lr * ASTRIDE + (kh << 4);
      int poff1 = poff0 + 64;
      bf16x8v pah0 = *(const bf16x8v*)(PsH[wid] + poff0);
      bf16x8v pal0 = *(const bf16x8v*)(PsL[wid] + poff0);
      bf16x8v pah1 = *(const bf16x8v*)(PsH[wid] + poff1);
      bf16x8v pal1 = *(const bf16x8v*)(PsL[wid] + poff1);
      __builtin_amdgcn_s_setprio(1);
#pragma unroll
      for (int n = 0; n < 4; ++n) {
        int vr = (n << 4) + lr;
        int voff0 = vr * ASTRIDE + (kh << 4);
        int voff1 = voff0 + 64;
        bf16x8v vfh0 = *(const bf16x8v*)(VtH + voff0);
        bf16x8v vfl0 = *(const bf16x8v*)(VtL + voff0);
        bf16x8v vfh1 = *(const bf16x8v*)(VtH + voff1);
        bf16x8v vfl1 = *(const bf16x8v*)(VtL + voff1);
        oacc[n] = MFMA(pal0, vfh0, oacc[n]);
        oacc[n] = MFMA(pah0, vfl0, oacc[n]);
        oacc[n] = MFMA(pah0, vfh0, oacc[n]);
        oacc[n] = MFMA(pal1, vfh1, oacc[n]);
        oacc[n] = MFMA(pah1, vfl1, oacc[n]);
        oacc[n] = MFMA(pah1, vfh1, oacc[n]);
      }
      __builtin_amdgcn_s_setprio(0);
    }

#pragma unroll
    for (int n = 0; n < 4; ++n)
#pragma unroll
      for (int rr = 0; rr < 4; ++rr) {
        int qr = qt * 64 + wid * 16 + (kh << 2) + rr;
        size_t ofs = (size_t)qr * HID + head * HDIM + (n << 4) + lr;
        float val = oacc[n][rr] / l_run[rr];
        __bf16 hb = (__bf16)val;
        OH[ofs] = hb;
        OL[ofs] = (__bf16)(val - (float)hb);
      }
  }
}

// ---------------------------------------------------------------------------
// MoE: fused gate+up+silu. BM=128, BN=64. 2-phase double-buffered.
// ---------------------------------------------------------------------------
__global__ __launch_bounds__(256) void gemm_moe_guf_kernel(
    const __bf16* __restrict__ Xh,
    const __bf16* __restrict__ MGH, const __bf16* __restrict__ MUH,
    __bf16* __restrict__ A2, const float* __restrict__ W,
    const int* __restrict__ list, const int* __restrict__ cnt8,
    const int* __restrict__ off8)
{
  const int e = blockIdx.z;
  const int cnt = cnt8[e];
  const int bn = blockIdx.x, bm = blockIdx.y;
  if (bm * 128 >= cnt) return;
  const int base = off8[e];
  constexpr int SBUF = 16384;   // AsB 8192 | BgB 4096 | BuB 4096
  __shared__ __align__(16) char smem[2 * SBUF];
  const int tid = threadIdx.x;
  const int wid = tid >> 6, lane = tid & 63;
  const int wm = (wid >> 1) << 6, wn = (wid & 1) << 5;
  const int lr = lane & 15, kh = lane >> 4;
  const int lrow = lane >> 2;
  const int lcol = (lane & 3) << 3;

  auto stage = [&](char* buf, int k0) {
    char* AsB = buf;
    char* BgB = buf + 8192;
    char* BuB = buf + 12288;
#pragma unroll
    for (int c = wid; c < 8; c += 4) {     // A: 128 rows
      int rg = bm * 128 + c * 16 + lrow;
      int tok = list[e * SEQ + (rg < cnt ? rg : cnt - 1)];
      gld_lds16(Xh + (size_t)tok * HID + k0 + lcol, AsB + c * 1024);
    }
    {                                       // B: 64 rows each (g,u)
      int c = wid;
      size_t wofs = (size_t)(e * IDIM + bn * 64 + c * 16 + lrow) * HID + k0 + lcol;
      gld_lds16(MGH + wofs, BgB + c * 1024);
      gld_lds16(MUH + wofs, BuB + c * 1024);
    }
  };

  f32x4v accg[4][2], accu[4][2];
  const f32x4v z4 = {0.f, 0.f, 0.f, 0.f};
#pragma unroll
  for (int i = 0; i < 4; ++i)
#pragma unroll
    for (int j = 0; j < 2; ++j) { accg[i][j] = z4; accu[i][j] = z4; }

  stage(smem, 0);
  int cur = 0;
  for (int k0 = 0; k0 < HID; k0 += 32) {
    __syncthreads();
    char* buf = smem + cur * SBUF;
    if (k0 + 32 < HID) stage(smem + (cur ^ 1) * SBUF, k0 + 32);
    char* AsB = buf;
    char* BgB = buf + 8192;
    char* BuB = buf + 12288;

    bf16x8v af[4], bg4[2], bu4[2];
#pragma unroll
    for (int i = 0; i < 4; ++i) {
      int r = wm + (i << 4) + lr;
      af[i] = *(const bf16x8v*)(AsB + r * 64 + (kh << 4));
    }
#pragma unroll
    for (int i = 0; i < 2; ++i) {
      int r = wn + (i << 4) + lr;
      bg4[i] = *(const bf16x8v*)(BgB + r * 64 + (kh << 4));
      bu4[i] = *(const bf16x8v*)(BuB + r * 64 + (kh << 4));
    }
#pragma unroll
    for (int mi = 0; mi < 4; ++mi)
#pragma unroll
      for (int ni = 0; ni < 2; ++ni) {
        accg[mi][ni] = MFMA(af[mi], bg4[ni], accg[mi][ni]);
        accu[mi][ni] = MFMA(af[mi], bu4[ni], accu[mi][ni]);
      }
    cur ^= 1;
  }

  const int cr0 = kh << 2;
#pragma unroll
  for (int mi = 0; mi < 4; ++mi)
#pragma unroll
    for (int ni = 0; ni < 2; ++ni)
#pragma unroll
      for (int r = 0; r < 4; ++r) {
        int row = bm * 128 + wm + (mi << 4) + cr0 + r;
        if (row < cnt) {
          int col = bn * 64 + wn + (ni << 4) + lr;
          int tok = list[e * SEQ + row];
          float w = W[tok * 8 + e];
          float gval = accg[mi][ni][r];
          float uval = accu[mi][ni][r];
          float a = gval / (1.f + __expf(-gval)) * uval * w;
          A2[(size_t)(base + row) * IDIM + col] = (__bf16)a;
        }
      }
}

__global__ __launch_bounds__(256) void gemm_moe_down2_kernel(
    const __bf16* __restrict__ A2, const __bf16* __restrict__ MDH,
    float* __restrict__ Y2,
    const int* __restrict__ cnt8, const int* __restrict__ off8)
{
  const int e = blockIdx.z;
  const int cnt = cnt8[e];
  const int bn = blockIdx.x, bm = blockIdx.y;
  if (bm * 128 >= cnt) return;
  const int base = off8[e];
  constexpr int SBUF = 12288;   // AsB 8192 | BsB 4096
  __shared__ __align__(16) char smem[2 * SBUF];
  const int tid = threadIdx.x;
  const int wid = tid >> 6, lane = tid & 63;
  const int wm = (wid >> 1) << 6, wn = (wid & 1) << 5;
  const int lr = lane & 15, kh = lane >> 4;
  const int lrow = lane >> 2;
  const int lcol = (lane & 3) << 3;

  auto stage = [&](char* buf, int k0) {
    char* AsB = buf;
    char* BsB = buf + 8192;
#pragma unroll
    for (int c = wid; c < 8; c += 4) {
      int rg = bm * 128 + c * 16 + lrow;
      int row = (rg < cnt ? rg : cnt - 1);
      gld_lds16(A2 + (size_t)(base + row) * IDIM + k0 + lcol, AsB + c * 1024);
    }
    {
      int c = wid;
      gld_lds16(MDH + (size_t)(e * HID + bn * 64 + c * 16 + lrow) * IDIM + k0 + lcol,
                BsB + c * 1024);
    }
  };

  f32x4v acc[4][2];
  const f32x4v z4 = {0.f, 0.f, 0.f, 0.f};
#pragma unroll
  for (int i = 0; i < 4; ++i)
#pragma unroll
    for (int j = 0; j < 2; ++j) acc[i][j] = z4;

  stage(smem, 0);
  int cur = 0;
  for (int k0 = 0; k0 < IDIM; k0 += 32) {
    __syncthreads();
    char* buf = smem + cur * SBUF;
    if (k0 + 32 < IDIM) stage(smem + (cur ^ 1) * SBUF, k0 + 32);
    char* AsB = buf;
    char* BsB = buf + 8192;

    bf16x8v af[4], bfv[2];
#pragma unroll
    for (int i = 0; i < 4; ++i) {
      int r = wm + (i << 4) + lr;
      af[i] = *(const bf16x8v*)(AsB + r * 64 + (kh << 4));
    }
#pragma unroll
    for (int i = 0; i < 2; ++i) {
      int r = wn + (i << 4) + lr;
      bfv[i] = *(const bf16x8v*)(BsB + r * 64 + (kh << 4));
    }
#pragma unroll
    for (int mi = 0; mi < 4; ++mi)
#pragma unroll
      for (int ni = 0; ni < 2; ++ni)
        acc[mi][ni] = MFMA(af[mi], bfv[ni], acc[mi][ni]);
    cur ^= 1;
  }

  const int cr0 = kh << 2;
#pragma unroll
  for (int mi = 0; mi < 4; ++mi)
#pragma unroll
    for (int ni = 0; ni < 2; ++ni)
#pragma unroll
      for (int r = 0; r < 4; ++r) {
        int row = bm * 128 + wm + (mi << 4) + cr0 + r;
        if (row < cnt) {
          int col = bn * 64 + wn + (ni << 4) + lr;
          Y2[(size_t)(base + row) * HID + col] = acc[mi][ni][r];
        }
      }
}

// h[t] += y(e_lo) + y(e_hi)  (ascending-e order == old serial order)
__global__ __launch_bounds__(256) void moe_scatter_kernel(
    const int* __restrict__ tokpair, const int* __restrict__ off8,
    const float* __restrict__ Y2, float* __restrict__ H)
{
  const int t = blockIdx.x;
  const int i = threadIdx.x;
  int p0 = tokpair[t * 2], p1 = tokpair[t * 2 + 1];
  size_t r0 = off8[p0 >> 16] + (p0 & 0xffff);
  size_t r1 = off8[p1 >> 16] + (p1 & 0xffff);
  float4 a = ((const float4*)(Y2 + r0 * HID))[i];
  float4 b = ((const float4*)(Y2 + r1 * HID))[i];
  float4 hv = ((float4*)(H + (size_t)t * HID))[i];
  hv.x = (hv.x + a.x) + b.x;
  hv.y = (hv.y + a.y) + b.y;
  hv.z = (hv.z + a.z) + b.z;
  hv.w = (hv.w + a.w) + b.w;
  ((float4*)(H + (size_t)t * HID))[i] = hv;
}

// ---------------------------------------------------------------------------
// Small kernels
// ---------------------------------------------------------------------------
__global__ void tables_kernel(float* __restrict__ CT, float* __restrict__ ST)
{
  int idx = blockIdx.x * 256 + threadIdx.x;
  int s = idx >> 5, i = idx & 31;
  double inv = exp(-log(10000.0) * (double)i / 32.0);
  double ang = (double)s * inv;
  CT[idx] = (float)cos(ang);
  ST[idx] = (float)sin(ang);
}

__global__ __launch_bounds__(256) void embed_kernel(
    const int* __restrict__ ids, const float* __restrict__ E, float* __restrict__ H)
{
  int t = blockIdx.x;
  int id = ids[t];
  ((float4*)(H + (size_t)t * HID))[threadIdx.x] =
      ((const float4*)(E + (size_t)id * HID))[threadIdx.x];
}

// WF32: write the f32 output (needed only before router); hi/lo always written
template<bool WF32>
__global__ __launch_bounds__(256) void rmsnorm_kernel(
    const float* __restrict__ X, const float* __restrict__ W,
    float* __restrict__ O, __bf16* __restrict__ OHb, __bf16* __restrict__ OLb)
{
  int t = blockIdx.x;
  int tid = threadIdx.x;
  float4 v = ((const float4*)(X + (size_t)t * HID))[tid];
  float ss = v.x * v.x + v.y * v.y + v.z * v.z + v.w * v.w;
#pragma unroll
  for (int d = 1; d < 64; d <<= 1) ss += __shfl_xor(ss, d);
  __shared__ float red[4];
  if ((tid & 63) == 0) red[tid >> 6] = ss;
  __syncthreads();
  float tot = red[0] + red[1] + red[2] + red[3];
  float inv = 1.0f / sqrtf(tot * (1.0f / 1024.0f) + 1e-6f);
  float4 w = ((const float4*)W)[tid];
  float4 r;
  r.x = v.x * inv * w.x; r.y = v.y * inv * w.y;
  r.z = v.z * inv * w.z; r.w = v.w * inv * w.w;
  if (WF32) ((float4*)(O + (size_t)t * HID))[tid] = r;
  float f[4] = {r.x, r.y, r.z, r.w};
  bf16x4v hv, lv;
#pragma unroll
  for (int j = 0; j < 4; ++j) {
    __bf16 hb = (__bf16)f[j];
    hv[j] = hb; lv[j] = (__bf16)(f[j] - (float)hb);
  }
  *(bf16x4v*)(OHb + (size_t)t * HID + tid * 4) = hv;
  *(bf16x4v*)(OLb + (size_t)t * HID + tid * 4) = lv;
}

__global__ __launch_bounds__(256) void router_kernel(
    const float* __restrict__ X, const float* __restrict__ RW, float* __restrict__ RL)
{
  int wid = threadIdx.x >> 6, lane = threadIdx.x & 63;
  int t = blockIdx.x * 4 + wid;
  const float* x = X + (size_t)t * HID;
  float a0 = 0, a1 = 0, a2 = 0, a3 = 0, a4 = 0, a5 = 0, a6 = 0, a7 = 0;
  for (int hh = lane; hh < HID; hh += 64) {
    float xv = x[hh];
    float4 f0 = *(const float4*)(RW + hh * 8);
    float4 f1 = *(const float4*)(RW + hh * 8 + 4);
    a0 += xv * f0.x; a1 += xv * f0.y; a2 += xv * f0.z; a3 += xv * f0.w;
    a4 += xv * f1.x; a5 += xv * f1.y; a6 += xv * f1.z; a7 += xv * f1.w;
  }
#pragma unroll
  for (int d = 1; d < 64; d <<= 1) {
    a0 += __shfl_xor(a0, d); a1 += __shfl_xor(a1, d);
    a2 += __shfl_xor(a2, d); a3 += __shfl_xor(a3, d);
    a4 += __shfl_xor(a4, d); a5 += __shfl_xor(a5, d);
    a6 += __shfl_xor(a6, d); a7 += __shfl_xor(a7, d);
  }
  if (lane == 0) {
    float* dst = RL + (size_t)t * 8;
    dst[0] = a0; dst[1] = a1; dst[2] = a2; dst[3] = a3;
    dst[4] = a4; dst[5] = a5; dst[6] = a6; dst[7] = a7;
  }
}

__global__ void zero_kernel(float* __restrict__ p, int n)
{
  int i = threadIdx.x;
  if (i < n) p[i] = 0.f;
}

__global__ void zeroi_kernel(int* __restrict__ p, int n)
{
  int i = threadIdx.x;
  if (i < n) p[i] = 0;
}

__global__ __launch_bounds__(256) void topk_kernel(
    const float* __restrict__ RL, float* __restrict__ W, float* __restrict__ AUX)
{
  int t = blockIdx.x * 256 + threadIdx.x;
  int lane = threadIdx.x & 63;
  float r[8];
#pragma unroll
  for (int e = 0; e < 8; ++e) r[e] = RL[t * 8 + e];
  float mx = r[0];
#pragma unroll
  for (int e = 1; e < 8; ++e) mx = fmaxf(mx, r[e]);
  float p[8];
  float se = 0.f;
#pragma unroll
  for (int e = 0; e < 8; ++e) { p[e] = __expf(r[e] - mx); se += p[e]; }
  float inv = 1.f / se;
#pragma unroll
  for (int e = 0; e < 8; ++e) p[e] *= inv;
  float lse = logf(se) + mx;
  int i1 = 0; float v1 = p[0];
#pragma unroll
  for (int e = 1; e < 8; ++e) if (p[e] > v1) { v1 = p[e]; i1 = e; }
  int i2 = -1; float v2 = -1.f;
#pragma unroll
  for (int e = 0; e < 8; ++e) if (e != i1 && p[e] > v2) { v2 = p[e]; i2 = e; }
  float s12 = v1 + v2;
#pragma unroll
  for (int e = 0; e < 8; ++e)
    W[t * 8 + e] = (e == i1) ? v1 / s12 : ((e == i2) ? v2 / s12 : 0.f);
#pragma unroll
  for (int e = 0; e < 8; ++e) {
    float fe = ((i1 == e) ? 1.f : 0.f) + ((i2 == e) ? 1.f : 0.f);
    float pe = p[e];
#pragma unroll
    for (int d = 1; d < 64; d <<= 1) { fe += __shfl_xor(fe, d); pe += __shfl_xor(pe, d); }
    if (lane == 0) { atomicAdd(&AUX[e], fe); atomicAdd(&AUX[8 + e], pe); }
  }
  float zz = lse * lse;
#pragma unroll
  for (int d = 1; d < 64; d <<= 1) zz += __shfl_xor(zz, d);
  if (lane == 0) atomicAdd(&AUX[16], zz);
}

__global__ void aux_kernel(const float* __restrict__ AUX, float* __restrict__ OUT)
{
  float s = 0.f;
#pragma unroll
  for (int e = 0; e < 8; ++e)
    s += (AUX[e] * (1.f / 2048.f)) * (AUX[8 + e] * (1.f / 2048.f));
  float auxv = 0.01f * 8.f * s;
  float z = 0.001f * (AUX[16] * (1.f / 2048.f));
  OUT[(size_t)SEQ * VOCAB] = auxv + z;
}

// records per-token (expert, pos) pairs in ascending-e order
__global__ __launch_bounds__(256) void build_list_kernel(
    const float* __restrict__ W, int* __restrict__ cnt, int* __restrict__ list,
    int* __restrict__ tokpair)
{
  int t = blockIdx.x * 256 + threadIdx.x;
  int j = 0;
#pragma unroll
  for (int e = 0; e < 8; ++e) {
    if (W[t * 8 + e] > 0.f) {
      int p = atomicAdd(&cnt[e], 1);
      list[e * SEQ + p] = t;
      tokpair[t * 2 + j] = (e << 16) | p;
      ++j;
    }
  }
}

__global__ void prefix_kernel(const int* __restrict__ cnt, int* __restrict__ off)
{
  if (threadIdx.x == 0) {
    int s = 0;
    for (int e = 0; e < 8; ++e) { off[e] = s; s += cnt[e]; }
  }
}

// ---------------------------------------------------------------------------
extern "C" void kernel_launch(void* const* d_in, const int* in_sizes, int n_in,
                              void* d_out, int out_size, void* d_ws, size_t ws_size,
                              hipStream_t stream)
{
  const int*   ids   = (const int*)d_in[0];
  const float* embed = (const float*)d_in[1];
  const float* ln1   = (const float*)d_in[2];
  const float* ln2   = (const float*)d_in[3];
  const float* wq    = (const float*)d_in[4];
  const float* wk    = (const float*)d_in[5];
  const float* wv    = (const float*)d_in[6];
  const float* wo    = (const float*)d_in[7];
  const float* dg    = (const float*)d_in[8];
  const float* du    = (const float*)d_in[9];
  const float* dd    = (const float*)d_in[10];
  const float* rw    = (const float*)d_in[11];
  const float* mg    = (const float*)d_in[12];
  const float* mu    = (const float*)d_in[13];
  const float* md    = (const float*)d_in[14];
  const float* fin   = (const float*)d_in[15];
  float* out = (float*)d_out;

  char* ws = (char*)d_ws;
  float* h    = (float*)(ws + 0);
  float* hn   = (float*)(ws + 8388608);
  float* q    = (float*)(ws + 16777216);
  float* k    = (float*)(ws + 25165824);
  float* v    = (float*)(ws + 33554432);
  __bf16* oh  = (__bf16*)(ws + 41943040);
  __bf16* ol  = (__bf16*)(ws + 46137344);
  float* g    = (float*)(ws + 50331648);
  float* u    = (float*)(ws + 73400320);
  float* ct   = (float*)(ws + 96468992);
  float* st   = (float*)(ws + 96731136);
  float* rl   = (float*)(ws + 96993280);
  float* wmoe = (float*)(ws + 97058816);
  float* aux  = (float*)(ws + 97124352);
  int*   cnt  = (int*)  (ws + 97124608);
  int*   list = (int*)  (ws + 97124864);
  int*   tokp = (int*)  (ws + 97190400);
  int*   off8 = (int*)  (ws + 97206784);
  __bf16* wqh = (__bf16*)(ws + 97320960);
  __bf16* wql = (__bf16*)(ws + 105709568);
  __bf16* wkh = (__bf16*)(ws + 114098176);
  __bf16* wkl = (__bf16*)(ws + 122486784);
  __bf16* wvh = (__bf16*)(ws + 130875392);
  __bf16* wvl = (__bf16*)(ws + 139264000);
  __bf16* woh = (__bf16*)(ws + 147652608);
  __bf16* wol = (__bf16*)(ws + 156041216);
  __bf16* dgh = (__bf16*)(ws + 164429824);
  __bf16* dgl = (__bf16*)(ws + 181731328);
  __bf16* duh = (__bf16*)(ws + 199032832);
  __bf16* dul = (__bf16*)(ws + 216334336);
  __bf16* ddh = (__bf16*)(ws + 233635840);
  __bf16* ddl = (__bf16*)(ws + 250937344);
  __bf16* eh  = (__bf16*)(ws + 268238848);
  __bf16* hnh = (__bf16*)(ws + 333774848);
  __bf16* hnl = (__bf16*)(ws + 337969152);
  __bf16* gh  = (__bf16*)(ws + 342163456);
  __bf16* gl  = (__bf16*)(ws + 353697792);
  __bf16* mgh = (__bf16*)(ws + 365232128);
  __bf16* muh = (__bf16*)(ws + 411369472);
  __bf16* mdh = (__bf16*)(ws + 457506816);
  // end: 503,644,160 bytes
  __bf16* qh  = (__bf16*)g;
  __bf16* ql  = (__bf16*)((char*)g + 4194304);
  __bf16* kbh = (__bf16*)((char*)g + 8388608);
  __bf16* kbl = (__bf16*)((char*)g + 12582912);
  __bf16* vth = (__bf16*)u;
  __bf16* vtl = (__bf16*)((char*)u + 4194304);
  __bf16* a2  = (__bf16*)g;
  float*  y2  = u;

  // merged QKVO wsplit (z = weight*4 + layer)
  wsplit_qkvo_kernel<<<dim3(16, 16, 16), 256, 0, stream>>>(wq, wk, wv, wo, wqh);
  wsplit_t_kernel<<<dim3(44, 16, 3), 256, 0, stream>>>(dg, dgh, dgl, HID, IDIM);
  wsplit_t_kernel<<<dim3(44, 16, 3), 256, 0, stream>>>(du, duh, dul, HID, IDIM);
  wsplit_t_kernel<<<dim3(16, 44, 3), 256, 0, stream>>>(dd, ddh, ddl, IDIM, HID);
  wsplit_th_kernel<<<dim3(44, 16, 8), 256, 0, stream>>>(mg, mgh, HID, IDIM);
  wsplit_th_kernel<<<dim3(44, 16, 8), 256, 0, stream>>>(mu, muh, HID, IDIM);
  wsplit_th_kernel<<<dim3(16, 44, 8), 256, 0, stream>>>(md, mdh, IDIM, HID);
  esplit_kernel<<<16000, 256, 0, stream>>>(embed, eh);

  tables_kernel<<<256, 256, 0, stream>>>(ct, st);
  embed_kernel<<<SEQ, 256, 0, stream>>>(ids, embed, h);

  for (int li = 0; li < 4; ++li) {
    const bool comp = (li <= 2);
    rmsnorm_kernel<false><<<SEQ, 256, 0, stream>>>(h, ln1 + li * HID, hn, hnh, hnl);
    size_t wofs = (size_t)li * HID * HID;
    // QKV GEMM: fused rope+split (q,k) and fused V-transpose hi/lo (z=2)
    if (comp)
      gemm_qkv_kernel<true><<<dim3(8, 32, 3), 256, 0, stream>>>(
          hnh, hnl, wqh + wofs, wql + wofs, wkh + wofs, wkl + wofs,
          wvh + wofs, wvl + wofs, qh, ql, kbh, kbl, vth, vtl, ct, st);
    else
      gemm_qkv_kernel<false><<<dim3(8, 32, 3), 256, 0, stream>>>(
          hnh, hnh, wqh + wofs, wqh + wofs, wkh + wofs, wkh + wofs,
          wvh + wofs, wvh + wofs, qh, ql, kbh, kbl, vth, vtl, ct, st);

    attn_flash_kernel<<<dim3(16, 16), 256, 0, stream>>>(
        qh, ql, kbh, kbl, vth, vtl, oh, ol);

    // wo GEMM: BN=64 -> 512 blocks (2/CU)
    if (comp)
      gemm_bt_kernel<true, true, 64, 64, false><<<dim3(16, 32, 1), 256, 0, stream>>>(
          oh, ol, woh + wofs, wol + wofs, woh + wofs, wol + wofs,
          woh + wofs, wol + wofs, h, h, h, SEQ, HID, HID);
    else
      gemm_bt_kernel<false, true, 64, 64, false><<<dim3(16, 32, 1), 256, 0, stream>>>(
          oh, oh, woh + wofs, woh + wofs, woh + wofs, woh + wofs,
          woh + wofs, woh + wofs, h, h, h, SEQ, HID, HID);

    if (li == 2) {
      rmsnorm_kernel<true><<<SEQ, 256, 0, stream>>>(h, ln2 + li * HID, hn, hnh, hnl);
      router_kernel<<<512, 256, 0, stream>>>(hn, rw, rl);
      zero_kernel<<<1, 32, 0, stream>>>(aux, 17);
      topk_kernel<<<8, 256, 0, stream>>>(rl, wmoe, aux);
      aux_kernel<<<1, 1, 0, stream>>>(aux, out);
      zeroi_kernel<<<1, 32, 0, stream>>>(cnt, 8);
      build_list_kernel<<<8, 256, 0, stream>>>(wmoe, cnt, list, tokp);
      prefix_kernel<<<1, 64, 0, stream>>>(cnt, off8);
      gemm_moe_guf_kernel<<<dim3(44, 16, 8), 256, 0, stream>>>(
          hnh, mgh, muh, a2, wmoe, list, cnt, off8);
      gemm_moe_down2_kernel<<<dim3(16, 16, 8), 256, 0, stream>>>(
          a2, mdh, y2, cnt, off8);
      moe_scatter_kernel<<<SEQ, 256, 0, stream>>>(tokp, off8, y2, h);
    } else {
      rmsnorm_kernel<false><<<SEQ, 256, 0, stream>>>(h, ln2 + li * HID, hn, hnh, hnl);
      int d = (li < 2) ? li : li - 1;
      size_t go = (size_t)d * HID * IDIM;
      // dense gate+up GEMM with fused silu + hi/lo split epilogue
      if (comp)
        gemm_dgu_kernel<true><<<dim3(44, 32), 256, 0, stream>>>(
            hnh, hnl, dgh + go, dgl + go, duh + go, dul + go, gh, gl);
      else
        gemm_dgu_kernel<false><<<dim3(44, 32), 256, 0, stream>>>(
            hnh, hnh, dgh + go, dgh + go, duh + go, duh + go, gh, gl);
      // down GEMM: BN=64 -> 512 blocks
      if (comp)
        gemm_bt_kernel<true, true, 64, 64, false><<<dim3(16, 32, 1), 256, 0, stream>>>(
            gh, gl, ddh + go, ddl + go, ddh + go, ddl + go,
            ddh + go, ddl + go, h, h, h, SEQ, HID, IDIM);
      else
        gemm_bt_kernel<false, true, 64, 64, false><<<dim3(16, 32, 1), 256, 0, stream>>>(
            gh, gh, ddh + go, ddh + go, ddh + go, ddh + go,
            ddh + go, ddh + go, h, h, h, SEQ, HID, IDIM);
    }
  }
  rmsnorm_kernel<false><<<SEQ, 256, 0, stream>>>(h, fin, hn, hnh, hnl);
  // logits: BM=128 + XCD-aware bijective swizzle (4096-block 1D grid)
  gemm_bt_kernel<false, false, 128, 128, true><<<dim3(4096, 1, 1), 256, 0, stream>>>(
      hnh, hnh, eh, eh, eh, eh, eh, eh, out, out, out, SEQ, VOCAB, HID);
}